// Round 9
// baseline (402.265 us; speedup 1.0000x reference)
//
#include <hip/hip_runtime.h>

#define NN 50000
#define NE 800000
#define NP 2048            // strided edge-work blocks for bucketed count/place
#define TB 782             // ceil(NN/64) gemm row-tile blocks
#define GBS 12504          // 8 * 1563 swizzled gather blocks (4 nodes each)
#define BCAP 103424        // per-bucket capacity (avg 100000, >11 sigma slack)
#define BBK 391            // bucket blocks = ceil(NE/2048)
#define CHKE 2048          // edges per bucket block

typedef __attribute__((ext_vector_type(8))) short bhalf8;
typedef __attribute__((ext_vector_type(4))) float floatx4;

// weight buffer offsets (ushort units); l plane = h + 64*K
#define WOFF_U1U 0
#define WOFF_U1D 24576
#define WOFF_W1U 49152
#define WOFF_W1D 65536
#define WOFF_W2U 81920
#define WOFF_U2U 98304
#define WOFF_WSUM 122880
#define WOFF_USUM 131072
#define WBUF_USHORTS 147456

// ---------------------------------------------------------------------------
// bf16 split helpers (RNE)
// ---------------------------------------------------------------------------
__device__ __forceinline__ unsigned short bf16hi(float v) {
  union { float f; unsigned u; } c; c.f = v;
  return (unsigned short)((c.u + 0x7FFFu + ((c.u >> 16) & 1u)) >> 16);
}
__device__ __forceinline__ float bf16tof(unsigned short h) {
  union { unsigned u; float f; } c; c.u = ((unsigned)h) << 16;
  return c.f;
}
__device__ __forceinline__ void split1(float v, unsigned short& h,
                                       unsigned short& l) {
  h = bf16hi(v);
  l = bf16hi(v - bf16tof(h));
}
__device__ __forceinline__ void split4(const float4 v, ushort4& h, ushort4& l) {
  split1(v.x, h.x, l.x);
  split1(v.y, h.y, l.y);
  split1(v.z, h.z, l.z);
  split1(v.w, h.w, l.w);
}
__device__ __forceinline__ void split8(const float4 v0, const float4 v1,
                                       uint4& H, uint4& L) {
  unsigned short h0, l0, h1, l1;
  split1(v0.x, h0, l0); split1(v0.y, h1, l1);
  H.x = (unsigned)h0 | ((unsigned)h1 << 16);
  L.x = (unsigned)l0 | ((unsigned)l1 << 16);
  split1(v0.z, h0, l0); split1(v0.w, h1, l1);
  H.y = (unsigned)h0 | ((unsigned)h1 << 16);
  L.y = (unsigned)l0 | ((unsigned)l1 << 16);
  split1(v1.x, h0, l0); split1(v1.y, h1, l1);
  H.z = (unsigned)h0 | ((unsigned)h1 << 16);
  L.z = (unsigned)l0 | ((unsigned)l1 << 16);
  split1(v1.z, h0, l0); split1(v1.w, h1, l1);
  H.w = (unsigned)h0 | ((unsigned)h1 << 16);
  L.w = (unsigned)l0 | ((unsigned)l1 << 16);
}

// swizzled LDS byte address for bf16 tile [64 rows][64 k] (128B rows)
#define SWZ(row, inrow) (((row) << 7) + ((inrow) ^ (((row)&7) << 4)))

// ---------------------------------------------------------------------------
// MFMA split-bf16 GEMM (single B): out = relu([A|G] @ B^T (+bias))
// ---------------------------------------------------------------------------
template <bool AF32>
__device__ __forceinline__ void mfma_gemm_dev(
    unsigned short* tAh, unsigned short* tAl,
    unsigned short* tBh, unsigned short* tBl,
    const unsigned short* __restrict__ Ah, const unsigned short* __restrict__ Al,
    int lda,
    const unsigned short* __restrict__ Gh, const unsigned short* __restrict__ Gl,
    const unsigned short* __restrict__ Bh, const unsigned short* __restrict__ Bl,
    int ldb, const float* __restrict__ bias,
    float* __restrict__ outF, unsigned short* __restrict__ outH,
    unsigned short* __restrict__ outL,
    int ldo, int colbase, int dup, int kchunks, int xchunks,
    int row0, int tid) {
  const int lane = tid & 63;
  const int wm = tid >> 6;
  const int m = lane & 15;
  const int kg = lane >> 4;
  floatx4 acc[4];
#pragma unroll
  for (int i = 0; i < 4; ++i) acc[i] = (floatx4){0.f, 0.f, 0.f, 0.f};

  for (int c = 0; c < kchunks; ++c) {
#pragma unroll
    for (int q = tid; q < 512; q += 256) {
      const int row = q >> 3, slot = q & 7;
      int gr = row0 + row;
      gr = (gr > NN - 1) ? NN - 1 : gr;
      const int ad = SWZ(row, slot << 4);
      if (AF32 && c < xchunks) {
        const float* f = (const float*)Ah;
        const size_t go = (size_t)gr * lda + (c << 6) + slot * 8;
        const float4 v0 = *(const float4*)(f + go);
        const float4 v1 = *(const float4*)(f + go + 4);
        uint4 H, L;
        split8(v0, v1, H, L);
        *(uint4*)((char*)tAh + ad) = H;
        *(uint4*)((char*)tAl + ad) = L;
      } else {
        const unsigned short* sh;
        const unsigned short* sl;
        int ld, kc;
        if (c < xchunks) { sh = Ah; sl = Al; ld = lda; kc = c << 6; }
        else             { sh = Gh; sl = Gl; ld = 64;  kc = 0; }
        const size_t go = (size_t)gr * ld + kc + slot * 8;
        *(uint4*)((char*)tAh + ad) = *(const uint4*)(sh + go);
        *(uint4*)((char*)tAl + ad) = *(const uint4*)(sl + go);
      }
      const size_t gob = (size_t)row * ldb + (c << 6) + slot * 8;
      *(uint4*)((char*)tBh + ad) = *(const uint4*)(Bh + gob);
      *(uint4*)((char*)tBl + ad) = *(const uint4*)(Bl + gob);
    }
    __syncthreads();
#pragma unroll
    for (int ks = 0; ks < 2; ++ks) {
      const int inrow = (ks << 6) + (kg << 4);
      const int rA = (wm << 4) + m;
      const bhalf8 ah = *(const bhalf8*)((const char*)tAh + SWZ(rA, inrow));
      const bhalf8 al = *(const bhalf8*)((const char*)tAl + SWZ(rA, inrow));
#pragma unroll
      for (int nt = 0; nt < 4; ++nt) {
        const int rB = (nt << 4) + m;
        const bhalf8 bh = *(const bhalf8*)((const char*)tBh + SWZ(rB, inrow));
        const bhalf8 bl = *(const bhalf8*)((const char*)tBl + SWZ(rB, inrow));
        acc[nt] = __builtin_amdgcn_mfma_f32_16x16x32_bf16(ah, bh, acc[nt], 0, 0, 0);
        acc[nt] = __builtin_amdgcn_mfma_f32_16x16x32_bf16(ah, bl, acc[nt], 0, 0, 0);
        acc[nt] = __builtin_amdgcn_mfma_f32_16x16x32_bf16(al, bh, acc[nt], 0, 0, 0);
      }
    }
    __syncthreads();
  }
#pragma unroll
  for (int nt = 0; nt < 4; ++nt) {
    const int col = colbase + (nt << 4) + m;
    const float bv = bias ? bias[(nt << 4) + m] : 0.f;
#pragma unroll
    for (int r = 0; r < 4; ++r) {
      const int row = row0 + (wm << 4) + (kg << 2) + r;
      if (row < NN) {
        const float v = fmaxf(acc[nt][r] + bv, 0.f);
        if (outF) {
          outF[(size_t)row * ldo + col] = v;
          if (dup) outF[(size_t)row * ldo + col + 64] = v;
        }
        if (outH) {
          unsigned short h, l;
          split1(v, h, l);
          outH[(size_t)row * ldo + col] = h;
          outL[(size_t)row * ldo + col] = l;
        }
      }
    }
  }
}

// ---------------------------------------------------------------------------
// Dual-output transform, 4-tile (32KB): stage x chunk once, run W_u1 B-tiles,
// resync, restage W_d1 into the SAME B-tiles.
// ---------------------------------------------------------------------------
__device__ __forceinline__ void trans2_dev(
    unsigned short* tAh, unsigned short* tAl,
    unsigned short* tBh, unsigned short* tBl,
    const float* __restrict__ x,
    const unsigned short* __restrict__ Wuh, const unsigned short* __restrict__ Wul,
    const unsigned short* __restrict__ Wdh, const unsigned short* __restrict__ Wdl,
    const float* __restrict__ bu, const float* __restrict__ bd,
    float* __restrict__ Yu, float* __restrict__ Yd, int row0, int tid) {
  const int lane = tid & 63;
  const int wm = tid >> 6;
  const int m = lane & 15;
  const int kg = lane >> 4;
  floatx4 accU[4], accD[4];
#pragma unroll
  for (int i = 0; i < 4; ++i) {
    accU[i] = (floatx4){0.f, 0.f, 0.f, 0.f};
    accD[i] = (floatx4){0.f, 0.f, 0.f, 0.f};
  }
  for (int c = 0; c < 2; ++c) {
#pragma unroll
    for (int q = tid; q < 512; q += 256) {
      const int row = q >> 3, slot = q & 7;
      int gr = row0 + row;
      gr = (gr > NN - 1) ? NN - 1 : gr;
      const int ad = SWZ(row, slot << 4);
      const size_t go = (size_t)gr * 128 + (c << 6) + slot * 8;
      const float4 v0 = *(const float4*)(x + go);
      const float4 v1 = *(const float4*)(x + go + 4);
      uint4 H, L;
      split8(v0, v1, H, L);
      *(uint4*)((char*)tAh + ad) = H;
      *(uint4*)((char*)tAl + ad) = L;
      const size_t gob = (size_t)row * 128 + (c << 6) + slot * 8;
      *(uint4*)((char*)tBh + ad) = *(const uint4*)(Wuh + gob);
      *(uint4*)((char*)tBl + ad) = *(const uint4*)(Wul + gob);
    }
    __syncthreads();
#pragma unroll
    for (int ks = 0; ks < 2; ++ks) {
      const int inrow = (ks << 6) + (kg << 4);
      const int rA = (wm << 4) + m;
      const bhalf8 ah = *(const bhalf8*)((const char*)tAh + SWZ(rA, inrow));
      const bhalf8 al = *(const bhalf8*)((const char*)tAl + SWZ(rA, inrow));
#pragma unroll
      for (int nt = 0; nt < 4; ++nt) {
        const int rB = (nt << 4) + m;
        const int adB = SWZ(rB, inrow);
        const bhalf8 bh = *(const bhalf8*)((const char*)tBh + adB);
        const bhalf8 bl = *(const bhalf8*)((const char*)tBl + adB);
        accU[nt] = __builtin_amdgcn_mfma_f32_16x16x32_bf16(ah, bh, accU[nt], 0, 0, 0);
        accU[nt] = __builtin_amdgcn_mfma_f32_16x16x32_bf16(ah, bl, accU[nt], 0, 0, 0);
        accU[nt] = __builtin_amdgcn_mfma_f32_16x16x32_bf16(al, bh, accU[nt], 0, 0, 0);
      }
    }
    __syncthreads();
#pragma unroll
    for (int q = tid; q < 512; q += 256) {
      const int row = q >> 3, slot = q & 7;
      const int ad = SWZ(row, slot << 4);
      const size_t gob = (size_t)row * 128 + (c << 6) + slot * 8;
      *(uint4*)((char*)tBh + ad) = *(const uint4*)(Wdh + gob);
      *(uint4*)((char*)tBl + ad) = *(const uint4*)(Wdl + gob);
    }
    __syncthreads();
#pragma unroll
    for (int ks = 0; ks < 2; ++ks) {
      const int inrow = (ks << 6) + (kg << 4);
      const int rA = (wm << 4) + m;
      const bhalf8 ah = *(const bhalf8*)((const char*)tAh + SWZ(rA, inrow));
      const bhalf8 al = *(const bhalf8*)((const char*)tAl + SWZ(rA, inrow));
#pragma unroll
      for (int nt = 0; nt < 4; ++nt) {
        const int rB = (nt << 4) + m;
        const int adB = SWZ(rB, inrow);
        const bhalf8 bh = *(const bhalf8*)((const char*)tBh + adB);
        const bhalf8 bl = *(const bhalf8*)((const char*)tBl + adB);
        accD[nt] = __builtin_amdgcn_mfma_f32_16x16x32_bf16(ah, bh, accD[nt], 0, 0, 0);
        accD[nt] = __builtin_amdgcn_mfma_f32_16x16x32_bf16(ah, bl, accD[nt], 0, 0, 0);
        accD[nt] = __builtin_amdgcn_mfma_f32_16x16x32_bf16(al, bh, accD[nt], 0, 0, 0);
      }
    }
    __syncthreads();
  }
#pragma unroll
  for (int nt = 0; nt < 4; ++nt) {
    const int col = (nt << 4) + m;
    const float bvu = bu[col];
    const float bvd = bd[col];
#pragma unroll
    for (int r = 0; r < 4; ++r) {
      const int row = row0 + (wm << 4) + (kg << 2) + r;
      if (row < NN) {
        Yu[(size_t)row * 64 + col] = fmaxf(accU[nt][r] + bvu, 0.f);
        Yd[(size_t)row * 64 + col] = fmaxf(accD[nt][r] + bvd, 0.f);
      }
    }
  }
}

__global__ __launch_bounds__(256) void mgemm_kernel(
    const unsigned short* Ah, const unsigned short* Al, int lda,
    const unsigned short* Gh, const unsigned short* Gl,
    const unsigned short* Bh, const unsigned short* Bl, int ldb,
    const float* bias, float* outF, unsigned short* outH, unsigned short* outL,
    int ldo, int colbase, int dup, int kchunks, int xchunks) {
  __shared__ unsigned short tiles[4][4096];
  mfma_gemm_dev<false>(tiles[0], tiles[1], tiles[2], tiles[3], Ah, Al, lda,
                       Gh, Gl, Bh, Bl, ldb, bias, outF, outH, outL, ldo,
                       colbase, dup, kchunks, xchunks, blockIdx.x * 64,
                       threadIdx.x);
}

// both layer-1 updates in one launch; A = f32 x (inline split)
__global__ __launch_bounds__(256) void update2m_kernel(
    const float* __restrict__ x,
    const unsigned short* auh, const unsigned short* aul,
    const unsigned short* adh, const unsigned short* adl,
    const unsigned short* U1uh, const unsigned short* U1ul,
    const unsigned short* U1dh, const unsigned short* U1dl,
    unsigned short* outH, unsigned short* outL) {
  __shared__ unsigned short tiles[4][4096];
  if (blockIdx.x < TB)
    mfma_gemm_dev<true>(tiles[0], tiles[1], tiles[2], tiles[3],
                        (const unsigned short*)x, nullptr, 128, auh, aul,
                        U1uh, U1ul, 192, nullptr, nullptr, outH, outL, 128,
                        0, 0, 3, 2, blockIdx.x * 64, threadIdx.x);
  else
    mfma_gemm_dev<true>(tiles[0], tiles[1], tiles[2], tiles[3],
                        (const unsigned short*)x, nullptr, 128, adh, adl,
                        U1dh, U1dl, 192, nullptr, nullptr, outH, outL, 128,
                        64, 0, 3, 2, (blockIdx.x - TB) * 64, threadIdx.x);
}

// ---------------------------------------------------------------------------
// prep: bucket counting-sort (blocks [0,BBK)) || weight conversion (32 blocks)
// Buckets: bin = node/6250 per direction; packed (s | d<<16) entries.
// ---------------------------------------------------------------------------
__global__ __launch_bounds__(256) void prep_kernel(
    const int* __restrict__ src, const int* __restrict__ dst,
    int* __restrict__ gcur,
    unsigned* __restrict__ bdst, unsigned* __restrict__ bsrc,
    const float* __restrict__ U_u1, const float* __restrict__ U_d1,
    const float* __restrict__ W_u1, const float* __restrict__ W_d1,
    const float* __restrict__ W_u2, const float* __restrict__ U_u2,
    unsigned short* __restrict__ wbuf) {
  int bi = blockIdx.x;
  const int t = threadIdx.x;
  if (bi < BBK) {
    __shared__ int hist[16];
    __shared__ int base[16];
    __shared__ int cur[16];
    const int chunk = bi * CHKE;
    if (t < 16) { hist[t] = 0; cur[t] = 0; }
    __syncthreads();
    unsigned ev[8];
    int bd[8], bs[8];
    bool ok[8];
#pragma unroll
    for (int i = 0; i < 8; ++i) {
      const int e = chunk + i * 256 + t;
      ok[i] = e < NE;
      bd[i] = 0; bs[i] = 0; ev[i] = 0;
      if (ok[i]) {
        const unsigned s = (unsigned)src[e], d = (unsigned)dst[e];
        ev[i] = s | (d << 16);
        bd[i] = (int)(d / 6250u);
        bs[i] = (int)(s / 6250u);
        atomicAdd(&hist[bd[i]], 1);
        atomicAdd(&hist[8 + bs[i]], 1);
      }
    }
    __syncthreads();
    if (t < 16) base[t] = atomicAdd(&gcur[t], hist[t]);
    __syncthreads();
#pragma unroll
    for (int i = 0; i < 8; ++i) {
      if (ok[i]) {
        const int r1 = atomicAdd(&cur[bd[i]], 1);
        bdst[bd[i] * BCAP + base[bd[i]] + r1] = ev[i];
        const int r2 = atomicAdd(&cur[8 + bs[i]], 1);
        bsrc[bs[i] * BCAP + base[8 + bs[i]] + r2] = ev[i];
      }
    }
    return;
  }
  bi -= BBK;
  // weights: 8 matrices x 4 blocks; convert + transpose (+presums)
  const int widx = bi >> 2;
  const int quad = bi & 3;
  const int Ks[8] = {192, 192, 128, 128, 128, 192, 64, 128};
  const int offs[8] = {WOFF_U1U, WOFF_U1D, WOFF_W1U, WOFF_W1D,
                       WOFF_W2U, WOFF_U2U, WOFF_WSUM, WOFF_USUM};
  const float* srcs[6] = {U_u1, U_d1, W_u1, W_d1, W_u2, U_u2};
  const int K = Ks[widx];
  const int off = offs[widx];
  const int qsz = K << 4;
  const int beg = quad * qsz;
  for (int e = beg + t; e < beg + qsz; e += 256) {
    const int cc = e / K;
    const int kk = e - cc * K;
    float v;
    if (widx < 6) v = srcs[widx][kk * 64 + cc];
    else if (widx == 6) v = W_u2[kk * 64 + cc] + W_u2[(kk + 64) * 64 + cc];
    else v = (kk < 64) ? (U_u2[kk * 64 + cc] + U_u2[(kk + 64) * 64 + cc])
                       : U_u2[(kk + 64) * 64 + cc];
    unsigned short h, l;
    split1(v, h, l);
    wbuf[off + cc * K + kk] = h;
    wbuf[off + (K << 6) + cc * K + kk] = l;
  }
}

// ---------------------------------------------------------------------------
// fusedC: bucketed count (blocks [0,NP)) || dual-output transform (TB blocks)
// Count blocks: full lane efficiency, XCD-local atomics (blockIdx&7 = bucket).
// ---------------------------------------------------------------------------
__global__ __launch_bounds__(256) void fusedC_kernel(
    const int* __restrict__ gcur,
    const unsigned* __restrict__ bdst, const unsigned* __restrict__ bsrc,
    int* __restrict__ rp_dst, int* __restrict__ rp_src,
    const float* __restrict__ x,
    const unsigned short* W1uh, const unsigned short* W1ul,
    const unsigned short* W1dh, const unsigned short* W1dl,
    const float* __restrict__ b_u1, const float* __restrict__ b_d1,
    float* __restrict__ Yu, float* __restrict__ Yd) {
  __shared__ unsigned short tiles[4][4096];
  int bi = blockIdx.x;
  if (bi < NP) {
    const int b = bi & 7;
    const int dirsrc = (bi >> 3) & 1;
    const int blk = bi >> 4;  // 0..127
    if (!dirsrc) {
      const int cnt = gcur[b];
      const unsigned* p = bdst + b * BCAP;
      for (int i = blk * 256 + threadIdx.x; i < cnt; i += 32768)
        atomicAdd(&rp_dst[p[i] >> 16], 1);
    } else {
      const int cnt = gcur[8 + b];
      const unsigned* p = bsrc + b * BCAP;
      for (int i = blk * 256 + threadIdx.x; i < cnt; i += 32768)
        atomicAdd(&rp_src[p[i] & 0xFFFFu], 1);
    }
    return;
  }
  bi -= NP;
  trans2_dev(tiles[0], tiles[1], tiles[2], tiles[3],
             x, W1uh, W1ul, W1dh, W1dl, b_u1, b_d1, Yu, Yd,
             bi * 64, threadIdx.x);
}

// ---------------------------------------------------------------------------
// place: bucketed, full lane efficiency, XCD-local cursors + col writes
// ---------------------------------------------------------------------------
__global__ __launch_bounds__(256) void place_kernel(
    const int* __restrict__ gcur,
    const unsigned* __restrict__ bdst, const unsigned* __restrict__ bsrc,
    int* __restrict__ rp_dst, int* __restrict__ rp_src,
    unsigned short* __restrict__ col_dst, unsigned short* __restrict__ col_src) {
  const int bi = blockIdx.x;
  const int b = bi & 7;
  const int dirsrc = (bi >> 3) & 1;
  const int blk = bi >> 4;
  if (!dirsrc) {
    const int cnt = gcur[b];
    const unsigned* p = bdst + b * BCAP;
    for (int i = blk * 256 + threadIdx.x; i < cnt; i += 32768) {
      const unsigned v = p[i];
      col_dst[atomicAdd(&rp_dst[v >> 16], 1)] = (unsigned short)(v & 0xFFFFu);
    }
  } else {
    const int cnt = gcur[8 + b];
    const unsigned* p = bsrc + b * BCAP;
    for (int i = blk * 256 + threadIdx.x; i < cnt; i += 32768) {
      const unsigned v = p[i];
      col_src[atomicAdd(&rp_src[v & 0xFFFFu], 1)] = (unsigned short)(v >> 16);
    }
  }
}

// ---------------------------------------------------------------------------
// CSR scan (2 blocks)
// ---------------------------------------------------------------------------
#define CHUNK 49
__global__ __launch_bounds__(1024) void scan_kernel(
    int* __restrict__ a0, int* __restrict__ a1) {
  int* a = (blockIdx.x == 0) ? a0 : a1;
  __shared__ int part[1024];
  const int t = threadIdx.x;
  const int beg = t * CHUNK;
  const int end = min(beg + CHUNK, NN);
  int s = 0;
  for (int i = beg; i < end; ++i) s += a[i];
  part[t] = s;
  __syncthreads();
  for (int off = 1; off < 1024; off <<= 1) {
    int add = (t >= off) ? part[t - off] : 0;
    __syncthreads();
    part[t] += add;
    __syncthreads();
  }
  int run = (t == 0) ? 0 : part[t - 1];
  for (int i = beg; i < end; ++i) {
    const int c = a[i];
    a[i] = run;
    run += c;
  }
}

// ---------------------------------------------------------------------------
// pull-gather mean (u16 col), XCD-aligned node swizzle
// ---------------------------------------------------------------------------
__device__ __forceinline__ void gather_dev(
    const float* __restrict__ Y, const int* __restrict__ rowptr,
    const unsigned short* __restrict__ col, float* __restrict__ AGGf,
    unsigned short* __restrict__ aggh, unsigned short* __restrict__ aggl,
    int seg, int tid) {
  const int w = tid >> 6;
  const int lane = tid & 63;
  const int off = (seg >> 3) * 4 + w;
  if (off >= 6250) return;
  const int node = (seg & 7) * 6250 + off;
  const int eg = lane >> 4;
  const int cq = (lane & 15) << 2;
  const int start = (node == 0) ? 0 : rowptr[node - 1];
  const int end = rowptr[node];
  float4 acc = make_float4(0.f, 0.f, 0.f, 0.f);
  int e = start + eg;
  for (; e + 12 < end; e += 16) {
    const int j0 = col[e];
    const int j1 = col[e + 4];
    const int j2 = col[e + 8];
    const int j3 = col[e + 12];
    const float4 y0 = *(const float4*)(Y + j0 * 64 + cq);
    const float4 y1 = *(const float4*)(Y + j1 * 64 + cq);
    const float4 y2 = *(const float4*)(Y + j2 * 64 + cq);
    const float4 y3 = *(const float4*)(Y + j3 * 64 + cq);
    acc.x += y0.x + y1.x + y2.x + y3.x;
    acc.y += y0.y + y1.y + y2.y + y3.y;
    acc.z += y0.z + y1.z + y2.z + y3.z;
    acc.w += y0.w + y1.w + y2.w + y3.w;
  }
  for (; e < end; e += 4) {
    const float4 y = *(const float4*)(Y + col[e] * 64 + cq);
    acc.x += y.x; acc.y += y.y; acc.z += y.z; acc.w += y.w;
  }
  acc.x += __shfl_xor(acc.x, 16);
  acc.y += __shfl_xor(acc.y, 16);
  acc.z += __shfl_xor(acc.z, 16);
  acc.w += __shfl_xor(acc.w, 16);
  acc.x += __shfl_xor(acc.x, 32);
  acc.y += __shfl_xor(acc.y, 32);
  acc.z += __shfl_xor(acc.z, 32);
  acc.w += __shfl_xor(acc.w, 32);
  if (eg == 0) {
    const float inv = 1.f / (float)max(end - start, 1);
    float4 o;
    o.x = acc.x * inv; o.y = acc.y * inv;
    o.z = acc.z * inv; o.w = acc.w * inv;
    if (AGGf) {
      *(float4*)(AGGf + node * 64 + cq) = o;
    } else {
      ushort4 h, l;
      split4(o, h, l);
      *(ushort4*)(aggh + node * 64 + cq) = h;
      *(ushort4*)(aggl + node * 64 + cq) = l;
    }
  }
}

__global__ __launch_bounds__(256) void gather_kernel(
    const float* __restrict__ Y, const int* __restrict__ rowptr,
    const unsigned short* __restrict__ col, float* __restrict__ AGGf,
    unsigned short* __restrict__ aggh, unsigned short* __restrict__ aggl) {
  gather_dev(Y, rowptr, col, AGGf, aggh, aggl, blockIdx.x, threadIdx.x);
}

__global__ __launch_bounds__(256) void gather2_kernel(
    const float* __restrict__ Yu, const int* __restrict__ rp_dst,
    const unsigned short* __restrict__ col_dst,
    unsigned short* auh, unsigned short* aul,
    const float* __restrict__ Yd, const int* __restrict__ rp_src,
    const unsigned short* __restrict__ col_src,
    unsigned short* adh, unsigned short* adl) {
  if (blockIdx.x < GBS)
    gather_dev(Yu, rp_dst, col_dst, nullptr, auh, aul, blockIdx.x, threadIdx.x);
  else
    gather_dev(Yd, rp_src, col_src, nullptr, adh, adl, blockIdx.x - GBS,
               threadIdx.x);
}

// ===========================================================================
// Fallback path (vector-f32 GEMM + replicated edge pass) for small workspaces
// ===========================================================================
__global__ __launch_bounds__(256) void pack_kernel(
    const int* __restrict__ src, const int* __restrict__ dst,
    unsigned* __restrict__ epack) {
  for (int e = blockIdx.x * 256 + threadIdx.x; e < NE; e += 1024 * 256)
    epack[e] = (unsigned)src[e] | ((unsigned)dst[e] << 16);
}

__device__ __forceinline__ void count_dev4(
    const unsigned* __restrict__ epack,
    int* __restrict__ rp_dst, int* __restrict__ rp_src, int bi, int tid) {
  const unsigned lo = (unsigned)(bi & 7) * 6250u;
  const int g = (bi >> 3) * 256 + tid;
  for (int e = g * 4; e < NE; e += 262144) {
    const uint4 v4 = *(const uint4*)(epack + e);
    const unsigned vs[4] = {v4.x, v4.y, v4.z, v4.w};
#pragma unroll
    for (int i = 0; i < 4; ++i) {
      const unsigned s = vs[i] & 0xFFFFu, d = vs[i] >> 16;
      if (d - lo < 6250u) atomicAdd(&rp_dst[d], 1);
      if (s - lo < 6250u) atomicAdd(&rp_src[s], 1);
    }
  }
}

__device__ __forceinline__ void place_dev4(
    const unsigned* __restrict__ epack,
    int* __restrict__ rp_dst, int* __restrict__ rp_src,
    unsigned short* __restrict__ col_dst, unsigned short* __restrict__ col_src,
    int bi, int tid) {
  const unsigned lo = (unsigned)(bi & 7) * 6250u;
  const int g = (bi >> 3) * 256 + tid;
  for (int e = g * 4; e < NE; e += 262144) {
    const uint4 v4 = *(const uint4*)(epack + e);
    const unsigned vs[4] = {v4.x, v4.y, v4.z, v4.w};
#pragma unroll
    for (int i = 0; i < 4; ++i) {
      const unsigned s = vs[i] & 0xFFFFu, d = vs[i] >> 16;
      if (d - lo < 6250u)
        col_dst[atomicAdd(&rp_dst[d], 1)] = (unsigned short)s;
      if (s - lo < 6250u)
        col_src[atomicAdd(&rp_src[s], 1)] = (unsigned short)d;
    }
  }
}

__device__ __forceinline__ void gemm64_dev(
    float (*Xt)[68], float* Ws, const float* __restrict__ X, int ldx,
    const float* __restrict__ AGG, const float* __restrict__ W,
    const float* __restrict__ b, float* __restrict__ out, int ldo,
    int colbase, int dup, int kchunks, int xchunks, int row0, int tid) {
  const int tx = tid & 15, ty = tid >> 4;
  float acc[4][4] = {{0.f}};
  for (int c = 0; c < kchunks; ++c) {
    {
      const int rr = tid >> 2;
      const int cg = (tid & 3) << 4;
      const float* srcp;
      int ld, co;
      if (c < xchunks) { srcp = X; ld = ldx; co = c * 64; }
      else             { srcp = AGG; ld = 64; co = 0; }
      int row = row0 + rr;
      if (row > NN - 1) row = NN - 1;
      const float* g = srcp + row * ld + co + cg;
      const float4 v0 = *(const float4*)(g + 0);
      const float4 v1 = *(const float4*)(g + 4);
      const float4 v2 = *(const float4*)(g + 8);
      const float4 v3 = *(const float4*)(g + 12);
      Xt[cg + 0][rr] = v0.x;  Xt[cg + 1][rr] = v0.y;
      Xt[cg + 2][rr] = v0.z;  Xt[cg + 3][rr] = v0.w;
      Xt[cg + 4][rr] = v1.x;  Xt[cg + 5][rr] = v1.y;
      Xt[cg + 6][rr] = v1.z;  Xt[cg + 7][rr] = v1.w;
      Xt[cg + 8][rr] = v2.x;  Xt[cg + 9][rr] = v2.y;
      Xt[cg + 10][rr] = v2.z; Xt[cg + 11][rr] = v2.w;
      Xt[cg + 12][rr] = v3.x; Xt[cg + 13][rr] = v3.y;
      Xt[cg + 14][rr] = v3.z; Xt[cg + 15][rr] = v3.w;
      const float4* wg = (const float4*)(W + c * 64 * 64);
      float4* wl = (float4*)Ws;
      wl[tid] = wg[tid];
      wl[tid + 256] = wg[tid + 256];
      wl[tid + 512] = wg[tid + 512];
      wl[tid + 768] = wg[tid + 768];
    }
    __syncthreads();
#pragma unroll 8
    for (int kk = 0; kk < 64; ++kk) {
      const float4 a = *(const float4*)&Xt[kk][tx << 2];
      const float4 w = *(const float4*)&Ws[kk * 64 + (ty << 2)];
      acc[0][0] += a.x * w.x; acc[0][1] += a.x * w.y;
      acc[0][2] += a.x * w.z; acc[0][3] += a.x * w.w;
      acc[1][0] += a.y * w.x; acc[1][1] += a.y * w.y;
      acc[1][2] += a.y * w.z; acc[1][3] += a.y * w.w;
      acc[2][0] += a.z * w.x; acc[2][1] += a.z * w.y;
      acc[2][2] += a.z * w.z; acc[2][3] += a.z * w.w;
      acc[3][0] += a.w * w.x; acc[3][1] += a.w * w.y;
      acc[3][2] += a.w * w.z; acc[3][3] += a.w * w.w;
    }
    __syncthreads();
  }
  float4 bv = make_float4(0.f, 0.f, 0.f, 0.f);
  if (b) bv = *(const float4*)(b + (ty << 2));
#pragma unroll
  for (int i = 0; i < 4; ++i) {
    const int row = row0 + (tx << 2) + i;
    if (row < NN) {
      float4 o;
      o.x = fmaxf(acc[i][0] + bv.x, 0.f);
      o.y = fmaxf(acc[i][1] + bv.y, 0.f);
      o.z = fmaxf(acc[i][2] + bv.z, 0.f);
      o.w = fmaxf(acc[i][3] + bv.w, 0.f);
      *(float4*)(out + row * ldo + colbase + (ty << 2)) = o;
      if (dup) *(float4*)(out + row * ldo + 64 + (ty << 2)) = o;
    }
  }
}

__global__ __launch_bounds__(256) void gemm_kernel(
    const float* __restrict__ X, int ldx, const float* __restrict__ AGG,
    const float* __restrict__ W, const float* __restrict__ b,
    float* __restrict__ out, int ldo, int colbase, int dup,
    int kchunks, int xchunks) {
  __shared__ __align__(16) float Xt[64][68];
  __shared__ __align__(16) float Ws[4096];
  gemm64_dev(Xt, Ws, X, ldx, AGG, W, b, out, ldo, colbase, dup, kchunks,
             xchunks, blockIdx.x * 64, threadIdx.x);
}

__global__ __launch_bounds__(256) void count_old_kernel(
    const unsigned* __restrict__ epack,
    int* __restrict__ rp_dst, int* __restrict__ rp_src) {
  count_dev4(epack, rp_dst, rp_src, blockIdx.x, threadIdx.x);
}

__global__ __launch_bounds__(256) void fused0_kernel(
    const unsigned* __restrict__ epack,
    int* __restrict__ rp_dst, int* __restrict__ rp_src,
    unsigned short* __restrict__ col_dst, unsigned short* __restrict__ col_src,
    const float* __restrict__ x,
    const float* __restrict__ W_u1, const float* __restrict__ b_u1,
    float* __restrict__ Y_u,
    const float* __restrict__ W_d1, const float* __restrict__ b_d1,
    float* __restrict__ Y_d) {
  __shared__ __align__(16) float Xt[64][68];
  __shared__ __align__(16) float Ws[4096];
  int bi = blockIdx.x;
  if (bi < NP) {
    place_dev4(epack, rp_dst, rp_src, col_dst, col_src, bi, threadIdx.x);
    return;
  }
  bi -= NP;
  if (bi < TB)
    gemm64_dev(Xt, Ws, x, 128, nullptr, W_u1, b_u1, Y_u, 64, 0, 0, 2, 2,
               bi * 64, threadIdx.x);
  else
    gemm64_dev(Xt, Ws, x, 128, nullptr, W_d1, b_d1, Y_d, 64, 0, 0, 2, 2,
               (bi - TB) * 64, threadIdx.x);
}

// ===========================================================================
extern "C" void kernel_launch(void* const* d_in, const int* in_sizes, int n_in,
                              void* d_out, int out_size, void* d_ws, size_t ws_size,
                              hipStream_t stream) {
  const float* x    = (const float*)d_in[0];
  const int*   ei   = (const int*)d_in[1];
  const float* W_u1 = (const float*)d_in[2];
  const float* b_u1 = (const float*)d_in[3];
  const float* U_u1 = (const float*)d_in[4];
  const float* W_d1 = (const float*)d_in[5];
  const float* b_d1 = (const float*)d_in[6];
  const float* U_d1 = (const float*)d_in[7];
  const float* W_u2 = (const float*)d_in[8];
  const float* b_u2 = (const float*)d_in[9];
  const float* U_u2 = (const float*)d_in[10];
  const int* src = ei;
  const int* dst = ei + NE;
  float* out = (float*)d_out;

  char* wsb = (char*)d_ws;
  int* rp_dst  = (int*)wsb;              wsb += NN * sizeof(int);
  int* rp_src  = (int*)wsb;              wsb += NN * sizeof(int);
  int* gcur    = (int*)wsb;              wsb += 32 * sizeof(int);
  unsigned short* col_dst = (unsigned short*)wsb; wsb += (size_t)NE * 2;
  unsigned short* col_src = (unsigned short*)wsb; wsb += (size_t)NE * 2;

  const size_t needM = (size_t)2 * NN * 4 + 128 + (size_t)NE * 4 +
                       (size_t)WBUF_USHORTS * 2 +
                       (size_t)NN * 64 * 4 * 2 +    // Yu, Yd (f32)
                       (size_t)NN * 64 * 2 * 4 +    // 4 agg bf16 planes
                       (size_t)NN * 64 * 2 * 2;     // O2h, O2l

  // zero rowptr counters + bucket cursors in one memset
  hipMemsetAsync(rp_dst, 0, 2 * NN * sizeof(int) + 32 * sizeof(int), stream);

  if (ws_size >= needM) {
    unsigned short* wbuf = (unsigned short*)wsb; wsb += (size_t)WBUF_USHORTS * 2;
    float* Yu = (float*)wsb;                     wsb += (size_t)NN * 64 * 4;
    float* Yd = (float*)wsb;                     wsb += (size_t)NN * 64 * 4;
    unsigned short* agg_uh = (unsigned short*)wsb; wsb += (size_t)NN * 64 * 2;
    unsigned short* agg_ul = (unsigned short*)wsb; wsb += (size_t)NN * 64 * 2;
    unsigned short* agg_dh = (unsigned short*)wsb; wsb += (size_t)NN * 64 * 2;
    unsigned short* agg_dl = (unsigned short*)wsb; wsb += (size_t)NN * 64 * 2;
    unsigned short* O2h = (unsigned short*)wsb;    wsb += (size_t)NN * 64 * 2;
    unsigned short* O2l = (unsigned short*)wsb;

    // bucket arrays alias agg planes (dead until gather2; place ends before)
    unsigned* bdst = (unsigned*)agg_uh;   // 8*BCAP*4 = 3.31MB <= 6.4MB
    unsigned* bsrc = (unsigned*)agg_ul;

    // other aliases (sequential lifetime reuse)
    unsigned short* outh = (unsigned short*)Yu;  // [N][128] bf16 hi
    unsigned short* outl = (unsigned short*)Yd;  // [N][128] bf16 lo
    float* Y2 = (float*)agg_uh;                  // [N][64] f32 (spans uh+ul)
    unsigned short* agg2h = agg_dh;
    unsigned short* agg2l = agg_dl;

    const unsigned short* U1uh = wbuf + WOFF_U1U;
    const unsigned short* U1ul = wbuf + WOFF_U1U + 64 * 192;
    const unsigned short* U1dh = wbuf + WOFF_U1D;
    const unsigned short* U1dl = wbuf + WOFF_U1D + 64 * 192;
    const unsigned short* W1uh = wbuf + WOFF_W1U;
    const unsigned short* W1ul = wbuf + WOFF_W1U + 64 * 128;
    const unsigned short* W1dh = wbuf + WOFF_W1D;
    const unsigned short* W1dl = wbuf + WOFF_W1D + 64 * 128;
    const unsigned short* W2uh = wbuf + WOFF_W2U;
    const unsigned short* W2ul = wbuf + WOFF_W2U + 64 * 128;
    const unsigned short* U2uh = wbuf + WOFF_U2U;
    const unsigned short* U2ul = wbuf + WOFF_U2U + 64 * 192;
    const unsigned short* Wsh  = wbuf + WOFF_WSUM;
    const unsigned short* Wsl  = wbuf + WOFF_WSUM + 64 * 64;
    const unsigned short* Ush  = wbuf + WOFF_USUM;
    const unsigned short* Usl  = wbuf + WOFF_USUM + 64 * 128;

    // bucket counting-sort || weight conversion
    prep_kernel<<<BBK + 32, 256, 0, stream>>>(
        src, dst, gcur, bdst, bsrc, U_u1, U_d1, W_u1, W_d1, W_u2, U_u2, wbuf);
    // bucketed count || layer-1 transforms
    fusedC_kernel<<<NP + TB, 256, 0, stream>>>(
        gcur, bdst, bsrc, rp_dst, rp_src, x, W1uh, W1ul, W1dh, W1dl,
        b_u1, b_d1, Yu, Yd);
    scan_kernel<<<2, 1024, 0, stream>>>(rp_dst, rp_src);
    // bucketed placement (full lane efficiency, XCD-local)
    place_kernel<<<NP, 256, 0, stream>>>(gcur, bdst, bsrc, rp_dst, rp_src,
                                         col_dst, col_src);
    // layer 1
    gather2_kernel<<<2 * GBS, 256, 0, stream>>>(Yu, rp_dst, col_dst, agg_uh,
                                                agg_ul, Yd, rp_src, col_src,
                                                agg_dh, agg_dl);
    update2m_kernel<<<2 * TB, 256, 0, stream>>>(x, agg_uh, agg_ul, agg_dh,
                                                agg_dl, U1uh, U1ul, U1dh,
                                                U1dl, outh, outl);
    // round 2
    mgemm_kernel<<<TB, 256, 0, stream>>>(outh, outl, 128, nullptr, nullptr,
                                         W2uh, W2ul, 128, b_u2, Y2, nullptr,
                                         nullptr, 64, 0, 0, 2, 2);
    gather_kernel<<<GBS, 256, 0, stream>>>(Y2, rp_dst, col_dst, nullptr,
                                           agg2h, agg2l);
    mgemm_kernel<<<TB, 256, 0, stream>>>(outh, outl, 128, agg2h, agg2l,
                                         U2uh, U2ul, 192, nullptr, nullptr,
                                         O2h, O2l, 64, 0, 0, 3, 2);
    // round 3 (h = [O2,O2] folded into presummed weights)
    mgemm_kernel<<<TB, 256, 0, stream>>>(O2h, O2l, 64, nullptr, nullptr,
                                         Wsh, Wsl, 64, b_u2, Y2, nullptr,
                                         nullptr, 64, 0, 0, 1, 1);
    gather_kernel<<<GBS, 256, 0, stream>>>(Y2, rp_dst, col_dst, nullptr,
                                           agg2h, agg2l);
    mgemm_kernel<<<TB, 256, 0, stream>>>(O2h, O2l, 64, agg2h, agg2l,
                                         Ush, Usl, 128, nullptr, out,
                                         nullptr, nullptr, 128, 0, 1, 2, 1);
  } else {
    // fallback: vector-f32 path with replicated edge passes
    unsigned* epack = (unsigned*)wsb; wsb += (size_t)NE * 4;
    float* Y_u = (float*)wsb; wsb += (size_t)NN * 64 * sizeof(float);
    float* Y_d = (float*)wsb; wsb += (size_t)NN * 64 * sizeof(float);
    float* AGG = (float*)wsb;
    pack_kernel<<<1024, 256, 0, stream>>>(src, dst, epack);
    count_old_kernel<<<NP, 256, 0, stream>>>(epack, rp_dst, rp_src);
    scan_kernel<<<2, 1024, 0, stream>>>(rp_dst, rp_src);
    fused0_kernel<<<NP + 2 * TB, 256, 0, stream>>>(
        epack, rp_dst, rp_src, col_dst, col_src, x, W_u1, b_u1, Y_u, W_d1,
        b_d1, Y_d);
    gather_kernel<<<GBS, 256, 0, stream>>>(Y_u, rp_dst, col_dst, AGG,
                                           nullptr, nullptr);
    gemm_kernel<<<TB, 256, 0, stream>>>(x, 128, AGG, U_u1, nullptr, out,
                                        128, 0, 0, 3, 2);
    gather_kernel<<<GBS, 256, 0, stream>>>(Y_d, rp_src, col_src, AGG,
                                           nullptr, nullptr);
    gemm_kernel<<<TB, 256, 0, stream>>>(x, 128, AGG, U_d1, nullptr, out,
                                        128, 64, 0, 3, 2);
    for (int r = 0; r < 2; ++r) {
      gemm_kernel<<<TB, 256, 0, stream>>>(out, 128, nullptr, W_u2, b_u2,
                                          Y_u, 64, 0, 0, 2, 2);
      gather_kernel<<<GBS, 256, 0, stream>>>(Y_u, rp_dst, col_dst, AGG,
                                             nullptr, nullptr);
      gemm_kernel<<<TB, 256, 0, stream>>>(out, 128, AGG, U_u2, nullptr,
                                          out, 128, 0, 1, 3, 2);
    }
  }
}

// Round 10
// 336.312 us; speedup vs baseline: 1.1961x; 1.1961x over previous
//
#include <hip/hip_runtime.h>

#define NN 50000
#define NE 800000
#define NP 2048            // bucketed count/place blocks
#define TB 782             // ceil(NN/64) gemm row-tile blocks
#define GBS 12504          // 8 * 1563 swizzled gather blocks (4 nodes each)
#define BCAP 103424        // per-bucket capacity
#define BBK 391            // bucket blocks = ceil(NE/2048)
#define CHKE 2048          // edges per bucket block
#define NCH 49             // scan chunks = ceil(NN/1024)

typedef __attribute__((ext_vector_type(8))) short bhalf8;
typedef __attribute__((ext_vector_type(4))) float floatx4;

// weight buffer offsets (ushort units); l plane = h + 64*K
#define WOFF_U1U 0
#define WOFF_U1D 24576
#define WOFF_W1U 49152
#define WOFF_W1D 65536
#define WOFF_W2U 81920
#define WOFF_U2U 98304
#define WOFF_WSUM 122880
#define WOFF_USUM 131072
#define WBUF_USHORTS 147456

// ---------------------------------------------------------------------------
// bf16 split helpers (RNE)
// ---------------------------------------------------------------------------
__device__ __forceinline__ unsigned short bf16hi(float v) {
  union { float f; unsigned u; } c; c.f = v;
  return (unsigned short)((c.u + 0x7FFFu + ((c.u >> 16) & 1u)) >> 16);
}
__device__ __forceinline__ float bf16tof(unsigned short h) {
  union { unsigned u; float f; } c; c.u = ((unsigned)h) << 16;
  return c.f;
}
__device__ __forceinline__ void split1(float v, unsigned short& h,
                                       unsigned short& l) {
  h = bf16hi(v);
  l = bf16hi(v - bf16tof(h));
}
__device__ __forceinline__ void split4(const float4 v, ushort4& h, ushort4& l) {
  split1(v.x, h.x, l.x);
  split1(v.y, h.y, l.y);
  split1(v.z, h.z, l.z);
  split1(v.w, h.w, l.w);
}
__device__ __forceinline__ void split8(const float4 v0, const float4 v1,
                                       uint4& H, uint4& L) {
  unsigned short h0, l0, h1, l1;
  split1(v0.x, h0, l0); split1(v0.y, h1, l1);
  H.x = (unsigned)h0 | ((unsigned)h1 << 16);
  L.x = (unsigned)l0 | ((unsigned)l1 << 16);
  split1(v0.z, h0, l0); split1(v0.w, h1, l1);
  H.y = (unsigned)h0 | ((unsigned)h1 << 16);
  L.y = (unsigned)l0 | ((unsigned)l1 << 16);
  split1(v1.x, h0, l0); split1(v1.y, h1, l1);
  H.z = (unsigned)h0 | ((unsigned)h1 << 16);
  L.z = (unsigned)l0 | ((unsigned)l1 << 16);
  split1(v1.z, h0, l0); split1(v1.w, h1, l1);
  H.w = (unsigned)h0 | ((unsigned)h1 << 16);
  L.w = (unsigned)l0 | ((unsigned)l1 << 16);
}

// swizzled LDS byte address for bf16 tile [64 rows][64 k] (128B rows)
#define SWZ(row, inrow) (((row) << 7) + ((inrow) ^ (((row)&7) << 4)))

// ---------------------------------------------------------------------------
// MFMA split-bf16 GEMM (single B): out = relu([A|G] @ B^T (+bias))
// ---------------------------------------------------------------------------
template <bool AF32>
__device__ __forceinline__ void mfma_gemm_dev(
    unsigned short* tAh, unsigned short* tAl,
    unsigned short* tBh, unsigned short* tBl,
    const unsigned short* __restrict__ Ah, const unsigned short* __restrict__ Al,
    int lda,
    const unsigned short* __restrict__ Gh, const unsigned short* __restrict__ Gl,
    const unsigned short* __restrict__ Bh, const unsigned short* __restrict__ Bl,
    int ldb, const float* __restrict__ bias,
    float* __restrict__ outF, unsigned short* __restrict__ outH,
    unsigned short* __restrict__ outL,
    int ldo, int colbase, int dup, int kchunks, int xchunks,
    int row0, int tid) {
  const int lane = tid & 63;
  const int wm = tid >> 6;
  const int m = lane & 15;
  const int kg = lane >> 4;
  floatx4 acc[4];
#pragma unroll
  for (int i = 0; i < 4; ++i) acc[i] = (floatx4){0.f, 0.f, 0.f, 0.f};

  for (int c = 0; c < kchunks; ++c) {
#pragma unroll
    for (int q = tid; q < 512; q += 256) {
      const int row = q >> 3, slot = q & 7;
      int gr = row0 + row;
      gr = (gr > NN - 1) ? NN - 1 : gr;
      const int ad = SWZ(row, slot << 4);
      if (AF32 && c < xchunks) {
        const float* f = (const float*)Ah;
        const size_t go = (size_t)gr * lda + (c << 6) + slot * 8;
        const float4 v0 = *(const float4*)(f + go);
        const float4 v1 = *(const float4*)(f + go + 4);
        uint4 H, L;
        split8(v0, v1, H, L);
        *(uint4*)((char*)tAh + ad) = H;
        *(uint4*)((char*)tAl + ad) = L;
      } else {
        const unsigned short* sh;
        const unsigned short* sl;
        int ld, kc;
        if (c < xchunks) { sh = Ah; sl = Al; ld = lda; kc = c << 6; }
        else             { sh = Gh; sl = Gl; ld = 64;  kc = 0; }
        const size_t go = (size_t)gr * ld + kc + slot * 8;
        *(uint4*)((char*)tAh + ad) = *(const uint4*)(sh + go);
        *(uint4*)((char*)tAl + ad) = *(const uint4*)(sl + go);
      }
      const size_t gob = (size_t)row * ldb + (c << 6) + slot * 8;
      *(uint4*)((char*)tBh + ad) = *(const uint4*)(Bh + gob);
      *(uint4*)((char*)tBl + ad) = *(const uint4*)(Bl + gob);
    }
    __syncthreads();
#pragma unroll
    for (int ks = 0; ks < 2; ++ks) {
      const int inrow = (ks << 6) + (kg << 4);
      const int rA = (wm << 4) + m;
      const bhalf8 ah = *(const bhalf8*)((const char*)tAh + SWZ(rA, inrow));
      const bhalf8 al = *(const bhalf8*)((const char*)tAl + SWZ(rA, inrow));
#pragma unroll
      for (int nt = 0; nt < 4; ++nt) {
        const int rB = (nt << 4) + m;
        const bhalf8 bh = *(const bhalf8*)((const char*)tBh + SWZ(rB, inrow));
        const bhalf8 bl = *(const bhalf8*)((const char*)tBl + SWZ(rB, inrow));
        acc[nt] = __builtin_amdgcn_mfma_f32_16x16x32_bf16(ah, bh, acc[nt], 0, 0, 0);
        acc[nt] = __builtin_amdgcn_mfma_f32_16x16x32_bf16(ah, bl, acc[nt], 0, 0, 0);
        acc[nt] = __builtin_amdgcn_mfma_f32_16x16x32_bf16(al, bh, acc[nt], 0, 0, 0);
      }
    }
    __syncthreads();
  }
#pragma unroll
  for (int nt = 0; nt < 4; ++nt) {
    const int col = colbase + (nt << 4) + m;
    const float bv = bias ? bias[(nt << 4) + m] : 0.f;
#pragma unroll
    for (int r = 0; r < 4; ++r) {
      const int row = row0 + (wm << 4) + (kg << 2) + r;
      if (row < NN) {
        const float v = fmaxf(acc[nt][r] + bv, 0.f);
        if (outF) {
          outF[(size_t)row * ldo + col] = v;
          if (dup) outF[(size_t)row * ldo + col + 64] = v;
        }
        if (outH) {
          unsigned short h, l;
          split1(v, h, l);
          outH[(size_t)row * ldo + col] = h;
          outL[(size_t)row * ldo + col] = l;
        }
      }
    }
  }
}

// ---------------------------------------------------------------------------
// Dual-output transform, 4-tile (32KB)
// ---------------------------------------------------------------------------
__device__ __forceinline__ void trans2_dev(
    unsigned short* tAh, unsigned short* tAl,
    unsigned short* tBh, unsigned short* tBl,
    const float* __restrict__ x,
    const unsigned short* __restrict__ Wuh, const unsigned short* __restrict__ Wul,
    const unsigned short* __restrict__ Wdh, const unsigned short* __restrict__ Wdl,
    const float* __restrict__ bu, const float* __restrict__ bd,
    float* __restrict__ Yu, float* __restrict__ Yd, int row0, int tid) {
  const int lane = tid & 63;
  const int wm = tid >> 6;
  const int m = lane & 15;
  const int kg = lane >> 4;
  floatx4 accU[4], accD[4];
#pragma unroll
  for (int i = 0; i < 4; ++i) {
    accU[i] = (floatx4){0.f, 0.f, 0.f, 0.f};
    accD[i] = (floatx4){0.f, 0.f, 0.f, 0.f};
  }
  for (int c = 0; c < 2; ++c) {
#pragma unroll
    for (int q = tid; q < 512; q += 256) {
      const int row = q >> 3, slot = q & 7;
      int gr = row0 + row;
      gr = (gr > NN - 1) ? NN - 1 : gr;
      const int ad = SWZ(row, slot << 4);
      const size_t go = (size_t)gr * 128 + (c << 6) + slot * 8;
      const float4 v0 = *(const float4*)(x + go);
      const float4 v1 = *(const float4*)(x + go + 4);
      uint4 H, L;
      split8(v0, v1, H, L);
      *(uint4*)((char*)tAh + ad) = H;
      *(uint4*)((char*)tAl + ad) = L;
      const size_t gob = (size_t)row * 128 + (c << 6) + slot * 8;
      *(uint4*)((char*)tBh + ad) = *(const uint4*)(Wuh + gob);
      *(uint4*)((char*)tBl + ad) = *(const uint4*)(Wul + gob);
    }
    __syncthreads();
#pragma unroll
    for (int ks = 0; ks < 2; ++ks) {
      const int inrow = (ks << 6) + (kg << 4);
      const int rA = (wm << 4) + m;
      const bhalf8 ah = *(const bhalf8*)((const char*)tAh + SWZ(rA, inrow));
      const bhalf8 al = *(const bhalf8*)((const char*)tAl + SWZ(rA, inrow));
#pragma unroll
      for (int nt = 0; nt < 4; ++nt) {
        const int rB = (nt << 4) + m;
        const int adB = SWZ(rB, inrow);
        const bhalf8 bh = *(const bhalf8*)((const char*)tBh + adB);
        const bhalf8 bl = *(const bhalf8*)((const char*)tBl + adB);
        accU[nt] = __builtin_amdgcn_mfma_f32_16x16x32_bf16(ah, bh, accU[nt], 0, 0, 0);
        accU[nt] = __builtin_amdgcn_mfma_f32_16x16x32_bf16(ah, bl, accU[nt], 0, 0, 0);
        accU[nt] = __builtin_amdgcn_mfma_f32_16x16x32_bf16(al, bh, accU[nt], 0, 0, 0);
      }
    }
    __syncthreads();
#pragma unroll
    for (int q = tid; q < 512; q += 256) {
      const int row = q >> 3, slot = q & 7;
      const int ad = SWZ(row, slot << 4);
      const size_t gob = (size_t)row * 128 + (c << 6) + slot * 8;
      *(uint4*)((char*)tBh + ad) = *(const uint4*)(Wdh + gob);
      *(uint4*)((char*)tBl + ad) = *(const uint4*)(Wdl + gob);
    }
    __syncthreads();
#pragma unroll
    for (int ks = 0; ks < 2; ++ks) {
      const int inrow = (ks << 6) + (kg << 4);
      const int rA = (wm << 4) + m;
      const bhalf8 ah = *(const bhalf8*)((const char*)tAh + SWZ(rA, inrow));
      const bhalf8 al = *(const bhalf8*)((const char*)tAl + SWZ(rA, inrow));
#pragma unroll
      for (int nt = 0; nt < 4; ++nt) {
        const int rB = (nt << 4) + m;
        const int adB = SWZ(rB, inrow);
        const bhalf8 bh = *(const bhalf8*)((const char*)tBh + adB);
        const bhalf8 bl = *(const bhalf8*)((const char*)tBl + adB);
        accD[nt] = __builtin_amdgcn_mfma_f32_16x16x32_bf16(ah, bh, accD[nt], 0, 0, 0);
        accD[nt] = __builtin_amdgcn_mfma_f32_16x16x32_bf16(ah, bl, accD[nt], 0, 0, 0);
        accD[nt] = __builtin_amdgcn_mfma_f32_16x16x32_bf16(al, bh, accD[nt], 0, 0, 0);
      }
    }
    __syncthreads();
  }
#pragma unroll
  for (int nt = 0; nt < 4; ++nt) {
    const int col = (nt << 4) + m;
    const float bvu = bu[col];
    const float bvd = bd[col];
#pragma unroll
    for (int r = 0; r < 4; ++r) {
      const int row = row0 + (wm << 4) + (kg << 2) + r;
      if (row < NN) {
        Yu[(size_t)row * 64 + col] = fmaxf(accU[nt][r] + bvu, 0.f);
        Yd[(size_t)row * 64 + col] = fmaxf(accD[nt][r] + bvd, 0.f);
      }
    }
  }
}

__global__ __launch_bounds__(256) void trans2_kernel(
    const float* __restrict__ x,
    const unsigned short* W1uh, const unsigned short* W1ul,
    const unsigned short* W1dh, const unsigned short* W1dl,
    const float* __restrict__ b_u1, const float* __restrict__ b_d1,
    float* __restrict__ Yu, float* __restrict__ Yd) {
  __shared__ unsigned short tiles[4][4096];
  trans2_dev(tiles[0], tiles[1], tiles[2], tiles[3], x, W1uh, W1ul, W1dh,
             W1dl, b_u1, b_d1, Yu, Yd, blockIdx.x * 64, threadIdx.x);
}

__global__ __launch_bounds__(256) void mgemm_kernel(
    const unsigned short* Ah, const unsigned short* Al, int lda,
    const unsigned short* Gh, const unsigned short* Gl,
    const unsigned short* Bh, const unsigned short* Bl, int ldb,
    const float* bias, float* outF, unsigned short* outH, unsigned short* outL,
    int ldo, int colbase, int dup, int kchunks, int xchunks) {
  __shared__ unsigned short tiles[4][4096];
  mfma_gemm_dev<false>(tiles[0], tiles[1], tiles[2], tiles[3], Ah, Al, lda,
                       Gh, Gl, Bh, Bl, ldb, bias, outF, outH, outL, ldo,
                       colbase, dup, kchunks, xchunks, blockIdx.x * 64,
                       threadIdx.x);
}

// both layer-1 updates in one launch; A = f32 x (inline split)
__global__ __launch_bounds__(256) void update2m_kernel(
    const float* __restrict__ x,
    const unsigned short* auh, const unsigned short* aul,
    const unsigned short* adh, const unsigned short* adl,
    const unsigned short* U1uh, const unsigned short* U1ul,
    const unsigned short* U1dh, const unsigned short* U1dl,
    unsigned short* outH, unsigned short* outL) {
  __shared__ unsigned short tiles[4][4096];
  if (blockIdx.x < TB)
    mfma_gemm_dev<true>(tiles[0], tiles[1], tiles[2], tiles[3],
                        (const unsigned short*)x, nullptr, 128, auh, aul,
                        U1uh, U1ul, 192, nullptr, nullptr, outH, outL, 128,
                        0, 0, 3, 2, blockIdx.x * 64, threadIdx.x);
  else
    mfma_gemm_dev<true>(tiles[0], tiles[1], tiles[2], tiles[3],
                        (const unsigned short*)x, nullptr, 128, adh, adl,
                        U1dh, U1dl, 192, nullptr, nullptr, outH, outL, 128,
                        64, 0, 3, 2, (blockIdx.x - TB) * 64, threadIdx.x);
}

// ---------------------------------------------------------------------------
// prep: bucket counting-sort (blocks [0,BBK)) || weight conversion (32 blocks)
// ---------------------------------------------------------------------------
__global__ __launch_bounds__(256) void prep_kernel(
    const int* __restrict__ src, const int* __restrict__ dst,
    int* __restrict__ gcur,
    unsigned* __restrict__ bdst, unsigned* __restrict__ bsrc,
    const float* __restrict__ U_u1, const float* __restrict__ U_d1,
    const float* __restrict__ W_u1, const float* __restrict__ W_d1,
    const float* __restrict__ W_u2, const float* __restrict__ U_u2,
    unsigned short* __restrict__ wbuf) {
  int bi = blockIdx.x;
  const int t = threadIdx.x;
  if (bi < BBK) {
    __shared__ int hist[16];
    __shared__ int base[16];
    __shared__ int cur[16];
    const int chunk = bi * CHKE;
    if (t < 16) { hist[t] = 0; cur[t] = 0; }
    __syncthreads();
    unsigned ev[8];
    int bd[8], bs[8];
    bool ok[8];
#pragma unroll
    for (int i = 0; i < 8; ++i) {
      const int e = chunk + i * 256 + t;
      ok[i] = e < NE;
      bd[i] = 0; bs[i] = 0; ev[i] = 0;
      if (ok[i]) {
        const unsigned s = (unsigned)src[e], d = (unsigned)dst[e];
        ev[i] = s | (d << 16);
        bd[i] = (int)(d / 6250u);
        bs[i] = (int)(s / 6250u);
        atomicAdd(&hist[bd[i]], 1);
        atomicAdd(&hist[8 + bs[i]], 1);
      }
    }
    __syncthreads();
    if (t < 16) base[t] = atomicAdd(&gcur[t], hist[t]);
    __syncthreads();
#pragma unroll
    for (int i = 0; i < 8; ++i) {
      if (ok[i]) {
        const int r1 = atomicAdd(&cur[bd[i]], 1);
        bdst[bd[i] * BCAP + base[bd[i]] + r1] = ev[i];
        const int r2 = atomicAdd(&cur[8 + bs[i]], 1);
        bsrc[bs[i] * BCAP + base[8 + bs[i]] + r2] = ev[i];
      }
    }
    return;
  }
  bi -= BBK;
  const int widx = bi >> 2;
  const int quad = bi & 3;
  const int Ks[8] = {192, 192, 128, 128, 128, 192, 64, 128};
  const int offs[8] = {WOFF_U1U, WOFF_U1D, WOFF_W1U, WOFF_W1D,
                       WOFF_W2U, WOFF_U2U, WOFF_WSUM, WOFF_USUM};
  const float* srcs[6] = {U_u1, U_d1, W_u1, W_d1, W_u2, U_u2};
  const int K = Ks[widx];
  const int off = offs[widx];
  const int qsz = K << 4;
  const int beg = quad * qsz;
  for (int e = beg + t; e < beg + qsz; e += 256) {
    const int cc = e / K;
    const int kk = e - cc * K;
    float v;
    if (widx < 6) v = srcs[widx][kk * 64 + cc];
    else if (widx == 6) v = W_u2[kk * 64 + cc] + W_u2[(kk + 64) * 64 + cc];
    else v = (kk < 64) ? (U_u2[kk * 64 + cc] + U_u2[(kk + 64) * 64 + cc])
                       : U_u2[(kk + 64) * 64 + cc];
    unsigned short h, l;
    split1(v, h, l);
    wbuf[off + cc * K + kk] = h;
    wbuf[off + (K << 6) + cc * K + kk] = l;
  }
}

// ---------------------------------------------------------------------------
// bucketed count (no LDS, high occupancy)
// ---------------------------------------------------------------------------
__global__ __launch_bounds__(256) void count_b_kernel(
    const int* __restrict__ gcur,
    const unsigned* __restrict__ bdst, const unsigned* __restrict__ bsrc,
    int* __restrict__ rp_dst, int* __restrict__ rp_src) {
  const int bi = blockIdx.x;
  const int b = bi & 7;
  const int dirsrc = (bi >> 3) & 1;
  const int blk = bi >> 4;
  if (!dirsrc) {
    const int cnt = gcur[b];
    const unsigned* p = bdst + b * BCAP;
    for (int i = blk * 256 + threadIdx.x; i < cnt; i += 32768)
      atomicAdd(&rp_dst[p[i] >> 16], 1);
  } else {
    const int cnt = gcur[8 + b];
    const unsigned* p = bsrc + b * BCAP;
    for (int i = blk * 256 + threadIdx.x; i < cnt; i += 32768)
      atomicAdd(&rp_src[p[i] & 0xFFFFu], 1);
  }
}

// ---------------------------------------------------------------------------
// place: bucketed cursors + col writes
// ---------------------------------------------------------------------------
__global__ __launch_bounds__(256) void place_kernel(
    const int* __restrict__ gcur,
    const unsigned* __restrict__ bdst, const unsigned* __restrict__ bsrc,
    int* __restrict__ rp_dst, int* __restrict__ rp_src,
    unsigned short* __restrict__ col_dst, unsigned short* __restrict__ col_src) {
  const int bi = blockIdx.x;
  const int b = bi & 7;
  const int dirsrc = (bi >> 3) & 1;
  const int blk = bi >> 4;
  if (!dirsrc) {
    const int cnt = gcur[b];
    const unsigned* p = bdst + b * BCAP;
    for (int i = blk * 256 + threadIdx.x; i < cnt; i += 32768) {
      const unsigned v = p[i];
      col_dst[atomicAdd(&rp_dst[v >> 16], 1)] = (unsigned short)(v & 0xFFFFu);
    }
  } else {
    const int cnt = gcur[8 + b];
    const unsigned* p = bsrc + b * BCAP;
    for (int i = blk * 256 + threadIdx.x; i < cnt; i += 32768) {
      const unsigned v = p[i];
      col_src[atomicAdd(&rp_src[v & 0xFFFFu], 1)] = (unsigned short)(v >> 16);
    }
  }
}

// ---------------------------------------------------------------------------
// Hierarchical coalesced exclusive scan (3 kernels). parts[arr*64 + c].
// ---------------------------------------------------------------------------
__global__ __launch_bounds__(256) void scanA_kernel(
    const int* __restrict__ a0, const int* __restrict__ a1,
    int* __restrict__ parts) {
  const int arr = blockIdx.x / NCH;
  const int c = blockIdx.x - arr * NCH;
  const int* a = arr ? a1 : a0;
  const int t = threadIdx.x;
  const int base = c * 1024 + t * 4;
  int s = 0;
  if (base < NN) {
    const int4 v = *(const int4*)(a + base);
    s = v.x + v.y + v.z + v.w;
  }
#pragma unroll
  for (int d = 32; d >= 1; d >>= 1) s += __shfl_xor(s, d);
  __shared__ int wsum[4];
  if ((t & 63) == 0) wsum[t >> 6] = s;
  __syncthreads();
  if (t == 0) parts[arr * 64 + c] = wsum[0] + wsum[1] + wsum[2] + wsum[3];
}

__global__ __launch_bounds__(64) void scanB_kernel(int* __restrict__ parts) {
  int* p = parts + blockIdx.x * 64;
  const int lane = threadIdx.x;
  int v = (lane < NCH) ? p[lane] : 0;
  int inc = v;
#pragma unroll
  for (int d = 1; d < 64; d <<= 1) {
    const int t = __shfl_up(inc, d);
    if (lane >= d) inc += t;
  }
  if (lane < NCH) p[lane] = inc - v;  // exclusive offset per chunk
}

__global__ __launch_bounds__(256) void scanC_kernel(
    int* __restrict__ a0, int* __restrict__ a1,
    const int* __restrict__ parts) {
  const int arr = blockIdx.x / NCH;
  const int c = blockIdx.x - arr * NCH;
  int* a = arr ? a1 : a0;
  const int t = threadIdx.x;
  const int lane = t & 63;
  const int w = t >> 6;
  const int base = c * 1024 + t * 4;
  int4 v = make_int4(0, 0, 0, 0);
  if (base < NN) v = *(const int4*)(a + base);
  const int s = v.x + v.y + v.z + v.w;
  int inc = s;
#pragma unroll
  for (int d = 1; d < 64; d <<= 1) {
    const int tv = __shfl_up(inc, d);
    if (lane >= d) inc += tv;
  }
  __shared__ int wsum[4];
  if (lane == 63) wsum[w] = inc;
  __syncthreads();
  int woff = 0;
#pragma unroll
  for (int i = 0; i < 4; ++i)
    if (i < w) woff += wsum[i];
  const int excl = parts[arr * 64 + c] + woff + inc - s;
  if (base < NN) {
    int4 o;
    o.x = excl;
    o.y = o.x + v.x;
    o.z = o.y + v.y;
    o.w = o.z + v.z;
    *(int4*)(a + base) = o;
  }
}

// ---------------------------------------------------------------------------
// pull-gather mean (u16 col), XCD-aligned node swizzle
// ---------------------------------------------------------------------------
__device__ __forceinline__ void gather_dev(
    const float* __restrict__ Y, const int* __restrict__ rowptr,
    const unsigned short* __restrict__ col, float* __restrict__ AGGf,
    unsigned short* __restrict__ aggh, unsigned short* __restrict__ aggl,
    int seg, int tid) {
  const int w = tid >> 6;
  const int lane = tid & 63;
  const int off = (seg >> 3) * 4 + w;
  if (off >= 6250) return;
  const int node = (seg & 7) * 6250 + off;
  const int eg = lane >> 4;
  const int cq = (lane & 15) << 2;
  const int start = (node == 0) ? 0 : rowptr[node - 1];
  const int end = rowptr[node];
  float4 acc = make_float4(0.f, 0.f, 0.f, 0.f);
  int e = start + eg;
  for (; e + 12 < end; e += 16) {
    const int j0 = col[e];
    const int j1 = col[e + 4];
    const int j2 = col[e + 8];
    const int j3 = col[e + 12];
    const float4 y0 = *(const float4*)(Y + j0 * 64 + cq);
    const float4 y1 = *(const float4*)(Y + j1 * 64 + cq);
    const float4 y2 = *(const float4*)(Y + j2 * 64 + cq);
    const float4 y3 = *(const float4*)(Y + j3 * 64 + cq);
    acc.x += y0.x + y1.x + y2.x + y3.x;
    acc.y += y0.y + y1.y + y2.y + y3.y;
    acc.z += y0.z + y1.z + y2.z + y3.z;
    acc.w += y0.w + y1.w + y2.w + y3.w;
  }
  for (; e < end; e += 4) {
    const float4 y = *(const float4*)(Y + col[e] * 64 + cq);
    acc.x += y.x; acc.y += y.y; acc.z += y.z; acc.w += y.w;
  }
  acc.x += __shfl_xor(acc.x, 16);
  acc.y += __shfl_xor(acc.y, 16);
  acc.z += __shfl_xor(acc.z, 16);
  acc.w += __shfl_xor(acc.w, 16);
  acc.x += __shfl_xor(acc.x, 32);
  acc.y += __shfl_xor(acc.y, 32);
  acc.z += __shfl_xor(acc.z, 32);
  acc.w += __shfl_xor(acc.w, 32);
  if (eg == 0) {
    const float inv = 1.f / (float)max(end - start, 1);
    float4 o;
    o.x = acc.x * inv; o.y = acc.y * inv;
    o.z = acc.z * inv; o.w = acc.w * inv;
    if (AGGf) {
      *(float4*)(AGGf + node * 64 + cq) = o;
    } else {
      ushort4 h, l;
      split4(o, h, l);
      *(ushort4*)(aggh + node * 64 + cq) = h;
      *(ushort4*)(aggl + node * 64 + cq) = l;
    }
  }
}

__global__ __launch_bounds__(256) void gather_kernel(
    const float* __restrict__ Y, const int* __restrict__ rowptr,
    const unsigned short* __restrict__ col, float* __restrict__ AGGf,
    unsigned short* __restrict__ aggh, unsigned short* __restrict__ aggl) {
  gather_dev(Y, rowptr, col, AGGf, aggh, aggl, blockIdx.x, threadIdx.x);
}

__global__ __launch_bounds__(256) void gather2_kernel(
    const float* __restrict__ Yu, const int* __restrict__ rp_dst,
    const unsigned short* __restrict__ col_dst,
    unsigned short* auh, unsigned short* aul,
    const float* __restrict__ Yd, const int* __restrict__ rp_src,
    const unsigned short* __restrict__ col_src,
    unsigned short* adh, unsigned short* adl) {
  if (blockIdx.x < GBS)
    gather_dev(Yu, rp_dst, col_dst, nullptr, auh, aul, blockIdx.x, threadIdx.x);
  else
    gather_dev(Yd, rp_src, col_src, nullptr, adh, adl, blockIdx.x - GBS,
               threadIdx.x);
}

// ===========================================================================
// Fallback path (vector-f32 GEMM + replicated edge pass) for small workspaces
// ===========================================================================
__global__ __launch_bounds__(256) void pack_kernel(
    const int* __restrict__ src, const int* __restrict__ dst,
    unsigned* __restrict__ epack) {
  for (int e = blockIdx.x * 256 + threadIdx.x; e < NE; e += 1024 * 256)
    epack[e] = (unsigned)src[e] | ((unsigned)dst[e] << 16);
}

__device__ __forceinline__ void place_dev4(
    const unsigned* __restrict__ epack,
    int* __restrict__ rp_dst, int* __restrict__ rp_src,
    unsigned short* __restrict__ col_dst, unsigned short* __restrict__ col_src,
    int bi, int tid) {
  const unsigned lo = (unsigned)(bi & 7) * 6250u;
  const int g = (bi >> 3) * 256 + tid;
  for (int e = g * 4; e < NE; e += 262144) {
    const uint4 v4 = *(const uint4*)(epack + e);
    const unsigned vs[4] = {v4.x, v4.y, v4.z, v4.w};
#pragma unroll
    for (int i = 0; i < 4; ++i) {
      const unsigned s = vs[i] & 0xFFFFu, d = vs[i] >> 16;
      if (d - lo < 6250u)
        col_dst[atomicAdd(&rp_dst[d], 1)] = (unsigned short)s;
      if (s - lo < 6250u)
        col_src[atomicAdd(&rp_src[s], 1)] = (unsigned short)d;
    }
  }
}

__global__ __launch_bounds__(256) void count_old_kernel(
    const unsigned* __restrict__ epack,
    int* __restrict__ rp_dst, int* __restrict__ rp_src) {
  const int bi = blockIdx.x;
  const unsigned lo = (unsigned)(bi & 7) * 6250u;
  const int g = (bi >> 3) * 256 + threadIdx.x;
  for (int e = g * 4; e < NE; e += 262144) {
    const uint4 v4 = *(const uint4*)(epack + e);
    const unsigned vs[4] = {v4.x, v4.y, v4.z, v4.w};
#pragma unroll
    for (int i = 0; i < 4; ++i) {
      const unsigned s = vs[i] & 0xFFFFu, d = vs[i] >> 16;
      if (d - lo < 6250u) atomicAdd(&rp_dst[d], 1);
      if (s - lo < 6250u) atomicAdd(&rp_src[s], 1);
    }
  }
}

#define CHUNK 49
__global__ __launch_bounds__(1024) void scan_kernel(
    int* __restrict__ a0, int* __restrict__ a1) {
  int* a = (blockIdx.x == 0) ? a0 : a1;
  __shared__ int part[1024];
  const int t = threadIdx.x;
  const int beg = t * CHUNK;
  const int end = min(beg + CHUNK, NN);
  int s = 0;
  for (int i = beg; i < end; ++i) s += a[i];
  part[t] = s;
  __syncthreads();
  for (int off = 1; off < 1024; off <<= 1) {
    int add = (t >= off) ? part[t - off] : 0;
    __syncthreads();
    part[t] += add;
    __syncthreads();
  }
  int run = (t == 0) ? 0 : part[t - 1];
  for (int i = beg; i < end; ++i) {
    const int c = a[i];
    a[i] = run;
    run += c;
  }
}

__device__ __forceinline__ void gemm64_dev(
    float (*Xt)[68], float* Ws, const float* __restrict__ X, int ldx,
    const float* __restrict__ AGG, const float* __restrict__ W,
    const float* __restrict__ b, float* __restrict__ out, int ldo,
    int colbase, int dup, int kchunks, int xchunks, int row0, int tid) {
  const int tx = tid & 15, ty = tid >> 4;
  float acc[4][4] = {{0.f}};
  for (int c = 0; c < kchunks; ++c) {
    {
      const int rr = tid >> 2;
      const int cg = (tid & 3) << 4;
      const float* srcp;
      int ld, co;
      if (c < xchunks) { srcp = X; ld = ldx; co = c * 64; }
      else             { srcp = AGG; ld = 64; co = 0; }
      int row = row0 + rr;
      if (row > NN - 1) row = NN - 1;
      const float* g = srcp + row * ld + co + cg;
      const float4 v0 = *(const float4*)(g + 0);
      const float4 v1 = *(const float4*)(g + 4);
      const float4 v2 = *(const float4*)(g + 8);
      const float4 v3 = *(const float4*)(g + 12);
      Xt[cg + 0][rr] = v0.x;  Xt[cg + 1][rr] = v0.y;
      Xt[cg + 2][rr] = v0.z;  Xt[cg + 3][rr] = v0.w;
      Xt[cg + 4][rr] = v1.x;  Xt[cg + 5][rr] = v1.y;
      Xt[cg + 6][rr] = v1.z;  Xt[cg + 7][rr] = v1.w;
      Xt[cg + 8][rr] = v2.x;  Xt[cg + 9][rr] = v2.y;
      Xt[cg + 10][rr] = v2.z; Xt[cg + 11][rr] = v2.w;
      Xt[cg + 12][rr] = v3.x; Xt[cg + 13][rr] = v3.y;
      Xt[cg + 14][rr] = v3.z; Xt[cg + 15][rr] = v3.w;
      const float4* wg = (const float4*)(W + c * 64 * 64);
      float4* wl = (float4*)Ws;
      wl[tid] = wg[tid];
      wl[tid + 256] = wg[tid + 256];
      wl[tid + 512] = wg[tid + 512];
      wl[tid + 768] = wg[tid + 768];
    }
    __syncthreads();
#pragma unroll 8
    for (int kk = 0; kk < 64; ++kk) {
      const float4 a = *(const float4*)&Xt[kk][tx << 2];
      const float4 w = *(const float4*)&Ws[kk * 64 + (ty << 2)];
      acc[0][0] += a.x * w.x; acc[0][1] += a.x * w.y;
      acc[0][2] += a.x * w.z; acc[0][3] += a.x * w.w;
      acc[1][0] += a.y * w.x; acc[1][1] += a.y * w.y;
      acc[1][2] += a.y * w.z; acc[1][3] += a.y * w.w;
      acc[2][0] += a.z * w.x; acc[2][1] += a.z * w.y;
      acc[2][2] += a.z * w.z; acc[2][3] += a.z * w.w;
      acc[3][0] += a.w * w.x; acc[3][1] += a.w * w.y;
      acc[3][2] += a.w * w.z; acc[3][3] += a.w * w.w;
    }
    __syncthreads();
  }
  float4 bv = make_float4(0.f, 0.f, 0.f, 0.f);
  if (b) bv = *(const float4*)(b + (ty << 2));
#pragma unroll
  for (int i = 0; i < 4; ++i) {
    const int row = row0 + (tx << 2) + i;
    if (row < NN) {
      float4 o;
      o.x = fmaxf(acc[i][0] + bv.x, 0.f);
      o.y = fmaxf(acc[i][1] + bv.y, 0.f);
      o.z = fmaxf(acc[i][2] + bv.z, 0.f);
      o.w = fmaxf(acc[i][3] + bv.w, 0.f);
      *(float4*)(out + row * ldo + colbase + (ty << 2)) = o;
      if (dup) *(float4*)(out + row * ldo + 64 + (ty << 2)) = o;
    }
  }
}

__global__ __launch_bounds__(256) void gemm_kernel(
    const float* __restrict__ X, int ldx, const float* __restrict__ AGG,
    const float* __restrict__ W, const float* __restrict__ b,
    float* __restrict__ out, int ldo, int colbase, int dup,
    int kchunks, int xchunks) {
  __shared__ __align__(16) float Xt[64][68];
  __shared__ __align__(16) float Ws[4096];
  gemm64_dev(Xt, Ws, X, ldx, AGG, W, b, out, ldo, colbase, dup, kchunks,
             xchunks, blockIdx.x * 64, threadIdx.x);
}

__global__ __launch_bounds__(256) void fused0_kernel(
    const unsigned* __restrict__ epack,
    int* __restrict__ rp_dst, int* __restrict__ rp_src,
    unsigned short* __restrict__ col_dst, unsigned short* __restrict__ col_src,
    const float* __restrict__ x,
    const float* __restrict__ W_u1, const float* __restrict__ b_u1,
    float* __restrict__ Y_u,
    const float* __restrict__ W_d1, const float* __restrict__ b_d1,
    float* __restrict__ Y_d) {
  __shared__ __align__(16) float Xt[64][68];
  __shared__ __align__(16) float Ws[4096];
  int bi = blockIdx.x;
  if (bi < NP) {
    place_dev4(epack, rp_dst, rp_src, col_dst, col_src, bi, threadIdx.x);
    return;
  }
  bi -= NP;
  if (bi < TB)
    gemm64_dev(Xt, Ws, x, 128, nullptr, W_u1, b_u1, Y_u, 64, 0, 0, 2, 2,
               bi * 64, threadIdx.x);
  else
    gemm64_dev(Xt, Ws, x, 128, nullptr, W_d1, b_d1, Y_d, 64, 0, 0, 2, 2,
               (bi - TB) * 64, threadIdx.x);
}

// ===========================================================================
extern "C" void kernel_launch(void* const* d_in, const int* in_sizes, int n_in,
                              void* d_out, int out_size, void* d_ws, size_t ws_size,
                              hipStream_t stream) {
  const float* x    = (const float*)d_in[0];
  const int*   ei   = (const int*)d_in[1];
  const float* W_u1 = (const float*)d_in[2];
  const float* b_u1 = (const float*)d_in[3];
  const float* U_u1 = (const float*)d_in[4];
  const float* W_d1 = (const float*)d_in[5];
  const float* b_d1 = (const float*)d_in[6];
  const float* U_d1 = (const float*)d_in[7];
  const float* W_u2 = (const float*)d_in[8];
  const float* b_u2 = (const float*)d_in[9];
  const float* U_u2 = (const float*)d_in[10];
  const int* src = ei;
  const int* dst = ei + NE;
  float* out = (float*)d_out;

  char* wsb = (char*)d_ws;
  int* rp_dst  = (int*)wsb;              wsb += NN * sizeof(int);
  int* rp_src  = (int*)wsb;              wsb += NN * sizeof(int);
  int* gcur    = (int*)wsb;              wsb += 32 * sizeof(int);
  int* parts   = (int*)wsb;              wsb += 128 * sizeof(int);
  unsigned short* col_dst = (unsigned short*)wsb; wsb += (size_t)NE * 2;
  unsigned short* col_src = (unsigned short*)wsb; wsb += (size_t)NE * 2;

  const size_t needM = (size_t)2 * NN * 4 + 640 + (size_t)NE * 4 +
                       (size_t)WBUF_USHORTS * 2 +
                       (size_t)NN * 64 * 4 * 2 +    // Yu, Yd (f32)
                       (size_t)NN * 64 * 2 * 4 +    // 4 agg bf16 planes
                       (size_t)NN * 64 * 2 * 2;     // O2h, O2l

  // zero rowptr counters + bucket cursors in one memset
  hipMemsetAsync(rp_dst, 0, 2 * NN * sizeof(int) + 32 * sizeof(int), stream);

  if (ws_size >= needM) {
    unsigned short* wbuf = (unsigned short*)wsb; wsb += (size_t)WBUF_USHORTS * 2;
    float* Yu = (float*)wsb;                     wsb += (size_t)NN * 64 * 4;
    float* Yd = (float*)wsb;                     wsb += (size_t)NN * 64 * 4;
    unsigned short* agg_uh = (unsigned short*)wsb; wsb += (size_t)NN * 64 * 2;
    unsigned short* agg_ul = (unsigned short*)wsb; wsb += (size_t)NN * 64 * 2;
    unsigned short* agg_dh = (unsigned short*)wsb; wsb += (size_t)NN * 64 * 2;
    unsigned short* agg_dl = (unsigned short*)wsb; wsb += (size_t)NN * 64 * 2;
    unsigned short* O2h = (unsigned short*)wsb;    wsb += (size_t)NN * 64 * 2;
    unsigned short* O2l = (unsigned short*)wsb;

    // bucket arrays alias agg planes (dead until gather2; place ends before)
    unsigned* bdst = (unsigned*)agg_uh;   // 8*BCAP*4 = 3.31MB <= 6.4MB
    unsigned* bsrc = (unsigned*)agg_ul;

    // other aliases (sequential lifetime reuse)
    unsigned short* outh = (unsigned short*)Yu;  // [N][128] bf16 hi
    unsigned short* outl = (unsigned short*)Yd;  // [N][128] bf16 lo
    float* Y2 = (float*)agg_uh;                  // [N][64] f32 (spans uh+ul)
    unsigned short* agg2h = agg_dh;
    unsigned short* agg2l = agg_dl;

    const unsigned short* U1uh = wbuf + WOFF_U1U;
    const unsigned short* U1ul = wbuf + WOFF_U1U + 64 * 192;
    const unsigned short* U1dh = wbuf + WOFF_U1D;
    const unsigned short* U1dl = wbuf + WOFF_U1D + 64 * 192;
    const unsigned short* W1uh = wbuf + WOFF_W1U;
    const unsigned short* W1ul = wbuf + WOFF_W1U + 64 * 128;
    const unsigned short* W1dh = wbuf + WOFF_W1D;
    const unsigned short* W1dl = wbuf + WOFF_W1D + 64 * 128;
    const unsigned short* W2uh = wbuf + WOFF_W2U;
    const unsigned short* W2ul = wbuf + WOFF_W2U + 64 * 128;
    const unsigned short* U2uh = wbuf + WOFF_U2U;
    const unsigned short* U2ul = wbuf + WOFF_U2U + 64 * 192;
    const unsigned short* Wsh  = wbuf + WOFF_WSUM;
    const unsigned short* Wsl  = wbuf + WOFF_WSUM + 64 * 64;
    const unsigned short* Ush  = wbuf + WOFF_USUM;
    const unsigned short* Usl  = wbuf + WOFF_USUM + 64 * 128;

    // bucket counting-sort || weight conversion
    prep_kernel<<<BBK + 32, 256, 0, stream>>>(
        src, dst, gcur, bdst, bsrc, U_u1, U_d1, W_u1, W_d1, W_u2, U_u2, wbuf);
    // bucketed count (LDS-free) -- separate for attribution
    count_b_kernel<<<NP, 256, 0, stream>>>(gcur, bdst, bsrc, rp_dst, rp_src);
    // layer-1 transforms (attribution: own dispatch row)
    trans2_kernel<<<TB, 256, 0, stream>>>(x, W1uh, W1ul, W1dh, W1dl,
                                          b_u1, b_d1, Yu, Yd);
    // hierarchical coalesced exclusive scan of both rowptr arrays
    scanA_kernel<<<2 * NCH, 256, 0, stream>>>(rp_dst, rp_src, parts);
    scanB_kernel<<<2, 64, 0, stream>>>(parts);
    scanC_kernel<<<2 * NCH, 256, 0, stream>>>(rp_dst, rp_src, parts);
    // bucketed placement
    place_kernel<<<NP, 256, 0, stream>>>(gcur, bdst, bsrc, rp_dst, rp_src,
                                         col_dst, col_src);
    // layer 1
    gather2_kernel<<<2 * GBS, 256, 0, stream>>>(Yu, rp_dst, col_dst, agg_uh,
                                                agg_ul, Yd, rp_src, col_src,
                                                agg_dh, agg_dl);
    update2m_kernel<<<2 * TB, 256, 0, stream>>>(x, agg_uh, agg_ul, agg_dh,
                                                agg_dl, U1uh, U1ul, U1dh,
                                                U1dl, outh, outl);
    // round 2
    mgemm_kernel<<<TB, 256, 0, stream>>>(outh, outl, 128, nullptr, nullptr,
                                         W2uh, W2ul, 128, b_u2, Y2, nullptr,
                                         nullptr, 64, 0, 0, 2, 2);
    gather_kernel<<<GBS, 256, 0, stream>>>(Y2, rp_dst, col_dst, nullptr,
                                           agg2h, agg2l);
    mgemm_kernel<<<TB, 256, 0, stream>>>(outh, outl, 128, agg2h, agg2l,
                                         U2uh, U2ul, 192, nullptr, nullptr,
                                         O2h, O2l, 64, 0, 0, 3, 2);
    // round 3 (h = [O2,O2] folded into presummed weights)
    mgemm_kernel<<<TB, 256, 0, stream>>>(O2h, O2l, 64, nullptr, nullptr,
                                         Wsh, Wsl, 64, b_u2, Y2, nullptr,
                                         nullptr, 64, 0, 0, 1, 1);
    gather_kernel<<<GBS, 256, 0, stream>>>(Y2, rp_dst, col_dst, nullptr,
                                           agg2h, agg2l);
    mgemm_kernel<<<TB, 256, 0, stream>>>(O2h, O2l, 64, agg2h, agg2l,
                                         Ush, Usl, 128, nullptr, out,
                                         nullptr, nullptr, 128, 0, 1, 2, 1);
  } else {
    // fallback: vector-f32 path with replicated edge passes
    unsigned* epack = (unsigned*)wsb; wsb += (size_t)NE * 4;
    float* Y_u = (float*)wsb; wsb += (size_t)NN * 64 * sizeof(float);
    float* Y_d = (float*)wsb; wsb += (size_t)NN * 64 * sizeof(float);
    float* AGG = (float*)wsb;
    pack_kernel<<<1024, 256, 0, stream>>>(src, dst, epack);
    count_old_kernel<<<NP, 256, 0, stream>>>(epack, rp_dst, rp_src);
    scan_kernel<<<2, 1024, 0, stream>>>(rp_dst, rp_src);
    fused0_kernel<<<NP + 2 * TB, 256, 0, stream>>>(
        epack, rp_dst, rp_src, col_dst, col_src, x, W_u1, b_u1, Y_u, W_d1,
        b_d1, Y_d);
    gather_kernel<<<GBS, 256, 0, stream>>>(Y_u, rp_dst, col_dst, AGG,
                                           nullptr, nullptr);
    gemm_kernel<<<TB, 256, 0, stream>>>(x, 128, AGG, U_u1, nullptr, out,
                                        128, 0, 0, 3, 2);
    gather_kernel<<<GBS, 256, 0, stream>>>(Y_d, rp_src, col_src, AGG,
                                           nullptr, nullptr);
    gemm_kernel<<<TB, 256, 0, stream>>>(x, 128, AGG, U_d1, nullptr, out,
                                        128, 64, 0, 3, 2);
    for (int r = 0; r < 2; ++r) {
      gemm_kernel<<<TB, 256, 0, stream>>>(out, 128, nullptr, W_u2, b_u2,
                                          Y_u, 64, 0, 0, 2, 2);
      gather_kernel<<<GBS, 256, 0, stream>>>(Y_u, rp_dst, col_dst, AGG,
                                             nullptr, nullptr);
      gemm_kernel<<<TB, 256, 0, stream>>>(out, 128, AGG, U_u2, nullptr,
                                          out, 128, 0, 1, 3, 2);
    }
  }
}

// Round 11
// 304.766 us; speedup vs baseline: 1.3199x; 1.1035x over previous
//
#include <hip/hip_runtime.h>

#define NN 50000
#define NE 800000
#define TB 782             // ceil(NN/64) gemm row-tile blocks
#define GBS 12504          // 8 * 1563 swizzled gather blocks (4 nodes each)
#define BCAP 103424        // per-bucket capacity
#define BBK 391            // bucket blocks = ceil(NE/2048)
#define CHKE 2048          // edges per bucket block
#define NCH 49             // scan chunks = ceil(NN/1024)
#define NSUB 8             // node-subranges per bucket
#define SUBN 782           // ceil(6250/8)
#define CB2 128            // count2/place2 blocks = 2 dirs * 8 buckets * NSUB

typedef __attribute__((ext_vector_type(8))) short bhalf8;
typedef __attribute__((ext_vector_type(4))) float floatx4;

// weight buffer offsets (ushort units); l plane = h + 64*K
#define WOFF_U1U 0
#define WOFF_U1D 24576
#define WOFF_W1U 49152
#define WOFF_W1D 65536
#define WOFF_W2U 81920
#define WOFF_U2U 98304
#define WOFF_WSUM 122880
#define WOFF_USUM 131072
#define WBUF_USHORTS 147456

// ---------------------------------------------------------------------------
// bf16 split helpers (RNE)
// ---------------------------------------------------------------------------
__device__ __forceinline__ unsigned short bf16hi(float v) {
  union { float f; unsigned u; } c; c.f = v;
  return (unsigned short)((c.u + 0x7FFFu + ((c.u >> 16) & 1u)) >> 16);
}
__device__ __forceinline__ float bf16tof(unsigned short h) {
  union { unsigned u; float f; } c; c.u = ((unsigned)h) << 16;
  return c.f;
}
__device__ __forceinline__ void split1(float v, unsigned short& h,
                                       unsigned short& l) {
  h = bf16hi(v);
  l = bf16hi(v - bf16tof(h));
}
__device__ __forceinline__ void split4(const float4 v, ushort4& h, ushort4& l) {
  split1(v.x, h.x, l.x);
  split1(v.y, h.y, l.y);
  split1(v.z, h.z, l.z);
  split1(v.w, h.w, l.w);
}
__device__ __forceinline__ void split8(const float4 v0, const float4 v1,
                                       uint4& H, uint4& L) {
  unsigned short h0, l0, h1, l1;
  split1(v0.x, h0, l0); split1(v0.y, h1, l1);
  H.x = (unsigned)h0 | ((unsigned)h1 << 16);
  L.x = (unsigned)l0 | ((unsigned)l1 << 16);
  split1(v0.z, h0, l0); split1(v0.w, h1, l1);
  H.y = (unsigned)h0 | ((unsigned)h1 << 16);
  L.y = (unsigned)l0 | ((unsigned)l1 << 16);
  split1(v1.x, h0, l0); split1(v1.y, h1, l1);
  H.z = (unsigned)h0 | ((unsigned)h1 << 16);
  L.z = (unsigned)l0 | ((unsigned)l1 << 16);
  split1(v1.z, h0, l0); split1(v1.w, h1, l1);
  H.w = (unsigned)h0 | ((unsigned)h1 << 16);
  L.w = (unsigned)l0 | ((unsigned)l1 << 16);
}

// swizzled LDS byte address for bf16 tile [64 rows][64 k] (128B rows)
#define SWZ(row, inrow) (((row) << 7) + ((inrow) ^ (((row)&7) << 4)))

// ---------------------------------------------------------------------------
// MFMA split-bf16 GEMM (single B): out = relu([A|G] @ B^T (+bias))
// ---------------------------------------------------------------------------
template <bool AF32>
__device__ __forceinline__ void mfma_gemm_dev(
    unsigned short* tAh, unsigned short* tAl,
    unsigned short* tBh, unsigned short* tBl,
    const unsigned short* __restrict__ Ah, const unsigned short* __restrict__ Al,
    int lda,
    const unsigned short* __restrict__ Gh, const unsigned short* __restrict__ Gl,
    const unsigned short* __restrict__ Bh, const unsigned short* __restrict__ Bl,
    int ldb, const float* __restrict__ bias,
    float* __restrict__ outF, unsigned short* __restrict__ outH,
    unsigned short* __restrict__ outL,
    int ldo, int colbase, int dup, int kchunks, int xchunks,
    int row0, int tid) {
  const int lane = tid & 63;
  const int wm = tid >> 6;
  const int m = lane & 15;
  const int kg = lane >> 4;
  floatx4 acc[4];
#pragma unroll
  for (int i = 0; i < 4; ++i) acc[i] = (floatx4){0.f, 0.f, 0.f, 0.f};

  for (int c = 0; c < kchunks; ++c) {
#pragma unroll
    for (int q = tid; q < 512; q += 256) {
      const int row = q >> 3, slot = q & 7;
      int gr = row0 + row;
      gr = (gr > NN - 1) ? NN - 1 : gr;
      const int ad = SWZ(row, slot << 4);
      if (AF32 && c < xchunks) {
        const float* f = (const float*)Ah;
        const size_t go = (size_t)gr * lda + (c << 6) + slot * 8;
        const float4 v0 = *(const float4*)(f + go);
        const float4 v1 = *(const float4*)(f + go + 4);
        uint4 H, L;
        split8(v0, v1, H, L);
        *(uint4*)((char*)tAh + ad) = H;
        *(uint4*)((char*)tAl + ad) = L;
      } else {
        const unsigned short* sh;
        const unsigned short* sl;
        int ld, kc;
        if (c < xchunks) { sh = Ah; sl = Al; ld = lda; kc = c << 6; }
        else             { sh = Gh; sl = Gl; ld = 64;  kc = 0; }
        const size_t go = (size_t)gr * ld + kc + slot * 8;
        *(uint4*)((char*)tAh + ad) = *(const uint4*)(sh + go);
        *(uint4*)((char*)tAl + ad) = *(const uint4*)(sl + go);
      }
      const size_t gob = (size_t)row * ldb + (c << 6) + slot * 8;
      *(uint4*)((char*)tBh + ad) = *(const uint4*)(Bh + gob);
      *(uint4*)((char*)tBl + ad) = *(const uint4*)(Bl + gob);
    }
    __syncthreads();
#pragma unroll
    for (int ks = 0; ks < 2; ++ks) {
      const int inrow = (ks << 6) + (kg << 4);
      const int rA = (wm << 4) + m;
      const bhalf8 ah = *(const bhalf8*)((const char*)tAh + SWZ(rA, inrow));
      const bhalf8 al = *(const bhalf8*)((const char*)tAl + SWZ(rA, inrow));
#pragma unroll
      for (int nt = 0; nt < 4; ++nt) {
        const int rB = (nt << 4) + m;
        const bhalf8 bh = *(const bhalf8*)((const char*)tBh + SWZ(rB, inrow));
        const bhalf8 bl = *(const bhalf8*)((const char*)tBl + SWZ(rB, inrow));
        acc[nt] = __builtin_amdgcn_mfma_f32_16x16x32_bf16(ah, bh, acc[nt], 0, 0, 0);
        acc[nt] = __builtin_amdgcn_mfma_f32_16x16x32_bf16(ah, bl, acc[nt], 0, 0, 0);
        acc[nt] = __builtin_amdgcn_mfma_f32_16x16x32_bf16(al, bh, acc[nt], 0, 0, 0);
      }
    }
    __syncthreads();
  }
#pragma unroll
  for (int nt = 0; nt < 4; ++nt) {
    const int col = colbase + (nt << 4) + m;
    const float bv = bias ? bias[(nt << 4) + m] : 0.f;
#pragma unroll
    for (int r = 0; r < 4; ++r) {
      const int row = row0 + (wm << 4) + (kg << 2) + r;
      if (row < NN) {
        const float v = fmaxf(acc[nt][r] + bv, 0.f);
        if (outF) {
          outF[(size_t)row * ldo + col] = v;
          if (dup) outF[(size_t)row * ldo + col + 64] = v;
        }
        if (outH) {
          unsigned short h, l;
          split1(v, h, l);
          outH[(size_t)row * ldo + col] = h;
          outL[(size_t)row * ldo + col] = l;
        }
      }
    }
  }
}

// ---------------------------------------------------------------------------
// Dual-output transform, 4-tile (32KB)
// ---------------------------------------------------------------------------
__device__ __forceinline__ void trans2_dev(
    unsigned short* tAh, unsigned short* tAl,
    unsigned short* tBh, unsigned short* tBl,
    const float* __restrict__ x,
    const unsigned short* __restrict__ Wuh, const unsigned short* __restrict__ Wul,
    const unsigned short* __restrict__ Wdh, const unsigned short* __restrict__ Wdl,
    const float* __restrict__ bu, const float* __restrict__ bd,
    float* __restrict__ Yu, float* __restrict__ Yd, int row0, int tid) {
  const int lane = tid & 63;
  const int wm = tid >> 6;
  const int m = lane & 15;
  const int kg = lane >> 4;
  floatx4 accU[4], accD[4];
#pragma unroll
  for (int i = 0; i < 4; ++i) {
    accU[i] = (floatx4){0.f, 0.f, 0.f, 0.f};
    accD[i] = (floatx4){0.f, 0.f, 0.f, 0.f};
  }
  for (int c = 0; c < 2; ++c) {
#pragma unroll
    for (int q = tid; q < 512; q += 256) {
      const int row = q >> 3, slot = q & 7;
      int gr = row0 + row;
      gr = (gr > NN - 1) ? NN - 1 : gr;
      const int ad = SWZ(row, slot << 4);
      const size_t go = (size_t)gr * 128 + (c << 6) + slot * 8;
      const float4 v0 = *(const float4*)(x + go);
      const float4 v1 = *(const float4*)(x + go + 4);
      uint4 H, L;
      split8(v0, v1, H, L);
      *(uint4*)((char*)tAh + ad) = H;
      *(uint4*)((char*)tAl + ad) = L;
      const size_t gob = (size_t)row * 128 + (c << 6) + slot * 8;
      *(uint4*)((char*)tBh + ad) = *(const uint4*)(Wuh + gob);
      *(uint4*)((char*)tBl + ad) = *(const uint4*)(Wul + gob);
    }
    __syncthreads();
#pragma unroll
    for (int ks = 0; ks < 2; ++ks) {
      const int inrow = (ks << 6) + (kg << 4);
      const int rA = (wm << 4) + m;
      const bhalf8 ah = *(const bhalf8*)((const char*)tAh + SWZ(rA, inrow));
      const bhalf8 al = *(const bhalf8*)((const char*)tAl + SWZ(rA, inrow));
#pragma unroll
      for (int nt = 0; nt < 4; ++nt) {
        const int rB = (nt << 4) + m;
        const int adB = SWZ(rB, inrow);
        const bhalf8 bh = *(const bhalf8*)((const char*)tBh + adB);
        const bhalf8 bl = *(const bhalf8*)((const char*)tBl + adB);
        accU[nt] = __builtin_amdgcn_mfma_f32_16x16x32_bf16(ah, bh, accU[nt], 0, 0, 0);
        accU[nt] = __builtin_amdgcn_mfma_f32_16x16x32_bf16(ah, bl, accU[nt], 0, 0, 0);
        accU[nt] = __builtin_amdgcn_mfma_f32_16x16x32_bf16(al, bh, accU[nt], 0, 0, 0);
      }
    }
    __syncthreads();
#pragma unroll
    for (int q = tid; q < 512; q += 256) {
      const int row = q >> 3, slot = q & 7;
      const int ad = SWZ(row, slot << 4);
      const size_t gob = (size_t)row * 128 + (c << 6) + slot * 8;
      *(uint4*)((char*)tBh + ad) = *(const uint4*)(Wdh + gob);
      *(uint4*)((char*)tBl + ad) = *(const uint4*)(Wdl + gob);
    }
    __syncthreads();
#pragma unroll
    for (int ks = 0; ks < 2; ++ks) {
      const int inrow = (ks << 6) + (kg << 4);
      const int rA = (wm << 4) + m;
      const bhalf8 ah = *(const bhalf8*)((const char*)tAh + SWZ(rA, inrow));
      const bhalf8 al = *(const bhalf8*)((const char*)tAl + SWZ(rA, inrow));
#pragma unroll
      for (int nt = 0; nt < 4; ++nt) {
        const int rB = (nt << 4) + m;
        const int adB = SWZ(rB, inrow);
        const bhalf8 bh = *(const bhalf8*)((const char*)tBh + adB);
        const bhalf8 bl = *(const bhalf8*)((const char*)tBl + adB);
        accD[nt] = __builtin_amdgcn_mfma_f32_16x16x32_bf16(ah, bh, accD[nt], 0, 0, 0);
        accD[nt] = __builtin_amdgcn_mfma_f32_16x16x32_bf16(ah, bl, accD[nt], 0, 0, 0);
        accD[nt] = __builtin_amdgcn_mfma_f32_16x16x32_bf16(al, bh, accD[nt], 0, 0, 0);
      }
    }
    __syncthreads();
  }
#pragma unroll
  for (int nt = 0; nt < 4; ++nt) {
    const int col = (nt << 4) + m;
    const float bvu = bu[col];
    const float bvd = bd[col];
#pragma unroll
    for (int r = 0; r < 4; ++r) {
      const int row = row0 + (wm << 4) + (kg << 2) + r;
      if (row < NN) {
        Yu[(size_t)row * 64 + col] = fmaxf(accU[nt][r] + bvu, 0.f);
        Yd[(size_t)row * 64 + col] = fmaxf(accD[nt][r] + bvd, 0.f);
      }
    }
  }
}

__global__ __launch_bounds__(256) void trans2_kernel(
    const float* __restrict__ x,
    const unsigned short* W1uh, const unsigned short* W1ul,
    const unsigned short* W1dh, const unsigned short* W1dl,
    const float* __restrict__ b_u1, const float* __restrict__ b_d1,
    float* __restrict__ Yu, float* __restrict__ Yd) {
  __shared__ unsigned short tiles[4][4096];
  trans2_dev(tiles[0], tiles[1], tiles[2], tiles[3], x, W1uh, W1ul, W1dh,
             W1dl, b_u1, b_d1, Yu, Yd, blockIdx.x * 64, threadIdx.x);
}

__global__ __launch_bounds__(256) void mgemm_kernel(
    const unsigned short* Ah, const unsigned short* Al, int lda,
    const unsigned short* Gh, const unsigned short* Gl,
    const unsigned short* Bh, const unsigned short* Bl, int ldb,
    const float* bias, float* outF, unsigned short* outH, unsigned short* outL,
    int ldo, int colbase, int dup, int kchunks, int xchunks) {
  __shared__ unsigned short tiles[4][4096];
  mfma_gemm_dev<false>(tiles[0], tiles[1], tiles[2], tiles[3], Ah, Al, lda,
                       Gh, Gl, Bh, Bl, ldb, bias, outF, outH, outL, ldo,
                       colbase, dup, kchunks, xchunks, blockIdx.x * 64,
                       threadIdx.x);
}

// both layer-1 updates in one launch; A = f32 x (inline split)
__global__ __launch_bounds__(256) void update2m_kernel(
    const float* __restrict__ x,
    const unsigned short* auh, const unsigned short* aul,
    const unsigned short* adh, const unsigned short* adl,
    const unsigned short* U1uh, const unsigned short* U1ul,
    const unsigned short* U1dh, const unsigned short* U1dl,
    unsigned short* outH, unsigned short* outL) {
  __shared__ unsigned short tiles[4][4096];
  if (blockIdx.x < TB)
    mfma_gemm_dev<true>(tiles[0], tiles[1], tiles[2], tiles[3],
                        (const unsigned short*)x, nullptr, 128, auh, aul,
                        U1uh, U1ul, 192, nullptr, nullptr, outH, outL, 128,
                        0, 0, 3, 2, blockIdx.x * 64, threadIdx.x);
  else
    mfma_gemm_dev<true>(tiles[0], tiles[1], tiles[2], tiles[3],
                        (const unsigned short*)x, nullptr, 128, adh, adl,
                        U1dh, U1dl, 192, nullptr, nullptr, outH, outL, 128,
                        64, 0, 3, 2, (blockIdx.x - TB) * 64, threadIdx.x);
}

// ---------------------------------------------------------------------------
// prep: bucket counting-sort (blocks [0,BBK)) || weight conversion (32 blocks)
// ---------------------------------------------------------------------------
__global__ __launch_bounds__(256) void prep_kernel(
    const int* __restrict__ src, const int* __restrict__ dst,
    int* __restrict__ gcur,
    unsigned* __restrict__ bdst, unsigned* __restrict__ bsrc,
    const float* __restrict__ U_u1, const float* __restrict__ U_d1,
    const float* __restrict__ W_u1, const float* __restrict__ W_d1,
    const float* __restrict__ W_u2, const float* __restrict__ U_u2,
    unsigned short* __restrict__ wbuf) {
  int bi = blockIdx.x;
  const int t = threadIdx.x;
  if (bi < BBK) {
    __shared__ int hist[16];
    __shared__ int base[16];
    __shared__ int cur[16];
    const int chunk = bi * CHKE;
    if (t < 16) { hist[t] = 0; cur[t] = 0; }
    __syncthreads();
    unsigned ev[8];
    int bd[8], bs[8];
    bool ok[8];
#pragma unroll
    for (int i = 0; i < 8; ++i) {
      const int e = chunk + i * 256 + t;
      ok[i] = e < NE;
      bd[i] = 0; bs[i] = 0; ev[i] = 0;
      if (ok[i]) {
        const unsigned s = (unsigned)src[e], d = (unsigned)dst[e];
        ev[i] = s | (d << 16);
        bd[i] = (int)(d / 6250u);
        bs[i] = (int)(s / 6250u);
        atomicAdd(&hist[bd[i]], 1);
        atomicAdd(&hist[8 + bs[i]], 1);
      }
    }
    __syncthreads();
    if (t < 16) base[t] = atomicAdd(&gcur[t], hist[t]);
    __syncthreads();
#pragma unroll
    for (int i = 0; i < 8; ++i) {
      if (ok[i]) {
        const int r1 = atomicAdd(&cur[bd[i]], 1);
        bdst[bd[i] * BCAP + base[bd[i]] + r1] = ev[i];
        const int r2 = atomicAdd(&cur[8 + bs[i]], 1);
        bsrc[bs[i] * BCAP + base[8 + bs[i]] + r2] = ev[i];
      }
    }
    return;
  }
  bi -= BBK;
  const int widx = bi >> 2;
  const int quad = bi & 3;
  const int Ks[8] = {192, 192, 128, 128, 128, 192, 64, 128};
  const int offs[8] = {WOFF_U1U, WOFF_U1D, WOFF_W1U, WOFF_W1D,
                       WOFF_W2U, WOFF_U2U, WOFF_WSUM, WOFF_USUM};
  const float* srcs[6] = {U_u1, U_d1, W_u1, W_d1, W_u2, U_u2};
  const int K = Ks[widx];
  const int off = offs[widx];
  const int qsz = K << 4;
  const int beg = quad * qsz;
  for (int e = beg + t; e < beg + qsz; e += 256) {
    const int cc = e / K;
    const int kk = e - cc * K;
    float v;
    if (widx < 6) v = srcs[widx][kk * 64 + cc];
    else if (widx == 6) v = W_u2[kk * 64 + cc] + W_u2[(kk + 64) * 64 + cc];
    else v = (kk < 64) ? (U_u2[kk * 64 + cc] + U_u2[(kk + 64) * 64 + cc])
                       : U_u2[(kk + 64) * 64 + cc];
    unsigned short h, l;
    split1(v, h, l);
    wbuf[off + cc * K + kk] = h;
    wbuf[off + (K << 6) + cc * K + kk] = l;
  }
}

// ---------------------------------------------------------------------------
// count2: per-subrange LDS histogram, NO global atomics (plain stores).
// block (dir, sub, b): b = bi&7 (XCD-local bucket), sub = (bi>>3)&7, dir=bi>>6
// ---------------------------------------------------------------------------
__global__ __launch_bounds__(256) void count2_kernel(
    const int* __restrict__ gcur,
    const unsigned* __restrict__ bdst, const unsigned* __restrict__ bsrc,
    int* __restrict__ rp_dst, int* __restrict__ rp_src) {
  const int bi = blockIdx.x;
  const int b = bi & 7;
  const int sub = (bi >> 3) & 7;
  const int dir = bi >> 6;
  const unsigned lo = (unsigned)(b * 6250 + sub * SUBN);
  const unsigned subn = (unsigned)min(SUBN, 6250 - sub * SUBN);
  __shared__ int hist[SUBN];
  const int t = threadIdx.x;
  for (int j = t; j < (int)subn; j += 256) hist[j] = 0;
  __syncthreads();
  const int cnt = gcur[dir * 8 + b];
  const unsigned* p = (dir ? bsrc : bdst) + b * BCAP;
  const int cnt4 = cnt & ~3;
  for (int i = t * 4; i < cnt4; i += 1024) {
    const uint4 v = *(const uint4*)(p + i);
    const unsigned n0 = dir ? (v.x & 0xFFFFu) : (v.x >> 16);
    const unsigned n1 = dir ? (v.y & 0xFFFFu) : (v.y >> 16);
    const unsigned n2 = dir ? (v.z & 0xFFFFu) : (v.z >> 16);
    const unsigned n3 = dir ? (v.w & 0xFFFFu) : (v.w >> 16);
    if (n0 - lo < subn) atomicAdd(&hist[n0 - lo], 1);
    if (n1 - lo < subn) atomicAdd(&hist[n1 - lo], 1);
    if (n2 - lo < subn) atomicAdd(&hist[n2 - lo], 1);
    if (n3 - lo < subn) atomicAdd(&hist[n3 - lo], 1);
  }
  for (int i = cnt4 + t; i < cnt; i += 256) {
    const unsigned v = p[i];
    const unsigned n = dir ? (v & 0xFFFFu) : (v >> 16);
    if (n - lo < subn) atomicAdd(&hist[n - lo], 1);
  }
  __syncthreads();
  int* rp = dir ? rp_src : rp_dst;
  for (int j = t; j < (int)subn; j += 256) rp[lo + j] = hist[j];
}

// ---------------------------------------------------------------------------
// place2: LDS cursors seeded from exclusive rp; col writes block-local;
// final cursors stored back (rp becomes inclusive ends). No global atomics.
// ---------------------------------------------------------------------------
__global__ __launch_bounds__(256) void place2_kernel(
    const int* __restrict__ gcur,
    const unsigned* __restrict__ bdst, const unsigned* __restrict__ bsrc,
    int* __restrict__ rp_dst, int* __restrict__ rp_src,
    unsigned short* __restrict__ col_dst, unsigned short* __restrict__ col_src) {
  const int bi = blockIdx.x;
  const int b = bi & 7;
  const int sub = (bi >> 3) & 7;
  const int dir = bi >> 6;
  const unsigned lo = (unsigned)(b * 6250 + sub * SUBN);
  const unsigned subn = (unsigned)min(SUBN, 6250 - sub * SUBN);
  __shared__ int cur[SUBN];
  const int t = threadIdx.x;
  int* rp = dir ? rp_src : rp_dst;
  unsigned short* col = dir ? col_src : col_dst;
  for (int j = t; j < (int)subn; j += 256) cur[j] = rp[lo + j];
  __syncthreads();
  const int cnt = gcur[dir * 8 + b];
  const unsigned* p = (dir ? bsrc : bdst) + b * BCAP;
  const int cnt4 = cnt & ~3;
  for (int i = t * 4; i < cnt4; i += 1024) {
    const uint4 v = *(const uint4*)(p + i);
    const unsigned vs[4] = {v.x, v.y, v.z, v.w};
#pragma unroll
    for (int k = 0; k < 4; ++k) {
      const unsigned n = dir ? (vs[k] & 0xFFFFu) : (vs[k] >> 16);
      const unsigned q = dir ? (vs[k] >> 16) : (vs[k] & 0xFFFFu);
      if (n - lo < subn) {
        const int idx = atomicAdd(&cur[n - lo], 1);
        col[idx] = (unsigned short)q;
      }
    }
  }
  for (int i = cnt4 + t; i < cnt; i += 256) {
    const unsigned v = p[i];
    const unsigned n = dir ? (v & 0xFFFFu) : (v >> 16);
    const unsigned q = dir ? (v >> 16) : (v & 0xFFFFu);
    if (n - lo < subn) {
      const int idx = atomicAdd(&cur[n - lo], 1);
      col[idx] = (unsigned short)q;
    }
  }
  __syncthreads();
  for (int j = t; j < (int)subn; j += 256) rp[lo + j] = cur[j];
}

// ---------------------------------------------------------------------------
// Hierarchical coalesced exclusive scan (3 kernels). parts[arr*64 + c].
// ---------------------------------------------------------------------------
__global__ __launch_bounds__(256) void scanA_kernel(
    const int* __restrict__ a0, const int* __restrict__ a1,
    int* __restrict__ parts) {
  const int arr = blockIdx.x / NCH;
  const int c = blockIdx.x - arr * NCH;
  const int* a = arr ? a1 : a0;
  const int t = threadIdx.x;
  const int base = c * 1024 + t * 4;
  int s = 0;
  if (base < NN) {
    const int4 v = *(const int4*)(a + base);
    s = v.x + v.y + v.z + v.w;
  }
#pragma unroll
  for (int d = 32; d >= 1; d >>= 1) s += __shfl_xor(s, d);
  __shared__ int wsum[4];
  if ((t & 63) == 0) wsum[t >> 6] = s;
  __syncthreads();
  if (t == 0) parts[arr * 64 + c] = wsum[0] + wsum[1] + wsum[2] + wsum[3];
}

__global__ __launch_bounds__(64) void scanB_kernel(int* __restrict__ parts) {
  int* p = parts + blockIdx.x * 64;
  const int lane = threadIdx.x;
  int v = (lane < NCH) ? p[lane] : 0;
  int inc = v;
#pragma unroll
  for (int d = 1; d < 64; d <<= 1) {
    const int t = __shfl_up(inc, d);
    if (lane >= d) inc += t;
  }
  if (lane < NCH) p[lane] = inc - v;  // exclusive offset per chunk
}

__global__ __launch_bounds__(256) void scanC_kernel(
    int* __restrict__ a0, int* __restrict__ a1,
    const int* __restrict__ parts) {
  const int arr = blockIdx.x / NCH;
  const int c = blockIdx.x - arr * NCH;
  int* a = arr ? a1 : a0;
  const int t = threadIdx.x;
  const int lane = t & 63;
  const int w = t >> 6;
  const int base = c * 1024 + t * 4;
  int4 v = make_int4(0, 0, 0, 0);
  if (base < NN) v = *(const int4*)(a + base);
  const int s = v.x + v.y + v.z + v.w;
  int inc = s;
#pragma unroll
  for (int d = 1; d < 64; d <<= 1) {
    const int tv = __shfl_up(inc, d);
    if (lane >= d) inc += tv;
  }
  __shared__ int wsum[4];
  if (lane == 63) wsum[w] = inc;
  __syncthreads();
  int woff = 0;
#pragma unroll
  for (int i = 0; i < 4; ++i)
    if (i < w) woff += wsum[i];
  const int excl = parts[arr * 64 + c] + woff + inc - s;
  if (base < NN) {
    int4 o;
    o.x = excl;
    o.y = o.x + v.x;
    o.z = o.y + v.y;
    o.w = o.z + v.z;
    *(int4*)(a + base) = o;
  }
}

// ---------------------------------------------------------------------------
// pull-gather mean (u16 col), XCD-aligned node swizzle
// ---------------------------------------------------------------------------
__device__ __forceinline__ void gather_dev(
    const float* __restrict__ Y, const int* __restrict__ rowptr,
    const unsigned short* __restrict__ col, float* __restrict__ AGGf,
    unsigned short* __restrict__ aggh, unsigned short* __restrict__ aggl,
    int seg, int tid) {
  const int w = tid >> 6;
  const int lane = tid & 63;
  const int off = (seg >> 3) * 4 + w;
  if (off >= 6250) return;
  const int node = (seg & 7) * 6250 + off;
  const int eg = lane >> 4;
  const int cq = (lane & 15) << 2;
  const int start = (node == 0) ? 0 : rowptr[node - 1];
  const int end = rowptr[node];
  float4 acc = make_float4(0.f, 0.f, 0.f, 0.f);
  int e = start + eg;
  for (; e + 12 < end; e += 16) {
    const int j0 = col[e];
    const int j1 = col[e + 4];
    const int j2 = col[e + 8];
    const int j3 = col[e + 12];
    const float4 y0 = *(const float4*)(Y + j0 * 64 + cq);
    const float4 y1 = *(const float4*)(Y + j1 * 64 + cq);
    const float4 y2 = *(const float4*)(Y + j2 * 64 + cq);
    const float4 y3 = *(const float4*)(Y + j3 * 64 + cq);
    acc.x += y0.x + y1.x + y2.x + y3.x;
    acc.y += y0.y + y1.y + y2.y + y3.y;
    acc.z += y0.z + y1.z + y2.z + y3.z;
    acc.w += y0.w + y1.w + y2.w + y3.w;
  }
  for (; e < end; e += 4) {
    const float4 y = *(const float4*)(Y + col[e] * 64 + cq);
    acc.x += y.x; acc.y += y.y; acc.z += y.z; acc.w += y.w;
  }
  acc.x += __shfl_xor(acc.x, 16);
  acc.y += __shfl_xor(acc.y, 16);
  acc.z += __shfl_xor(acc.z, 16);
  acc.w += __shfl_xor(acc.w, 16);
  acc.x += __shfl_xor(acc.x, 32);
  acc.y += __shfl_xor(acc.y, 32);
  acc.z += __shfl_xor(acc.z, 32);
  acc.w += __shfl_xor(acc.w, 32);
  if (eg == 0) {
    const float inv = 1.f / (float)max(end - start, 1);
    float4 o;
    o.x = acc.x * inv; o.y = acc.y * inv;
    o.z = acc.z * inv; o.w = acc.w * inv;
    if (AGGf) {
      *(float4*)(AGGf + node * 64 + cq) = o;
    } else {
      ushort4 h, l;
      split4(o, h, l);
      *(ushort4*)(aggh + node * 64 + cq) = h;
      *(ushort4*)(aggl + node * 64 + cq) = l;
    }
  }
}

__global__ __launch_bounds__(256) void gather_kernel(
    const float* __restrict__ Y, const int* __restrict__ rowptr,
    const unsigned short* __restrict__ col, float* __restrict__ AGGf,
    unsigned short* __restrict__ aggh, unsigned short* __restrict__ aggl) {
  gather_dev(Y, rowptr, col, AGGf, aggh, aggl, blockIdx.x, threadIdx.x);
}

__global__ __launch_bounds__(256) void gather2_kernel(
    const float* __restrict__ Yu, const int* __restrict__ rp_dst,
    const unsigned short* __restrict__ col_dst,
    unsigned short* auh, unsigned short* aul,
    const float* __restrict__ Yd, const int* __restrict__ rp_src,
    const unsigned short* __restrict__ col_src,
    unsigned short* adh, unsigned short* adl) {
  if (blockIdx.x < GBS)
    gather_dev(Yu, rp_dst, col_dst, nullptr, auh, aul, blockIdx.x, threadIdx.x);
  else
    gather_dev(Yd, rp_src, col_src, nullptr, adh, adl, blockIdx.x - GBS,
               threadIdx.x);
}

// ===========================================================================
// Fallback path (vector-f32 GEMM + replicated edge pass) for small workspaces
// ===========================================================================
__global__ __launch_bounds__(256) void pack_kernel(
    const int* __restrict__ src, const int* __restrict__ dst,
    unsigned* __restrict__ epack) {
  for (int e = blockIdx.x * 256 + threadIdx.x; e < NE; e += 1024 * 256)
    epack[e] = (unsigned)src[e] | ((unsigned)dst[e] << 16);
}

__device__ __forceinline__ void place_dev4(
    const unsigned* __restrict__ epack,
    int* __restrict__ rp_dst, int* __restrict__ rp_src,
    unsigned short* __restrict__ col_dst, unsigned short* __restrict__ col_src,
    int bi, int tid) {
  const unsigned lo = (unsigned)(bi & 7) * 6250u;
  const int g = (bi >> 3) * 256 + tid;
  for (int e = g * 4; e < NE; e += 262144) {
    const uint4 v4 = *(const uint4*)(epack + e);
    const unsigned vs[4] = {v4.x, v4.y, v4.z, v4.w};
#pragma unroll
    for (int i = 0; i < 4; ++i) {
      const unsigned s = vs[i] & 0xFFFFu, d = vs[i] >> 16;
      if (d - lo < 6250u)
        col_dst[atomicAdd(&rp_dst[d], 1)] = (unsigned short)s;
      if (s - lo < 6250u)
        col_src[atomicAdd(&rp_src[s], 1)] = (unsigned short)d;
    }
  }
}

__global__ __launch_bounds__(256) void count_old_kernel(
    const unsigned* __restrict__ epack,
    int* __restrict__ rp_dst, int* __restrict__ rp_src) {
  const int bi = blockIdx.x;
  const unsigned lo = (unsigned)(bi & 7) * 6250u;
  const int g = (bi >> 3) * 256 + threadIdx.x;
  for (int e = g * 4; e < NE; e += 262144) {
    const uint4 v4 = *(const uint4*)(epack + e);
    const unsigned vs[4] = {v4.x, v4.y, v4.z, v4.w};
#pragma unroll
    for (int i = 0; i < 4; ++i) {
      const unsigned s = vs[i] & 0xFFFFu, d = vs[i] >> 16;
      if (d - lo < 6250u) atomicAdd(&rp_dst[d], 1);
      if (s - lo < 6250u) atomicAdd(&rp_src[s], 1);
    }
  }
}

#define CHUNK 49
__global__ __launch_bounds__(1024) void scan_kernel(
    int* __restrict__ a0, int* __restrict__ a1) {
  int* a = (blockIdx.x == 0) ? a0 : a1;
  __shared__ int part[1024];
  const int t = threadIdx.x;
  const int beg = t * CHUNK;
  const int end = min(beg + CHUNK, NN);
  int s = 0;
  for (int i = beg; i < end; ++i) s += a[i];
  part[t] = s;
  __syncthreads();
  for (int off = 1; off < 1024; off <<= 1) {
    int add = (t >= off) ? part[t - off] : 0;
    __syncthreads();
    part[t] += add;
    __syncthreads();
  }
  int run = (t == 0) ? 0 : part[t - 1];
  for (int i = beg; i < end; ++i) {
    const int c = a[i];
    a[i] = run;
    run += c;
  }
}

__device__ __forceinline__ void gemm64_dev(
    float (*Xt)[68], float* Ws, const float* __restrict__ X, int ldx,
    const float* __restrict__ AGG, const float* __restrict__ W,
    const float* __restrict__ b, float* __restrict__ out, int ldo,
    int colbase, int dup, int kchunks, int xchunks, int row0, int tid) {
  const int tx = tid & 15, ty = tid >> 4;
  float acc[4][4] = {{0.f}};
  for (int c = 0; c < kchunks; ++c) {
    {
      const int rr = tid >> 2;
      const int cg = (tid & 3) << 4;
      const float* srcp;
      int ld, co;
      if (c < xchunks) { srcp = X; ld = ldx; co = c * 64; }
      else             { srcp = AGG; ld = 64; co = 0; }
      int row = row0 + rr;
      if (row > NN - 1) row = NN - 1;
      const float* g = srcp + row * ld + co + cg;
      const float4 v0 = *(const float4*)(g + 0);
      const float4 v1 = *(const float4*)(g + 4);
      const float4 v2 = *(const float4*)(g + 8);
      const float4 v3 = *(const float4*)(g + 12);
      Xt[cg + 0][rr] = v0.x;  Xt[cg + 1][rr] = v0.y;
      Xt[cg + 2][rr] = v0.z;  Xt[cg + 3][rr] = v0.w;
      Xt[cg + 4][rr] = v1.x;  Xt[cg + 5][rr] = v1.y;
      Xt[cg + 6][rr] = v1.z;  Xt[cg + 7][rr] = v1.w;
      Xt[cg + 8][rr] = v2.x;  Xt[cg + 9][rr] = v2.y;
      Xt[cg + 10][rr] = v2.z; Xt[cg + 11][rr] = v2.w;
      Xt[cg + 12][rr] = v3.x; Xt[cg + 13][rr] = v3.y;
      Xt[cg + 14][rr] = v3.z; Xt[cg + 15][rr] = v3.w;
      const float4* wg = (const float4*)(W + c * 64 * 64);
      float4* wl = (float4*)Ws;
      wl[tid] = wg[tid];
      wl[tid + 256] = wg[tid + 256];
      wl[tid + 512] = wg[tid + 512];
      wl[tid + 768] = wg[tid + 768];
    }
    __syncthreads();
#pragma unroll 8
    for (int kk = 0; kk < 64; ++kk) {
      const float4 a = *(const float4*)&Xt[kk][tx << 2];
      const float4 w = *(const float4*)&Ws[kk * 64 + (ty << 2)];
      acc[0][0] += a.x * w.x; acc[0][1] += a.x * w.y;
      acc[0][2] += a.x * w.z; acc[0][3] += a.x * w.w;
      acc[1][0] += a.y * w.x; acc[1][1] += a.y * w.y;
      acc[1][2] += a.y * w.z; acc[1][3] += a.y * w.w;
      acc[2][0] += a.z * w.x; acc[2][1] += a.z * w.y;
      acc[2][2] += a.z * w.z; acc[2][3] += a.z * w.w;
      acc[3][0] += a.w * w.x; acc[3][1] += a.w * w.y;
      acc[3][2] += a.w * w.z; acc[3][3] += a.w * w.w;
    }
    __syncthreads();
  }
  float4 bv = make_float4(0.f, 0.f, 0.f, 0.f);
  if (b) bv = *(const float4*)(b + (ty << 2));
#pragma unroll
  for (int i = 0; i < 4; ++i) {
    const int row = row0 + (tx << 2) + i;
    if (row < NN) {
      float4 o;
      o.x = fmaxf(acc[i][0] + bv.x, 0.f);
      o.y = fmaxf(acc[i][1] + bv.y, 0.f);
      o.z = fmaxf(acc[i][2] + bv.z, 0.f);
      o.w = fmaxf(acc[i][3] + bv.w, 0.f);
      *(float4*)(out + row * ldo + colbase + (ty << 2)) = o;
      if (dup) *(float4*)(out + row * ldo + 64 + (ty << 2)) = o;
    }
  }
}

__global__ __launch_bounds__(256) void gemm_kernel(
    const float* __restrict__ X, int ldx, const float* __restrict__ AGG,
    const float* __restrict__ W, const float* __restrict__ b,
    float* __restrict__ out, int ldo, int colbase, int dup,
    int kchunks, int xchunks) {
  __shared__ __align__(16) float Xt[64][68];
  __shared__ __align__(16) float Ws[4096];
  gemm64_dev(Xt, Ws, X, ldx, AGG, W, b, out, ldo, colbase, dup, kchunks,
             xchunks, blockIdx.x * 64, threadIdx.x);
}

__global__ __launch_bounds__(256) void fused0_kernel(
    const unsigned* __restrict__ epack,
    int* __restrict__ rp_dst, int* __restrict__ rp_src,
    unsigned short* __restrict__ col_dst, unsigned short* __restrict__ col_src,
    const float* __restrict__ x,
    const float* __restrict__ W_u1, const float* __restrict__ b_u1,
    float* __restrict__ Y_u,
    const float* __restrict__ W_d1, const float* __restrict__ b_d1,
    float* __restrict__ Y_d) {
  __shared__ __align__(16) float Xt[64][68];
  __shared__ __align__(16) float Ws[4096];
  int bi = blockIdx.x;
  if (bi < 2048) {
    place_dev4(epack, rp_dst, rp_src, col_dst, col_src, bi, threadIdx.x);
    return;
  }
  bi -= 2048;
  if (bi < TB)
    gemm64_dev(Xt, Ws, x, 128, nullptr, W_u1, b_u1, Y_u, 64, 0, 0, 2, 2,
               bi * 64, threadIdx.x);
  else
    gemm64_dev(Xt, Ws, x, 128, nullptr, W_d1, b_d1, Y_d, 64, 0, 0, 2, 2,
               (bi - TB) * 64, threadIdx.x);
}

// ===========================================================================
extern "C" void kernel_launch(void* const* d_in, const int* in_sizes, int n_in,
                              void* d_out, int out_size, void* d_ws, size_t ws_size,
                              hipStream_t stream) {
  const float* x    = (const float*)d_in[0];
  const int*   ei   = (const int*)d_in[1];
  const float* W_u1 = (const float*)d_in[2];
  const float* b_u1 = (const float*)d_in[3];
  const float* U_u1 = (const float*)d_in[4];
  const float* W_d1 = (const float*)d_in[5];
  const float* b_d1 = (const float*)d_in[6];
  const float* U_d1 = (const float*)d_in[7];
  const float* W_u2 = (const float*)d_in[8];
  const float* b_u2 = (const float*)d_in[9];
  const float* U_u2 = (const float*)d_in[10];
  const int* src = ei;
  const int* dst = ei + NE;
  float* out = (float*)d_out;

  char* wsb = (char*)d_ws;
  int* rp_dst  = (int*)wsb;              wsb += NN * sizeof(int);
  int* rp_src  = (int*)wsb;              wsb += NN * sizeof(int);
  int* gcur    = (int*)wsb;              wsb += 32 * sizeof(int);
  int* parts   = (int*)wsb;              wsb += 128 * sizeof(int);
  unsigned short* col_dst = (unsigned short*)wsb; wsb += (size_t)NE * 2;
  unsigned short* col_src = (unsigned short*)wsb; wsb += (size_t)NE * 2;

  const size_t needM = (size_t)2 * NN * 4 + 640 + (size_t)NE * 4 +
                       (size_t)WBUF_USHORTS * 2 +
                       (size_t)NN * 64 * 4 * 2 +    // Yu, Yd (f32)
                       (size_t)NN * 64 * 2 * 4 +    // 4 agg bf16 planes
                       (size_t)NN * 64 * 2 * 2;     // O2h, O2l

  // zero bucket cursors (rp arrays fully overwritten by count2)
  hipMemsetAsync(gcur, 0, 32 * sizeof(int), stream);

  if (ws_size >= needM) {
    unsigned short* wbuf = (unsigned short*)wsb; wsb += (size_t)WBUF_USHORTS * 2;
    float* Yu = (float*)wsb;                     wsb += (size_t)NN * 64 * 4;
    float* Yd = (float*)wsb;                     wsb += (size_t)NN * 64 * 4;
    unsigned short* agg_uh = (unsigned short*)wsb; wsb += (size_t)NN * 64 * 2;
    unsigned short* agg_ul = (unsigned short*)wsb; wsb += (size_t)NN * 64 * 2;
    unsigned short* agg_dh = (unsigned short*)wsb; wsb += (size_t)NN * 64 * 2;
    unsigned short* agg_dl = (unsigned short*)wsb; wsb += (size_t)NN * 64 * 2;
    unsigned short* O2h = (unsigned short*)wsb;    wsb += (size_t)NN * 64 * 2;
    unsigned short* O2l = (unsigned short*)wsb;

    // bucket arrays alias agg planes (dead until gather2; place2 ends before)
    unsigned* bdst = (unsigned*)agg_uh;   // 8*BCAP*4 = 3.31MB <= 6.4MB
    unsigned* bsrc = (unsigned*)agg_ul;

    // other aliases (sequential lifetime reuse)
    unsigned short* outh = (unsigned short*)Yu;  // [N][128] bf16 hi
    unsigned short* outl = (unsigned short*)Yd;  // [N][128] bf16 lo
    float* Y2 = (float*)agg_uh;                  // [N][64] f32 (spans uh+ul)
    unsigned short* agg2h = agg_dh;
    unsigned short* agg2l = agg_dl;

    const unsigned short* U1uh = wbuf + WOFF_U1U;
    const unsigned short* U1ul = wbuf + WOFF_U1U + 64 * 192;
    const unsigned short* U1dh = wbuf + WOFF_U1D;
    const unsigned short* U1dl = wbuf + WOFF_U1D + 64 * 192;
    const unsigned short* W1uh = wbuf + WOFF_W1U;
    const unsigned short* W1ul = wbuf + WOFF_W1U + 64 * 128;
    const unsigned short* W1dh = wbuf + WOFF_W1D;
    const unsigned short* W1dl = wbuf + WOFF_W1D + 64 * 128;
    const unsigned short* W2uh = wbuf + WOFF_W2U;
    const unsigned short* W2ul = wbuf + WOFF_W2U + 64 * 128;
    const unsigned short* U2uh = wbuf + WOFF_U2U;
    const unsigned short* U2ul = wbuf + WOFF_U2U + 64 * 192;
    const unsigned short* Wsh  = wbuf + WOFF_WSUM;
    const unsigned short* Wsl  = wbuf + WOFF_WSUM + 64 * 64;
    const unsigned short* Ush  = wbuf + WOFF_USUM;
    const unsigned short* Usl  = wbuf + WOFF_USUM + 64 * 128;

    // bucket counting-sort || weight conversion
    prep_kernel<<<BBK + 32, 256, 0, stream>>>(
        src, dst, gcur, bdst, bsrc, U_u1, U_d1, W_u1, W_d1, W_u2, U_u2, wbuf);
    // per-subrange LDS-histogram count (zero global atomics)
    count2_kernel<<<CB2, 256, 0, stream>>>(gcur, bdst, bsrc, rp_dst, rp_src);
    // layer-1 transforms
    trans2_kernel<<<TB, 256, 0, stream>>>(x, W1uh, W1ul, W1dh, W1dl,
                                          b_u1, b_d1, Yu, Yd);
    // hierarchical coalesced exclusive scan of both rowptr arrays
    scanA_kernel<<<2 * NCH, 256, 0, stream>>>(rp_dst, rp_src, parts);
    scanB_kernel<<<2, 64, 0, stream>>>(parts);
    scanC_kernel<<<2 * NCH, 256, 0, stream>>>(rp_dst, rp_src, parts);
    // LDS-cursor placement (zero global atomics; rp -> inclusive ends)
    place2_kernel<<<CB2, 256, 0, stream>>>(gcur, bdst, bsrc, rp_dst, rp_src,
                                           col_dst, col_src);
    // layer 1
    gather2_kernel<<<2 * GBS, 256, 0, stream>>>(Yu, rp_dst, col_dst, agg_uh,
                                                agg_ul, Yd, rp_src, col_src,
                                                agg_dh, agg_dl);
    update2m_kernel<<<2 * TB, 256, 0, stream>>>(x, agg_uh, agg_ul, agg_dh,
                                                agg_dl, U1uh, U1ul, U1dh,
                                                U1dl, outh, outl);
    // round 2
    mgemm_kernel<<<TB, 256, 0, stream>>>(outh, outl, 128, nullptr, nullptr,
                                         W2uh, W2ul, 128, b_u2, Y2, nullptr,
                                         nullptr, 64, 0, 0, 2, 2);
    gather_kernel<<<GBS, 256, 0, stream>>>(Y2, rp_dst, col_dst, nullptr,
                                           agg2h, agg2l);
    mgemm_kernel<<<TB, 256, 0, stream>>>(outh, outl, 128, agg2h, agg2l,
                                         U2uh, U2ul, 192, nullptr, nullptr,
                                         O2h, O2l, 64, 0, 0, 3, 2);
    // round 3 (h = [O2,O2] folded into presummed weights)
    mgemm_kernel<<<TB, 256, 0, stream>>>(O2h, O2l, 64, nullptr, nullptr,
                                         Wsh, Wsl, 64, b_u2, Y2, nullptr,
                                         nullptr, 64, 0, 0, 1, 1);
    gather_kernel<<<GBS, 256, 0, stream>>>(Y2, rp_dst, col_dst, nullptr,
                                           agg2h, agg2l);
    mgemm_kernel<<<TB, 256, 0, stream>>>(O2h, O2l, 64, agg2h, agg2l,
                                         Ush, Usl, 128, nullptr, out,
                                         nullptr, nullptr, 128, 0, 1, 2, 1);
  } else {
    // fallback: vector-f32 path with replicated edge passes
    unsigned* epack = (unsigned*)wsb; wsb += (size_t)NE * 4;
    float* Y_u = (float*)wsb; wsb += (size_t)NN * 64 * sizeof(float);
    float* Y_d = (float*)wsb; wsb += (size_t)NN * 64 * sizeof(float);
    float* AGG = (float*)wsb;
    hipMemsetAsync(rp_dst, 0, 2 * NN * sizeof(int), stream);
    pack_kernel<<<1024, 256, 0, stream>>>(src, dst, epack);
    count_old_kernel<<<2048, 256, 0, stream>>>(epack, rp_dst, rp_src);
    scan_kernel<<<2, 1024, 0, stream>>>(rp_dst, rp_src);
    fused0_kernel<<<2048 + 2 * TB, 256, 0, stream>>>(
        epack, rp_dst, rp_src, col_dst, col_src, x, W_u1, b_u1, Y_u, W_d1,
        b_d1, Y_d);
    gather_kernel<<<GBS, 256, 0, stream>>>(Y_u, rp_dst, col_dst, AGG,
                                           nullptr, nullptr);
    gemm_kernel<<<TB, 256, 0, stream>>>(x, 128, AGG, U_u1, nullptr, out,
                                        128, 0, 0, 3, 2);
    gather_kernel<<<GBS, 256, 0, stream>>>(Y_d, rp_src, col_src, AGG,
                                           nullptr, nullptr);
    gemm_kernel<<<TB, 256, 0, stream>>>(x, 128, AGG, U_d1, nullptr, out,
                                        128, 64, 0, 3, 2);
    for (int r = 0; r < 2; ++r) {
      gemm_kernel<<<TB, 256, 0, stream>>>(out, 128, nullptr, W_u2, b_u2,
                                          Y_u, 64, 0, 0, 2, 2);
      gather_kernel<<<GBS, 256, 0, stream>>>(Y_u, rp_dst, col_dst, AGG,
                                             nullptr, nullptr);
      gemm_kernel<<<TB, 256, 0, stream>>>(out, 128, AGG, U_u2, nullptr,
                                          out, 128, 0, 1, 3, 2);
    }
  }
}

// Round 12
// 225.681 us; speedup vs baseline: 1.7825x; 1.3504x over previous
//
#include <hip/hip_runtime.h>

#define NN 50000
#define NE 800000
#define TB 782             // ceil(NN/64) gemm row-tile blocks
#define GBS 12504          // 8 * 1563 swizzled gather blocks (4 nodes each)
#define BBK 391            // bucket blocks = ceil(NE/2048)
#define CHKE 2048          // edges per bucket block
#define BINS 256           // bins per direction (8 buckets x 32 subs)
#define BINCAP 4096        // per-bin capacity (mean 3125, >17 sigma slack)
#define SUBW 196           // nodes per bin (last bin of bucket: 174)

typedef __attribute__((ext_vector_type(8))) short bhalf8;
typedef __attribute__((ext_vector_type(4))) float floatx4;

// weight buffer offsets (ushort units); l plane = h + 64*K
#define WOFF_U1U 0
#define WOFF_U1D 24576
#define WOFF_W1U 49152
#define WOFF_W1D 65536
#define WOFF_W2U 81920
#define WOFF_U2U 98304
#define WOFF_WSUM 122880
#define WOFF_USUM 131072
#define WBUF_USHORTS 147456

// ---------------------------------------------------------------------------
// bf16 split helpers (RNE)
// ---------------------------------------------------------------------------
__device__ __forceinline__ unsigned short bf16hi(float v) {
  union { float f; unsigned u; } c; c.f = v;
  return (unsigned short)((c.u + 0x7FFFu + ((c.u >> 16) & 1u)) >> 16);
}
__device__ __forceinline__ float bf16tof(unsigned short h) {
  union { unsigned u; float f; } c; c.u = ((unsigned)h) << 16;
  return c.f;
}
__device__ __forceinline__ void split1(float v, unsigned short& h,
                                       unsigned short& l) {
  h = bf16hi(v);
  l = bf16hi(v - bf16tof(h));
}
__device__ __forceinline__ void split4(const float4 v, ushort4& h, ushort4& l) {
  split1(v.x, h.x, l.x);
  split1(v.y, h.y, l.y);
  split1(v.z, h.z, l.z);
  split1(v.w, h.w, l.w);
}
__device__ __forceinline__ void split8(const float4 v0, const float4 v1,
                                       uint4& H, uint4& L) {
  unsigned short h0, l0, h1, l1;
  split1(v0.x, h0, l0); split1(v0.y, h1, l1);
  H.x = (unsigned)h0 | ((unsigned)h1 << 16);
  L.x = (unsigned)l0 | ((unsigned)l1 << 16);
  split1(v0.z, h0, l0); split1(v0.w, h1, l1);
  H.y = (unsigned)h0 | ((unsigned)h1 << 16);
  L.y = (unsigned)l0 | ((unsigned)l1 << 16);
  split1(v1.x, h0, l0); split1(v1.y, h1, l1);
  H.z = (unsigned)h0 | ((unsigned)h1 << 16);
  L.z = (unsigned)l0 | ((unsigned)l1 << 16);
  split1(v1.z, h0, l0); split1(v1.w, h1, l1);
  H.w = (unsigned)h0 | ((unsigned)h1 << 16);
  L.w = (unsigned)l0 | ((unsigned)l1 << 16);
}

// swizzled LDS byte address for bf16 tile [64 rows][64 k] (128B rows)
#define SWZ(row, inrow) (((row) << 7) + ((inrow) ^ (((row)&7) << 4)))

// ---------------------------------------------------------------------------
// MFMA split-bf16 GEMM (single B): out = relu([A|G] @ B^T (+bias))
// ---------------------------------------------------------------------------
template <bool AF32>
__device__ __forceinline__ void mfma_gemm_dev(
    unsigned short* tAh, unsigned short* tAl,
    unsigned short* tBh, unsigned short* tBl,
    const unsigned short* __restrict__ Ah, const unsigned short* __restrict__ Al,
    int lda,
    const unsigned short* __restrict__ Gh, const unsigned short* __restrict__ Gl,
    const unsigned short* __restrict__ Bh, const unsigned short* __restrict__ Bl,
    int ldb, const float* __restrict__ bias,
    float* __restrict__ outF, unsigned short* __restrict__ outH,
    unsigned short* __restrict__ outL,
    int ldo, int colbase, int dup, int kchunks, int xchunks,
    int row0, int tid) {
  const int lane = tid & 63;
  const int wm = tid >> 6;
  const int m = lane & 15;
  const int kg = lane >> 4;
  floatx4 acc[4];
#pragma unroll
  for (int i = 0; i < 4; ++i) acc[i] = (floatx4){0.f, 0.f, 0.f, 0.f};

  for (int c = 0; c < kchunks; ++c) {
#pragma unroll
    for (int q = tid; q < 512; q += 256) {
      const int row = q >> 3, slot = q & 7;
      int gr = row0 + row;
      gr = (gr > NN - 1) ? NN - 1 : gr;
      const int ad = SWZ(row, slot << 4);
      if (AF32 && c < xchunks) {
        const float* f = (const float*)Ah;
        const size_t go = (size_t)gr * lda + (c << 6) + slot * 8;
        const float4 v0 = *(const float4*)(f + go);
        const float4 v1 = *(const float4*)(f + go + 4);
        uint4 H, L;
        split8(v0, v1, H, L);
        *(uint4*)((char*)tAh + ad) = H;
        *(uint4*)((char*)tAl + ad) = L;
      } else {
        const unsigned short* sh;
        const unsigned short* sl;
        int ld, kc;
        if (c < xchunks) { sh = Ah; sl = Al; ld = lda; kc = c << 6; }
        else             { sh = Gh; sl = Gl; ld = 64;  kc = 0; }
        const size_t go = (size_t)gr * ld + kc + slot * 8;
        *(uint4*)((char*)tAh + ad) = *(const uint4*)(sh + go);
        *(uint4*)((char*)tAl + ad) = *(const uint4*)(sl + go);
      }
      const size_t gob = (size_t)row * ldb + (c << 6) + slot * 8;
      *(uint4*)((char*)tBh + ad) = *(const uint4*)(Bh + gob);
      *(uint4*)((char*)tBl + ad) = *(const uint4*)(Bl + gob);
    }
    __syncthreads();
#pragma unroll
    for (int ks = 0; ks < 2; ++ks) {
      const int inrow = (ks << 6) + (kg << 4);
      const int rA = (wm << 4) + m;
      const bhalf8 ah = *(const bhalf8*)((const char*)tAh + SWZ(rA, inrow));
      const bhalf8 al = *(const bhalf8*)((const char*)tAl + SWZ(rA, inrow));
#pragma unroll
      for (int nt = 0; nt < 4; ++nt) {
        const int rB = (nt << 4) + m;
        const bhalf8 bh = *(const bhalf8*)((const char*)tBh + SWZ(rB, inrow));
        const bhalf8 bl = *(const bhalf8*)((const char*)tBl + SWZ(rB, inrow));
        acc[nt] = __builtin_amdgcn_mfma_f32_16x16x32_bf16(ah, bh, acc[nt], 0, 0, 0);
        acc[nt] = __builtin_amdgcn_mfma_f32_16x16x32_bf16(ah, bl, acc[nt], 0, 0, 0);
        acc[nt] = __builtin_amdgcn_mfma_f32_16x16x32_bf16(al, bh, acc[nt], 0, 0, 0);
      }
    }
    __syncthreads();
  }
#pragma unroll
  for (int nt = 0; nt < 4; ++nt) {
    const int col = colbase + (nt << 4) + m;
    const float bv = bias ? bias[(nt << 4) + m] : 0.f;
#pragma unroll
    for (int r = 0; r < 4; ++r) {
      const int row = row0 + (wm << 4) + (kg << 2) + r;
      if (row < NN) {
        const float v = fmaxf(acc[nt][r] + bv, 0.f);
        if (outF) {
          outF[(size_t)row * ldo + col] = v;
          if (dup) outF[(size_t)row * ldo + col + 64] = v;
        }
        if (outH) {
          unsigned short h, l;
          split1(v, h, l);
          outH[(size_t)row * ldo + col] = h;
          outL[(size_t)row * ldo + col] = l;
        }
      }
    }
  }
}

// ---------------------------------------------------------------------------
// Dual-output transform, 4-tile (32KB)
// ---------------------------------------------------------------------------
__device__ __forceinline__ void trans2_dev(
    unsigned short* tAh, unsigned short* tAl,
    unsigned short* tBh, unsigned short* tBl,
    const float* __restrict__ x,
    const unsigned short* __restrict__ Wuh, const unsigned short* __restrict__ Wul,
    const unsigned short* __restrict__ Wdh, const unsigned short* __restrict__ Wdl,
    const float* __restrict__ bu, const float* __restrict__ bd,
    float* __restrict__ Yu, float* __restrict__ Yd, int row0, int tid) {
  const int lane = tid & 63;
  const int wm = tid >> 6;
  const int m = lane & 15;
  const int kg = lane >> 4;
  floatx4 accU[4], accD[4];
#pragma unroll
  for (int i = 0; i < 4; ++i) {
    accU[i] = (floatx4){0.f, 0.f, 0.f, 0.f};
    accD[i] = (floatx4){0.f, 0.f, 0.f, 0.f};
  }
  for (int c = 0; c < 2; ++c) {
#pragma unroll
    for (int q = tid; q < 512; q += 256) {
      const int row = q >> 3, slot = q & 7;
      int gr = row0 + row;
      gr = (gr > NN - 1) ? NN - 1 : gr;
      const int ad = SWZ(row, slot << 4);
      const size_t go = (size_t)gr * 128 + (c << 6) + slot * 8;
      const float4 v0 = *(const float4*)(x + go);
      const float4 v1 = *(const float4*)(x + go + 4);
      uint4 H, L;
      split8(v0, v1, H, L);
      *(uint4*)((char*)tAh + ad) = H;
      *(uint4*)((char*)tAl + ad) = L;
      const size_t gob = (size_t)row * 128 + (c << 6) + slot * 8;
      *(uint4*)((char*)tBh + ad) = *(const uint4*)(Wuh + gob);
      *(uint4*)((char*)tBl + ad) = *(const uint4*)(Wul + gob);
    }
    __syncthreads();
#pragma unroll
    for (int ks = 0; ks < 2; ++ks) {
      const int inrow = (ks << 6) + (kg << 4);
      const int rA = (wm << 4) + m;
      const bhalf8 ah = *(const bhalf8*)((const char*)tAh + SWZ(rA, inrow));
      const bhalf8 al = *(const bhalf8*)((const char*)tAl + SWZ(rA, inrow));
#pragma unroll
      for (int nt = 0; nt < 4; ++nt) {
        const int rB = (nt << 4) + m;
        const int adB = SWZ(rB, inrow);
        const bhalf8 bh = *(const bhalf8*)((const char*)tBh + adB);
        const bhalf8 bl = *(const bhalf8*)((const char*)tBl + adB);
        accU[nt] = __builtin_amdgcn_mfma_f32_16x16x32_bf16(ah, bh, accU[nt], 0, 0, 0);
        accU[nt] = __builtin_amdgcn_mfma_f32_16x16x32_bf16(ah, bl, accU[nt], 0, 0, 0);
        accU[nt] = __builtin_amdgcn_mfma_f32_16x16x32_bf16(al, bh, accU[nt], 0, 0, 0);
      }
    }
    __syncthreads();
#pragma unroll
    for (int q = tid; q < 512; q += 256) {
      const int row = q >> 3, slot = q & 7;
      const int ad = SWZ(row, slot << 4);
      const size_t gob = (size_t)row * 128 + (c << 6) + slot * 8;
      *(uint4*)((char*)tBh + ad) = *(const uint4*)(Wdh + gob);
      *(uint4*)((char*)tBl + ad) = *(const uint4*)(Wdl + gob);
    }
    __syncthreads();
#pragma unroll
    for (int ks = 0; ks < 2; ++ks) {
      const int inrow = (ks << 6) + (kg << 4);
      const int rA = (wm << 4) + m;
      const bhalf8 ah = *(const bhalf8*)((const char*)tAh + SWZ(rA, inrow));
      const bhalf8 al = *(const bhalf8*)((const char*)tAl + SWZ(rA, inrow));
#pragma unroll
      for (int nt = 0; nt < 4; ++nt) {
        const int rB = (nt << 4) + m;
        const int adB = SWZ(rB, inrow);
        const bhalf8 bh = *(const bhalf8*)((const char*)tBh + adB);
        const bhalf8 bl = *(const bhalf8*)((const char*)tBl + adB);
        accD[nt] = __builtin_amdgcn_mfma_f32_16x16x32_bf16(ah, bh, accD[nt], 0, 0, 0);
        accD[nt] = __builtin_amdgcn_mfma_f32_16x16x32_bf16(ah, bl, accD[nt], 0, 0, 0);
        accD[nt] = __builtin_amdgcn_mfma_f32_16x16x32_bf16(al, bh, accD[nt], 0, 0, 0);
      }
    }
    __syncthreads();
  }
#pragma unroll
  for (int nt = 0; nt < 4; ++nt) {
    const int col = (nt << 4) + m;
    const float bvu = bu[col];
    const float bvd = bd[col];
#pragma unroll
    for (int r = 0; r < 4; ++r) {
      const int row = row0 + (wm << 4) + (kg << 2) + r;
      if (row < NN) {
        Yu[(size_t)row * 64 + col] = fmaxf(accU[nt][r] + bvu, 0.f);
        Yd[(size_t)row * 64 + col] = fmaxf(accD[nt][r] + bvd, 0.f);
      }
    }
  }
}

__global__ __launch_bounds__(256) void trans2_kernel(
    const float* __restrict__ x,
    const unsigned short* W1uh, const unsigned short* W1ul,
    const unsigned short* W1dh, const unsigned short* W1dl,
    const float* __restrict__ b_u1, const float* __restrict__ b_d1,
    float* __restrict__ Yu, float* __restrict__ Yd) {
  __shared__ unsigned short tiles[4][4096];
  trans2_dev(tiles[0], tiles[1], tiles[2], tiles[3], x, W1uh, W1ul, W1dh,
             W1dl, b_u1, b_d1, Yu, Yd, blockIdx.x * 64, threadIdx.x);
}

__global__ __launch_bounds__(256) void mgemm_kernel(
    const unsigned short* Ah, const unsigned short* Al, int lda,
    const unsigned short* Gh, const unsigned short* Gl,
    const unsigned short* Bh, const unsigned short* Bl, int ldb,
    const float* bias, float* outF, unsigned short* outH, unsigned short* outL,
    int ldo, int colbase, int dup, int kchunks, int xchunks) {
  __shared__ unsigned short tiles[4][4096];
  mfma_gemm_dev<false>(tiles[0], tiles[1], tiles[2], tiles[3], Ah, Al, lda,
                       Gh, Gl, Bh, Bl, ldb, bias, outF, outH, outL, ldo,
                       colbase, dup, kchunks, xchunks, blockIdx.x * 64,
                       threadIdx.x);
}

// both layer-1 updates in one launch; A = f32 x (inline split)
__global__ __launch_bounds__(256) void update2m_kernel(
    const float* __restrict__ x,
    const unsigned short* auh, const unsigned short* aul,
    const unsigned short* adh, const unsigned short* adl,
    const unsigned short* U1uh, const unsigned short* U1ul,
    const unsigned short* U1dh, const unsigned short* U1dl,
    unsigned short* outH, unsigned short* outL) {
  __shared__ unsigned short tiles[4][4096];
  if (blockIdx.x < TB)
    mfma_gemm_dev<true>(tiles[0], tiles[1], tiles[2], tiles[3],
                        (const unsigned short*)x, nullptr, 128, auh, aul,
                        U1uh, U1ul, 192, nullptr, nullptr, outH, outL, 128,
                        0, 0, 3, 2, blockIdx.x * 64, threadIdx.x);
  else
    mfma_gemm_dev<true>(tiles[0], tiles[1], tiles[2], tiles[3],
                        (const unsigned short*)x, nullptr, 128, adh, adl,
                        U1dh, U1dl, 192, nullptr, nullptr, outH, outL, 128,
                        64, 0, 3, 2, (blockIdx.x - TB) * 64, threadIdx.x);
}

// ---------------------------------------------------------------------------
// bin index: node -> (node/6250)*32 + (node%6250)/196, in [0,256)
// ---------------------------------------------------------------------------
__device__ __forceinline__ int bin_of(unsigned n) {
  const unsigned bucket = n / 6250u;
  const unsigned rem = n - bucket * 6250u;
  return (int)(bucket * 32u + rem / 196u);
}

// ---------------------------------------------------------------------------
// prep: fine counting-sort into 256 bins/dir (blocks [0,BBK)) || weights (32)
// ---------------------------------------------------------------------------
__global__ __launch_bounds__(256) void prep_kernel(
    const int* __restrict__ src, const int* __restrict__ dst,
    int* __restrict__ gcur,
    unsigned* __restrict__ bdst, unsigned* __restrict__ bsrc,
    const float* __restrict__ U_u1, const float* __restrict__ U_d1,
    const float* __restrict__ W_u1, const float* __restrict__ W_d1,
    const float* __restrict__ W_u2, const float* __restrict__ U_u2,
    unsigned short* __restrict__ wbuf) {
  int bi = blockIdx.x;
  const int t = threadIdx.x;
  if (bi < BBK) {
    __shared__ int hist[512];
    __shared__ int base[512];
    __shared__ int cur[512];
    const int chunk = bi * CHKE;
    for (int j = t; j < 512; j += 256) { hist[j] = 0; cur[j] = 0; }
    __syncthreads();
    unsigned ev[8];
    int bd[8], bs[8];
    bool ok[8];
#pragma unroll
    for (int i = 0; i < 8; ++i) {
      const int e = chunk + i * 256 + t;
      ok[i] = e < NE;
      bd[i] = 0; bs[i] = 0; ev[i] = 0;
      if (ok[i]) {
        const unsigned s = (unsigned)src[e], d = (unsigned)dst[e];
        ev[i] = s | (d << 16);
        bd[i] = bin_of(d);
        bs[i] = bin_of(s);
        atomicAdd(&hist[bd[i]], 1);
        atomicAdd(&hist[256 + bs[i]], 1);
      }
    }
    __syncthreads();
    for (int j = t; j < 512; j += 256)
      base[j] = atomicAdd(&gcur[j], hist[j]);
    __syncthreads();
#pragma unroll
    for (int i = 0; i < 8; ++i) {
      if (ok[i]) {
        const int r1 = base[bd[i]] + atomicAdd(&cur[bd[i]], 1);
        if (r1 < BINCAP) bdst[bd[i] * BINCAP + r1] = ev[i];
        const int r2 = base[256 + bs[i]] + atomicAdd(&cur[256 + bs[i]], 1);
        if (r2 < BINCAP) bsrc[bs[i] * BINCAP + r2] = ev[i];
      }
    }
    return;
  }
  bi -= BBK;
  const int widx = bi >> 2;
  const int quad = bi & 3;
  const int Ks[8] = {192, 192, 128, 128, 128, 192, 64, 128};
  const int offs[8] = {WOFF_U1U, WOFF_U1D, WOFF_W1U, WOFF_W1D,
                       WOFF_W2U, WOFF_U2U, WOFF_WSUM, WOFF_USUM};
  const float* srcs[6] = {U_u1, U_d1, W_u1, W_d1, W_u2, U_u2};
  const int K = Ks[widx];
  const int off = offs[widx];
  const int qsz = K << 4;
  const int beg = quad * qsz;
  for (int e = beg + t; e < beg + qsz; e += 256) {
    const int cc = e / K;
    const int kk = e - cc * K;
    float v;
    if (widx < 6) v = srcs[widx][kk * 64 + cc];
    else if (widx == 6) v = W_u2[kk * 64 + cc] + W_u2[(kk + 64) * 64 + cc];
    else v = (kk < 64) ? (U_u2[kk * 64 + cc] + U_u2[(kk + 64) * 64 + cc])
                       : U_u2[(kk + 64) * 64 + cc];
    unsigned short h, l;
    split1(v, h, l);
    wbuf[off + cc * K + kk] = h;
    wbuf[off + (K << 6) + cc * K + kk] = l;
  }
}

// ---------------------------------------------------------------------------
// binscan: per-direction exclusive scan of 256 bin counts -> binbase
// grid = 2 (one block per direction)
// ---------------------------------------------------------------------------
__global__ __launch_bounds__(256) void binscan_kernel(
    const int* __restrict__ gcur, int* __restrict__ binbase) {
  const int dir = blockIdx.x;
  const int t = threadIdx.x;
  __shared__ int sc[256];
  const int v = gcur[dir * 256 + t];
  sc[t] = v;
  __syncthreads();
  for (int off = 1; off < 256; off <<= 1) {
    int add = (t >= off) ? sc[t - off] : 0;
    __syncthreads();
    sc[t] += add;
    __syncthreads();
  }
  binbase[dir * 256 + t] = sc[t] - v;  // exclusive
}

// ---------------------------------------------------------------------------
// placeC: one block per bin. Stream own bin: LDS hist -> LDS scan ->
// write rowptr inclusive ends -> place cols via LDS cursors.
// Zero global atomics, zero membership tests.
// ---------------------------------------------------------------------------
__global__ __launch_bounds__(256) void placeC_kernel(
    const int* __restrict__ gcur, const int* __restrict__ binbase,
    const unsigned* __restrict__ bdst, const unsigned* __restrict__ bsrc,
    int* __restrict__ rp_dst, int* __restrict__ rp_src,
    unsigned short* __restrict__ col_dst, unsigned short* __restrict__ col_src) {
  const int gbin = blockIdx.x;         // 0..511
  const int dir = gbin >> 8;
  const int bin = gbin & 255;
  const int bucket = bin >> 5;
  const int sub = bin & 31;
  const unsigned lo = (unsigned)(bucket * 6250 + sub * SUBW);
  const int subn = min(SUBW, 6250 - sub * SUBW);
  __shared__ int hist[SUBW];
  __shared__ int sc[SUBW];
  __shared__ int cur[SUBW];
  const int t = threadIdx.x;
  if (t < subn) hist[t] = 0;
  __syncthreads();
  const int cnt = min(gcur[gbin], BINCAP);
  const unsigned* p = (dir ? bsrc : bdst) + (size_t)bin * BINCAP;
  const int cnt4 = cnt & ~3;
  for (int i = t * 4; i < cnt4; i += 1024) {
    const uint4 v = *(const uint4*)(p + i);
    const unsigned n0 = dir ? (v.x & 0xFFFFu) : (v.x >> 16);
    const unsigned n1 = dir ? (v.y & 0xFFFFu) : (v.y >> 16);
    const unsigned n2 = dir ? (v.z & 0xFFFFu) : (v.z >> 16);
    const unsigned n3 = dir ? (v.w & 0xFFFFu) : (v.w >> 16);
    atomicAdd(&hist[n0 - lo], 1);
    atomicAdd(&hist[n1 - lo], 1);
    atomicAdd(&hist[n2 - lo], 1);
    atomicAdd(&hist[n3 - lo], 1);
  }
  for (int i = cnt4 + t; i < cnt; i += 256) {
    const unsigned n = dir ? (p[i] & 0xFFFFu) : (p[i] >> 16);
    atomicAdd(&hist[n - lo], 1);
  }
  __syncthreads();
  // inclusive scan of hist into sc
  if (t < subn) sc[t] = hist[t];
  __syncthreads();
  for (int off = 1; off < SUBW; off <<= 1) {
    int add = (t < subn && t >= off) ? sc[t - off] : 0;
    __syncthreads();
    if (t < subn) sc[t] += add;
    __syncthreads();
  }
  const int bb = binbase[gbin];
  int* rp = dir ? rp_src : rp_dst;
  if (t < subn) {
    rp[lo + t] = bb + sc[t];            // inclusive end
    cur[t] = bb + sc[t] - hist[t];      // exclusive start cursor
  }
  __syncthreads();
  unsigned short* col = dir ? col_src : col_dst;
  for (int i = t * 4; i < cnt4; i += 1024) {
    const uint4 v = *(const uint4*)(p + i);
    const unsigned vs[4] = {v.x, v.y, v.z, v.w};
#pragma unroll
    for (int k = 0; k < 4; ++k) {
      const unsigned n = dir ? (vs[k] & 0xFFFFu) : (vs[k] >> 16);
      const unsigned q = dir ? (vs[k] >> 16) : (vs[k] & 0xFFFFu);
      col[atomicAdd(&cur[n - lo], 1)] = (unsigned short)q;
    }
  }
  for (int i = cnt4 + t; i < cnt; i += 256) {
    const unsigned v = p[i];
    const unsigned n = dir ? (v & 0xFFFFu) : (v >> 16);
    const unsigned q = dir ? (v >> 16) : (v & 0xFFFFu);
    col[atomicAdd(&cur[n - lo], 1)] = (unsigned short)q;
  }
}

// ---------------------------------------------------------------------------
// pull-gather mean (u16 col), XCD-aligned node swizzle
// ---------------------------------------------------------------------------
__device__ __forceinline__ void gather_dev(
    const float* __restrict__ Y, const int* __restrict__ rowptr,
    const unsigned short* __restrict__ col, float* __restrict__ AGGf,
    unsigned short* __restrict__ aggh, unsigned short* __restrict__ aggl,
    int seg, int tid) {
  const int w = tid >> 6;
  const int lane = tid & 63;
  const int off = (seg >> 3) * 4 + w;
  if (off >= 6250) return;
  const int node = (seg & 7) * 6250 + off;
  const int eg = lane >> 4;
  const int cq = (lane & 15) << 2;
  const int start = (node == 0) ? 0 : rowptr[node - 1];
  const int end = rowptr[node];
  float4 acc = make_float4(0.f, 0.f, 0.f, 0.f);
  int e = start + eg;
  for (; e + 12 < end; e += 16) {
    const int j0 = col[e];
    const int j1 = col[e + 4];
    const int j2 = col[e + 8];
    const int j3 = col[e + 12];
    const float4 y0 = *(const float4*)(Y + j0 * 64 + cq);
    const float4 y1 = *(const float4*)(Y + j1 * 64 + cq);
    const float4 y2 = *(const float4*)(Y + j2 * 64 + cq);
    const float4 y3 = *(const float4*)(Y + j3 * 64 + cq);
    acc.x += y0.x + y1.x + y2.x + y3.x;
    acc.y += y0.y + y1.y + y2.y + y3.y;
    acc.z += y0.z + y1.z + y2.z + y3.z;
    acc.w += y0.w + y1.w + y2.w + y3.w;
  }
  for (; e < end; e += 4) {
    const float4 y = *(const float4*)(Y + col[e] * 64 + cq);
    acc.x += y.x; acc.y += y.y; acc.z += y.z; acc.w += y.w;
  }
  acc.x += __shfl_xor(acc.x, 16);
  acc.y += __shfl_xor(acc.y, 16);
  acc.z += __shfl_xor(acc.z, 16);
  acc.w += __shfl_xor(acc.w, 16);
  acc.x += __shfl_xor(acc.x, 32);
  acc.y += __shfl_xor(acc.y, 32);
  acc.z += __shfl_xor(acc.z, 32);
  acc.w += __shfl_xor(acc.w, 32);
  if (eg == 0) {
    const float inv = 1.f / (float)max(end - start, 1);
    float4 o;
    o.x = acc.x * inv; o.y = acc.y * inv;
    o.z = acc.z * inv; o.w = acc.w * inv;
    if (AGGf) {
      *(float4*)(AGGf + node * 64 + cq) = o;
    } else {
      ushort4 h, l;
      split4(o, h, l);
      *(ushort4*)(aggh + node * 64 + cq) = h;
      *(ushort4*)(aggl + node * 64 + cq) = l;
    }
  }
}

__global__ __launch_bounds__(256) void gather_kernel(
    const float* __restrict__ Y, const int* __restrict__ rowptr,
    const unsigned short* __restrict__ col, float* __restrict__ AGGf,
    unsigned short* __restrict__ aggh, unsigned short* __restrict__ aggl) {
  gather_dev(Y, rowptr, col, AGGf, aggh, aggl, blockIdx.x, threadIdx.x);
}

__global__ __launch_bounds__(256) void gather2_kernel(
    const float* __restrict__ Yu, const int* __restrict__ rp_dst,
    const unsigned short* __restrict__ col_dst,
    unsigned short* auh, unsigned short* aul,
    const float* __restrict__ Yd, const int* __restrict__ rp_src,
    const unsigned short* __restrict__ col_src,
    unsigned short* adh, unsigned short* adl) {
  if (blockIdx.x < GBS)
    gather_dev(Yu, rp_dst, col_dst, nullptr, auh, aul, blockIdx.x, threadIdx.x);
  else
    gather_dev(Yd, rp_src, col_src, nullptr, adh, adl, blockIdx.x - GBS,
               threadIdx.x);
}

// ===========================================================================
// Fallback path (vector-f32 GEMM + replicated edge pass) for small workspaces
// ===========================================================================
__global__ __launch_bounds__(256) void pack_kernel(
    const int* __restrict__ src, const int* __restrict__ dst,
    unsigned* __restrict__ epack) {
  for (int e = blockIdx.x * 256 + threadIdx.x; e < NE; e += 1024 * 256)
    epack[e] = (unsigned)src[e] | ((unsigned)dst[e] << 16);
}

__device__ __forceinline__ void place_dev4(
    const unsigned* __restrict__ epack,
    int* __restrict__ rp_dst, int* __restrict__ rp_src,
    unsigned short* __restrict__ col_dst, unsigned short* __restrict__ col_src,
    int bi, int tid) {
  const unsigned lo = (unsigned)(bi & 7) * 6250u;
  const int g = (bi >> 3) * 256 + tid;
  for (int e = g * 4; e < NE; e += 262144) {
    const uint4 v4 = *(const uint4*)(epack + e);
    const unsigned vs[4] = {v4.x, v4.y, v4.z, v4.w};
#pragma unroll
    for (int i = 0; i < 4; ++i) {
      const unsigned s = vs[i] & 0xFFFFu, d = vs[i] >> 16;
      if (d - lo < 6250u)
        col_dst[atomicAdd(&rp_dst[d], 1)] = (unsigned short)s;
      if (s - lo < 6250u)
        col_src[atomicAdd(&rp_src[s], 1)] = (unsigned short)d;
    }
  }
}

__global__ __launch_bounds__(256) void count_old_kernel(
    const unsigned* __restrict__ epack,
    int* __restrict__ rp_dst, int* __restrict__ rp_src) {
  const int bi = blockIdx.x;
  const unsigned lo = (unsigned)(bi & 7) * 6250u;
  const int g = (bi >> 3) * 256 + threadIdx.x;
  for (int e = g * 4; e < NE; e += 262144) {
    const uint4 v4 = *(const uint4*)(epack + e);
    const unsigned vs[4] = {v4.x, v4.y, v4.z, v4.w};
#pragma unroll
    for (int i = 0; i < 4; ++i) {
      const unsigned s = vs[i] & 0xFFFFu, d = vs[i] >> 16;
      if (d - lo < 6250u) atomicAdd(&rp_dst[d], 1);
      if (s - lo < 6250u) atomicAdd(&rp_src[s], 1);
    }
  }
}

#define CHUNK 49
__global__ __launch_bounds__(1024) void scan_kernel(
    int* __restrict__ a0, int* __restrict__ a1) {
  int* a = (blockIdx.x == 0) ? a0 : a1;
  __shared__ int part[1024];
  const int t = threadIdx.x;
  const int beg = t * CHUNK;
  const int end = min(beg + CHUNK, NN);
  int s = 0;
  for (int i = beg; i < end; ++i) s += a[i];
  part[t] = s;
  __syncthreads();
  for (int off = 1; off < 1024; off <<= 1) {
    int add = (t >= off) ? part[t - off] : 0;
    __syncthreads();
    part[t] += add;
    __syncthreads();
  }
  int run = (t == 0) ? 0 : part[t - 1];
  for (int i = beg; i < end; ++i) {
    const int c = a[i];
    a[i] = run;
    run += c;
  }
}

__device__ __forceinline__ void gemm64_dev(
    float (*Xt)[68], float* Ws, const float* __restrict__ X, int ldx,
    const float* __restrict__ AGG, const float* __restrict__ W,
    const float* __restrict__ b, float* __restrict__ out, int ldo,
    int colbase, int dup, int kchunks, int xchunks, int row0, int tid) {
  const int tx = tid & 15, ty = tid >> 4;
  float acc[4][4] = {{0.f}};
  for (int c = 0; c < kchunks; ++c) {
    {
      const int rr = tid >> 2;
      const int cg = (tid & 3) << 4;
      const float* srcp;
      int ld, co;
      if (c < xchunks) { srcp = X; ld = ldx; co = c * 64; }
      else             { srcp = AGG; ld = 64; co = 0; }
      int row = row0 + rr;
      if (row > NN - 1) row = NN - 1;
      const float* g = srcp + row * ld + co + cg;
      const float4 v0 = *(const float4*)(g + 0);
      const float4 v1 = *(const float4*)(g + 4);
      const float4 v2 = *(const float4*)(g + 8);
      const float4 v3 = *(const float4*)(g + 12);
      Xt[cg + 0][rr] = v0.x;  Xt[cg + 1][rr] = v0.y;
      Xt[cg + 2][rr] = v0.z;  Xt[cg + 3][rr] = v0.w;
      Xt[cg + 4][rr] = v1.x;  Xt[cg + 5][rr] = v1.y;
      Xt[cg + 6][rr] = v1.z;  Xt[cg + 7][rr] = v1.w;
      Xt[cg + 8][rr] = v2.x;  Xt[cg + 9][rr] = v2.y;
      Xt[cg + 10][rr] = v2.z; Xt[cg + 11][rr] = v2.w;
      Xt[cg + 12][rr] = v3.x; Xt[cg + 13][rr] = v3.y;
      Xt[cg + 14][rr] = v3.z; Xt[cg + 15][rr] = v3.w;
      const float4* wg = (const float4*)(W + c * 64 * 64);
      float4* wl = (float4*)Ws;
      wl[tid] = wg[tid];
      wl[tid + 256] = wg[tid + 256];
      wl[tid + 512] = wg[tid + 512];
      wl[tid + 768] = wg[tid + 768];
    }
    __syncthreads();
#pragma unroll 8
    for (int kk = 0; kk < 64; ++kk) {
      const float4 a = *(const float4*)&Xt[kk][tx << 2];
      const float4 w = *(const float4*)&Ws[kk * 64 + (ty << 2)];
      acc[0][0] += a.x * w.x; acc[0][1] += a.x * w.y;
      acc[0][2] += a.x * w.z; acc[0][3] += a.x * w.w;
      acc[1][0] += a.y * w.x; acc[1][1] += a.y * w.y;
      acc[1][2] += a.y * w.z; acc[1][3] += a.y * w.w;
      acc[2][0] += a.z * w.x; acc[2][1] += a.z * w.y;
      acc[2][2] += a.z * w.z; acc[2][3] += a.z * w.w;
      acc[3][0] += a.w * w.x; acc[3][1] += a.w * w.y;
      acc[3][2] += a.w * w.z; acc[3][3] += a.w * w.w;
    }
    __syncthreads();
  }
  float4 bv = make_float4(0.f, 0.f, 0.f, 0.f);
  if (b) bv = *(const float4*)(b + (ty << 2));
#pragma unroll
  for (int i = 0; i < 4; ++i) {
    const int row = row0 + (tx << 2) + i;
    if (row < NN) {
      float4 o;
      o.x = fmaxf(acc[i][0] + bv.x, 0.f);
      o.y = fmaxf(acc[i][1] + bv.y, 0.f);
      o.z = fmaxf(acc[i][2] + bv.z, 0.f);
      o.w = fmaxf(acc[i][3] + bv.w, 0.f);
      *(float4*)(out + row * ldo + colbase + (ty << 2)) = o;
      if (dup) *(float4*)(out + row * ldo + 64 + (ty << 2)) = o;
    }
  }
}

__global__ __launch_bounds__(256) void gemm_kernel(
    const float* __restrict__ X, int ldx, const float* __restrict__ AGG,
    const float* __restrict__ W, const float* __restrict__ b,
    float* __restrict__ out, int ldo, int colbase, int dup,
    int kchunks, int xchunks) {
  __shared__ __align__(16) float Xt[64][68];
  __shared__ __align__(16) float Ws[4096];
  gemm64_dev(Xt, Ws, X, ldx, AGG, W, b, out, ldo, colbase, dup, kchunks,
             xchunks, blockIdx.x * 64, threadIdx.x);
}

__global__ __launch_bounds__(256) void fused0_kernel(
    const unsigned* __restrict__ epack,
    int* __restrict__ rp_dst, int* __restrict__ rp_src,
    unsigned short* __restrict__ col_dst, unsigned short* __restrict__ col_src,
    const float* __restrict__ x,
    const float* __restrict__ W_u1, const float* __restrict__ b_u1,
    float* __restrict__ Y_u,
    const float* __restrict__ W_d1, const float* __restrict__ b_d1,
    float* __restrict__ Y_d) {
  __shared__ __align__(16) float Xt[64][68];
  __shared__ __align__(16) float Ws[4096];
  int bi = blockIdx.x;
  if (bi < 2048) {
    place_dev4(epack, rp_dst, rp_src, col_dst, col_src, bi, threadIdx.x);
    return;
  }
  bi -= 2048;
  if (bi < TB)
    gemm64_dev(Xt, Ws, x, 128, nullptr, W_u1, b_u1, Y_u, 64, 0, 0, 2, 2,
               bi * 64, threadIdx.x);
  else
    gemm64_dev(Xt, Ws, x, 128, nullptr, W_d1, b_d1, Y_d, 64, 0, 0, 2, 2,
               (bi - TB) * 64, threadIdx.x);
}

// ===========================================================================
extern "C" void kernel_launch(void* const* d_in, const int* in_sizes, int n_in,
                              void* d_out, int out_size, void* d_ws, size_t ws_size,
                              hipStream_t stream) {
  const float* x    = (const float*)d_in[0];
  const int*   ei   = (const int*)d_in[1];
  const float* W_u1 = (const float*)d_in[2];
  const float* b_u1 = (const float*)d_in[3];
  const float* U_u1 = (const float*)d_in[4];
  const float* W_d1 = (const float*)d_in[5];
  const float* b_d1 = (const float*)d_in[6];
  const float* U_d1 = (const float*)d_in[7];
  const float* W_u2 = (const float*)d_in[8];
  const float* b_u2 = (const float*)d_in[9];
  const float* U_u2 = (const float*)d_in[10];
  const int* src = ei;
  const int* dst = ei + NE;
  float* out = (float*)d_out;

  char* wsb = (char*)d_ws;
  int* rp_dst  = (int*)wsb;              wsb += NN * sizeof(int);
  int* rp_src  = (int*)wsb;              wsb += NN * sizeof(int);
  int* gcur    = (int*)wsb;              wsb += 512 * sizeof(int);
  int* binbase = (int*)wsb;              wsb += 512 * sizeof(int);
  unsigned short* col_dst = (unsigned short*)wsb; wsb += (size_t)NE * 2;
  unsigned short* col_src = (unsigned short*)wsb; wsb += (size_t)NE * 2;

  const size_t needM = (size_t)2 * NN * 4 + 4096 + (size_t)NE * 4 +
                       (size_t)WBUF_USHORTS * 2 +
                       (size_t)NN * 64 * 4 * 2 +    // Yu, Yd (f32)
                       (size_t)NN * 64 * 2 * 4 +    // 4 agg bf16 planes
                       (size_t)NN * 64 * 2 * 2;     // O2h, O2l

  // zero bin cursors (rp arrays fully overwritten by placeC)
  hipMemsetAsync(gcur, 0, 512 * sizeof(int), stream);

  if (ws_size >= needM) {
    unsigned short* wbuf = (unsigned short*)wsb; wsb += (size_t)WBUF_USHORTS * 2;
    float* Yu = (float*)wsb;                     wsb += (size_t)NN * 64 * 4;
    float* Yd = (float*)wsb;                     wsb += (size_t)NN * 64 * 4;
    unsigned short* agg_uh = (unsigned short*)wsb; wsb += (size_t)NN * 64 * 2;
    unsigned short* agg_ul = (unsigned short*)wsb; wsb += (size_t)NN * 64 * 2;
    unsigned short* agg_dh = (unsigned short*)wsb; wsb += (size_t)NN * 64 * 2;
    unsigned short* agg_dl = (unsigned short*)wsb; wsb += (size_t)NN * 64 * 2;
    unsigned short* O2h = (unsigned short*)wsb;    wsb += (size_t)NN * 64 * 2;
    unsigned short* O2l = (unsigned short*)wsb;

    // bin arrays alias agg planes (dead until gather2; placeC ends before)
    unsigned* bdst = (unsigned*)agg_uh;   // 256*4096*4 = 4MB <= 6.4MB plane
    unsigned* bsrc = (unsigned*)agg_ul;

    // other aliases (sequential lifetime reuse)
    unsigned short* outh = (unsigned short*)Yu;  // [N][128] bf16 hi
    unsigned short* outl = (unsigned short*)Yd;  // [N][128] bf16 lo
    float* Y2 = (float*)agg_uh;                  // [N][64] f32 (spans uh+ul)
    unsigned short* agg2h = agg_dh;
    unsigned short* agg2l = agg_dl;

    const unsigned short* U1uh = wbuf + WOFF_U1U;
    const unsigned short* U1ul = wbuf + WOFF_U1U + 64 * 192;
    const unsigned short* U1dh = wbuf + WOFF_U1D;
    const unsigned short* U1dl = wbuf + WOFF_U1D + 64 * 192;
    const unsigned short* W1uh = wbuf + WOFF_W1U;
    const unsigned short* W1ul = wbuf + WOFF_W1U + 64 * 128;
    const unsigned short* W1dh = wbuf + WOFF_W1D;
    const unsigned short* W1dl = wbuf + WOFF_W1D + 64 * 128;
    const unsigned short* W2uh = wbuf + WOFF_W2U;
    const unsigned short* W2ul = wbuf + WOFF_W2U + 64 * 128;
    const unsigned short* U2uh = wbuf + WOFF_U2U;
    const unsigned short* U2ul = wbuf + WOFF_U2U + 64 * 192;
    const unsigned short* Wsh  = wbuf + WOFF_WSUM;
    const unsigned short* Wsl  = wbuf + WOFF_WSUM + 64 * 64;
    const unsigned short* Ush  = wbuf + WOFF_USUM;
    const unsigned short* Usl  = wbuf + WOFF_USUM + 64 * 128;

    // fine counting-sort || weight conversion
    prep_kernel<<<BBK + 32, 256, 0, stream>>>(
        src, dst, gcur, bdst, bsrc, U_u1, U_d1, W_u1, W_d1, W_u2, U_u2, wbuf);
    // per-direction bin-base scan (replaces the 50000-wide scans)
    binscan_kernel<<<2, 256, 0, stream>>>(gcur, binbase);
    // layer-1 transforms
    trans2_kernel<<<TB, 256, 0, stream>>>(x, W1uh, W1ul, W1dh, W1dl,
                                          b_u1, b_d1, Yu, Yd);
    // self-contained per-bin CSR finalize: rowptr + col in one pass
    placeC_kernel<<<512, 256, 0, stream>>>(gcur, binbase, bdst, bsrc,
                                           rp_dst, rp_src, col_dst, col_src);
    // layer 1
    gather2_kernel<<<2 * GBS, 256, 0, stream>>>(Yu, rp_dst, col_dst, agg_uh,
                                                agg_ul, Yd, rp_src, col_src,
                                                agg_dh, agg_dl);
    update2m_kernel<<<2 * TB, 256, 0, stream>>>(x, agg_uh, agg_ul, agg_dh,
                                                agg_dl, U1uh, U1ul, U1dh,
                                                U1dl, outh, outl);
    // round 2
    mgemm_kernel<<<TB, 256, 0, stream>>>(outh, outl, 128, nullptr, nullptr,
                                         W2uh, W2ul, 128, b_u2, Y2, nullptr,
                                         nullptr, 64, 0, 0, 2, 2);
    gather_kernel<<<GBS, 256, 0, stream>>>(Y2, rp_dst, col_dst, nullptr,
                                           agg2h, agg2l);
    mgemm_kernel<<<TB, 256, 0, stream>>>(outh, outl, 128, agg2h, agg2l,
                                         U2uh, U2ul, 192, nullptr, nullptr,
                                         O2h, O2l, 64, 0, 0, 3, 2);
    // round 3 (h = [O2,O2] folded into presummed weights)
    mgemm_kernel<<<TB, 256, 0, stream>>>(O2h, O2l, 64, nullptr, nullptr,
                                         Wsh, Wsl, 64, b_u2, Y2, nullptr,
                                         nullptr, 64, 0, 0, 1, 1);
    gather_kernel<<<GBS, 256, 0, stream>>>(Y2, rp_dst, col_dst, nullptr,
                                           agg2h, agg2l);
    mgemm_kernel<<<TB, 256, 0, stream>>>(O2h, O2l, 64, agg2h, agg2l,
                                         Ush, Usl, 128, nullptr, out,
                                         nullptr, nullptr, 128, 0, 1, 2, 1);
  } else {
    // fallback: vector-f32 path with replicated edge passes
    unsigned* epack = (unsigned*)wsb; wsb += (size_t)NE * 4;
    float* Y_u = (float*)wsb; wsb += (size_t)NN * 64 * sizeof(float);
    float* Y_d = (float*)wsb; wsb += (size_t)NN * 64 * sizeof(float);
    float* AGG = (float*)wsb;
    hipMemsetAsync(rp_dst, 0, 2 * NN * sizeof(int), stream);
    pack_kernel<<<1024, 256, 0, stream>>>(src, dst, epack);
    count_old_kernel<<<2048, 256, 0, stream>>>(epack, rp_dst, rp_src);
    scan_kernel<<<2, 1024, 0, stream>>>(rp_dst, rp_src);
    fused0_kernel<<<2048 + 2 * TB, 256, 0, stream>>>(
        epack, rp_dst, rp_src, col_dst, col_src, x, W_u1, b_u1, Y_u, W_d1,
        b_d1, Y_d);
    gather_kernel<<<GBS, 256, 0, stream>>>(Y_u, rp_dst, col_dst, AGG,
                                           nullptr, nullptr);
    gemm_kernel<<<TB, 256, 0, stream>>>(x, 128, AGG, U_u1, nullptr, out,
                                        128, 0, 0, 3, 2);
    gather_kernel<<<GBS, 256, 0, stream>>>(Y_d, rp_src, col_src, AGG,
                                           nullptr, nullptr);
    gemm_kernel<<<TB, 256, 0, stream>>>(x, 128, AGG, U_d1, nullptr, out,
                                        128, 64, 0, 3, 2);
    for (int r = 0; r < 2; ++r) {
      gemm_kernel<<<TB, 256, 0, stream>>>(out, 128, nullptr, W_u2, b_u2,
                                          Y_u, 64, 0, 0, 2, 2);
      gather_kernel<<<GBS, 256, 0, stream>>>(Y_u, rp_dst, col_dst, AGG,
                                             nullptr, nullptr);
      gemm_kernel<<<TB, 256, 0, stream>>>(out, 128, AGG, U_u2, nullptr,
                                          out, 128, 0, 1, 3, 2);
    }
  }
}

// Round 13
// 203.553 us; speedup vs baseline: 1.9762x; 1.1087x over previous
//
#include <hip/hip_runtime.h>

#define NN 50000
#define NE 800000
#define TB 782             // ceil(NN/64) gemm row-tile blocks
#define GBS 12504          // 8 * 1563 swizzled gather blocks (4 nodes each)
#define BBK 391            // bucket blocks = ceil(NE/2048)
#define CHKE 2048          // edges per bucket block
#define BINS 256           // bins per direction
#define BINCAP 4096        // per-bin capacity (mean 3125, >17 sigma slack)
#define SUBW 196           // nodes per bin

typedef __attribute__((ext_vector_type(8))) short bhalf8;
typedef __attribute__((ext_vector_type(4))) float floatx4;

// weight buffer offsets (ushort units); l plane = h + 64*K
#define WOFF_U1U 0
#define WOFF_U1D 24576
#define WOFF_W1U 49152
#define WOFF_W1D 65536
#define WOFF_W2U 81920
#define WOFF_U2U 98304
#define WOFF_WSUM 122880
#define WOFF_USUM 131072
#define WBUF_USHORTS 147456

// ---------------------------------------------------------------------------
// bf16 helpers (RNE)
// ---------------------------------------------------------------------------
__device__ __forceinline__ unsigned short bf16hi(float v) {
  union { float f; unsigned u; } c; c.f = v;
  return (unsigned short)((c.u + 0x7FFFu + ((c.u >> 16) & 1u)) >> 16);
}
__device__ __forceinline__ float bf16tof(unsigned short h) {
  union { unsigned u; float f; } c; c.u = ((unsigned)h) << 16;
  return c.f;
}
__device__ __forceinline__ float bfu_lo(unsigned u) {
  union { unsigned v; float f; } c; c.v = u << 16; return c.f;
}
__device__ __forceinline__ float bfu_hi(unsigned u) {
  union { unsigned v; float f; } c; c.v = u & 0xFFFF0000u; return c.f;
}
__device__ __forceinline__ void split1(float v, unsigned short& h,
                                       unsigned short& l) {
  h = bf16hi(v);
  l = bf16hi(v - bf16tof(h));
}
__device__ __forceinline__ void split8(const float4 v0, const float4 v1,
                                       uint4& H, uint4& L) {
  unsigned short h0, l0, h1, l1;
  split1(v0.x, h0, l0); split1(v0.y, h1, l1);
  H.x = (unsigned)h0 | ((unsigned)h1 << 16);
  L.x = (unsigned)l0 | ((unsigned)l1 << 16);
  split1(v0.z, h0, l0); split1(v0.w, h1, l1);
  H.y = (unsigned)h0 | ((unsigned)h1 << 16);
  L.y = (unsigned)l0 | ((unsigned)l1 << 16);
  split1(v1.x, h0, l0); split1(v1.y, h1, l1);
  H.z = (unsigned)h0 | ((unsigned)h1 << 16);
  L.z = (unsigned)l0 | ((unsigned)l1 << 16);
  split1(v1.z, h0, l0); split1(v1.w, h1, l1);
  H.w = (unsigned)h0 | ((unsigned)h1 << 16);
  L.w = (unsigned)l0 | ((unsigned)l1 << 16);
}

// swizzled LDS byte address for bf16 tile [64 rows][64 k] (128B rows)
#define SWZ(row, inrow) (((row) << 7) + ((inrow) ^ (((row)&7) << 4)))

// ---------------------------------------------------------------------------
// MFMA split-bf16 GEMM (single B): out = relu([A|G] @ B^T (+bias))
// outF: f32 (optional dup). outH (+optional outL): bf16 hi(/lo) planes.
// ---------------------------------------------------------------------------
template <bool AF32>
__device__ __forceinline__ void mfma_gemm_dev(
    unsigned short* tAh, unsigned short* tAl,
    unsigned short* tBh, unsigned short* tBl,
    const unsigned short* __restrict__ Ah, const unsigned short* __restrict__ Al,
    int lda,
    const unsigned short* __restrict__ Gh, const unsigned short* __restrict__ Gl,
    const unsigned short* __restrict__ Bh, const unsigned short* __restrict__ Bl,
    int ldb, const float* __restrict__ bias,
    float* __restrict__ outF, unsigned short* __restrict__ outH,
    unsigned short* __restrict__ outL,
    int ldo, int colbase, int dup, int kchunks, int xchunks,
    int row0, int tid) {
  const int lane = tid & 63;
  const int wm = tid >> 6;
  const int m = lane & 15;
  const int kg = lane >> 4;
  floatx4 acc[4];
#pragma unroll
  for (int i = 0; i < 4; ++i) acc[i] = (floatx4){0.f, 0.f, 0.f, 0.f};

  for (int c = 0; c < kchunks; ++c) {
#pragma unroll
    for (int q = tid; q < 512; q += 256) {
      const int row = q >> 3, slot = q & 7;
      int gr = row0 + row;
      gr = (gr > NN - 1) ? NN - 1 : gr;
      const int ad = SWZ(row, slot << 4);
      if (AF32 && c < xchunks) {
        const float* f = (const float*)Ah;
        const size_t go = (size_t)gr * lda + (c << 6) + slot * 8;
        const float4 v0 = *(const float4*)(f + go);
        const float4 v1 = *(const float4*)(f + go + 4);
        uint4 H, L;
        split8(v0, v1, H, L);
        *(uint4*)((char*)tAh + ad) = H;
        *(uint4*)((char*)tAl + ad) = L;
      } else {
        const unsigned short* sh;
        const unsigned short* sl;
        int ld, kc;
        if (c < xchunks) { sh = Ah; sl = Al; ld = lda; kc = c << 6; }
        else             { sh = Gh; sl = Gl; ld = 64;  kc = 0; }
        const size_t go = (size_t)gr * ld + kc + slot * 8;
        *(uint4*)((char*)tAh + ad) = *(const uint4*)(sh + go);
        *(uint4*)((char*)tAl + ad) = *(const uint4*)(sl + go);
      }
      const size_t gob = (size_t)row * ldb + (c << 6) + slot * 8;
      *(uint4*)((char*)tBh + ad) = *(const uint4*)(Bh + gob);
      *(uint4*)((char*)tBl + ad) = *(const uint4*)(Bl + gob);
    }
    __syncthreads();
#pragma unroll
    for (int ks = 0; ks < 2; ++ks) {
      const int inrow = (ks << 6) + (kg << 4);
      const int rA = (wm << 4) + m;
      const bhalf8 ah = *(const bhalf8*)((const char*)tAh + SWZ(rA, inrow));
      const bhalf8 al = *(const bhalf8*)((const char*)tAl + SWZ(rA, inrow));
#pragma unroll
      for (int nt = 0; nt < 4; ++nt) {
        const int rB = (nt << 4) + m;
        const bhalf8 bh = *(const bhalf8*)((const char*)tBh + SWZ(rB, inrow));
        const bhalf8 bl = *(const bhalf8*)((const char*)tBl + SWZ(rB, inrow));
        acc[nt] = __builtin_amdgcn_mfma_f32_16x16x32_bf16(ah, bh, acc[nt], 0, 0, 0);
        acc[nt] = __builtin_amdgcn_mfma_f32_16x16x32_bf16(ah, bl, acc[nt], 0, 0, 0);
        acc[nt] = __builtin_amdgcn_mfma_f32_16x16x32_bf16(al, bh, acc[nt], 0, 0, 0);
      }
    }
    __syncthreads();
  }
#pragma unroll
  for (int nt = 0; nt < 4; ++nt) {
    const int col = colbase + (nt << 4) + m;
    const float bv = bias ? bias[(nt << 4) + m] : 0.f;
#pragma unroll
    for (int r = 0; r < 4; ++r) {
      const int row = row0 + (wm << 4) + (kg << 2) + r;
      if (row < NN) {
        const float v = fmaxf(acc[nt][r] + bv, 0.f);
        if (outF) {
          outF[(size_t)row * ldo + col] = v;
          if (dup) outF[(size_t)row * ldo + col + 64] = v;
        }
        if (outH) {
          unsigned short h, l;
          split1(v, h, l);
          outH[(size_t)row * ldo + col] = h;
          if (outL) outL[(size_t)row * ldo + col] = l;
        }
      }
    }
  }
}

// ---------------------------------------------------------------------------
// Dual-output transform, 4-tile (32KB); Y outputs are bf16-hi planes
// ---------------------------------------------------------------------------
__device__ __forceinline__ void trans2_dev(
    unsigned short* tAh, unsigned short* tAl,
    unsigned short* tBh, unsigned short* tBl,
    const float* __restrict__ x,
    const unsigned short* __restrict__ Wuh, const unsigned short* __restrict__ Wul,
    const unsigned short* __restrict__ Wdh, const unsigned short* __restrict__ Wdl,
    const float* __restrict__ bu, const float* __restrict__ bd,
    unsigned short* __restrict__ Yu, unsigned short* __restrict__ Yd,
    int row0, int tid) {
  const int lane = tid & 63;
  const int wm = tid >> 6;
  const int m = lane & 15;
  const int kg = lane >> 4;
  floatx4 accU[4], accD[4];
#pragma unroll
  for (int i = 0; i < 4; ++i) {
    accU[i] = (floatx4){0.f, 0.f, 0.f, 0.f};
    accD[i] = (floatx4){0.f, 0.f, 0.f, 0.f};
  }
  for (int c = 0; c < 2; ++c) {
#pragma unroll
    for (int q = tid; q < 512; q += 256) {
      const int row = q >> 3, slot = q & 7;
      int gr = row0 + row;
      gr = (gr > NN - 1) ? NN - 1 : gr;
      const int ad = SWZ(row, slot << 4);
      const size_t go = (size_t)gr * 128 + (c << 6) + slot * 8;
      const float4 v0 = *(const float4*)(x + go);
      const float4 v1 = *(const float4*)(x + go + 4);
      uint4 H, L;
      split8(v0, v1, H, L);
      *(uint4*)((char*)tAh + ad) = H;
      *(uint4*)((char*)tAl + ad) = L;
      const size_t gob = (size_t)row * 128 + (c << 6) + slot * 8;
      *(uint4*)((char*)tBh + ad) = *(const uint4*)(Wuh + gob);
      *(uint4*)((char*)tBl + ad) = *(const uint4*)(Wul + gob);
    }
    __syncthreads();
#pragma unroll
    for (int ks = 0; ks < 2; ++ks) {
      const int inrow = (ks << 6) + (kg << 4);
      const int rA = (wm << 4) + m;
      const bhalf8 ah = *(const bhalf8*)((const char*)tAh + SWZ(rA, inrow));
      const bhalf8 al = *(const bhalf8*)((const char*)tAl + SWZ(rA, inrow));
#pragma unroll
      for (int nt = 0; nt < 4; ++nt) {
        const int rB = (nt << 4) + m;
        const int adB = SWZ(rB, inrow);
        const bhalf8 bh = *(const bhalf8*)((const char*)tBh + adB);
        const bhalf8 bl = *(const bhalf8*)((const char*)tBl + adB);
        accU[nt] = __builtin_amdgcn_mfma_f32_16x16x32_bf16(ah, bh, accU[nt], 0, 0, 0);
        accU[nt] = __builtin_amdgcn_mfma_f32_16x16x32_bf16(ah, bl, accU[nt], 0, 0, 0);
        accU[nt] = __builtin_amdgcn_mfma_f32_16x16x32_bf16(al, bh, accU[nt], 0, 0, 0);
      }
    }
    __syncthreads();
#pragma unroll
    for (int q = tid; q < 512; q += 256) {
      const int row = q >> 3, slot = q & 7;
      const int ad = SWZ(row, slot << 4);
      const size_t gob = (size_t)row * 128 + (c << 6) + slot * 8;
      *(uint4*)((char*)tBh + ad) = *(const uint4*)(Wdh + gob);
      *(uint4*)((char*)tBl + ad) = *(const uint4*)(Wdl + gob);
    }
    __syncthreads();
#pragma unroll
    for (int ks = 0; ks < 2; ++ks) {
      const int inrow = (ks << 6) + (kg << 4);
      const int rA = (wm << 4) + m;
      const bhalf8 ah = *(const bhalf8*)((const char*)tAh + SWZ(rA, inrow));
      const bhalf8 al = *(const bhalf8*)((const char*)tAl + SWZ(rA, inrow));
#pragma unroll
      for (int nt = 0; nt < 4; ++nt) {
        const int rB = (nt << 4) + m;
        const int adB = SWZ(rB, inrow);
        const bhalf8 bh = *(const bhalf8*)((const char*)tBh + adB);
        const bhalf8 bl = *(const bhalf8*)((const char*)tBl + adB);
        accD[nt] = __builtin_amdgcn_mfma_f32_16x16x32_bf16(ah, bh, accD[nt], 0, 0, 0);
        accD[nt] = __builtin_amdgcn_mfma_f32_16x16x32_bf16(ah, bl, accD[nt], 0, 0, 0);
        accD[nt] = __builtin_amdgcn_mfma_f32_16x16x32_bf16(al, bh, accD[nt], 0, 0, 0);
      }
    }
    __syncthreads();
  }
#pragma unroll
  for (int nt = 0; nt < 4; ++nt) {
    const int col = (nt << 4) + m;
    const float bvu = bu[col];
    const float bvd = bd[col];
#pragma unroll
    for (int r = 0; r < 4; ++r) {
      const int row = row0 + (wm << 4) + (kg << 2) + r;
      if (row < NN) {
        Yu[(size_t)row * 64 + col] = bf16hi(fmaxf(accU[nt][r] + bvu, 0.f));
        Yd[(size_t)row * 64 + col] = bf16hi(fmaxf(accD[nt][r] + bvd, 0.f));
      }
    }
  }
}

__global__ __launch_bounds__(256) void trans2_kernel(
    const float* __restrict__ x,
    const unsigned short* W1uh, const unsigned short* W1ul,
    const unsigned short* W1dh, const unsigned short* W1dl,
    const float* __restrict__ b_u1, const float* __restrict__ b_d1,
    unsigned short* __restrict__ Yu, unsigned short* __restrict__ Yd) {
  __shared__ unsigned short tiles[4][4096];
  trans2_dev(tiles[0], tiles[1], tiles[2], tiles[3], x, W1uh, W1ul, W1dh,
             W1dl, b_u1, b_d1, Yu, Yd, blockIdx.x * 64, threadIdx.x);
}

__global__ __launch_bounds__(256) void mgemm_kernel(
    const unsigned short* Ah, const unsigned short* Al, int lda,
    const unsigned short* Gh, const unsigned short* Gl,
    const unsigned short* Bh, const unsigned short* Bl, int ldb,
    const float* bias, float* outF, unsigned short* outH, unsigned short* outL,
    int ldo, int colbase, int dup, int kchunks, int xchunks) {
  __shared__ unsigned short tiles[4][4096];
  mfma_gemm_dev<false>(tiles[0], tiles[1], tiles[2], tiles[3], Ah, Al, lda,
                       Gh, Gl, Bh, Bl, ldb, bias, outF, outH, outL, ldo,
                       colbase, dup, kchunks, xchunks, blockIdx.x * 64,
                       threadIdx.x);
}

// both layer-1 updates in one launch; A = f32 x (inline split)
__global__ __launch_bounds__(256) void update2m_kernel(
    const float* __restrict__ x,
    const unsigned short* auh, const unsigned short* aul,
    const unsigned short* adh, const unsigned short* adl,
    const unsigned short* U1uh, const unsigned short* U1ul,
    const unsigned short* U1dh, const unsigned short* U1dl,
    unsigned short* outH, unsigned short* outL) {
  __shared__ unsigned short tiles[4][4096];
  if (blockIdx.x < TB)
    mfma_gemm_dev<true>(tiles[0], tiles[1], tiles[2], tiles[3],
                        (const unsigned short*)x, nullptr, 128, auh, aul,
                        U1uh, U1ul, 192, nullptr, nullptr, outH, outL, 128,
                        0, 0, 3, 2, blockIdx.x * 64, threadIdx.x);
  else
    mfma_gemm_dev<true>(tiles[0], tiles[1], tiles[2], tiles[3],
                        (const unsigned short*)x, nullptr, 128, adh, adl,
                        U1dh, U1dl, 192, nullptr, nullptr, outH, outL, 128,
                        64, 0, 3, 2, (blockIdx.x - TB) * 64, threadIdx.x);
}

// ---------------------------------------------------------------------------
// bin index: node -> (node/6250)*32 + (node%6250)/196, in [0,256)
// ---------------------------------------------------------------------------
__device__ __forceinline__ int bin_of(unsigned n) {
  const unsigned bucket = n / 6250u;
  const unsigned rem = n - bucket * 6250u;
  return (int)(bucket * 32u + rem / 196u);
}

// ---------------------------------------------------------------------------
// prep: fine counting-sort into 256 bins/dir (blocks [0,BBK)) || weights (32)
// ---------------------------------------------------------------------------
__global__ __launch_bounds__(256) void prep_kernel(
    const int* __restrict__ src, const int* __restrict__ dst,
    int* __restrict__ gcur,
    unsigned* __restrict__ bdst, unsigned* __restrict__ bsrc,
    const float* __restrict__ U_u1, const float* __restrict__ U_d1,
    const float* __restrict__ W_u1, const float* __restrict__ W_d1,
    const float* __restrict__ W_u2, const float* __restrict__ U_u2,
    unsigned short* __restrict__ wbuf) {
  int bi = blockIdx.x;
  const int t = threadIdx.x;
  if (bi < BBK) {
    __shared__ int hist[512];
    __shared__ int base[512];
    __shared__ int cur[512];
    const int chunk = bi * CHKE;
    for (int j = t; j < 512; j += 256) { hist[j] = 0; cur[j] = 0; }
    __syncthreads();
    unsigned ev[8];
    int bd[8], bs[8];
    bool ok[8];
#pragma unroll
    for (int i = 0; i < 8; ++i) {
      const int e = chunk + i * 256 + t;
      ok[i] = e < NE;
      bd[i] = 0; bs[i] = 0; ev[i] = 0;
      if (ok[i]) {
        const unsigned s = (unsigned)src[e], d = (unsigned)dst[e];
        ev[i] = s | (d << 16);
        bd[i] = bin_of(d);
        bs[i] = bin_of(s);
        atomicAdd(&hist[bd[i]], 1);
        atomicAdd(&hist[256 + bs[i]], 1);
      }
    }
    __syncthreads();
    for (int j = t; j < 512; j += 256)
      base[j] = atomicAdd(&gcur[j], hist[j]);
    __syncthreads();
#pragma unroll
    for (int i = 0; i < 8; ++i) {
      if (ok[i]) {
        const int r1 = base[bd[i]] + atomicAdd(&cur[bd[i]], 1);
        if (r1 < BINCAP) bdst[bd[i] * BINCAP + r1] = ev[i];
        const int r2 = base[256 + bs[i]] + atomicAdd(&cur[256 + bs[i]], 1);
        if (r2 < BINCAP) bsrc[bs[i] * BINCAP + r2] = ev[i];
      }
    }
    return;
  }
  bi -= BBK;
  const int widx = bi >> 2;
  const int quad = bi & 3;
  const int Ks[8] = {192, 192, 128, 128, 128, 192, 64, 128};
  const int offs[8] = {WOFF_U1U, WOFF_U1D, WOFF_W1U, WOFF_W1D,
                       WOFF_W2U, WOFF_U2U, WOFF_WSUM, WOFF_USUM};
  const float* srcs[6] = {U_u1, U_d1, W_u1, W_d1, W_u2, U_u2};
  const int K = Ks[widx];
  const int off = offs[widx];
  const int qsz = K << 4;
  const int beg = quad * qsz;
  for (int e = beg + t; e < beg + qsz; e += 256) {
    const int cc = e / K;
    const int kk = e - cc * K;
    float v;
    if (widx < 6) v = srcs[widx][kk * 64 + cc];
    else if (widx == 6) v = W_u2[kk * 64 + cc] + W_u2[(kk + 64) * 64 + cc];
    else v = (kk < 64) ? (U_u2[kk * 64 + cc] + U_u2[(kk + 64) * 64 + cc])
                       : U_u2[(kk + 64) * 64 + cc];
    unsigned short h, l;
    split1(v, h, l);
    wbuf[off + cc * K + kk] = h;
    wbuf[off + (K << 6) + cc * K + kk] = l;
  }
}

// ---------------------------------------------------------------------------
// binscan: per-direction exclusive scan of 256 bin counts -> binbase
// ---------------------------------------------------------------------------
__global__ __launch_bounds__(256) void binscan_kernel(
    const int* __restrict__ gcur, int* __restrict__ binbase) {
  const int dir = blockIdx.x;
  const int t = threadIdx.x;
  __shared__ int sc[256];
  const int v = gcur[dir * 256 + t];
  sc[t] = v;
  __syncthreads();
  for (int off = 1; off < 256; off <<= 1) {
    int add = (t >= off) ? sc[t - off] : 0;
    __syncthreads();
    sc[t] += add;
    __syncthreads();
  }
  binbase[dir * 256 + t] = sc[t] - v;  // exclusive
}

// ---------------------------------------------------------------------------
// placeC: one block per bin; LDS hist -> scan -> rowptr + cols, no gl atomics
// ---------------------------------------------------------------------------
__global__ __launch_bounds__(256) void placeC_kernel(
    const int* __restrict__ gcur, const int* __restrict__ binbase,
    const unsigned* __restrict__ bdst, const unsigned* __restrict__ bsrc,
    int* __restrict__ rp_dst, int* __restrict__ rp_src,
    unsigned short* __restrict__ col_dst, unsigned short* __restrict__ col_src) {
  const int gbin = blockIdx.x;         // 0..511
  const int dir = gbin >> 8;
  const int bin = gbin & 255;
  const int bucket = bin >> 5;
  const int sub = bin & 31;
  const unsigned lo = (unsigned)(bucket * 6250 + sub * SUBW);
  const int subn = min(SUBW, 6250 - sub * SUBW);
  __shared__ int hist[SUBW];
  __shared__ int sc[SUBW];
  __shared__ int cur[SUBW];
  const int t = threadIdx.x;
  if (t < subn) hist[t] = 0;
  __syncthreads();
  const int cnt = min(gcur[gbin], BINCAP);
  const unsigned* p = (dir ? bsrc : bdst) + (size_t)bin * BINCAP;
  const int cnt4 = cnt & ~3;
  for (int i = t * 4; i < cnt4; i += 1024) {
    const uint4 v = *(const uint4*)(p + i);
    const unsigned n0 = dir ? (v.x & 0xFFFFu) : (v.x >> 16);
    const unsigned n1 = dir ? (v.y & 0xFFFFu) : (v.y >> 16);
    const unsigned n2 = dir ? (v.z & 0xFFFFu) : (v.z >> 16);
    const unsigned n3 = dir ? (v.w & 0xFFFFu) : (v.w >> 16);
    atomicAdd(&hist[n0 - lo], 1);
    atomicAdd(&hist[n1 - lo], 1);
    atomicAdd(&hist[n2 - lo], 1);
    atomicAdd(&hist[n3 - lo], 1);
  }
  for (int i = cnt4 + t; i < cnt; i += 256) {
    const unsigned n = dir ? (p[i] & 0xFFFFu) : (p[i] >> 16);
    atomicAdd(&hist[n - lo], 1);
  }
  __syncthreads();
  if (t < subn) sc[t] = hist[t];
  __syncthreads();
  for (int off = 1; off < SUBW; off <<= 1) {
    int add = (t < subn && t >= off) ? sc[t - off] : 0;
    __syncthreads();
    if (t < subn) sc[t] += add;
    __syncthreads();
  }
  const int bb = binbase[gbin];
  int* rp = dir ? rp_src : rp_dst;
  if (t < subn) {
    rp[lo + t] = bb + sc[t];            // inclusive end
    cur[t] = bb + sc[t] - hist[t];      // exclusive start cursor
  }
  __syncthreads();
  unsigned short* col = dir ? col_src : col_dst;
  for (int i = t * 4; i < cnt4; i += 1024) {
    const uint4 v = *(const uint4*)(p + i);
    const unsigned vs[4] = {v.x, v.y, v.z, v.w};
#pragma unroll
    for (int k = 0; k < 4; ++k) {
      const unsigned n = dir ? (vs[k] & 0xFFFFu) : (vs[k] >> 16);
      const unsigned q = dir ? (vs[k] >> 16) : (vs[k] & 0xFFFFu);
      col[atomicAdd(&cur[n - lo], 1)] = (unsigned short)q;
    }
  }
  for (int i = cnt4 + t; i < cnt; i += 256) {
    const unsigned v = p[i];
    const unsigned n = dir ? (v & 0xFFFFu) : (v >> 16);
    const unsigned q = dir ? (v >> 16) : (v & 0xFFFFu);
    col[atomicAdd(&cur[n - lo], 1)] = (unsigned short)q;
  }
}

// ---------------------------------------------------------------------------
// pull-gather mean from bf16 Y rows (128B), XCD-aligned node swizzle.
// 8 edge groups x 8 lanes x 8 bf16; agg written as hi/lo bf16 planes.
// ---------------------------------------------------------------------------
__device__ __forceinline__ void gatherb_dev(
    const unsigned short* __restrict__ Yb, const int* __restrict__ rowptr,
    const unsigned short* __restrict__ col,
    unsigned short* __restrict__ aggh, unsigned short* __restrict__ aggl,
    int seg, int tid) {
  const int w = tid >> 6;
  const int lane = tid & 63;
  const int off = (seg >> 3) * 4 + w;
  if (off >= 6250) return;
  const int node = (seg & 7) * 6250 + off;
  const int eg = lane >> 3;          // 0..7
  const int cq = (lane & 7) << 3;    // 8-col slice
  const int start = (node == 0) ? 0 : rowptr[node - 1];
  const int end = rowptr[node];
  float acc[8];
#pragma unroll
  for (int i = 0; i < 8; ++i) acc[i] = 0.f;
  int e = start + eg;
  for (; e + 8 < end; e += 16) {
    const int j0 = col[e];
    const int j1 = col[e + 8];
    const uint4 v0 = *(const uint4*)(Yb + (size_t)j0 * 64 + cq);
    const uint4 v1 = *(const uint4*)(Yb + (size_t)j1 * 64 + cq);
    acc[0] += bfu_lo(v0.x) + bfu_lo(v1.x);
    acc[1] += bfu_hi(v0.x) + bfu_hi(v1.x);
    acc[2] += bfu_lo(v0.y) + bfu_lo(v1.y);
    acc[3] += bfu_hi(v0.y) + bfu_hi(v1.y);
    acc[4] += bfu_lo(v0.z) + bfu_lo(v1.z);
    acc[5] += bfu_hi(v0.z) + bfu_hi(v1.z);
    acc[6] += bfu_lo(v0.w) + bfu_lo(v1.w);
    acc[7] += bfu_hi(v0.w) + bfu_hi(v1.w);
  }
  for (; e < end; e += 8) {
    const int j = col[e];
    const uint4 v = *(const uint4*)(Yb + (size_t)j * 64 + cq);
    acc[0] += bfu_lo(v.x);
    acc[1] += bfu_hi(v.x);
    acc[2] += bfu_lo(v.y);
    acc[3] += bfu_hi(v.y);
    acc[4] += bfu_lo(v.z);
    acc[5] += bfu_hi(v.z);
    acc[6] += bfu_lo(v.w);
    acc[7] += bfu_hi(v.w);
  }
#pragma unroll
  for (int i = 0; i < 8; ++i) {
    acc[i] += __shfl_xor(acc[i], 8);
    acc[i] += __shfl_xor(acc[i], 16);
    acc[i] += __shfl_xor(acc[i], 32);
  }
  if (eg == 0) {
    const float inv = 1.f / (float)max(end - start, 1);
    unsigned short h[8], l[8];
#pragma unroll
    for (int i = 0; i < 8; ++i) split1(acc[i] * inv, h[i], l[i]);
    uint4 H, L;
    H.x = (unsigned)h[0] | ((unsigned)h[1] << 16);
    H.y = (unsigned)h[2] | ((unsigned)h[3] << 16);
    H.z = (unsigned)h[4] | ((unsigned)h[5] << 16);
    H.w = (unsigned)h[6] | ((unsigned)h[7] << 16);
    L.x = (unsigned)l[0] | ((unsigned)l[1] << 16);
    L.y = (unsigned)l[2] | ((unsigned)l[3] << 16);
    L.z = (unsigned)l[4] | ((unsigned)l[5] << 16);
    L.w = (unsigned)l[6] | ((unsigned)l[7] << 16);
    *(uint4*)(aggh + (size_t)node * 64 + cq) = H;
    *(uint4*)(aggl + (size_t)node * 64 + cq) = L;
  }
}

__global__ __launch_bounds__(256) void gatherb_kernel(
    const unsigned short* __restrict__ Yb, const int* __restrict__ rowptr,
    const unsigned short* __restrict__ col,
    unsigned short* __restrict__ aggh, unsigned short* __restrict__ aggl) {
  gatherb_dev(Yb, rowptr, col, aggh, aggl, blockIdx.x, threadIdx.x);
}

__global__ __launch_bounds__(256) void gatherb2_kernel(
    const unsigned short* __restrict__ Ybu, const int* __restrict__ rp_dst,
    const unsigned short* __restrict__ col_dst,
    unsigned short* auh, unsigned short* aul,
    const unsigned short* __restrict__ Ybd, const int* __restrict__ rp_src,
    const unsigned short* __restrict__ col_src,
    unsigned short* adh, unsigned short* adl) {
  if (blockIdx.x < GBS)
    gatherb_dev(Ybu, rp_dst, col_dst, auh, aul, blockIdx.x, threadIdx.x);
  else
    gatherb_dev(Ybd, rp_src, col_src, adh, adl, blockIdx.x - GBS, threadIdx.x);
}

// ===========================================================================
// Fallback path (vector-f32 GEMM + replicated edge pass) for small workspaces
// ===========================================================================
__global__ __launch_bounds__(256) void pack_kernel(
    const int* __restrict__ src, const int* __restrict__ dst,
    unsigned* __restrict__ epack) {
  for (int e = blockIdx.x * 256 + threadIdx.x; e < NE; e += 1024 * 256)
    epack[e] = (unsigned)src[e] | ((unsigned)dst[e] << 16);
}

__device__ __forceinline__ void place_dev4(
    const unsigned* __restrict__ epack,
    int* __restrict__ rp_dst, int* __restrict__ rp_src,
    unsigned short* __restrict__ col_dst, unsigned short* __restrict__ col_src,
    int bi, int tid) {
  const unsigned lo = (unsigned)(bi & 7) * 6250u;
  const int g = (bi >> 3) * 256 + tid;
  for (int e = g * 4; e < NE; e += 262144) {
    const uint4 v4 = *(const uint4*)(epack + e);
    const unsigned vs[4] = {v4.x, v4.y, v4.z, v4.w};
#pragma unroll
    for (int i = 0; i < 4; ++i) {
      const unsigned s = vs[i] & 0xFFFFu, d = vs[i] >> 16;
      if (d - lo < 6250u)
        col_dst[atomicAdd(&rp_dst[d], 1)] = (unsigned short)s;
      if (s - lo < 6250u)
        col_src[atomicAdd(&rp_src[s], 1)] = (unsigned short)d;
    }
  }
}

__global__ __launch_bounds__(256) void count_old_kernel(
    const unsigned* __restrict__ epack,
    int* __restrict__ rp_dst, int* __restrict__ rp_src) {
  const int bi = blockIdx.x;
  const unsigned lo = (unsigned)(bi & 7) * 6250u;
  const int g = (bi >> 3) * 256 + threadIdx.x;
  for (int e = g * 4; e < NE; e += 262144) {
    const uint4 v4 = *(const uint4*)(epack + e);
    const unsigned vs[4] = {v4.x, v4.y, v4.z, v4.w};
#pragma unroll
    for (int i = 0; i < 4; ++i) {
      const unsigned s = vs[i] & 0xFFFFu, d = vs[i] >> 16;
      if (d - lo < 6250u) atomicAdd(&rp_dst[d], 1);
      if (s - lo < 6250u) atomicAdd(&rp_src[s], 1);
    }
  }
}

#define CHUNK 49
__global__ __launch_bounds__(1024) void scan_kernel(
    int* __restrict__ a0, int* __restrict__ a1) {
  int* a = (blockIdx.x == 0) ? a0 : a1;
  __shared__ int part[1024];
  const int t = threadIdx.x;
  const int beg = t * CHUNK;
  const int end = min(beg + CHUNK, NN);
  int s = 0;
  for (int i = beg; i < end; ++i) s += a[i];
  part[t] = s;
  __syncthreads();
  for (int off = 1; off < 1024; off <<= 1) {
    int add = (t >= off) ? part[t - off] : 0;
    __syncthreads();
    part[t] += add;
    __syncthreads();
  }
  int run = (t == 0) ? 0 : part[t - 1];
  for (int i = beg; i < end; ++i) {
    const int c = a[i];
    a[i] = run;
    run += c;
  }
}

__device__ __forceinline__ void gatherF_dev(
    const float* __restrict__ Y, const int* __restrict__ rowptr,
    const unsigned short* __restrict__ col, float* __restrict__ AGGf,
    int seg, int tid) {
  const int w = tid >> 6;
  const int lane = tid & 63;
  const int off = (seg >> 3) * 4 + w;
  if (off >= 6250) return;
  const int node = (seg & 7) * 6250 + off;
  const int eg = lane >> 4;
  const int cq = (lane & 15) << 2;
  const int start = (node == 0) ? 0 : rowptr[node - 1];
  const int end = rowptr[node];
  float4 acc = make_float4(0.f, 0.f, 0.f, 0.f);
  for (int e = start + eg; e < end; e += 4) {
    const float4 y = *(const float4*)(Y + (size_t)col[e] * 64 + cq);
    acc.x += y.x; acc.y += y.y; acc.z += y.z; acc.w += y.w;
  }
  acc.x += __shfl_xor(acc.x, 16);
  acc.y += __shfl_xor(acc.y, 16);
  acc.z += __shfl_xor(acc.z, 16);
  acc.w += __shfl_xor(acc.w, 16);
  acc.x += __shfl_xor(acc.x, 32);
  acc.y += __shfl_xor(acc.y, 32);
  acc.z += __shfl_xor(acc.z, 32);
  acc.w += __shfl_xor(acc.w, 32);
  if (eg == 0) {
    const float inv = 1.f / (float)max(end - start, 1);
    float4 o;
    o.x = acc.x * inv; o.y = acc.y * inv;
    o.z = acc.z * inv; o.w = acc.w * inv;
    *(float4*)(AGGf + (size_t)node * 64 + cq) = o;
  }
}

__global__ __launch_bounds__(256) void gatherF_kernel(
    const float* __restrict__ Y, const int* __restrict__ rowptr,
    const unsigned short* __restrict__ col, float* __restrict__ AGGf) {
  gatherF_dev(Y, rowptr, col, AGGf, blockIdx.x, threadIdx.x);
}

__device__ __forceinline__ void gemm64_dev(
    float (*Xt)[68], float* Ws, const float* __restrict__ X, int ldx,
    const float* __restrict__ AGG, const float* __restrict__ W,
    const float* __restrict__ b, float* __restrict__ out, int ldo,
    int colbase, int dup, int kchunks, int xchunks, int row0, int tid) {
  const int tx = tid & 15, ty = tid >> 4;
  float acc[4][4] = {{0.f}};
  for (int c = 0; c < kchunks; ++c) {
    {
      const int rr = tid >> 2;
      const int cg = (tid & 3) << 4;
      const float* srcp;
      int ld, co;
      if (c < xchunks) { srcp = X; ld = ldx; co = c * 64; }
      else             { srcp = AGG; ld = 64; co = 0; }
      int row = row0 + rr;
      if (row > NN - 1) row = NN - 1;
      const float* g = srcp + row * ld + co + cg;
      const float4 v0 = *(const float4*)(g + 0);
      const float4 v1 = *(const float4*)(g + 4);
      const float4 v2 = *(const float4*)(g + 8);
      const float4 v3 = *(const float4*)(g + 12);
      Xt[cg + 0][rr] = v0.x;  Xt[cg + 1][rr] = v0.y;
      Xt[cg + 2][rr] = v0.z;  Xt[cg + 3][rr] = v0.w;
      Xt[cg + 4][rr] = v1.x;  Xt[cg + 5][rr] = v1.y;
      Xt[cg + 6][rr] = v1.z;  Xt[cg + 7][rr] = v1.w;
      Xt[cg + 8][rr] = v2.x;  Xt[cg + 9][rr] = v2.y;
      Xt[cg + 10][rr] = v2.z; Xt[cg + 11][rr] = v2.w;
      Xt[cg + 12][rr] = v3.x; Xt[cg + 13][rr] = v3.y;
      Xt[cg + 14][rr] = v3.z; Xt[cg + 15][rr] = v3.w;
      const float4* wg = (const float4*)(W + c * 64 * 64);
      float4* wl = (float4*)Ws;
      wl[tid] = wg[tid];
      wl[tid + 256] = wg[tid + 256];
      wl[tid + 512] = wg[tid + 512];
      wl[tid + 768] = wg[tid + 768];
    }
    __syncthreads();
#pragma unroll 8
    for (int kk = 0; kk < 64; ++kk) {
      const float4 a = *(const float4*)&Xt[kk][tx << 2];
      const float4 w = *(const float4*)&Ws[kk * 64 + (ty << 2)];
      acc[0][0] += a.x * w.x; acc[0][1] += a.x * w.y;
      acc[0][2] += a.x * w.z; acc[0][3] += a.x * w.w;
      acc[1][0] += a.y * w.x; acc[1][1] += a.y * w.y;
      acc[1][2] += a.y * w.z; acc[1][3] += a.y * w.w;
      acc[2][0] += a.z * w.x; acc[2][1] += a.z * w.y;
      acc[2][2] += a.z * w.z; acc[2][3] += a.z * w.w;
      acc[3][0] += a.w * w.x; acc[3][1] += a.w * w.y;
      acc[3][2] += a.w * w.z; acc[3][3] += a.w * w.w;
    }
    __syncthreads();
  }
  float4 bv = make_float4(0.f, 0.f, 0.f, 0.f);
  if (b) bv = *(const float4*)(b + (ty << 2));
#pragma unroll
  for (int i = 0; i < 4; ++i) {
    const int row = row0 + (tx << 2) + i;
    if (row < NN) {
      float4 o;
      o.x = fmaxf(acc[i][0] + bv.x, 0.f);
      o.y = fmaxf(acc[i][1] + bv.y, 0.f);
      o.z = fmaxf(acc[i][2] + bv.z, 0.f);
      o.w = fmaxf(acc[i][3] + bv.w, 0.f);
      *(float4*)(out + row * ldo + colbase + (ty << 2)) = o;
      if (dup) *(float4*)(out + row * ldo + 64 + (ty << 2)) = o;
    }
  }
}

__global__ __launch_bounds__(256) void gemm_kernel(
    const float* __restrict__ X, int ldx, const float* __restrict__ AGG,
    const float* __restrict__ W, const float* __restrict__ b,
    float* __restrict__ out, int ldo, int colbase, int dup,
    int kchunks, int xchunks) {
  __shared__ __align__(16) float Xt[64][68];
  __shared__ __align__(16) float Ws[4096];
  gemm64_dev(Xt, Ws, X, ldx, AGG, W, b, out, ldo, colbase, dup, kchunks,
             xchunks, blockIdx.x * 64, threadIdx.x);
}

__global__ __launch_bounds__(256) void fused0_kernel(
    const unsigned* __restrict__ epack,
    int* __restrict__ rp_dst, int* __restrict__ rp_src,
    unsigned short* __restrict__ col_dst, unsigned short* __restrict__ col_src,
    const float* __restrict__ x,
    const float* __restrict__ W_u1, const float* __restrict__ b_u1,
    float* __restrict__ Y_u,
    const float* __restrict__ W_d1, const float* __restrict__ b_d1,
    float* __restrict__ Y_d) {
  __shared__ __align__(16) float Xt[64][68];
  __shared__ __align__(16) float Ws[4096];
  int bi = blockIdx.x;
  if (bi < 2048) {
    place_dev4(epack, rp_dst, rp_src, col_dst, col_src, bi, threadIdx.x);
    return;
  }
  bi -= 2048;
  if (bi < TB)
    gemm64_dev(Xt, Ws, x, 128, nullptr, W_u1, b_u1, Y_u, 64, 0, 0, 2, 2,
               bi * 64, threadIdx.x);
  else
    gemm64_dev(Xt, Ws, x, 128, nullptr, W_d1, b_d1, Y_d, 64, 0, 0, 2, 2,
               (bi - TB) * 64, threadIdx.x);
}

// ===========================================================================
extern "C" void kernel_launch(void* const* d_in, const int* in_sizes, int n_in,
                              void* d_out, int out_size, void* d_ws, size_t ws_size,
                              hipStream_t stream) {
  const float* x    = (const float*)d_in[0];
  const int*   ei   = (const int*)d_in[1];
  const float* W_u1 = (const float*)d_in[2];
  const float* b_u1 = (const float*)d_in[3];
  const float* U_u1 = (const float*)d_in[4];
  const float* W_d1 = (const float*)d_in[5];
  const float* b_d1 = (const float*)d_in[6];
  const float* U_d1 = (const float*)d_in[7];
  const float* W_u2 = (const float*)d_in[8];
  const float* b_u2 = (const float*)d_in[9];
  const float* U_u2 = (const float*)d_in[10];
  const int* src = ei;
  const int* dst = ei + NE;
  float* out = (float*)d_out;

  char* wsb = (char*)d_ws;
  int* rp_dst  = (int*)wsb;              wsb += NN * sizeof(int);
  int* rp_src  = (int*)wsb;              wsb += NN * sizeof(int);
  int* gcur    = (int*)wsb;              wsb += 512 * sizeof(int);
  int* binbase = (int*)wsb;              wsb += 512 * sizeof(int);
  unsigned short* col_dst = (unsigned short*)wsb; wsb += (size_t)NE * 2;
  unsigned short* col_src = (unsigned short*)wsb; wsb += (size_t)NE * 2;

  const size_t plane = (size_t)NN * 64 * 2;   // 6.4 MB bf16 plane
  const size_t needM = (size_t)2 * NN * 4 + 4096 + (size_t)NE * 4 +
                       (size_t)WBUF_USHORTS * 2 +
                       6 * plane +               // A..F
                       2 * (size_t)NN * 128 * 2; // outh, outl

  hipMemsetAsync(gcur, 0, 512 * sizeof(int), stream);

  if (ws_size >= needM) {
    unsigned short* wbuf = (unsigned short*)wsb; wsb += (size_t)WBUF_USHORTS * 2;
    unsigned short* A = (unsigned short*)wsb; wsb += plane;  // Yb_u
    unsigned short* B = (unsigned short*)wsb; wsb += plane;  // Yb_d
    unsigned short* C = (unsigned short*)wsb; wsb += plane;  // agg_uh
    unsigned short* D = (unsigned short*)wsb; wsb += plane;  // agg_ul
    unsigned short* E = (unsigned short*)wsb; wsb += plane;  // agg_dh
    unsigned short* F = (unsigned short*)wsb; wsb += plane;  // agg_dl
    unsigned short* outh = (unsigned short*)wsb; wsb += (size_t)NN * 128 * 2;
    unsigned short* outl = (unsigned short*)wsb;

    // aliases (strict sequential lifetimes):
    unsigned* bdst = (unsigned*)C;   // bins (4MB) live until placeC
    unsigned* bsrc = (unsigned*)D;
    unsigned short* Yb2  = C;        // r2 trans output (bins dead)
    unsigned short* agg2h = E;       // r2 gather out (agg_dh/dl dead)
    unsigned short* agg2l = F;
    unsigned short* O2h = C;         // r2 update out (Yb2 dead)
    unsigned short* O2l = D;
    unsigned short* Yb3 = E;         // r3 trans out (agg2 dead)
    unsigned short* agg3h = A;       // r3 gather out (Yb_u/d dead)
    unsigned short* agg3l = B;

    const unsigned short* U1uh = wbuf + WOFF_U1U;
    const unsigned short* U1ul = wbuf + WOFF_U1U + 64 * 192;
    const unsigned short* U1dh = wbuf + WOFF_U1D;
    const unsigned short* U1dl = wbuf + WOFF_U1D + 64 * 192;
    const unsigned short* W1uh = wbuf + WOFF_W1U;
    const unsigned short* W1ul = wbuf + WOFF_W1U + 64 * 128;
    const unsigned short* W1dh = wbuf + WOFF_W1D;
    const unsigned short* W1dl = wbuf + WOFF_W1D + 64 * 128;
    const unsigned short* W2uh = wbuf + WOFF_W2U;
    const unsigned short* W2ul = wbuf + WOFF_W2U + 64 * 128;
    const unsigned short* U2uh = wbuf + WOFF_U2U;
    const unsigned short* U2ul = wbuf + WOFF_U2U + 64 * 192;
    const unsigned short* Wsh  = wbuf + WOFF_WSUM;
    const unsigned short* Wsl  = wbuf + WOFF_WSUM + 64 * 64;
    const unsigned short* Ush  = wbuf + WOFF_USUM;
    const unsigned short* Usl  = wbuf + WOFF_USUM + 64 * 128;

    // fine counting-sort || weight conversion
    prep_kernel<<<BBK + 32, 256, 0, stream>>>(
        src, dst, gcur, bdst, bsrc, U_u1, U_d1, W_u1, W_d1, W_u2, U_u2, wbuf);
    binscan_kernel<<<2, 256, 0, stream>>>(gcur, binbase);
    // per-bin CSR finalize (reads bins in C,D)
    placeC_kernel<<<512, 256, 0, stream>>>(gcur, binbase, bdst, bsrc,
                                           rp_dst, rp_src, col_dst, col_src);
    // layer-1 transforms -> bf16 Y planes
    trans2_kernel<<<TB, 256, 0, stream>>>(x, W1uh, W1ul, W1dh, W1dl,
                                          b_u1, b_d1, A, B);
    // layer-1 gathers (both dirs)
    gatherb2_kernel<<<2 * GBS, 256, 0, stream>>>(A, rp_dst, col_dst, C, D,
                                                 B, rp_src, col_src, E, F);
    update2m_kernel<<<2 * TB, 256, 0, stream>>>(x, C, D, E, F, U1uh, U1ul,
                                                U1dh, U1dl, outh, outl);
    // round 2
    mgemm_kernel<<<TB, 256, 0, stream>>>(outh, outl, 128, nullptr, nullptr,
                                         W2uh, W2ul, 128, b_u2, nullptr,
                                         Yb2, nullptr, 64, 0, 0, 2, 2);
    gatherb_kernel<<<GBS, 256, 0, stream>>>(Yb2, rp_dst, col_dst, agg2h,
                                            agg2l);
    mgemm_kernel<<<TB, 256, 0, stream>>>(outh, outl, 128, agg2h, agg2l,
                                         U2uh, U2ul, 192, nullptr, nullptr,
                                         O2h, O2l, 64, 0, 0, 3, 2);
    // round 3 (h = [O2,O2] folded into presummed weights)
    mgemm_kernel<<<TB, 256, 0, stream>>>(O2h, O2l, 64, nullptr, nullptr,
                                         Wsh, Wsl, 64, b_u2, nullptr,
                                         Yb3, nullptr, 64, 0, 0, 1, 1);
    gatherb_kernel<<<GBS, 256, 0, stream>>>(Yb3, rp_dst, col_dst, agg3h,
                                            agg3l);
    mgemm_kernel<<<TB, 256, 0, stream>>>(O2h, O2l, 64, agg3h, agg3l,
                                         Ush, Usl, 128, nullptr, out,
                                         nullptr, nullptr, 128, 0, 1, 2, 1);
  } else {
    // fallback: vector-f32 path with replicated edge passes
    unsigned* epack = (unsigned*)wsb; wsb += (size_t)NE * 4;
    float* Y_u = (float*)wsb; wsb += (size_t)NN * 64 * sizeof(float);
    float* Y_d = (float*)wsb; wsb += (size_t)NN * 64 * sizeof(float);
    float* AGG = (float*)wsb;
    hipMemsetAsync(rp_dst, 0, 2 * NN * sizeof(int), stream);
    pack_kernel<<<1024, 256, 0, stream>>>(src, dst, epack);
    count_old_kernel<<<2048, 256, 0, stream>>>(epack, rp_dst, rp_src);
    scan_kernel<<<2, 1024, 0, stream>>>(rp_dst, rp_src);
    fused0_kernel<<<2048 + 2 * TB, 256, 0, stream>>>(
        epack, rp_dst, rp_src, col_dst, col_src, x, W_u1, b_u1, Y_u, W_d1,
        b_d1, Y_d);
    gatherF_kernel<<<GBS, 256, 0, stream>>>(Y_u, rp_dst, col_dst, AGG);
    gemm_kernel<<<TB, 256, 0, stream>>>(x, 128, AGG, U_u1, nullptr, out,
                                        128, 0, 0, 3, 2);
    gatherF_kernel<<<GBS, 256, 0, stream>>>(Y_d, rp_src, col_src, AGG);
    gemm_kernel<<<TB, 256, 0, stream>>>(x, 128, AGG, U_d1, nullptr, out,
                                        128, 64, 0, 3, 2);
    for (int r = 0; r < 2; ++r) {
      gemm_kernel<<<TB, 256, 0, stream>>>(out, 128, nullptr, W_u2, b_u2,
                                          Y_u, 64, 0, 0, 2, 2);
      gatherF_kernel<<<GBS, 256, 0, stream>>>(Y_u, rp_dst, col_dst, AGG);
      gemm_kernel<<<TB, 256, 0, stream>>>(out, 128, AGG, U_u2, nullptr,
                                          out, 128, 0, 1, 3, 2);
    }
  }
}

// Round 14
// 200.840 us; speedup vs baseline: 2.0029x; 1.0135x over previous
//
#include <hip/hip_runtime.h>

#define NN 50000
#define NE 800000
#define TB 782             // ceil(NN/64) gemm row-tile blocks
#define GBS 12504          // 8 * 1563 swizzled gather blocks (4 nodes each)
#define BBK 391            // bucket blocks = ceil(NE/2048)
#define CHKE 2048          // edges per bucket block
#define BINS 256           // bins per direction
#define BINCAP 4096        // per-bin capacity (mean 3125, >17 sigma slack)
#define SUBW 196           // nodes per bin

typedef __attribute__((ext_vector_type(8))) short bhalf8;
typedef __attribute__((ext_vector_type(4))) float floatx4;
typedef __attribute__((ext_vector_type(2))) _Float16 half2v;

// weight buffer offsets (ushort units); l plane = h + 64*K
#define WOFF_U1U 0
#define WOFF_U1D 24576
#define WOFF_W1U 49152
#define WOFF_W1D 65536
#define WOFF_W2U 81920
#define WOFF_U2U 98304
#define WOFF_WSUM 122880
#define WOFF_USUM 131072
#define WBUF_USHORTS 147456

// ---------------------------------------------------------------------------
// bf16 / fp16 helpers
// ---------------------------------------------------------------------------
__device__ __forceinline__ unsigned short bf16hi(float v) {
  union { float f; unsigned u; } c; c.f = v;
  return (unsigned short)((c.u + 0x7FFFu + ((c.u >> 16) & 1u)) >> 16);
}
__device__ __forceinline__ float bf16tof(unsigned short h) {
  union { unsigned u; float f; } c; c.u = ((unsigned)h) << 16;
  return c.f;
}
__device__ __forceinline__ void split1(float v, unsigned short& h,
                                       unsigned short& l) {
  h = bf16hi(v);
  l = bf16hi(v - bf16tof(h));
}
__device__ __forceinline__ void split8(const float4 v0, const float4 v1,
                                       uint4& H, uint4& L) {
  unsigned short h0, l0, h1, l1;
  split1(v0.x, h0, l0); split1(v0.y, h1, l1);
  H.x = (unsigned)h0 | ((unsigned)h1 << 16);
  L.x = (unsigned)l0 | ((unsigned)l1 << 16);
  split1(v0.z, h0, l0); split1(v0.w, h1, l1);
  H.y = (unsigned)h0 | ((unsigned)h1 << 16);
  L.y = (unsigned)l0 | ((unsigned)l1 << 16);
  split1(v1.x, h0, l0); split1(v1.y, h1, l1);
  H.z = (unsigned)h0 | ((unsigned)h1 << 16);
  L.z = (unsigned)l0 | ((unsigned)l1 << 16);
  split1(v1.z, h0, l0); split1(v1.w, h1, l1);
  H.w = (unsigned)h0 | ((unsigned)h1 << 16);
  L.w = (unsigned)l0 | ((unsigned)l1 << 16);
}
__device__ __forceinline__ unsigned short f16b(float v) {
  union { _Float16 h; unsigned short u; } c;
  c.h = (_Float16)v;
  return c.u;
}
__device__ __forceinline__ half2v h2_of(unsigned u) {
  union { unsigned v; half2v h; } c; c.v = u; return c.h;
}
__device__ __forceinline__ unsigned u_of(half2v h) {
  union { half2v h; unsigned v; } c; c.h = h; return c.v;
}

// swizzled LDS byte address for bf16 tile [64 rows][64 k] (128B rows)
#define SWZ(row, inrow) (((row) << 7) + ((inrow) ^ (((row)&7) << 4)))

// ---------------------------------------------------------------------------
// MFMA split-bf16 GEMM (single B): out = relu([A|G] @ B^T (+bias))
// outF: f32 (optional dup). outH+outL: bf16 hi/lo. outH only: fp16 plane.
// ---------------------------------------------------------------------------
template <bool AF32>
__device__ __forceinline__ void mfma_gemm_dev(
    unsigned short* tAh, unsigned short* tAl,
    unsigned short* tBh, unsigned short* tBl,
    const unsigned short* __restrict__ Ah, const unsigned short* __restrict__ Al,
    int lda,
    const unsigned short* __restrict__ Gh, const unsigned short* __restrict__ Gl,
    const unsigned short* __restrict__ Bh, const unsigned short* __restrict__ Bl,
    int ldb, const float* __restrict__ bias,
    float* __restrict__ outF, unsigned short* __restrict__ outH,
    unsigned short* __restrict__ outL,
    int ldo, int colbase, int dup, int kchunks, int xchunks,
    int row0, int tid) {
  const int lane = tid & 63;
  const int wm = tid >> 6;
  const int m = lane & 15;
  const int kg = lane >> 4;
  floatx4 acc[4];
#pragma unroll
  for (int i = 0; i < 4; ++i) acc[i] = (floatx4){0.f, 0.f, 0.f, 0.f};

  for (int c = 0; c < kchunks; ++c) {
#pragma unroll
    for (int q = tid; q < 512; q += 256) {
      const int row = q >> 3, slot = q & 7;
      int gr = row0 + row;
      gr = (gr > NN - 1) ? NN - 1 : gr;
      const int ad = SWZ(row, slot << 4);
      if (AF32 && c < xchunks) {
        const float* f = (const float*)Ah;
        const size_t go = (size_t)gr * lda + (c << 6) + slot * 8;
        const float4 v0 = *(const float4*)(f + go);
        const float4 v1 = *(const float4*)(f + go + 4);
        uint4 H, L;
        split8(v0, v1, H, L);
        *(uint4*)((char*)tAh + ad) = H;
        *(uint4*)((char*)tAl + ad) = L;
      } else {
        const unsigned short* sh;
        const unsigned short* sl;
        int ld, kc;
        if (c < xchunks) { sh = Ah; sl = Al; ld = lda; kc = c << 6; }
        else             { sh = Gh; sl = Gl; ld = 64;  kc = 0; }
        const size_t go = (size_t)gr * ld + kc + slot * 8;
        *(uint4*)((char*)tAh + ad) = *(const uint4*)(sh + go);
        *(uint4*)((char*)tAl + ad) = *(const uint4*)(sl + go);
      }
      const size_t gob = (size_t)row * ldb + (c << 6) + slot * 8;
      *(uint4*)((char*)tBh + ad) = *(const uint4*)(Bh + gob);
      *(uint4*)((char*)tBl + ad) = *(const uint4*)(Bl + gob);
    }
    __syncthreads();
#pragma unroll
    for (int ks = 0; ks < 2; ++ks) {
      const int inrow = (ks << 6) + (kg << 4);
      const int rA = (wm << 4) + m;
      const bhalf8 ah = *(const bhalf8*)((const char*)tAh + SWZ(rA, inrow));
      const bhalf8 al = *(const bhalf8*)((const char*)tAl + SWZ(rA, inrow));
#pragma unroll
      for (int nt = 0; nt < 4; ++nt) {
        const int rB = (nt << 4) + m;
        const bhalf8 bh = *(const bhalf8*)((const char*)tBh + SWZ(rB, inrow));
        const bhalf8 bl = *(const bhalf8*)((const char*)tBl + SWZ(rB, inrow));
        acc[nt] = __builtin_amdgcn_mfma_f32_16x16x32_bf16(ah, bh, acc[nt], 0, 0, 0);
        acc[nt] = __builtin_amdgcn_mfma_f32_16x16x32_bf16(ah, bl, acc[nt], 0, 0, 0);
        acc[nt] = __builtin_amdgcn_mfma_f32_16x16x32_bf16(al, bh, acc[nt], 0, 0, 0);
      }
    }
    __syncthreads();
  }
#pragma unroll
  for (int nt = 0; nt < 4; ++nt) {
    const int col = colbase + (nt << 4) + m;
    const float bv = bias ? bias[(nt << 4) + m] : 0.f;
#pragma unroll
    for (int r = 0; r < 4; ++r) {
      const int row = row0 + (wm << 4) + (kg << 2) + r;
      if (row < NN) {
        const float v = fmaxf(acc[nt][r] + bv, 0.f);
        if (outF) {
          outF[(size_t)row * ldo + col] = v;
          if (dup) outF[(size_t)row * ldo + col + 64] = v;
        }
        if (outH) {
          if (outL) {
            unsigned short h, l;
            split1(v, h, l);
            outH[(size_t)row * ldo + col] = h;
            outL[(size_t)row * ldo + col] = l;
          } else {
            outH[(size_t)row * ldo + col] = f16b(v);
          }
        }
      }
    }
  }
}

// ---------------------------------------------------------------------------
// Dual-output transform, 4-tile (32KB); Y outputs are fp16 planes
// ---------------------------------------------------------------------------
__device__ __forceinline__ void trans2_dev(
    unsigned short* tAh, unsigned short* tAl,
    unsigned short* tBh, unsigned short* tBl,
    const float* __restrict__ x,
    const unsigned short* __restrict__ Wuh, const unsigned short* __restrict__ Wul,
    const unsigned short* __restrict__ Wdh, const unsigned short* __restrict__ Wdl,
    const float* __restrict__ bu, const float* __restrict__ bd,
    unsigned short* __restrict__ Yu, unsigned short* __restrict__ Yd,
    int row0, int tid) {
  const int lane = tid & 63;
  const int wm = tid >> 6;
  const int m = lane & 15;
  const int kg = lane >> 4;
  floatx4 accU[4], accD[4];
#pragma unroll
  for (int i = 0; i < 4; ++i) {
    accU[i] = (floatx4){0.f, 0.f, 0.f, 0.f};
    accD[i] = (floatx4){0.f, 0.f, 0.f, 0.f};
  }
  for (int c = 0; c < 2; ++c) {
#pragma unroll
    for (int q = tid; q < 512; q += 256) {
      const int row = q >> 3, slot = q & 7;
      int gr = row0 + row;
      gr = (gr > NN - 1) ? NN - 1 : gr;
      const int ad = SWZ(row, slot << 4);
      const size_t go = (size_t)gr * 128 + (c << 6) + slot * 8;
      const float4 v0 = *(const float4*)(x + go);
      const float4 v1 = *(const float4*)(x + go + 4);
      uint4 H, L;
      split8(v0, v1, H, L);
      *(uint4*)((char*)tAh + ad) = H;
      *(uint4*)((char*)tAl + ad) = L;
      const size_t gob = (size_t)row * 128 + (c << 6) + slot * 8;
      *(uint4*)((char*)tBh + ad) = *(const uint4*)(Wuh + gob);
      *(uint4*)((char*)tBl + ad) = *(const uint4*)(Wul + gob);
    }
    __syncthreads();
#pragma unroll
    for (int ks = 0; ks < 2; ++ks) {
      const int inrow = (ks << 6) + (kg << 4);
      const int rA = (wm << 4) + m;
      const bhalf8 ah = *(const bhalf8*)((const char*)tAh + SWZ(rA, inrow));
      const bhalf8 al = *(const bhalf8*)((const char*)tAl + SWZ(rA, inrow));
#pragma unroll
      for (int nt = 0; nt < 4; ++nt) {
        const int rB = (nt << 4) + m;
        const int adB = SWZ(rB, inrow);
        const bhalf8 bh = *(const bhalf8*)((const char*)tBh + adB);
        const bhalf8 bl = *(const bhalf8*)((const char*)tBl + adB);
        accU[nt] = __builtin_amdgcn_mfma_f32_16x16x32_bf16(ah, bh, accU[nt], 0, 0, 0);
        accU[nt] = __builtin_amdgcn_mfma_f32_16x16x32_bf16(ah, bl, accU[nt], 0, 0, 0);
        accU[nt] = __builtin_amdgcn_mfma_f32_16x16x32_bf16(al, bh, accU[nt], 0, 0, 0);
      }
    }
    __syncthreads();
#pragma unroll
    for (int q = tid; q < 512; q += 256) {
      const int row = q >> 3, slot = q & 7;
      const int ad = SWZ(row, slot << 4);
      const size_t gob = (size_t)row * 128 + (c << 6) + slot * 8;
      *(uint4*)((char*)tBh + ad) = *(const uint4*)(Wdh + gob);
      *(uint4*)((char*)tBl + ad) = *(const uint4*)(Wdl + gob);
    }
    __syncthreads();
#pragma unroll
    for (int ks = 0; ks < 2; ++ks) {
      const int inrow = (ks << 6) + (kg << 4);
      const int rA = (wm << 4) + m;
      const bhalf8 ah = *(const bhalf8*)((const char*)tAh + SWZ(rA, inrow));
      const bhalf8 al = *(const bhalf8*)((const char*)tAl + SWZ(rA, inrow));
#pragma unroll
      for (int nt = 0; nt < 4; ++nt) {
        const int rB = (nt << 4) + m;
        const int adB = SWZ(rB, inrow);
        const bhalf8 bh = *(const bhalf8*)((const char*)tBh + adB);
        const bhalf8 bl = *(const bhalf8*)((const char*)tBl + adB);
        accD[nt] = __builtin_amdgcn_mfma_f32_16x16x32_bf16(ah, bh, accD[nt], 0, 0, 0);
        accD[nt] = __builtin_amdgcn_mfma_f32_16x16x32_bf16(ah, bl, accD[nt], 0, 0, 0);
        accD[nt] = __builtin_amdgcn_mfma_f32_16x16x32_bf16(al, bh, accD[nt], 0, 0, 0);
      }
    }
    __syncthreads();
  }
#pragma unroll
  for (int nt = 0; nt < 4; ++nt) {
    const int col = (nt << 4) + m;
    const float bvu = bu[col];
    const float bvd = bd[col];
#pragma unroll
    for (int r = 0; r < 4; ++r) {
      const int row = row0 + (wm << 4) + (kg << 2) + r;
      if (row < NN) {
        Yu[(size_t)row * 64 + col] = f16b(fmaxf(accU[nt][r] + bvu, 0.f));
        Yd[(size_t)row * 64 + col] = f16b(fmaxf(accD[nt][r] + bvd, 0.f));
      }
    }
  }
}

__global__ __launch_bounds__(256) void trans2_kernel(
    const float* __restrict__ x,
    const unsigned short* W1uh, const unsigned short* W1ul,
    const unsigned short* W1dh, const unsigned short* W1dl,
    const float* __restrict__ b_u1, const float* __restrict__ b_d1,
    unsigned short* __restrict__ Yu, unsigned short* __restrict__ Yd) {
  __shared__ unsigned short tiles[4][4096];
  trans2_dev(tiles[0], tiles[1], tiles[2], tiles[3], x, W1uh, W1ul, W1dh,
             W1dl, b_u1, b_d1, Yu, Yd, blockIdx.x * 64, threadIdx.x);
}

__global__ __launch_bounds__(256) void mgemm_kernel(
    const unsigned short* Ah, const unsigned short* Al, int lda,
    const unsigned short* Gh, const unsigned short* Gl,
    const unsigned short* Bh, const unsigned short* Bl, int ldb,
    const float* bias, float* outF, unsigned short* outH, unsigned short* outL,
    int ldo, int colbase, int dup, int kchunks, int xchunks) {
  __shared__ unsigned short tiles[4][4096];
  mfma_gemm_dev<false>(tiles[0], tiles[1], tiles[2], tiles[3], Ah, Al, lda,
                       Gh, Gl, Bh, Bl, ldb, bias, outF, outH, outL, ldo,
                       colbase, dup, kchunks, xchunks, blockIdx.x * 64,
                       threadIdx.x);
}

// both layer-1 updates in one launch; A = f32 x (inline split)
__global__ __launch_bounds__(256) void update2m_kernel(
    const float* __restrict__ x,
    const unsigned short* auh, const unsigned short* aul,
    const unsigned short* adh, const unsigned short* adl,
    const unsigned short* U1uh, const unsigned short* U1ul,
    const unsigned short* U1dh, const unsigned short* U1dl,
    unsigned short* outH, unsigned short* outL) {
  __shared__ unsigned short tiles[4][4096];
  if (blockIdx.x < TB)
    mfma_gemm_dev<true>(tiles[0], tiles[1], tiles[2], tiles[3],
                        (const unsigned short*)x, nullptr, 128, auh, aul,
                        U1uh, U1ul, 192, nullptr, nullptr, outH, outL, 128,
                        0, 0, 3, 2, blockIdx.x * 64, threadIdx.x);
  else
    mfma_gemm_dev<true>(tiles[0], tiles[1], tiles[2], tiles[3],
                        (const unsigned short*)x, nullptr, 128, adh, adl,
                        U1dh, U1dl, 192, nullptr, nullptr, outH, outL, 128,
                        64, 0, 3, 2, (blockIdx.x - TB) * 64, threadIdx.x);
}

// ---------------------------------------------------------------------------
// bin index: node -> (node/6250)*32 + (node%6250)/196, in [0,256)
// ---------------------------------------------------------------------------
__device__ __forceinline__ int bin_of(unsigned n) {
  const unsigned bucket = n / 6250u;
  const unsigned rem = n - bucket * 6250u;
  return (int)(bucket * 32u + rem / 196u);
}

// ---------------------------------------------------------------------------
// prep: fine counting-sort into 256 bins/dir (blocks [0,BBK)) || weights (32)
// ---------------------------------------------------------------------------
__global__ __launch_bounds__(256) void prep_kernel(
    const int* __restrict__ src, const int* __restrict__ dst,
    int* __restrict__ gcur,
    unsigned* __restrict__ bdst, unsigned* __restrict__ bsrc,
    const float* __restrict__ U_u1, const float* __restrict__ U_d1,
    const float* __restrict__ W_u1, const float* __restrict__ W_d1,
    const float* __restrict__ W_u2, const float* __restrict__ U_u2,
    unsigned short* __restrict__ wbuf) {
  int bi = blockIdx.x;
  const int t = threadIdx.x;
  if (bi < BBK) {
    __shared__ int hist[512];
    __shared__ int base[512];
    __shared__ int cur[512];
    const int chunk = bi * CHKE;
    for (int j = t; j < 512; j += 256) { hist[j] = 0; cur[j] = 0; }
    __syncthreads();
    unsigned ev[8];
    int bd[8], bs[8];
    bool ok[8];
#pragma unroll
    for (int i = 0; i < 8; ++i) {
      const int e = chunk + i * 256 + t;
      ok[i] = e < NE;
      bd[i] = 0; bs[i] = 0; ev[i] = 0;
      if (ok[i]) {
        const unsigned s = (unsigned)src[e], d = (unsigned)dst[e];
        ev[i] = s | (d << 16);
        bd[i] = bin_of(d);
        bs[i] = bin_of(s);
        atomicAdd(&hist[bd[i]], 1);
        atomicAdd(&hist[256 + bs[i]], 1);
      }
    }
    __syncthreads();
    for (int j = t; j < 512; j += 256)
      base[j] = atomicAdd(&gcur[j], hist[j]);
    __syncthreads();
#pragma unroll
    for (int i = 0; i < 8; ++i) {
      if (ok[i]) {
        const int r1 = base[bd[i]] + atomicAdd(&cur[bd[i]], 1);
        if (r1 < BINCAP) bdst[bd[i] * BINCAP + r1] = ev[i];
        const int r2 = base[256 + bs[i]] + atomicAdd(&cur[256 + bs[i]], 1);
        if (r2 < BINCAP) bsrc[bs[i] * BINCAP + r2] = ev[i];
      }
    }
    return;
  }
  bi -= BBK;
  const int widx = bi >> 2;
  const int quad = bi & 3;
  const int Ks[8] = {192, 192, 128, 128, 128, 192, 64, 128};
  const int offs[8] = {WOFF_U1U, WOFF_U1D, WOFF_W1U, WOFF_W1D,
                       WOFF_W2U, WOFF_U2U, WOFF_WSUM, WOFF_USUM};
  const float* srcs[6] = {U_u1, U_d1, W_u1, W_d1, W_u2, U_u2};
  const int K = Ks[widx];
  const int off = offs[widx];
  const int qsz = K << 4;
  const int beg = quad * qsz;
  for (int e = beg + t; e < beg + qsz; e += 256) {
    const int cc = e / K;
    const int kk = e - cc * K;
    float v;
    if (widx < 6) v = srcs[widx][kk * 64 + cc];
    else if (widx == 6) v = W_u2[kk * 64 + cc] + W_u2[(kk + 64) * 64 + cc];
    else v = (kk < 64) ? (U_u2[kk * 64 + cc] + U_u2[(kk + 64) * 64 + cc])
                       : U_u2[(kk + 64) * 64 + cc];
    unsigned short h, l;
    split1(v, h, l);
    wbuf[off + cc * K + kk] = h;
    wbuf[off + (K << 6) + cc * K + kk] = l;
  }
}

// ---------------------------------------------------------------------------
// binscan: per-direction exclusive scan of 256 bin counts -> binbase
// ---------------------------------------------------------------------------
__global__ __launch_bounds__(256) void binscan_kernel(
    const int* __restrict__ gcur, int* __restrict__ binbase) {
  const int dir = blockIdx.x;
  const int t = threadIdx.x;
  __shared__ int sc[256];
  const int v = gcur[dir * 256 + t];
  sc[t] = v;
  __syncthreads();
  for (int off = 1; off < 256; off <<= 1) {
    int add = (t >= off) ? sc[t - off] : 0;
    __syncthreads();
    sc[t] += add;
    __syncthreads();
  }
  binbase[dir * 256 + t] = sc[t] - v;  // exclusive
}

// ---------------------------------------------------------------------------
// placeC: one block per bin; LDS hist -> scan -> rowptr + cols, no gl atomics
// ---------------------------------------------------------------------------
__global__ __launch_bounds__(256) void placeC_kernel(
    const int* __restrict__ gcur, const int* __restrict__ binbase,
    const unsigned* __restrict__ bdst, const unsigned* __restrict__ bsrc,
    int* __restrict__ rp_dst, int* __restrict__ rp_src,
    unsigned short* __restrict__ col_dst, unsigned short* __restrict__ col_src) {
  const int gbin = blockIdx.x;         // 0..511
  const int dir = gbin >> 8;
  const int bin = gbin & 255;
  const int bucket = bin >> 5;
  const int sub = bin & 31;
  const unsigned lo = (unsigned)(bucket * 6250 + sub * SUBW);
  const int subn = min(SUBW, 6250 - sub * SUBW);
  __shared__ int hist[SUBW];
  __shared__ int sc[SUBW];
  __shared__ int cur[SUBW];
  const int t = threadIdx.x;
  if (t < subn) hist[t] = 0;
  __syncthreads();
  const int cnt = min(gcur[gbin], BINCAP);
  const unsigned* p = (dir ? bsrc : bdst) + (size_t)bin * BINCAP;
  const int cnt4 = cnt & ~3;
  for (int i = t * 4; i < cnt4; i += 1024) {
    const uint4 v = *(const uint4*)(p + i);
    const unsigned n0 = dir ? (v.x & 0xFFFFu) : (v.x >> 16);
    const unsigned n1 = dir ? (v.y & 0xFFFFu) : (v.y >> 16);
    const unsigned n2 = dir ? (v.z & 0xFFFFu) : (v.z >> 16);
    const unsigned n3 = dir ? (v.w & 0xFFFFu) : (v.w >> 16);
    atomicAdd(&hist[n0 - lo], 1);
    atomicAdd(&hist[n1 - lo], 1);
    atomicAdd(&hist[n2 - lo], 1);
    atomicAdd(&hist[n3 - lo], 1);
  }
  for (int i = cnt4 + t; i < cnt; i += 256) {
    const unsigned n = dir ? (p[i] & 0xFFFFu) : (p[i] >> 16);
    atomicAdd(&hist[n - lo], 1);
  }
  __syncthreads();
  if (t < subn) sc[t] = hist[t];
  __syncthreads();
  for (int off = 1; off < SUBW; off <<= 1) {
    int add = (t < subn && t >= off) ? sc[t - off] : 0;
    __syncthreads();
    if (t < subn) sc[t] += add;
    __syncthreads();
  }
  const int bb = binbase[gbin];
  int* rp = dir ? rp_src : rp_dst;
  if (t < subn) {
    rp[lo + t] = bb + sc[t];            // inclusive end
    cur[t] = bb + sc[t] - hist[t];      // exclusive start cursor
  }
  __syncthreads();
  unsigned short* col = dir ? col_src : col_dst;
  for (int i = t * 4; i < cnt4; i += 1024) {
    const uint4 v = *(const uint4*)(p + i);
    const unsigned vs[4] = {v.x, v.y, v.z, v.w};
#pragma unroll
    for (int k = 0; k < 4; ++k) {
      const unsigned n = dir ? (vs[k] & 0xFFFFu) : (vs[k] >> 16);
      const unsigned q = dir ? (vs[k] >> 16) : (vs[k] & 0xFFFFu);
      col[atomicAdd(&cur[n - lo], 1)] = (unsigned short)q;
    }
  }
  for (int i = cnt4 + t; i < cnt; i += 256) {
    const unsigned v = p[i];
    const unsigned n = dir ? (v & 0xFFFFu) : (v >> 16);
    const unsigned q = dir ? (v >> 16) : (v & 0xFFFFu);
    col[atomicAdd(&cur[n - lo], 1)] = (unsigned short)q;
  }
}

// ---------------------------------------------------------------------------
// pull-gather mean from fp16 Y rows (128B) with packed fp16 accumulation.
// 8 edge groups x 8 lanes x 8 fp16; agg written as hi/lo bf16 planes.
// ---------------------------------------------------------------------------
__device__ __forceinline__ void gatherh_dev(
    const unsigned short* __restrict__ Yh, const int* __restrict__ rowptr,
    const unsigned short* __restrict__ col,
    unsigned short* __restrict__ aggh, unsigned short* __restrict__ aggl,
    int seg, int tid) {
  const int w = tid >> 6;
  const int lane = tid & 63;
  const int off = (seg >> 3) * 4 + w;
  if (off >= 6250) return;
  const int node = (seg & 7) * 6250 + off;
  const int eg = lane >> 3;          // 0..7
  const int cq = (lane & 7) << 3;    // 8-col slice
  const int start = (node == 0) ? 0 : rowptr[node - 1];
  const int end = rowptr[node];
  half2v a0 = h2_of(0u), a1 = h2_of(0u), a2 = h2_of(0u), a3 = h2_of(0u);
  int e = start + eg;
  for (; e + 8 < end; e += 16) {
    const int j0 = col[e];
    const int j1 = col[e + 8];
    const uint4 v0 = *(const uint4*)(Yh + (size_t)j0 * 64 + cq);
    const uint4 v1 = *(const uint4*)(Yh + (size_t)j1 * 64 + cq);
    a0 += h2_of(v0.x) + h2_of(v1.x);
    a1 += h2_of(v0.y) + h2_of(v1.y);
    a2 += h2_of(v0.z) + h2_of(v1.z);
    a3 += h2_of(v0.w) + h2_of(v1.w);
  }
  for (; e < end; e += 8) {
    const int j = col[e];
    const uint4 v = *(const uint4*)(Yh + (size_t)j * 64 + cq);
    a0 += h2_of(v.x);
    a1 += h2_of(v.y);
    a2 += h2_of(v.z);
    a3 += h2_of(v.w);
  }
  // packed shuffle-reduce across the 8 edge groups
#pragma unroll
  for (int d = 8; d <= 32; d <<= 1) {
    a0 += h2_of((unsigned)__shfl_xor((int)u_of(a0), d));
    a1 += h2_of((unsigned)__shfl_xor((int)u_of(a1), d));
    a2 += h2_of((unsigned)__shfl_xor((int)u_of(a2), d));
    a3 += h2_of((unsigned)__shfl_xor((int)u_of(a3), d));
  }
  if (eg == 0) {
    const float inv = 1.f / (float)max(end - start, 1);
    float s[8];
    s[0] = (float)a0[0]; s[1] = (float)a0[1];
    s[2] = (float)a1[0]; s[3] = (float)a1[1];
    s[4] = (float)a2[0]; s[5] = (float)a2[1];
    s[6] = (float)a3[0]; s[7] = (float)a3[1];
    unsigned short h[8], l[8];
#pragma unroll
    for (int i = 0; i < 8; ++i) split1(s[i] * inv, h[i], l[i]);
    uint4 H, L;
    H.x = (unsigned)h[0] | ((unsigned)h[1] << 16);
    H.y = (unsigned)h[2] | ((unsigned)h[3] << 16);
    H.z = (unsigned)h[4] | ((unsigned)h[5] << 16);
    H.w = (unsigned)h[6] | ((unsigned)h[7] << 16);
    L.x = (unsigned)l[0] | ((unsigned)l[1] << 16);
    L.y = (unsigned)l[2] | ((unsigned)l[3] << 16);
    L.z = (unsigned)l[4] | ((unsigned)l[5] << 16);
    L.w = (unsigned)l[6] | ((unsigned)l[7] << 16);
    *(uint4*)(aggh + (size_t)node * 64 + cq) = H;
    *(uint4*)(aggl + (size_t)node * 64 + cq) = L;
  }
}

__global__ __launch_bounds__(256) void gatherh_kernel(
    const unsigned short* __restrict__ Yh, const int* __restrict__ rowptr,
    const unsigned short* __restrict__ col,
    unsigned short* __restrict__ aggh, unsigned short* __restrict__ aggl) {
  gatherh_dev(Yh, rowptr, col, aggh, aggl, blockIdx.x, threadIdx.x);
}

__global__ __launch_bounds__(256) void gatherh2_kernel(
    const unsigned short* __restrict__ Yhu, const int* __restrict__ rp_dst,
    const unsigned short* __restrict__ col_dst,
    unsigned short* auh, unsigned short* aul,
    const unsigned short* __restrict__ Yhd, const int* __restrict__ rp_src,
    const unsigned short* __restrict__ col_src,
    unsigned short* adh, unsigned short* adl) {
  if (blockIdx.x < GBS)
    gatherh_dev(Yhu, rp_dst, col_dst, auh, aul, blockIdx.x, threadIdx.x);
  else
    gatherh_dev(Yhd, rp_src, col_src, adh, adl, blockIdx.x - GBS, threadIdx.x);
}

// ===========================================================================
// Fallback path (vector-f32 GEMM + replicated edge pass) for small workspaces
// ===========================================================================
__global__ __launch_bounds__(256) void pack_kernel(
    const int* __restrict__ src, const int* __restrict__ dst,
    unsigned* __restrict__ epack) {
  for (int e = blockIdx.x * 256 + threadIdx.x; e < NE; e += 1024 * 256)
    epack[e] = (unsigned)src[e] | ((unsigned)dst[e] << 16);
}

__device__ __forceinline__ void place_dev4(
    const unsigned* __restrict__ epack,
    int* __restrict__ rp_dst, int* __restrict__ rp_src,
    unsigned short* __restrict__ col_dst, unsigned short* __restrict__ col_src,
    int bi, int tid) {
  const unsigned lo = (unsigned)(bi & 7) * 6250u;
  const int g = (bi >> 3) * 256 + tid;
  for (int e = g * 4; e < NE; e += 262144) {
    const uint4 v4 = *(const uint4*)(epack + e);
    const unsigned vs[4] = {v4.x, v4.y, v4.z, v4.w};
#pragma unroll
    for (int i = 0; i < 4; ++i) {
      const unsigned s = vs[i] & 0xFFFFu, d = vs[i] >> 16;
      if (d - lo < 6250u)
        col_dst[atomicAdd(&rp_dst[d], 1)] = (unsigned short)s;
      if (s - lo < 6250u)
        col_src[atomicAdd(&rp_src[s], 1)] = (unsigned short)d;
    }
  }
}

__global__ __launch_bounds__(256) void count_old_kernel(
    const unsigned* __restrict__ epack,
    int* __restrict__ rp_dst, int* __restrict__ rp_src) {
  const int bi = blockIdx.x;
  const unsigned lo = (unsigned)(bi & 7) * 6250u;
  const int g = (bi >> 3) * 256 + threadIdx.x;
  for (int e = g * 4; e < NE; e += 262144) {
    const uint4 v4 = *(const uint4*)(epack + e);
    const unsigned vs[4] = {v4.x, v4.y, v4.z, v4.w};
#pragma unroll
    for (int i = 0; i < 4; ++i) {
      const unsigned s = vs[i] & 0xFFFFu, d = vs[i] >> 16;
      if (d - lo < 6250u) atomicAdd(&rp_dst[d], 1);
      if (s - lo < 6250u) atomicAdd(&rp_src[s], 1);
    }
  }
}

#define CHUNK 49
__global__ __launch_bounds__(1024) void scan_kernel(
    int* __restrict__ a0, int* __restrict__ a1) {
  int* a = (blockIdx.x == 0) ? a0 : a1;
  __shared__ int part[1024];
  const int t = threadIdx.x;
  const int beg = t * CHUNK;
  const int end = min(beg + CHUNK, NN);
  int s = 0;
  for (int i = beg; i < end; ++i) s += a[i];
  part[t] = s;
  __syncthreads();
  for (int off = 1; off < 1024; off <<= 1) {
    int add = (t >= off) ? part[t - off] : 0;
    __syncthreads();
    part[t] += add;
    __syncthreads();
  }
  int run = (t == 0) ? 0 : part[t - 1];
  for (int i = beg; i < end; ++i) {
    const int c = a[i];
    a[i] = run;
    run += c;
  }
}

__device__ __forceinline__ void gatherF_dev(
    const float* __restrict__ Y, const int* __restrict__ rowptr,
    const unsigned short* __restrict__ col, float* __restrict__ AGGf,
    int seg, int tid) {
  const int w = tid >> 6;
  const int lane = tid & 63;
  const int off = (seg >> 3) * 4 + w;
  if (off >= 6250) return;
  const int node = (seg & 7) * 6250 + off;
  const int eg = lane >> 4;
  const int cq = (lane & 15) << 2;
  const int start = (node == 0) ? 0 : rowptr[node - 1];
  const int end = rowptr[node];
  float4 acc = make_float4(0.f, 0.f, 0.f, 0.f);
  for (int e = start + eg; e < end; e += 4) {
    const float4 y = *(const float4*)(Y + (size_t)col[e] * 64 + cq);
    acc.x += y.x; acc.y += y.y; acc.z += y.z; acc.w += y.w;
  }
  acc.x += __shfl_xor(acc.x, 16);
  acc.y += __shfl_xor(acc.y, 16);
  acc.z += __shfl_xor(acc.z, 16);
  acc.w += __shfl_xor(acc.w, 16);
  acc.x += __shfl_xor(acc.x, 32);
  acc.y += __shfl_xor(acc.y, 32);
  acc.z += __shfl_xor(acc.z, 32);
  acc.w += __shfl_xor(acc.w, 32);
  if (eg == 0) {
    const float inv = 1.f / (float)max(end - start, 1);
    float4 o;
    o.x = acc.x * inv; o.y = acc.y * inv;
    o.z = acc.z * inv; o.w = acc.w * inv;
    *(float4*)(AGGf + (size_t)node * 64 + cq) = o;
  }
}

__global__ __launch_bounds__(256) void gatherF_kernel(
    const float* __restrict__ Y, const int* __restrict__ rowptr,
    const unsigned short* __restrict__ col, float* __restrict__ AGGf) {
  gatherF_dev(Y, rowptr, col, AGGf, blockIdx.x, threadIdx.x);
}

__device__ __forceinline__ void gemm64_dev(
    float (*Xt)[68], float* Ws, const float* __restrict__ X, int ldx,
    const float* __restrict__ AGG, const float* __restrict__ W,
    const float* __restrict__ b, float* __restrict__ out, int ldo,
    int colbase, int dup, int kchunks, int xchunks, int row0, int tid) {
  const int tx = tid & 15, ty = tid >> 4;
  float acc[4][4] = {{0.f}};
  for (int c = 0; c < kchunks; ++c) {
    {
      const int rr = tid >> 2;
      const int cg = (tid & 3) << 4;
      const float* srcp;
      int ld, co;
      if (c < xchunks) { srcp = X; ld = ldx; co = c * 64; }
      else             { srcp = AGG; ld = 64; co = 0; }
      int row = row0 + rr;
      if (row > NN - 1) row = NN - 1;
      const float* g = srcp + row * ld + co + cg;
      const float4 v0 = *(const float4*)(g + 0);
      const float4 v1 = *(const float4*)(g + 4);
      const float4 v2 = *(const float4*)(g + 8);
      const float4 v3 = *(const float4*)(g + 12);
      Xt[cg + 0][rr] = v0.x;  Xt[cg + 1][rr] = v0.y;
      Xt[cg + 2][rr] = v0.z;  Xt[cg + 3][rr] = v0.w;
      Xt[cg + 4][rr] = v1.x;  Xt[cg + 5][rr] = v1.y;
      Xt[cg + 6][rr] = v1.z;  Xt[cg + 7][rr] = v1.w;
      Xt[cg + 8][rr] = v2.x;  Xt[cg + 9][rr] = v2.y;
      Xt[cg + 10][rr] = v2.z; Xt[cg + 11][rr] = v2.w;
      Xt[cg + 12][rr] = v3.x; Xt[cg + 13][rr] = v3.y;
      Xt[cg + 14][rr] = v3.z; Xt[cg + 15][rr] = v3.w;
      const float4* wg = (const float4*)(W + c * 64 * 64);
      float4* wl = (float4*)Ws;
      wl[tid] = wg[tid];
      wl[tid + 256] = wg[tid + 256];
      wl[tid + 512] = wg[tid + 512];
      wl[tid + 768] = wg[tid + 768];
    }
    __syncthreads();
#pragma unroll 8
    for (int kk = 0; kk < 64; ++kk) {
      const float4 a = *(const float4*)&Xt[kk][tx << 2];
      const float4 w = *(const float4*)&Ws[kk * 64 + (ty << 2)];
      acc[0][0] += a.x * w.x; acc[0][1] += a.x * w.y;
      acc[0][2] += a.x * w.z; acc[0][3] += a.x * w.w;
      acc[1][0] += a.y * w.x; acc[1][1] += a.y * w.y;
      acc[1][2] += a.y * w.z; acc[1][3] += a.y * w.w;
      acc[2][0] += a.z * w.x; acc[2][1] += a.z * w.y;
      acc[2][2] += a.z * w.z; acc[2][3] += a.z * w.w;
      acc[3][0] += a.w * w.x; acc[3][1] += a.w * w.y;
      acc[3][2] += a.w * w.z; acc[3][3] += a.w * w.w;
    }
    __syncthreads();
  }
  float4 bv = make_float4(0.f, 0.f, 0.f, 0.f);
  if (b) bv = *(const float4*)(b + (ty << 2));
#pragma unroll
  for (int i = 0; i < 4; ++i) {
    const int row = row0 + (tx << 2) + i;
    if (row < NN) {
      float4 o;
      o.x = fmaxf(acc[i][0] + bv.x, 0.f);
      o.y = fmaxf(acc[i][1] + bv.y, 0.f);
      o.z = fmaxf(acc[i][2] + bv.z, 0.f);
      o.w = fmaxf(acc[i][3] + bv.w, 0.f);
      *(float4*)(out + row * ldo + colbase + (ty << 2)) = o;
      if (dup) *(float4*)(out + row * ldo + 64 + (ty << 2)) = o;
    }
  }
}

__global__ __launch_bounds__(256) void gemm_kernel(
    const float* __restrict__ X, int ldx, const float* __restrict__ AGG,
    const float* __restrict__ W, const float* __restrict__ b,
    float* __restrict__ out, int ldo, int colbase, int dup,
    int kchunks, int xchunks) {
  __shared__ __align__(16) float Xt[64][68];
  __shared__ __align__(16) float Ws[4096];
  gemm64_dev(Xt, Ws, X, ldx, AGG, W, b, out, ldo, colbase, dup, kchunks,
             xchunks, blockIdx.x * 64, threadIdx.x);
}

__global__ __launch_bounds__(256) void fused0_kernel(
    const unsigned* __restrict__ epack,
    int* __restrict__ rp_dst, int* __restrict__ rp_src,
    unsigned short* __restrict__ col_dst, unsigned short* __restrict__ col_src,
    const float* __restrict__ x,
    const float* __restrict__ W_u1, const float* __restrict__ b_u1,
    float* __restrict__ Y_u,
    const float* __restrict__ W_d1, const float* __restrict__ b_d1,
    float* __restrict__ Y_d) {
  __shared__ __align__(16) float Xt[64][68];
  __shared__ __align__(16) float Ws[4096];
  int bi = blockIdx.x;
  if (bi < 2048) {
    place_dev4(epack, rp_dst, rp_src, col_dst, col_src, bi, threadIdx.x);
    return;
  }
  bi -= 2048;
  if (bi < TB)
    gemm64_dev(Xt, Ws, x, 128, nullptr, W_u1, b_u1, Y_u, 64, 0, 0, 2, 2,
               bi * 64, threadIdx.x);
  else
    gemm64_dev(Xt, Ws, x, 128, nullptr, W_d1, b_d1, Y_d, 64, 0, 0, 2, 2,
               (bi - TB) * 64, threadIdx.x);
}

// ===========================================================================
extern "C" void kernel_launch(void* const* d_in, const int* in_sizes, int n_in,
                              void* d_out, int out_size, void* d_ws, size_t ws_size,
                              hipStream_t stream) {
  const float* x    = (const float*)d_in[0];
  const int*   ei   = (const int*)d_in[1];
  const float* W_u1 = (const float*)d_in[2];
  const float* b_u1 = (const float*)d_in[3];
  const float* U_u1 = (const float*)d_in[4];
  const float* W_d1 = (const float*)d_in[5];
  const float* b_d1 = (const float*)d_in[6];
  const float* U_d1 = (const float*)d_in[7];
  const float* W_u2 = (const float*)d_in[8];
  const float* b_u2 = (const float*)d_in[9];
  const float* U_u2 = (const float*)d_in[10];
  const int* src = ei;
  const int* dst = ei + NE;
  float* out = (float*)d_out;

  char* wsb = (char*)d_ws;
  int* rp_dst  = (int*)wsb;              wsb += NN * sizeof(int);
  int* rp_src  = (int*)wsb;              wsb += NN * sizeof(int);
  int* gcur    = (int*)wsb;              wsb += 512 * sizeof(int);
  int* binbase = (int*)wsb;              wsb += 512 * sizeof(int);
  unsigned short* col_dst = (unsigned short*)wsb; wsb += (size_t)NE * 2;
  unsigned short* col_src = (unsigned short*)wsb; wsb += (size_t)NE * 2;

  const size_t plane = (size_t)NN * 64 * 2;   // 6.4 MB u16 plane
  const size_t needM = (size_t)2 * NN * 4 + 4096 + (size_t)NE * 4 +
                       (size_t)WBUF_USHORTS * 2 +
                       6 * plane +               // A..F
                       2 * (size_t)NN * 128 * 2; // outh, outl

  hipMemsetAsync(gcur, 0, 512 * sizeof(int), stream);

  if (ws_size >= needM) {
    unsigned short* wbuf = (unsigned short*)wsb; wsb += (size_t)WBUF_USHORTS * 2;
    unsigned short* A = (unsigned short*)wsb; wsb += plane;  // Yh_u
    unsigned short* B = (unsigned short*)wsb; wsb += plane;  // Yh_d
    unsigned short* C = (unsigned short*)wsb; wsb += plane;  // agg_uh
    unsigned short* D = (unsigned short*)wsb; wsb += plane;  // agg_ul
    unsigned short* E = (unsigned short*)wsb; wsb += plane;  // agg_dh
    unsigned short* F = (unsigned short*)wsb; wsb += plane;  // agg_dl
    unsigned short* outh = (unsigned short*)wsb; wsb += (size_t)NN * 128 * 2;
    unsigned short* outl = (unsigned short*)wsb;

    // aliases (strict sequential lifetimes):
    unsigned* bdst = (unsigned*)C;   // bins (4MB) live until placeC
    unsigned* bsrc = (unsigned*)D;
    unsigned short* Yh2  = C;        // r2 trans output (bins dead)
    unsigned short* agg2h = E;       // r2 gather out (agg_dh/dl dead)
    unsigned short* agg2l = F;
    unsigned short* O2h = C;         // r2 update out (Yh2 dead)
    unsigned short* O2l = D;
    unsigned short* Yh3 = E;         // r3 trans out (agg2 dead)
    unsigned short* agg3h = A;       // r3 gather out (Yh_u/d dead)
    unsigned short* agg3l = B;

    const unsigned short* U1uh = wbuf + WOFF_U1U;
    const unsigned short* U1ul = wbuf + WOFF_U1U + 64 * 192;
    const unsigned short* U1dh = wbuf + WOFF_U1D;
    const unsigned short* U1dl = wbuf + WOFF_U1D + 64 * 192;
    const unsigned short* W1uh = wbuf + WOFF_W1U;
    const unsigned short* W1ul = wbuf + WOFF_W1U + 64 * 128;
    const unsigned short* W1dh = wbuf + WOFF_W1D;
    const unsigned short* W1dl = wbuf + WOFF_W1D + 64 * 128;
    const unsigned short* W2uh = wbuf + WOFF_W2U;
    const unsigned short* W2ul = wbuf + WOFF_W2U + 64 * 128;
    const unsigned short* U2uh = wbuf + WOFF_U2U;
    const unsigned short* U2ul = wbuf + WOFF_U2U + 64 * 192;
    const unsigned short* Wsh  = wbuf + WOFF_WSUM;
    const unsigned short* Wsl  = wbuf + WOFF_WSUM + 64 * 64;
    const unsigned short* Ush  = wbuf + WOFF_USUM;
    const unsigned short* Usl  = wbuf + WOFF_USUM + 64 * 128;

    // fine counting-sort || weight conversion
    prep_kernel<<<BBK + 32, 256, 0, stream>>>(
        src, dst, gcur, bdst, bsrc, U_u1, U_d1, W_u1, W_d1, W_u2, U_u2, wbuf);
    binscan_kernel<<<2, 256, 0, stream>>>(gcur, binbase);
    // per-bin CSR finalize (reads bins in C,D)
    placeC_kernel<<<512, 256, 0, stream>>>(gcur, binbase, bdst, bsrc,
                                           rp_dst, rp_src, col_dst, col_src);
    // layer-1 transforms -> fp16 Y planes
    trans2_kernel<<<TB, 256, 0, stream>>>(x, W1uh, W1ul, W1dh, W1dl,
                                          b_u1, b_d1, A, B);
    // layer-1 gathers (both dirs), packed fp16 accumulate
    gatherh2_kernel<<<2 * GBS, 256, 0, stream>>>(A, rp_dst, col_dst, C, D,
                                                 B, rp_src, col_src, E, F);
    update2m_kernel<<<2 * TB, 256, 0, stream>>>(x, C, D, E, F, U1uh, U1ul,
                                                U1dh, U1dl, outh, outl);
    // round 2
    mgemm_kernel<<<TB, 256, 0, stream>>>(outh, outl, 128, nullptr, nullptr,
                                         W2uh, W2ul, 128, b_u2, nullptr,
                                         Yh2, nullptr, 64, 0, 0, 2, 2);
    gatherh_kernel<<<GBS, 256, 0, stream>>>(Yh2, rp_dst, col_dst, agg2h,
                                            agg2l);
    mgemm_kernel<<<TB, 256, 0, stream>>>(outh, outl, 128, agg2h, agg2l,
                                         U2uh, U2ul, 192, nullptr, nullptr,
                                         O2h, O2l, 64, 0, 0, 3, 2);
    // round 3 (h = [O2,O2] folded into presummed weights)
    mgemm_kernel<<<TB, 256, 0, stream>>>(O2h, O2l, 64, nullptr, nullptr,
                                         Wsh, Wsl, 64, b_u2, nullptr,
                                         Yh3, nullptr, 64, 0, 0, 1, 1);
    gatherh_kernel<<<GBS, 256, 0, stream>>>(Yh3, rp_dst, col_dst, agg3h,
                                            agg3l);
    mgemm_kernel<<<TB, 256, 0, stream>>>(O2h, O2l, 64, agg3h, agg3l,
                                         Ush, Usl, 128, nullptr, out,
                                         nullptr, nullptr, 128, 0, 1, 2, 1);
  } else {
    // fallback: vector-f32 path with replicated edge passes
    unsigned* epack = (unsigned*)wsb; wsb += (size_t)NE * 4;
    float* Y_u = (float*)wsb; wsb += (size_t)NN * 64 * sizeof(float);
    float* Y_d = (float*)wsb; wsb += (size_t)NN * 64 * sizeof(float);
    float* AGG = (float*)wsb;
    hipMemsetAsync(rp_dst, 0, 2 * NN * sizeof(int), stream);
    pack_kernel<<<1024, 256, 0, stream>>>(src, dst, epack);
    count_old_kernel<<<2048, 256, 0, stream>>>(epack, rp_dst, rp_src);
    scan_kernel<<<2, 1024, 0, stream>>>(rp_dst, rp_src);
    fused0_kernel<<<2048 + 2 * TB, 256, 0, stream>>>(
        epack, rp_dst, rp_src, col_dst, col_src, x, W_u1, b_u1, Y_u, W_d1,
        b_d1, Y_d);
    gatherF_kernel<<<GBS, 256, 0, stream>>>(Y_u, rp_dst, col_dst, AGG);
    gemm_kernel<<<TB, 256, 0, stream>>>(x, 128, AGG, U_u1, nullptr, out,
                                        128, 0, 0, 3, 2);
    gatherF_kernel<<<GBS, 256, 0, stream>>>(Y_d, rp_src, col_src, AGG);
    gemm_kernel<<<TB, 256, 0, stream>>>(x, 128, AGG, U_d1, nullptr, out,
                                        128, 64, 0, 3, 2);
    for (int r = 0; r < 2; ++r) {
      gemm_kernel<<<TB, 256, 0, stream>>>(out, 128, nullptr, W_u2, b_u2,
                                          Y_u, 64, 0, 0, 2, 2);
      gatherF_kernel<<<GBS, 256, 0, stream>>>(Y_u, rp_dst, col_dst, AGG);
      gemm_kernel<<<TB, 256, 0, stream>>>(out, 128, AGG, U_u2, nullptr,
                                          out, 128, 0, 1, 3, 2);
    }
  }
}

// Round 15
// 200.126 us; speedup vs baseline: 2.0101x; 1.0036x over previous
//
#include <hip/hip_runtime.h>

#define NN 50000
#define NE 800000
#define TB 782             // ceil(NN/64) gemm row-tile blocks
#define GBS 12504          // 8 * 1563 swizzled gather blocks (4 nodes each)
#define BBK 391            // bucket blocks = ceil(NE/2048)
#define CHKE 2048          // edges per bucket block
#define BINS 256           // bins per direction
#define BINCAP 4096        // per-bin capacity (mean 3125, >17 sigma slack)
#define SUBW 196           // nodes per bin

typedef __attribute__((ext_vector_type(8))) short bhalf8;
typedef __attribute__((ext_vector_type(4))) float floatx4;
typedef __attribute__((ext_vector_type(2))) _Float16 half2v;

// weight buffer offsets (ushort units); l plane = h + 64*K
#define WOFF_U1U 0
#define WOFF_U1D 24576
#define WOFF_W1U 49152
#define WOFF_W1D 65536
#define WOFF_W2U 81920
#define WOFF_U2U 98304
#define WOFF_WSUM 122880
#define WOFF_USUM 131072
#define WBUF_USHORTS 147456

// ---------------------------------------------------------------------------
// bf16 / fp16 helpers
// ---------------------------------------------------------------------------
__device__ __forceinline__ unsigned short bf16hi(float v) {
  union { float f; unsigned u; } c; c.f = v;
  return (unsigned short)((c.u + 0x7FFFu + ((c.u >> 16) & 1u)) >> 16);
}
__device__ __forceinline__ float bf16tof(unsigned short h) {
  union { unsigned u; float f; } c; c.u = ((unsigned)h) << 16;
  return c.f;
}
__device__ __forceinline__ void split1(float v, unsigned short& h,
                                       unsigned short& l) {
  h = bf16hi(v);
  l = bf16hi(v - bf16tof(h));
}
__device__ __forceinline__ void split8(const float4 v0, const float4 v1,
                                       uint4& H, uint4& L) {
  unsigned short h0, l0, h1, l1;
  split1(v0.x, h0, l0); split1(v0.y, h1, l1);
  H.x = (unsigned)h0 | ((unsigned)h1 << 16);
  L.x = (unsigned)l0 | ((unsigned)l1 << 16);
  split1(v0.z, h0, l0); split1(v0.w, h1, l1);
  H.y = (unsigned)h0 | ((unsigned)h1 << 16);
  L.y = (unsigned)l0 | ((unsigned)l1 << 16);
  split1(v1.x, h0, l0); split1(v1.y, h1, l1);
  H.z = (unsigned)h0 | ((unsigned)h1 << 16);
  L.z = (unsigned)l0 | ((unsigned)l1 << 16);
  split1(v1.z, h0, l0); split1(v1.w, h1, l1);
  H.w = (unsigned)h0 | ((unsigned)h1 << 16);
  L.w = (unsigned)l0 | ((unsigned)l1 << 16);
}
__device__ __forceinline__ unsigned short f16b(float v) {
  union { _Float16 h; unsigned short u; } c;
  c.h = (_Float16)v;
  return c.u;
}
__device__ __forceinline__ half2v h2_of(unsigned u) {
  union { unsigned v; half2v h; } c; c.v = u; return c.h;
}
__device__ __forceinline__ unsigned u_of(half2v h) {
  union { half2v h; unsigned v; } c; c.h = h; return c.v;
}

// swizzled LDS byte address for bf16 tile [64 rows][64 k] (128B rows)
#define SWZ(row, inrow) (((row) << 7) + ((inrow) ^ (((row)&7) << 4)))

// ---------------------------------------------------------------------------
// MFMA split-bf16 GEMM (single B): out = relu([A|G] @ B^T (+bias))
// outF: f32 (optional dup). outH+outL: bf16 hi/lo. outH only: fp16 plane.
// ---------------------------------------------------------------------------
template <bool AF32>
__device__ __forceinline__ void mfma_gemm_dev(
    unsigned short* tAh, unsigned short* tAl,
    unsigned short* tBh, unsigned short* tBl,
    const unsigned short* __restrict__ Ah, const unsigned short* __restrict__ Al,
    int lda,
    const unsigned short* __restrict__ Gh, const unsigned short* __restrict__ Gl,
    const unsigned short* __restrict__ Bh, const unsigned short* __restrict__ Bl,
    int ldb, const float* __restrict__ bias,
    float* __restrict__ outF, unsigned short* __restrict__ outH,
    unsigned short* __restrict__ outL,
    int ldo, int colbase, int dup, int kchunks, int xchunks,
    int row0, int tid) {
  const int lane = tid & 63;
  const int wm = tid >> 6;
  const int m = lane & 15;
  const int kg = lane >> 4;
  floatx4 acc[4];
#pragma unroll
  for (int i = 0; i < 4; ++i) acc[i] = (floatx4){0.f, 0.f, 0.f, 0.f};

  for (int c = 0; c < kchunks; ++c) {
#pragma unroll
    for (int q = tid; q < 512; q += 256) {
      const int row = q >> 3, slot = q & 7;
      int gr = row0 + row;
      gr = (gr > NN - 1) ? NN - 1 : gr;
      const int ad = SWZ(row, slot << 4);
      if (AF32 && c < xchunks) {
        const float* f = (const float*)Ah;
        const size_t go = (size_t)gr * lda + (c << 6) + slot * 8;
        const float4 v0 = *(const float4*)(f + go);
        const float4 v1 = *(const float4*)(f + go + 4);
        uint4 H, L;
        split8(v0, v1, H, L);
        *(uint4*)((char*)tAh + ad) = H;
        *(uint4*)((char*)tAl + ad) = L;
      } else {
        const unsigned short* sh;
        const unsigned short* sl;
        int ld, kc;
        if (c < xchunks) { sh = Ah; sl = Al; ld = lda; kc = c << 6; }
        else             { sh = Gh; sl = Gl; ld = 64;  kc = 0; }
        const size_t go = (size_t)gr * ld + kc + slot * 8;
        *(uint4*)((char*)tAh + ad) = *(const uint4*)(sh + go);
        *(uint4*)((char*)tAl + ad) = *(const uint4*)(sl + go);
      }
      const size_t gob = (size_t)row * ldb + (c << 6) + slot * 8;
      *(uint4*)((char*)tBh + ad) = *(const uint4*)(Bh + gob);
      *(uint4*)((char*)tBl + ad) = *(const uint4*)(Bl + gob);
    }
    __syncthreads();
#pragma unroll
    for (int ks = 0; ks < 2; ++ks) {
      const int inrow = (ks << 6) + (kg << 4);
      const int rA = (wm << 4) + m;
      const bhalf8 ah = *(const bhalf8*)((const char*)tAh + SWZ(rA, inrow));
      const bhalf8 al = *(const bhalf8*)((const char*)tAl + SWZ(rA, inrow));
#pragma unroll
      for (int nt = 0; nt < 4; ++nt) {
        const int rB = (nt << 4) + m;
        const bhalf8 bh = *(const bhalf8*)((const char*)tBh + SWZ(rB, inrow));
        const bhalf8 bl = *(const bhalf8*)((const char*)tBl + SWZ(rB, inrow));
        acc[nt] = __builtin_amdgcn_mfma_f32_16x16x32_bf16(ah, bh, acc[nt], 0, 0, 0);
        acc[nt] = __builtin_amdgcn_mfma_f32_16x16x32_bf16(ah, bl, acc[nt], 0, 0, 0);
        acc[nt] = __builtin_amdgcn_mfma_f32_16x16x32_bf16(al, bh, acc[nt], 0, 0, 0);
      }
    }
    __syncthreads();
  }
#pragma unroll
  for (int nt = 0; nt < 4; ++nt) {
    const int col = colbase + (nt << 4) + m;
    const float bv = bias ? bias[(nt << 4) + m] : 0.f;
#pragma unroll
    for (int r = 0; r < 4; ++r) {
      const int row = row0 + (wm << 4) + (kg << 2) + r;
      if (row < NN) {
        const float v = fmaxf(acc[nt][r] + bv, 0.f);
        if (outF) {
          outF[(size_t)row * ldo + col] = v;
          if (dup) outF[(size_t)row * ldo + col + 64] = v;
        }
        if (outH) {
          if (outL) {
            unsigned short h, l;
            split1(v, h, l);
            outH[(size_t)row * ldo + col] = h;
            outL[(size_t)row * ldo + col] = l;
          } else {
            outH[(size_t)row * ldo + col] = f16b(v);
          }
        }
      }
    }
  }
}

// ---------------------------------------------------------------------------
// Dual-output transform, 4-tile (32KB); Y outputs are fp16 planes
// ---------------------------------------------------------------------------
__device__ __forceinline__ void trans2_dev(
    unsigned short* tAh, unsigned short* tAl,
    unsigned short* tBh, unsigned short* tBl,
    const float* __restrict__ x,
    const unsigned short* __restrict__ Wuh, const unsigned short* __restrict__ Wul,
    const unsigned short* __restrict__ Wdh, const unsigned short* __restrict__ Wdl,
    const float* __restrict__ bu, const float* __restrict__ bd,
    unsigned short* __restrict__ Yu, unsigned short* __restrict__ Yd,
    int row0, int tid) {
  const int lane = tid & 63;
  const int wm = tid >> 6;
  const int m = lane & 15;
  const int kg = lane >> 4;
  floatx4 accU[4], accD[4];
#pragma unroll
  for (int i = 0; i < 4; ++i) {
    accU[i] = (floatx4){0.f, 0.f, 0.f, 0.f};
    accD[i] = (floatx4){0.f, 0.f, 0.f, 0.f};
  }
  for (int c = 0; c < 2; ++c) {
#pragma unroll
    for (int q = tid; q < 512; q += 256) {
      const int row = q >> 3, slot = q & 7;
      int gr = row0 + row;
      gr = (gr > NN - 1) ? NN - 1 : gr;
      const int ad = SWZ(row, slot << 4);
      const size_t go = (size_t)gr * 128 + (c << 6) + slot * 8;
      const float4 v0 = *(const float4*)(x + go);
      const float4 v1 = *(const float4*)(x + go + 4);
      uint4 H, L;
      split8(v0, v1, H, L);
      *(uint4*)((char*)tAh + ad) = H;
      *(uint4*)((char*)tAl + ad) = L;
      const size_t gob = (size_t)row * 128 + (c << 6) + slot * 8;
      *(uint4*)((char*)tBh + ad) = *(const uint4*)(Wuh + gob);
      *(uint4*)((char*)tBl + ad) = *(const uint4*)(Wul + gob);
    }
    __syncthreads();
#pragma unroll
    for (int ks = 0; ks < 2; ++ks) {
      const int inrow = (ks << 6) + (kg << 4);
      const int rA = (wm << 4) + m;
      const bhalf8 ah = *(const bhalf8*)((const char*)tAh + SWZ(rA, inrow));
      const bhalf8 al = *(const bhalf8*)((const char*)tAl + SWZ(rA, inrow));
#pragma unroll
      for (int nt = 0; nt < 4; ++nt) {
        const int rB = (nt << 4) + m;
        const int adB = SWZ(rB, inrow);
        const bhalf8 bh = *(const bhalf8*)((const char*)tBh + adB);
        const bhalf8 bl = *(const bhalf8*)((const char*)tBl + adB);
        accU[nt] = __builtin_amdgcn_mfma_f32_16x16x32_bf16(ah, bh, accU[nt], 0, 0, 0);
        accU[nt] = __builtin_amdgcn_mfma_f32_16x16x32_bf16(ah, bl, accU[nt], 0, 0, 0);
        accU[nt] = __builtin_amdgcn_mfma_f32_16x16x32_bf16(al, bh, accU[nt], 0, 0, 0);
      }
    }
    __syncthreads();
#pragma unroll
    for (int q = tid; q < 512; q += 256) {
      const int row = q >> 3, slot = q & 7;
      const int ad = SWZ(row, slot << 4);
      const size_t gob = (size_t)row * 128 + (c << 6) + slot * 8;
      *(uint4*)((char*)tBh + ad) = *(const uint4*)(Wdh + gob);
      *(uint4*)((char*)tBl + ad) = *(const uint4*)(Wdl + gob);
    }
    __syncthreads();
#pragma unroll
    for (int ks = 0; ks < 2; ++ks) {
      const int inrow = (ks << 6) + (kg << 4);
      const int rA = (wm << 4) + m;
      const bhalf8 ah = *(const bhalf8*)((const char*)tAh + SWZ(rA, inrow));
      const bhalf8 al = *(const bhalf8*)((const char*)tAl + SWZ(rA, inrow));
#pragma unroll
      for (int nt = 0; nt < 4; ++nt) {
        const int rB = (nt << 4) + m;
        const int adB = SWZ(rB, inrow);
        const bhalf8 bh = *(const bhalf8*)((const char*)tBh + adB);
        const bhalf8 bl = *(const bhalf8*)((const char*)tBl + adB);
        accD[nt] = __builtin_amdgcn_mfma_f32_16x16x32_bf16(ah, bh, accD[nt], 0, 0, 0);
        accD[nt] = __builtin_amdgcn_mfma_f32_16x16x32_bf16(ah, bl, accD[nt], 0, 0, 0);
        accD[nt] = __builtin_amdgcn_mfma_f32_16x16x32_bf16(al, bh, accD[nt], 0, 0, 0);
      }
    }
    __syncthreads();
  }
#pragma unroll
  for (int nt = 0; nt < 4; ++nt) {
    const int col = (nt << 4) + m;
    const float bvu = bu[col];
    const float bvd = bd[col];
#pragma unroll
    for (int r = 0; r < 4; ++r) {
      const int row = row0 + (wm << 4) + (kg << 2) + r;
      if (row < NN) {
        Yu[(size_t)row * 64 + col] = f16b(fmaxf(accU[nt][r] + bvu, 0.f));
        Yd[(size_t)row * 64 + col] = f16b(fmaxf(accD[nt][r] + bvd, 0.f));
      }
    }
  }
}

__global__ __launch_bounds__(256) void trans2_kernel(
    const float* __restrict__ x,
    const unsigned short* W1uh, const unsigned short* W1ul,
    const unsigned short* W1dh, const unsigned short* W1dl,
    const float* __restrict__ b_u1, const float* __restrict__ b_d1,
    unsigned short* __restrict__ Yu, unsigned short* __restrict__ Yd) {
  __shared__ unsigned short tiles[4][4096];
  trans2_dev(tiles[0], tiles[1], tiles[2], tiles[3], x, W1uh, W1ul, W1dh,
             W1dl, b_u1, b_d1, Yu, Yd, blockIdx.x * 64, threadIdx.x);
}

__global__ __launch_bounds__(256) void mgemm_kernel(
    const unsigned short* Ah, const unsigned short* Al, int lda,
    const unsigned short* Gh, const unsigned short* Gl,
    const unsigned short* Bh, const unsigned short* Bl, int ldb,
    const float* bias, float* outF, unsigned short* outH, unsigned short* outL,
    int ldo, int colbase, int dup, int kchunks, int xchunks) {
  __shared__ unsigned short tiles[4][4096];
  mfma_gemm_dev<false>(tiles[0], tiles[1], tiles[2], tiles[3], Ah, Al, lda,
                       Gh, Gl, Bh, Bl, ldb, bias, outF, outH, outL, ldo,
                       colbase, dup, kchunks, xchunks, blockIdx.x * 64,
                       threadIdx.x);
}

// both layer-1 updates in one launch; A = f32 x (inline split)
__global__ __launch_bounds__(256) void update2m_kernel(
    const float* __restrict__ x,
    const unsigned short* auh, const unsigned short* aul,
    const unsigned short* adh, const unsigned short* adl,
    const unsigned short* U1uh, const unsigned short* U1ul,
    const unsigned short* U1dh, const unsigned short* U1dl,
    unsigned short* outH, unsigned short* outL) {
  __shared__ unsigned short tiles[4][4096];
  if (blockIdx.x < TB)
    mfma_gemm_dev<true>(tiles[0], tiles[1], tiles[2], tiles[3],
                        (const unsigned short*)x, nullptr, 128, auh, aul,
                        U1uh, U1ul, 192, nullptr, nullptr, outH, outL, 128,
                        0, 0, 3, 2, blockIdx.x * 64, threadIdx.x);
  else
    mfma_gemm_dev<true>(tiles[0], tiles[1], tiles[2], tiles[3],
                        (const unsigned short*)x, nullptr, 128, adh, adl,
                        U1dh, U1dl, 192, nullptr, nullptr, outH, outL, 128,
                        64, 0, 3, 2, (blockIdx.x - TB) * 64, threadIdx.x);
}

// ---------------------------------------------------------------------------
// bin index: node -> (node/6250)*32 + (node%6250)/196, in [0,256)
// ---------------------------------------------------------------------------
__device__ __forceinline__ int bin_of(unsigned n) {
  const unsigned bucket = n / 6250u;
  const unsigned rem = n - bucket * 6250u;
  return (int)(bucket * 32u + rem / 196u);
}

// ---------------------------------------------------------------------------
// prep: fine counting-sort into 256 bins/dir (blocks [0,BBK)) || weights (32)
// ---------------------------------------------------------------------------
__global__ __launch_bounds__(256) void prep_kernel(
    const int* __restrict__ src, const int* __restrict__ dst,
    int* __restrict__ gcur,
    unsigned* __restrict__ bdst, unsigned* __restrict__ bsrc,
    const float* __restrict__ U_u1, const float* __restrict__ U_d1,
    const float* __restrict__ W_u1, const float* __restrict__ W_d1,
    const float* __restrict__ W_u2, const float* __restrict__ U_u2,
    unsigned short* __restrict__ wbuf) {
  int bi = blockIdx.x;
  const int t = threadIdx.x;
  if (bi < BBK) {
    __shared__ int hist[512];
    __shared__ int base[512];
    __shared__ int cur[512];
    const int chunk = bi * CHKE;
    for (int j = t; j < 512; j += 256) { hist[j] = 0; cur[j] = 0; }
    __syncthreads();
    unsigned ev[8];
    int bd[8], bs[8];
    bool ok[8];
#pragma unroll
    for (int i = 0; i < 8; ++i) {
      const int e = chunk + i * 256 + t;
      ok[i] = e < NE;
      bd[i] = 0; bs[i] = 0; ev[i] = 0;
      if (ok[i]) {
        const unsigned s = (unsigned)src[e], d = (unsigned)dst[e];
        ev[i] = s | (d << 16);
        bd[i] = bin_of(d);
        bs[i] = bin_of(s);
        atomicAdd(&hist[bd[i]], 1);
        atomicAdd(&hist[256 + bs[i]], 1);
      }
    }
    __syncthreads();
    for (int j = t; j < 512; j += 256)
      base[j] = atomicAdd(&gcur[j], hist[j]);
    __syncthreads();
#pragma unroll
    for (int i = 0; i < 8; ++i) {
      if (ok[i]) {
        const int r1 = base[bd[i]] + atomicAdd(&cur[bd[i]], 1);
        if (r1 < BINCAP) bdst[bd[i] * BINCAP + r1] = ev[i];
        const int r2 = base[256 + bs[i]] + atomicAdd(&cur[256 + bs[i]], 1);
        if (r2 < BINCAP) bsrc[bs[i] * BINCAP + r2] = ev[i];
      }
    }
    return;
  }
  bi -= BBK;
  const int widx = bi >> 2;
  const int quad = bi & 3;
  const int Ks[8] = {192, 192, 128, 128, 128, 192, 64, 128};
  const int offs[8] = {WOFF_U1U, WOFF_U1D, WOFF_W1U, WOFF_W1D,
                       WOFF_W2U, WOFF_U2U, WOFF_WSUM, WOFF_USUM};
  const float* srcs[6] = {U_u1, U_d1, W_u1, W_d1, W_u2, U_u2};
  const int K = Ks[widx];
  const int off = offs[widx];
  const int qsz = K << 4;
  const int beg = quad * qsz;
  for (int e = beg + t; e < beg + qsz; e += 256) {
    const int cc = e / K;
    const int kk = e - cc * K;
    float v;
    if (widx < 6) v = srcs[widx][kk * 64 + cc];
    else if (widx == 6) v = W_u2[kk * 64 + cc] + W_u2[(kk + 64) * 64 + cc];
    else v = (kk < 64) ? (U_u2[kk * 64 + cc] + U_u2[(kk + 64) * 64 + cc])
                       : U_u2[(kk + 64) * 64 + cc];
    unsigned short h, l;
    split1(v, h, l);
    wbuf[off + cc * K + kk] = h;
    wbuf[off + (K << 6) + cc * K + kk] = l;
  }
}

// ---------------------------------------------------------------------------
// binscan: per-direction exclusive scan of 256 bin counts -> binbase
// ---------------------------------------------------------------------------
__global__ __launch_bounds__(256) void binscan_kernel(
    const int* __restrict__ gcur, int* __restrict__ binbase) {
  const int dir = blockIdx.x;
  const int t = threadIdx.x;
  __shared__ int sc[256];
  const int v = gcur[dir * 256 + t];
  sc[t] = v;
  __syncthreads();
  for (int off = 1; off < 256; off <<= 1) {
    int add = (t >= off) ? sc[t - off] : 0;
    __syncthreads();
    sc[t] += add;
    __syncthreads();
  }
  binbase[dir * 256 + t] = sc[t] - v;  // exclusive
}

// ---------------------------------------------------------------------------
// placeC: one block per bin; LDS hist -> scan -> rowptr + cols (u32 byte
// offsets = neighbor<<7), no global atomics
// ---------------------------------------------------------------------------
__global__ __launch_bounds__(256) void placeC_kernel(
    const int* __restrict__ gcur, const int* __restrict__ binbase,
    const unsigned* __restrict__ bdst, const unsigned* __restrict__ bsrc,
    int* __restrict__ rp_dst, int* __restrict__ rp_src,
    unsigned* __restrict__ col_dst, unsigned* __restrict__ col_src) {
  const int gbin = blockIdx.x;         // 0..511
  const int dir = gbin >> 8;
  const int bin = gbin & 255;
  const int bucket = bin >> 5;
  const int sub = bin & 31;
  const unsigned lo = (unsigned)(bucket * 6250 + sub * SUBW);
  const int subn = min(SUBW, 6250 - sub * SUBW);
  __shared__ int hist[SUBW];
  __shared__ int sc[SUBW];
  __shared__ int cur[SUBW];
  const int t = threadIdx.x;
  if (t < subn) hist[t] = 0;
  __syncthreads();
  const int cnt = min(gcur[gbin], BINCAP);
  const unsigned* p = (dir ? bsrc : bdst) + (size_t)bin * BINCAP;
  const int cnt4 = cnt & ~3;
  for (int i = t * 4; i < cnt4; i += 1024) {
    const uint4 v = *(const uint4*)(p + i);
    const unsigned n0 = dir ? (v.x & 0xFFFFu) : (v.x >> 16);
    const unsigned n1 = dir ? (v.y & 0xFFFFu) : (v.y >> 16);
    const unsigned n2 = dir ? (v.z & 0xFFFFu) : (v.z >> 16);
    const unsigned n3 = dir ? (v.w & 0xFFFFu) : (v.w >> 16);
    atomicAdd(&hist[n0 - lo], 1);
    atomicAdd(&hist[n1 - lo], 1);
    atomicAdd(&hist[n2 - lo], 1);
    atomicAdd(&hist[n3 - lo], 1);
  }
  for (int i = cnt4 + t; i < cnt; i += 256) {
    const unsigned n = dir ? (p[i] & 0xFFFFu) : (p[i] >> 16);
    atomicAdd(&hist[n - lo], 1);
  }
  __syncthreads();
  if (t < subn) sc[t] = hist[t];
  __syncthreads();
  for (int off = 1; off < SUBW; off <<= 1) {
    int add = (t < subn && t >= off) ? sc[t - off] : 0;
    __syncthreads();
    if (t < subn) sc[t] += add;
    __syncthreads();
  }
  const int bb = binbase[gbin];
  int* rp = dir ? rp_src : rp_dst;
  if (t < subn) {
    rp[lo + t] = bb + sc[t];            // inclusive end
    cur[t] = bb + sc[t] - hist[t];      // exclusive start cursor
  }
  __syncthreads();
  unsigned* col = dir ? col_src : col_dst;
  for (int i = t * 4; i < cnt4; i += 1024) {
    const uint4 v = *(const uint4*)(p + i);
    const unsigned vs[4] = {v.x, v.y, v.z, v.w};
#pragma unroll
    for (int k = 0; k < 4; ++k) {
      const unsigned n = dir ? (vs[k] & 0xFFFFu) : (vs[k] >> 16);
      const unsigned q = dir ? (vs[k] >> 16) : (vs[k] & 0xFFFFu);
      col[atomicAdd(&cur[n - lo], 1)] = q << 7;   // byte offset into Y plane
    }
  }
  for (int i = cnt4 + t; i < cnt; i += 256) {
    const unsigned v = p[i];
    const unsigned n = dir ? (v & 0xFFFFu) : (v >> 16);
    const unsigned q = dir ? (v >> 16) : (v & 0xFFFFu);
    col[atomicAdd(&cur[n - lo], 1)] = q << 7;
  }
}

// ---------------------------------------------------------------------------
// pull-gather mean from fp16 Y rows (128B) with packed fp16 accumulation.
// col holds pre-shifted u32 byte offsets -> single 32-bit add addressing.
// ---------------------------------------------------------------------------
__device__ __forceinline__ void gatherh_dev(
    const unsigned short* __restrict__ Yh, const int* __restrict__ rowptr,
    const unsigned* __restrict__ col,
    unsigned short* __restrict__ aggh, unsigned short* __restrict__ aggl,
    int seg, int tid) {
  const int w = tid >> 6;
  const int lane = tid & 63;
  const int off = (seg >> 3) * 4 + w;
  if (off >= 6250) return;
  const int node = (seg & 7) * 6250 + off;
  const int eg = lane >> 3;          // 0..7
  const unsigned lb = (unsigned)((lane & 7) << 4);  // lane byte offset
  const char* Yb = (const char*)Yh;
  const int start = (node == 0) ? 0 : rowptr[node - 1];
  const int end = rowptr[node];
  half2v a0 = h2_of(0u), a1 = h2_of(0u), a2 = h2_of(0u), a3 = h2_of(0u);
  int e = start + eg;
  for (; e + 8 < end; e += 16) {
    const unsigned o0 = col[e] + lb;
    const unsigned o1 = col[e + 8] + lb;
    const uint4 v0 = *(const uint4*)(Yb + o0);
    const uint4 v1 = *(const uint4*)(Yb + o1);
    a0 += h2_of(v0.x) + h2_of(v1.x);
    a1 += h2_of(v0.y) + h2_of(v1.y);
    a2 += h2_of(v0.z) + h2_of(v1.z);
    a3 += h2_of(v0.w) + h2_of(v1.w);
  }
  for (; e < end; e += 8) {
    const unsigned o = col[e] + lb;
    const uint4 v = *(const uint4*)(Yb + o);
    a0 += h2_of(v.x);
    a1 += h2_of(v.y);
    a2 += h2_of(v.z);
    a3 += h2_of(v.w);
  }
  // packed shuffle-reduce across the 8 edge groups
#pragma unroll
  for (int d = 8; d <= 32; d <<= 1) {
    a0 += h2_of((unsigned)__shfl_xor((int)u_of(a0), d));
    a1 += h2_of((unsigned)__shfl_xor((int)u_of(a1), d));
    a2 += h2_of((unsigned)__shfl_xor((int)u_of(a2), d));
    a3 += h2_of((unsigned)__shfl_xor((int)u_of(a3), d));
  }
  if (eg == 0) {
    const float inv = 1.f / (float)max(end - start, 1);
    const int cq = (lane & 7) << 3;
    float s[8];
    s[0] = (float)a0[0]; s[1] = (float)a0[1];
    s[2] = (float)a1[0]; s[3] = (float)a1[1];
    s[4] = (float)a2[0]; s[5] = (float)a2[1];
    s[6] = (float)a3[0]; s[7] = (float)a3[1];
    unsigned short h[8], l[8];
#pragma unroll
    for (int i = 0; i < 8; ++i) split1(s[i] * inv, h[i], l[i]);
    uint4 H, L;
    H.x = (unsigned)h[0] | ((unsigned)h[1] << 16);
    H.y = (unsigned)h[2] | ((unsigned)h[3] << 16);
    H.z = (unsigned)h[4] | ((unsigned)h[5] << 16);
    H.w = (unsigned)h[6] | ((unsigned)h[7] << 16);
    L.x = (unsigned)l[0] | ((unsigned)l[1] << 16);
    L.y = (unsigned)l[2] | ((unsigned)l[3] << 16);
    L.z = (unsigned)l[4] | ((unsigned)l[5] << 16);
    L.w = (unsigned)l[6] | ((unsigned)l[7] << 16);
    *(uint4*)(aggh + (size_t)node * 64 + cq) = H;
    *(uint4*)(aggl + (size_t)node * 64 + cq) = L;
  }
}

__global__ __launch_bounds__(256) void gatherh_kernel(
    const unsigned short* __restrict__ Yh, const int* __restrict__ rowptr,
    const unsigned* __restrict__ col,
    unsigned short* __restrict__ aggh, unsigned short* __restrict__ aggl) {
  gatherh_dev(Yh, rowptr, col, aggh, aggl, blockIdx.x, threadIdx.x);
}

__global__ __launch_bounds__(256) void gatherh2_kernel(
    const unsigned short* __restrict__ Yhu, const int* __restrict__ rp_dst,
    const unsigned* __restrict__ col_dst,
    unsigned short* auh, unsigned short* aul,
    const unsigned short* __restrict__ Yhd, const int* __restrict__ rp_src,
    const unsigned* __restrict__ col_src,
    unsigned short* adh, unsigned short* adl) {
  if (blockIdx.x < GBS)
    gatherh_dev(Yhu, rp_dst, col_dst, auh, aul, blockIdx.x, threadIdx.x);
  else
    gatherh_dev(Yhd, rp_src, col_src, adh, adl, blockIdx.x - GBS, threadIdx.x);
}

// ===========================================================================
// Fallback path (vector-f32 GEMM + replicated edge pass) for small workspaces
// ===========================================================================
__global__ __launch_bounds__(256) void pack_kernel(
    const int* __restrict__ src, const int* __restrict__ dst,
    unsigned* __restrict__ epack) {
  for (int e = blockIdx.x * 256 + threadIdx.x; e < NE; e += 1024 * 256)
    epack[e] = (unsigned)src[e] | ((unsigned)dst[e] << 16);
}

__device__ __forceinline__ void place_dev4(
    const unsigned* __restrict__ epack,
    int* __restrict__ rp_dst, int* __restrict__ rp_src,
    unsigned short* __restrict__ col_dst, unsigned short* __restrict__ col_src,
    int bi, int tid) {
  const unsigned lo = (unsigned)(bi & 7) * 6250u;
  const int g = (bi >> 3) * 256 + tid;
  for (int e = g * 4; e < NE; e += 262144) {
    const uint4 v4 = *(const uint4*)(epack + e);
    const unsigned vs[4] = {v4.x, v4.y, v4.z, v4.w};
#pragma unroll
    for (int i = 0; i < 4; ++i) {
      const unsigned s = vs[i] & 0xFFFFu, d = vs[i] >> 16;
      if (d - lo < 6250u)
        col_dst[atomicAdd(&rp_dst[d], 1)] = (unsigned short)s;
      if (s - lo < 6250u)
        col_src[atomicAdd(&rp_src[s], 1)] = (unsigned short)d;
    }
  }
}

__global__ __launch_bounds__(256) void count_old_kernel(
    const unsigned* __restrict__ epack,
    int* __restrict__ rp_dst, int* __restrict__ rp_src) {
  const int bi = blockIdx.x;
  const unsigned lo = (unsigned)(bi & 7) * 6250u;
  const int g = (bi >> 3) * 256 + threadIdx.x;
  for (int e = g * 4; e < NE; e += 262144) {
    const uint4 v4 = *(const uint4*)(epack + e);
    const unsigned vs[4] = {v4.x, v4.y, v4.z, v4.w};
#pragma unroll
    for (int i = 0; i < 4; ++i) {
      const unsigned s = vs[i] & 0xFFFFu, d = vs[i] >> 16;
      if (d - lo < 6250u) atomicAdd(&rp_dst[d], 1);
      if (s - lo < 6250u) atomicAdd(&rp_src[s], 1);
    }
  }
}

#define CHUNK 49
__global__ __launch_bounds__(1024) void scan_kernel(
    int* __restrict__ a0, int* __restrict__ a1) {
  int* a = (blockIdx.x == 0) ? a0 : a1;
  __shared__ int part[1024];
  const int t = threadIdx.x;
  const int beg = t * CHUNK;
  const int end = min(beg + CHUNK, NN);
  int s = 0;
  for (int i = beg; i < end; ++i) s += a[i];
  part[t] = s;
  __syncthreads();
  for (int off = 1; off < 1024; off <<= 1) {
    int add = (t >= off) ? part[t - off] : 0;
    __syncthreads();
    part[t] += add;
    __syncthreads();
  }
  int run = (t == 0) ? 0 : part[t - 1];
  for (int i = beg; i < end; ++i) {
    const int c = a[i];
    a[i] = run;
    run += c;
  }
}

__device__ __forceinline__ void gatherF_dev(
    const float* __restrict__ Y, const int* __restrict__ rowptr,
    const unsigned short* __restrict__ col, float* __restrict__ AGGf,
    int seg, int tid) {
  const int w = tid >> 6;
  const int lane = tid & 63;
  const int off = (seg >> 3) * 4 + w;
  if (off >= 6250) return;
  const int node = (seg & 7) * 6250 + off;
  const int eg = lane >> 4;
  const int cq = (lane & 15) << 2;
  const int start = (node == 0) ? 0 : rowptr[node - 1];
  const int end = rowptr[node];
  float4 acc = make_float4(0.f, 0.f, 0.f, 0.f);
  for (int e = start + eg; e < end; e += 4) {
    const float4 y = *(const float4*)(Y + (size_t)col[e] * 64 + cq);
    acc.x += y.x; acc.y += y.y; acc.z += y.z; acc.w += y.w;
  }
  acc.x += __shfl_xor(acc.x, 16);
  acc.y += __shfl_xor(acc.y, 16);
  acc.z += __shfl_xor(acc.z, 16);
  acc.w += __shfl_xor(acc.w, 16);
  acc.x += __shfl_xor(acc.x, 32);
  acc.y += __shfl_xor(acc.y, 32);
  acc.z += __shfl_xor(acc.z, 32);
  acc.w += __shfl_xor(acc.w, 32);
  if (eg == 0) {
    const float inv = 1.f / (float)max(end - start, 1);
    float4 o;
    o.x = acc.x * inv; o.y = acc.y * inv;
    o.z = acc.z * inv; o.w = acc.w * inv;
    *(float4*)(AGGf + (size_t)node * 64 + cq) = o;
  }
}

__global__ __launch_bounds__(256) void gatherF_kernel(
    const float* __restrict__ Y, const int* __restrict__ rowptr,
    const unsigned short* __restrict__ col, float* __restrict__ AGGf) {
  gatherF_dev(Y, rowptr, col, AGGf, blockIdx.x, threadIdx.x);
}

__device__ __forceinline__ void gemm64_dev(
    float (*Xt)[68], float* Ws, const float* __restrict__ X, int ldx,
    const float* __restrict__ AGG, const float* __restrict__ W,
    const float* __restrict__ b, float* __restrict__ out, int ldo,
    int colbase, int dup, int kchunks, int xchunks, int row0, int tid) {
  const int tx = tid & 15, ty = tid >> 4;
  float acc[4][4] = {{0.f}};
  for (int c = 0; c < kchunks; ++c) {
    {
      const int rr = tid >> 2;
      const int cg = (tid & 3) << 4;
      const float* srcp;
      int ld, co;
      if (c < xchunks) { srcp = X; ld = ldx; co = c * 64; }
      else             { srcp = AGG; ld = 64; co = 0; }
      int row = row0 + rr;
      if (row > NN - 1) row = NN - 1;
      const float* g = srcp + row * ld + co + cg;
      const float4 v0 = *(const float4*)(g + 0);
      const float4 v1 = *(const float4*)(g + 4);
      const float4 v2 = *(const float4*)(g + 8);
      const float4 v3 = *(const float4*)(g + 12);
      Xt[cg + 0][rr] = v0.x;  Xt[cg + 1][rr] = v0.y;
      Xt[cg + 2][rr] = v0.z;  Xt[cg + 3][rr] = v0.w;
      Xt[cg + 4][rr] = v1.x;  Xt[cg + 5][rr] = v1.y;
      Xt[cg + 6][rr] = v1.z;  Xt[cg + 7][rr] = v1.w;
      Xt[cg + 8][rr] = v2.x;  Xt[cg + 9][rr] = v2.y;
      Xt[cg + 10][rr] = v2.z; Xt[cg + 11][rr] = v2.w;
      Xt[cg + 12][rr] = v3.x; Xt[cg + 13][rr] = v3.y;
      Xt[cg + 14][rr] = v3.z; Xt[cg + 15][rr] = v3.w;
      const float4* wg = (const float4*)(W + c * 64 * 64);
      float4* wl = (float4*)Ws;
      wl[tid] = wg[tid];
      wl[tid + 256] = wg[tid + 256];
      wl[tid + 512] = wg[tid + 512];
      wl[tid + 768] = wg[tid + 768];
    }
    __syncthreads();
#pragma unroll 8
    for (int kk = 0; kk < 64; ++kk) {
      const float4 a = *(const float4*)&Xt[kk][tx << 2];
      const float4 w = *(const float4*)&Ws[kk * 64 + (ty << 2)];
      acc[0][0] += a.x * w.x; acc[0][1] += a.x * w.y;
      acc[0][2] += a.x * w.z; acc[0][3] += a.x * w.w;
      acc[1][0] += a.y * w.x; acc[1][1] += a.y * w.y;
      acc[1][2] += a.y * w.z; acc[1][3] += a.y * w.w;
      acc[2][0] += a.z * w.x; acc[2][1] += a.z * w.y;
      acc[2][2] += a.z * w.z; acc[2][3] += a.z * w.w;
      acc[3][0] += a.w * w.x; acc[3][1] += a.w * w.y;
      acc[3][2] += a.w * w.z; acc[3][3] += a.w * w.w;
    }
    __syncthreads();
  }
  float4 bv = make_float4(0.f, 0.f, 0.f, 0.f);
  if (b) bv = *(const float4*)(b + (ty << 2));
#pragma unroll
  for (int i = 0; i < 4; ++i) {
    const int row = row0 + (tx << 2) + i;
    if (row < NN) {
      float4 o;
      o.x = fmaxf(acc[i][0] + bv.x, 0.f);
      o.y = fmaxf(acc[i][1] + bv.y, 0.f);
      o.z = fmaxf(acc[i][2] + bv.z, 0.f);
      o.w = fmaxf(acc[i][3] + bv.w, 0.f);
      *(float4*)(out + row * ldo + colbase + (ty << 2)) = o;
      if (dup) *(float4*)(out + row * ldo + 64 + (ty << 2)) = o;
    }
  }
}

__global__ __launch_bounds__(256) void gemm_kernel(
    const float* __restrict__ X, int ldx, const float* __restrict__ AGG,
    const float* __restrict__ W, const float* __restrict__ b,
    float* __restrict__ out, int ldo, int colbase, int dup,
    int kchunks, int xchunks) {
  __shared__ __align__(16) float Xt[64][68];
  __shared__ __align__(16) float Ws[4096];
  gemm64_dev(Xt, Ws, X, ldx, AGG, W, b, out, ldo, colbase, dup, kchunks,
             xchunks, blockIdx.x * 64, threadIdx.x);
}

__global__ __launch_bounds__(256) void fused0_kernel(
    const unsigned* __restrict__ epack,
    int* __restrict__ rp_dst, int* __restrict__ rp_src,
    unsigned short* __restrict__ col_dst, unsigned short* __restrict__ col_src,
    const float* __restrict__ x,
    const float* __restrict__ W_u1, const float* __restrict__ b_u1,
    float* __restrict__ Y_u,
    const float* __restrict__ W_d1, const float* __restrict__ b_d1,
    float* __restrict__ Y_d) {
  __shared__ __align__(16) float Xt[64][68];
  __shared__ __align__(16) float Ws[4096];
  int bi = blockIdx.x;
  if (bi < 2048) {
    place_dev4(epack, rp_dst, rp_src, col_dst, col_src, bi, threadIdx.x);
    return;
  }
  bi -= 2048;
  if (bi < TB)
    gemm64_dev(Xt, Ws, x, 128, nullptr, W_u1, b_u1, Y_u, 64, 0, 0, 2, 2,
               bi * 64, threadIdx.x);
  else
    gemm64_dev(Xt, Ws, x, 128, nullptr, W_d1, b_d1, Y_d, 64, 0, 0, 2, 2,
               (bi - TB) * 64, threadIdx.x);
}

// ===========================================================================
extern "C" void kernel_launch(void* const* d_in, const int* in_sizes, int n_in,
                              void* d_out, int out_size, void* d_ws, size_t ws_size,
                              hipStream_t stream) {
  const float* x    = (const float*)d_in[0];
  const int*   ei   = (const int*)d_in[1];
  const float* W_u1 = (const float*)d_in[2];
  const float* b_u1 = (const float*)d_in[3];
  const float* U_u1 = (const float*)d_in[4];
  const float* W_d1 = (const float*)d_in[5];
  const float* b_d1 = (const float*)d_in[6];
  const float* U_d1 = (const float*)d_in[7];
  const float* W_u2 = (const float*)d_in[8];
  const float* b_u2 = (const float*)d_in[9];
  const float* U_u2 = (const float*)d_in[10];
  const int* src = ei;
  const int* dst = ei + NE;
  float* out = (float*)d_out;

  char* wsb = (char*)d_ws;
  int* rp_dst  = (int*)wsb;              wsb += NN * sizeof(int);
  int* rp_src  = (int*)wsb;              wsb += NN * sizeof(int);
  int* gcur    = (int*)wsb;              wsb += 512 * sizeof(int);
  int* binbase = (int*)wsb;              wsb += 512 * sizeof(int);
  unsigned* col_dst = (unsigned*)wsb;    wsb += (size_t)NE * 4;
  unsigned* col_src = (unsigned*)wsb;    wsb += (size_t)NE * 4;

  const size_t plane = (size_t)NN * 64 * 2;   // 6.4 MB u16 plane
  const size_t needM = (size_t)2 * NN * 4 + 4096 + (size_t)NE * 8 +
                       (size_t)WBUF_USHORTS * 2 +
                       6 * plane +               // A..F
                       2 * (size_t)NN * 128 * 2; // outh, outl

  hipMemsetAsync(gcur, 0, 512 * sizeof(int), stream);

  if (ws_size >= needM) {
    unsigned short* wbuf = (unsigned short*)wsb; wsb += (size_t)WBUF_USHORTS * 2;
    unsigned short* A = (unsigned short*)wsb; wsb += plane;  // Yh_u
    unsigned short* B = (unsigned short*)wsb; wsb += plane;  // Yh_d
    unsigned short* C = (unsigned short*)wsb; wsb += plane;  // agg_uh
    unsigned short* D = (unsigned short*)wsb; wsb += plane;  // agg_ul
    unsigned short* E = (unsigned short*)wsb; wsb += plane;  // agg_dh
    unsigned short* F = (unsigned short*)wsb; wsb += plane;  // agg_dl
    unsigned short* outh = (unsigned short*)wsb; wsb += (size_t)NN * 128 * 2;
    unsigned short* outl = (unsigned short*)wsb;

    // aliases (strict sequential lifetimes):
    unsigned* bdst = (unsigned*)C;   // bins (4MB) live until placeC
    unsigned* bsrc = (unsigned*)D;
    unsigned short* Yh2  = C;        // r2 trans output (bins dead)
    unsigned short* agg2h = E;       // r2 gather out (agg_dh/dl dead)
    unsigned short* agg2l = F;
    unsigned short* O2h = C;         // r2 update out (Yh2 dead)
    unsigned short* O2l = D;
    unsigned short* Yh3 = E;         // r3 trans out (agg2 dead)
    unsigned short* agg3h = A;       // r3 gather out (Yh_u/d dead)
    unsigned short* agg3l = B;

    const unsigned short* U1uh = wbuf + WOFF_U1U;
    const unsigned short* U1ul = wbuf + WOFF_U1U + 64 * 192;
    const unsigned short* U1dh = wbuf + WOFF_U1D;
    const unsigned short* U1dl = wbuf + WOFF_U1D + 64 * 192;
    const unsigned short* W1uh = wbuf + WOFF_W1U;
    const unsigned short* W1ul = wbuf + WOFF_W1U + 64 * 128;
    const unsigned short* W1dh = wbuf + WOFF_W1D;
    const unsigned short* W1dl = wbuf + WOFF_W1D + 64 * 128;
    const unsigned short* W2uh = wbuf + WOFF_W2U;
    const unsigned short* W2ul = wbuf + WOFF_W2U + 64 * 128;
    const unsigned short* U2uh = wbuf + WOFF_U2U;
    const unsigned short* U2ul = wbuf + WOFF_U2U + 64 * 192;
    const unsigned short* Wsh  = wbuf + WOFF_WSUM;
    const unsigned short* Wsl  = wbuf + WOFF_WSUM + 64 * 64;
    const unsigned short* Ush  = wbuf + WOFF_USUM;
    const unsigned short* Usl  = wbuf + WOFF_USUM + 64 * 128;

    // fine counting-sort || weight conversion
    prep_kernel<<<BBK + 32, 256, 0, stream>>>(
        src, dst, gcur, bdst, bsrc, U_u1, U_d1, W_u1, W_d1, W_u2, U_u2, wbuf);
    binscan_kernel<<<2, 256, 0, stream>>>(gcur, binbase);
    // per-bin CSR finalize (reads bins in C,D; cols = byte offsets)
    placeC_kernel<<<512, 256, 0, stream>>>(gcur, binbase, bdst, bsrc,
                                           rp_dst, rp_src, col_dst, col_src);
    // layer-1 transforms -> fp16 Y planes
    trans2_kernel<<<TB, 256, 0, stream>>>(x, W1uh, W1ul, W1dh, W1dl,
                                          b_u1, b_d1, A, B);
    // layer-1 gathers (both dirs), packed fp16 accumulate
    gatherh2_kernel<<<2 * GBS, 256, 0, stream>>>(A, rp_dst, col_dst, C, D,
                                                 B, rp_src, col_src, E, F);
    update2m_kernel<<<2 * TB, 256, 0, stream>>>(x, C, D, E, F, U1uh, U1ul,
                                                U1dh, U1dl, outh, outl);
    // round 2
    mgemm_kernel<<<TB, 256, 0, stream>>>(outh, outl, 128, nullptr, nullptr,
                                         W2uh, W2ul, 128, b_u2, nullptr,
                                         Yh2, nullptr, 64, 0, 0, 2, 2);
    gatherh_kernel<<<GBS, 256, 0, stream>>>(Yh2, rp_dst, col_dst, agg2h,
                                            agg2l);
    mgemm_kernel<<<TB, 256, 0, stream>>>(outh, outl, 128, agg2h, agg2l,
                                         U2uh, U2ul, 192, nullptr, nullptr,
                                         O2h, O2l, 64, 0, 0, 3, 2);
    // round 3 (h = [O2,O2] folded into presummed weights)
    mgemm_kernel<<<TB, 256, 0, stream>>>(O2h, O2l, 64, nullptr, nullptr,
                                         Wsh, Wsl, 64, b_u2, nullptr,
                                         Yh3, nullptr, 64, 0, 0, 1, 1);
    gatherh_kernel<<<GBS, 256, 0, stream>>>(Yh3, rp_dst, col_dst, agg3h,
                                            agg3l);
    mgemm_kernel<<<TB, 256, 0, stream>>>(O2h, O2l, 64, agg3h, agg3l,
                                         Ush, Usl, 128, nullptr, out,
                                         nullptr, nullptr, 128, 0, 1, 2, 1);
  } else {
    // fallback: vector-f32 path with replicated edge passes (u16 cols)
    unsigned* epack = (unsigned*)wsb; wsb += (size_t)NE * 4;
    float* Y_u = (float*)wsb; wsb += (size_t)NN * 64 * sizeof(float);
    float* Y_d = (float*)wsb; wsb += (size_t)NN * 64 * sizeof(float);
    float* AGG = (float*)wsb;
    unsigned short* cds = (unsigned short*)col_dst;
    unsigned short* css = (unsigned short*)col_src;
    hipMemsetAsync(rp_dst, 0, 2 * NN * sizeof(int), stream);
    pack_kernel<<<1024, 256, 0, stream>>>(src, dst, epack);
    count_old_kernel<<<2048, 256, 0, stream>>>(epack, rp_dst, rp_src);
    scan_kernel<<<2, 1024, 0, stream>>>(rp_dst, rp_src);
    fused0_kernel<<<2048 + 2 * TB, 256, 0, stream>>>(
        epack, rp_dst, rp_src, cds, css, x, W_u1, b_u1, Y_u, W_d1,
        b_d1, Y_d);
    gatherF_kernel<<<GBS, 256, 0, stream>>>(Y_u, rp_dst, cds, AGG);
    gemm_kernel<<<TB, 256, 0, stream>>>(x, 128, AGG, U_u1, nullptr, out,
                                        128, 0, 0, 3, 2);
    gatherF_kernel<<<GBS, 256, 0, stream>>>(Y_d, rp_src, css, AGG);
    gemm_kernel<<<TB, 256, 0, stream>>>(x, 128, AGG, U_d1, nullptr, out,
                                        128, 64, 0, 3, 2);
    for (int r = 0; r < 2; ++r) {
      gemm_kernel<<<TB, 256, 0, stream>>>(out, 128, nullptr, W_u2, b_u2,
                                          Y_u, 64, 0, 0, 2, 2);
      gatherF_kernel<<<GBS, 256, 0, stream>>>(Y_u, rp_dst, cds, AGG);
      gemm_kernel<<<TB, 256, 0, stream>>>(out, 128, AGG, U_u2, nullptr,
                                          out, 128, 0, 1, 3, 2);
    }
  }
}

// Round 16
// 194.144 us; speedup vs baseline: 2.0720x; 1.0308x over previous
//
#include <hip/hip_runtime.h>

#define NN 50000
#define NE 800000
#define TB 782             // ceil(NN/64) gemm row-tile blocks
#define GBS 12504          // 8 * 1563 swizzled gather blocks (4 nodes each)
#define BBK 391            // bucket blocks = ceil(NE/2048)
#define CHKE 2048          // edges per bucket block
#define BINS 256           // bins per direction
#define BINCAP 4096        // per-bin capacity (mean 3125, >17 sigma slack)
#define SUBW 196           // nodes per bin

typedef __attribute__((ext_vector_type(8))) short bhalf8;
typedef __attribute__((ext_vector_type(4))) float floatx4;
typedef __attribute__((ext_vector_type(2))) _Float16 half2v;

// weight buffer offsets (ushort units); l plane = h + 64*K
#define WOFF_U1U 0
#define WOFF_U1D 24576
#define WOFF_W1U 49152
#define WOFF_W1D 65536
#define WOFF_W2U 81920
#define WOFF_U2U 98304
#define WOFF_WSUM 122880
#define WOFF_USUM 131072
#define WBUF_USHORTS 147456

// ---------------------------------------------------------------------------
// bf16 / fp16 helpers
// ---------------------------------------------------------------------------
__device__ __forceinline__ unsigned short bf16hi(float v) {
  union { float f; unsigned u; } c; c.f = v;
  return (unsigned short)((c.u + 0x7FFFu + ((c.u >> 16) & 1u)) >> 16);
}
__device__ __forceinline__ float bf16tof(unsigned short h) {
  union { unsigned u; float f; } c; c.u = ((unsigned)h) << 16;
  return c.f;
}
__device__ __forceinline__ void split1(float v, unsigned short& h,
                                       unsigned short& l) {
  h = bf16hi(v);
  l = bf16hi(v - bf16tof(h));
}
__device__ __forceinline__ void split8(const float4 v0, const float4 v1,
                                       uint4& H, uint4& L) {
  unsigned short h0, l0, h1, l1;
  split1(v0.x, h0, l0); split1(v0.y, h1, l1);
  H.x = (unsigned)h0 | ((unsigned)h1 << 16);
  L.x = (unsigned)l0 | ((unsigned)l1 << 16);
  split1(v0.z, h0, l0); split1(v0.w, h1, l1);
  H.y = (unsigned)h0 | ((unsigned)h1 << 16);
  L.y = (unsigned)l0 | ((unsigned)l1 << 16);
  split1(v1.x, h0, l0); split1(v1.y, h1, l1);
  H.z = (unsigned)h0 | ((unsigned)h1 << 16);
  L.z = (unsigned)l0 | ((unsigned)l1 << 16);
  split1(v1.z, h0, l0); split1(v1.w, h1, l1);
  H.w = (unsigned)h0 | ((unsigned)h1 << 16);
  L.w = (unsigned)l0 | ((unsigned)l1 << 16);
}
__device__ __forceinline__ unsigned short f16b(float v) {
  union { _Float16 h; unsigned short u; } c;
  c.h = (_Float16)v;
  return c.u;
}
__device__ __forceinline__ half2v h2_of(unsigned u) {
  union { unsigned v; half2v h; } c; c.v = u; return c.h;
}
__device__ __forceinline__ unsigned u_of(half2v h) {
  union { half2v h; unsigned v; } c; c.h = h; return c.v;
}

// swizzled LDS byte address for bf16 tile [64 rows][64 k] (128B rows)
#define SWZ(row, inrow) (((row) << 7) + ((inrow) ^ (((row)&7) << 4)))

// ---------------------------------------------------------------------------
// MFMA split-bf16 GEMM (single B): out = relu([A|G] @ B^T (+bias))
// outF: f32 (optional dup). outH+outL: bf16 hi/lo. outH only: fp16 plane.
// ---------------------------------------------------------------------------
template <bool AF32>
__device__ __forceinline__ void mfma_gemm_dev(
    unsigned short* tAh, unsigned short* tAl,
    unsigned short* tBh, unsigned short* tBl,
    const unsigned short* __restrict__ Ah, const unsigned short* __restrict__ Al,
    int lda,
    const unsigned short* __restrict__ Gh, const unsigned short* __restrict__ Gl,
    const unsigned short* __restrict__ Bh, const unsigned short* __restrict__ Bl,
    int ldb, const float* __restrict__ bias,
    float* __restrict__ outF, unsigned short* __restrict__ outH,
    unsigned short* __restrict__ outL,
    int ldo, int colbase, int dup, int kchunks, int xchunks,
    int row0, int tid) {
  const int lane = tid & 63;
  const int wm = tid >> 6;
  const int m = lane & 15;
  const int kg = lane >> 4;
  floatx4 acc[4];
#pragma unroll
  for (int i = 0; i < 4; ++i) acc[i] = (floatx4){0.f, 0.f, 0.f, 0.f};

  for (int c = 0; c < kchunks; ++c) {
#pragma unroll
    for (int q = tid; q < 512; q += 256) {
      const int row = q >> 3, slot = q & 7;
      int gr = row0 + row;
      gr = (gr > NN - 1) ? NN - 1 : gr;
      const int ad = SWZ(row, slot << 4);
      if (AF32 && c < xchunks) {
        const float* f = (const float*)Ah;
        const size_t go = (size_t)gr * lda + (c << 6) + slot * 8;
        const float4 v0 = *(const float4*)(f + go);
        const float4 v1 = *(const float4*)(f + go + 4);
        uint4 H, L;
        split8(v0, v1, H, L);
        *(uint4*)((char*)tAh + ad) = H;
        *(uint4*)((char*)tAl + ad) = L;
      } else {
        const unsigned short* sh;
        const unsigned short* sl;
        int ld, kc;
        if (c < xchunks) { sh = Ah; sl = Al; ld = lda; kc = c << 6; }
        else             { sh = Gh; sl = Gl; ld = 64;  kc = 0; }
        const size_t go = (size_t)gr * ld + kc + slot * 8;
        *(uint4*)((char*)tAh + ad) = *(const uint4*)(sh + go);
        *(uint4*)((char*)tAl + ad) = *(const uint4*)(sl + go);
      }
      const size_t gob = (size_t)row * ldb + (c << 6) + slot * 8;
      *(uint4*)((char*)tBh + ad) = *(const uint4*)(Bh + gob);
      *(uint4*)((char*)tBl + ad) = *(const uint4*)(Bl + gob);
    }
    __syncthreads();
#pragma unroll
    for (int ks = 0; ks < 2; ++ks) {
      const int inrow = (ks << 6) + (kg << 4);
      const int rA = (wm << 4) + m;
      const bhalf8 ah = *(const bhalf8*)((const char*)tAh + SWZ(rA, inrow));
      const bhalf8 al = *(const bhalf8*)((const char*)tAl + SWZ(rA, inrow));
#pragma unroll
      for (int nt = 0; nt < 4; ++nt) {
        const int rB = (nt << 4) + m;
        const bhalf8 bh = *(const bhalf8*)((const char*)tBh + SWZ(rB, inrow));
        const bhalf8 bl = *(const bhalf8*)((const char*)tBl + SWZ(rB, inrow));
        acc[nt] = __builtin_amdgcn_mfma_f32_16x16x32_bf16(ah, bh, acc[nt], 0, 0, 0);
        acc[nt] = __builtin_amdgcn_mfma_f32_16x16x32_bf16(ah, bl, acc[nt], 0, 0, 0);
        acc[nt] = __builtin_amdgcn_mfma_f32_16x16x32_bf16(al, bh, acc[nt], 0, 0, 0);
      }
    }
    __syncthreads();
  }
#pragma unroll
  for (int nt = 0; nt < 4; ++nt) {
    const int col = colbase + (nt << 4) + m;
    const float bv = bias ? bias[(nt << 4) + m] : 0.f;
#pragma unroll
    for (int r = 0; r < 4; ++r) {
      const int row = row0 + (wm << 4) + (kg << 2) + r;
      if (row < NN) {
        const float v = fmaxf(acc[nt][r] + bv, 0.f);
        if (outF) {
          outF[(size_t)row * ldo + col] = v;
          if (dup) outF[(size_t)row * ldo + col + 64] = v;
        }
        if (outH) {
          if (outL) {
            unsigned short h, l;
            split1(v, h, l);
            outH[(size_t)row * ldo + col] = h;
            outL[(size_t)row * ldo + col] = l;
          } else {
            outH[(size_t)row * ldo + col] = f16b(v);
          }
        }
      }
    }
  }
}

// ---------------------------------------------------------------------------
// Dual-output transform, 4-tile (32KB); Y outputs are fp16 planes
// ---------------------------------------------------------------------------
__device__ __forceinline__ void trans2_dev(
    unsigned short* tAh, unsigned short* tAl,
    unsigned short* tBh, unsigned short* tBl,
    const float* __restrict__ x,
    const unsigned short* __restrict__ Wuh, const unsigned short* __restrict__ Wul,
    const unsigned short* __restrict__ Wdh, const unsigned short* __restrict__ Wdl,
    const float* __restrict__ bu, const float* __restrict__ bd,
    unsigned short* __restrict__ Yu, unsigned short* __restrict__ Yd,
    int row0, int tid) {
  const int lane = tid & 63;
  const int wm = tid >> 6;
  const int m = lane & 15;
  const int kg = lane >> 4;
  floatx4 accU[4], accD[4];
#pragma unroll
  for (int i = 0; i < 4; ++i) {
    accU[i] = (floatx4){0.f, 0.f, 0.f, 0.f};
    accD[i] = (floatx4){0.f, 0.f, 0.f, 0.f};
  }
  for (int c = 0; c < 2; ++c) {
#pragma unroll
    for (int q = tid; q < 512; q += 256) {
      const int row = q >> 3, slot = q & 7;
      int gr = row0 + row;
      gr = (gr > NN - 1) ? NN - 1 : gr;
      const int ad = SWZ(row, slot << 4);
      const size_t go = (size_t)gr * 128 + (c << 6) + slot * 8;
      const float4 v0 = *(const float4*)(x + go);
      const float4 v1 = *(const float4*)(x + go + 4);
      uint4 H, L;
      split8(v0, v1, H, L);
      *(uint4*)((char*)tAh + ad) = H;
      *(uint4*)((char*)tAl + ad) = L;
      const size_t gob = (size_t)row * 128 + (c << 6) + slot * 8;
      *(uint4*)((char*)tBh + ad) = *(const uint4*)(Wuh + gob);
      *(uint4*)((char*)tBl + ad) = *(const uint4*)(Wul + gob);
    }
    __syncthreads();
#pragma unroll
    for (int ks = 0; ks < 2; ++ks) {
      const int inrow = (ks << 6) + (kg << 4);
      const int rA = (wm << 4) + m;
      const bhalf8 ah = *(const bhalf8*)((const char*)tAh + SWZ(rA, inrow));
      const bhalf8 al = *(const bhalf8*)((const char*)tAl + SWZ(rA, inrow));
#pragma unroll
      for (int nt = 0; nt < 4; ++nt) {
        const int rB = (nt << 4) + m;
        const int adB = SWZ(rB, inrow);
        const bhalf8 bh = *(const bhalf8*)((const char*)tBh + adB);
        const bhalf8 bl = *(const bhalf8*)((const char*)tBl + adB);
        accU[nt] = __builtin_amdgcn_mfma_f32_16x16x32_bf16(ah, bh, accU[nt], 0, 0, 0);
        accU[nt] = __builtin_amdgcn_mfma_f32_16x16x32_bf16(ah, bl, accU[nt], 0, 0, 0);
        accU[nt] = __builtin_amdgcn_mfma_f32_16x16x32_bf16(al, bh, accU[nt], 0, 0, 0);
      }
    }
    __syncthreads();
#pragma unroll
    for (int q = tid; q < 512; q += 256) {
      const int row = q >> 3, slot = q & 7;
      const int ad = SWZ(row, slot << 4);
      const size_t gob = (size_t)row * 128 + (c << 6) + slot * 8;
      *(uint4*)((char*)tBh + ad) = *(const uint4*)(Wdh + gob);
      *(uint4*)((char*)tBl + ad) = *(const uint4*)(Wdl + gob);
    }
    __syncthreads();
#pragma unroll
    for (int ks = 0; ks < 2; ++ks) {
      const int inrow = (ks << 6) + (kg << 4);
      const int rA = (wm << 4) + m;
      const bhalf8 ah = *(const bhalf8*)((const char*)tAh + SWZ(rA, inrow));
      const bhalf8 al = *(const bhalf8*)((const char*)tAl + SWZ(rA, inrow));
#pragma unroll
      for (int nt = 0; nt < 4; ++nt) {
        const int rB = (nt << 4) + m;
        const int adB = SWZ(rB, inrow);
        const bhalf8 bh = *(const bhalf8*)((const char*)tBh + adB);
        const bhalf8 bl = *(const bhalf8*)((const char*)tBl + adB);
        accD[nt] = __builtin_amdgcn_mfma_f32_16x16x32_bf16(ah, bh, accD[nt], 0, 0, 0);
        accD[nt] = __builtin_amdgcn_mfma_f32_16x16x32_bf16(ah, bl, accD[nt], 0, 0, 0);
        accD[nt] = __builtin_amdgcn_mfma_f32_16x16x32_bf16(al, bh, accD[nt], 0, 0, 0);
      }
    }
    __syncthreads();
  }
#pragma unroll
  for (int nt = 0; nt < 4; ++nt) {
    const int col = (nt << 4) + m;
    const float bvu = bu[col];
    const float bvd = bd[col];
#pragma unroll
    for (int r = 0; r < 4; ++r) {
      const int row = row0 + (wm << 4) + (kg << 2) + r;
      if (row < NN) {
        Yu[(size_t)row * 64 + col] = f16b(fmaxf(accU[nt][r] + bvu, 0.f));
        Yd[(size_t)row * 64 + col] = f16b(fmaxf(accD[nt][r] + bvd, 0.f));
      }
    }
  }
}

__global__ __launch_bounds__(256) void trans2_kernel(
    const float* __restrict__ x,
    const unsigned short* W1uh, const unsigned short* W1ul,
    const unsigned short* W1dh, const unsigned short* W1dl,
    const float* __restrict__ b_u1, const float* __restrict__ b_d1,
    unsigned short* __restrict__ Yu, unsigned short* __restrict__ Yd) {
  __shared__ unsigned short tiles[4][4096];
  trans2_dev(tiles[0], tiles[1], tiles[2], tiles[3], x, W1uh, W1ul, W1dh,
             W1dl, b_u1, b_d1, Yu, Yd, blockIdx.x * 64, threadIdx.x);
}

__global__ __launch_bounds__(256) void mgemm_kernel(
    const unsigned short* Ah, const unsigned short* Al, int lda,
    const unsigned short* Gh, const unsigned short* Gl,
    const unsigned short* Bh, const unsigned short* Bl, int ldb,
    const float* bias, float* outF, unsigned short* outH, unsigned short* outL,
    int ldo, int colbase, int dup, int kchunks, int xchunks) {
  __shared__ unsigned short tiles[4][4096];
  mfma_gemm_dev<false>(tiles[0], tiles[1], tiles[2], tiles[3], Ah, Al, lda,
                       Gh, Gl, Bh, Bl, ldb, bias, outF, outH, outL, ldo,
                       colbase, dup, kchunks, xchunks, blockIdx.x * 64,
                       threadIdx.x);
}

// both layer-1 updates in one launch; A = f32 x (inline split)
__global__ __launch_bounds__(256) void update2m_kernel(
    const float* __restrict__ x,
    const unsigned short* auh, const unsigned short* aul,
    const unsigned short* adh, const unsigned short* adl,
    const unsigned short* U1uh, const unsigned short* U1ul,
    const unsigned short* U1dh, const unsigned short* U1dl,
    unsigned short* outH, unsigned short* outL) {
  __shared__ unsigned short tiles[4][4096];
  if (blockIdx.x < TB)
    mfma_gemm_dev<true>(tiles[0], tiles[1], tiles[2], tiles[3],
                        (const unsigned short*)x, nullptr, 128, auh, aul,
                        U1uh, U1ul, 192, nullptr, nullptr, outH, outL, 128,
                        0, 0, 3, 2, blockIdx.x * 64, threadIdx.x);
  else
    mfma_gemm_dev<true>(tiles[0], tiles[1], tiles[2], tiles[3],
                        (const unsigned short*)x, nullptr, 128, adh, adl,
                        U1dh, U1dl, 192, nullptr, nullptr, outH, outL, 128,
                        64, 0, 3, 2, (blockIdx.x - TB) * 64, threadIdx.x);
}

// ---------------------------------------------------------------------------
// bin index: node -> (node/6250)*32 + (node%6250)/196, in [0,256)
// ---------------------------------------------------------------------------
__device__ __forceinline__ int bin_of(unsigned n) {
  const unsigned bucket = n / 6250u;
  const unsigned rem = n - bucket * 6250u;
  return (int)(bucket * 32u + rem / 196u);
}

// ---------------------------------------------------------------------------
// prep: fine counting-sort into 256 bins/dir (blocks [0,BBK)) || weights (32)
// ---------------------------------------------------------------------------
__global__ __launch_bounds__(256) void prep_kernel(
    const int* __restrict__ src, const int* __restrict__ dst,
    int* __restrict__ gcur,
    unsigned* __restrict__ bdst, unsigned* __restrict__ bsrc,
    const float* __restrict__ U_u1, const float* __restrict__ U_d1,
    const float* __restrict__ W_u1, const float* __restrict__ W_d1,
    const float* __restrict__ W_u2, const float* __restrict__ U_u2,
    unsigned short* __restrict__ wbuf) {
  int bi = blockIdx.x;
  const int t = threadIdx.x;
  if (bi < BBK) {
    __shared__ int hist[512];
    __shared__ int base[512];
    __shared__ int cur[512];
    const int chunk = bi * CHKE;
    for (int j = t; j < 512; j += 256) { hist[j] = 0; cur[j] = 0; }
    __syncthreads();
    unsigned ev[8];
    int bd[8], bs[8];
    bool ok[8];
#pragma unroll
    for (int i = 0; i < 8; ++i) {
      const int e = chunk + i * 256 + t;
      ok[i] = e < NE;
      bd[i] = 0; bs[i] = 0; ev[i] = 0;
      if (ok[i]) {
        const unsigned s = (unsigned)src[e], d = (unsigned)dst[e];
        ev[i] = s | (d << 16);
        bd[i] = bin_of(d);
        bs[i] = bin_of(s);
        atomicAdd(&hist[bd[i]], 1);
        atomicAdd(&hist[256 + bs[i]], 1);
      }
    }
    __syncthreads();
    for (int j = t; j < 512; j += 256)
      base[j] = atomicAdd(&gcur[j], hist[j]);
    __syncthreads();
#pragma unroll
    for (int i = 0; i < 8; ++i) {
      if (ok[i]) {
        const int r1 = base[bd[i]] + atomicAdd(&cur[bd[i]], 1);
        if (r1 < BINCAP) bdst[bd[i] * BINCAP + r1] = ev[i];
        const int r2 = base[256 + bs[i]] + atomicAdd(&cur[256 + bs[i]], 1);
        if (r2 < BINCAP) bsrc[bs[i] * BINCAP + r2] = ev[i];
      }
    }
    return;
  }
  bi -= BBK;
  const int widx = bi >> 2;
  const int quad = bi & 3;
  const int Ks[8] = {192, 192, 128, 128, 128, 192, 64, 128};
  const int offs[8] = {WOFF_U1U, WOFF_U1D, WOFF_W1U, WOFF_W1D,
                       WOFF_W2U, WOFF_U2U, WOFF_WSUM, WOFF_USUM};
  const float* srcs[6] = {U_u1, U_d1, W_u1, W_d1, W_u2, U_u2};
  const int K = Ks[widx];
  const int off = offs[widx];
  const int qsz = K << 4;
  const int beg = quad * qsz;
  for (int e = beg + t; e < beg + qsz; e += 256) {
    const int cc = e / K;
    const int kk = e - cc * K;
    float v;
    if (widx < 6) v = srcs[widx][kk * 64 + cc];
    else if (widx == 6) v = W_u2[kk * 64 + cc] + W_u2[(kk + 64) * 64 + cc];
    else v = (kk < 64) ? (U_u2[kk * 64 + cc] + U_u2[(kk + 64) * 64 + cc])
                       : U_u2[(kk + 64) * 64 + cc];
    unsigned short h, l;
    split1(v, h, l);
    wbuf[off + cc * K + kk] = h;
    wbuf[off + (K << 6) + cc * K + kk] = l;
  }
}

// ---------------------------------------------------------------------------
// binscan: per-direction exclusive scan of 256 bin counts -> binbase
// ---------------------------------------------------------------------------
__global__ __launch_bounds__(256) void binscan_kernel(
    const int* __restrict__ gcur, int* __restrict__ binbase) {
  const int dir = blockIdx.x;
  const int t = threadIdx.x;
  __shared__ int sc[256];
  const int v = gcur[dir * 256 + t];
  sc[t] = v;
  __syncthreads();
  for (int off = 1; off < 256; off <<= 1) {
    int add = (t >= off) ? sc[t - off] : 0;
    __syncthreads();
    sc[t] += add;
    __syncthreads();
  }
  binbase[dir * 256 + t] = sc[t] - v;  // exclusive
}

// ---------------------------------------------------------------------------
// placeC: one block per bin; LDS hist -> scan -> rowptr + cols (u32 byte
// offsets = neighbor<<7), no global atomics
// ---------------------------------------------------------------------------
__global__ __launch_bounds__(256) void placeC_kernel(
    const int* __restrict__ gcur, const int* __restrict__ binbase,
    const unsigned* __restrict__ bdst, const unsigned* __restrict__ bsrc,
    int* __restrict__ rp_dst, int* __restrict__ rp_src,
    unsigned* __restrict__ col_dst, unsigned* __restrict__ col_src) {
  const int gbin = blockIdx.x;         // 0..511
  const int dir = gbin >> 8;
  const int bin = gbin & 255;
  const int bucket = bin >> 5;
  const int sub = bin & 31;
  const unsigned lo = (unsigned)(bucket * 6250 + sub * SUBW);
  const int subn = min(SUBW, 6250 - sub * SUBW);
  __shared__ int hist[SUBW];
  __shared__ int sc[SUBW];
  __shared__ int cur[SUBW];
  const int t = threadIdx.x;
  if (t < subn) hist[t] = 0;
  __syncthreads();
  const int cnt = min(gcur[gbin], BINCAP);
  const unsigned* p = (dir ? bsrc : bdst) + (size_t)bin * BINCAP;
  const int cnt4 = cnt & ~3;
  for (int i = t * 4; i < cnt4; i += 1024) {
    const uint4 v = *(const uint4*)(p + i);
    const unsigned n0 = dir ? (v.x & 0xFFFFu) : (v.x >> 16);
    const unsigned n1 = dir ? (v.y & 0xFFFFu) : (v.y >> 16);
    const unsigned n2 = dir ? (v.z & 0xFFFFu) : (v.z >> 16);
    const unsigned n3 = dir ? (v.w & 0xFFFFu) : (v.w >> 16);
    atomicAdd(&hist[n0 - lo], 1);
    atomicAdd(&hist[n1 - lo], 1);
    atomicAdd(&hist[n2 - lo], 1);
    atomicAdd(&hist[n3 - lo], 1);
  }
  for (int i = cnt4 + t; i < cnt; i += 256) {
    const unsigned n = dir ? (p[i] & 0xFFFFu) : (p[i] >> 16);
    atomicAdd(&hist[n - lo], 1);
  }
  __syncthreads();
  if (t < subn) sc[t] = hist[t];
  __syncthreads();
  for (int off = 1; off < SUBW; off <<= 1) {
    int add = (t < subn && t >= off) ? sc[t - off] : 0;
    __syncthreads();
    if (t < subn) sc[t] += add;
    __syncthreads();
  }
  const int bb = binbase[gbin];
  int* rp = dir ? rp_src : rp_dst;
  if (t < subn) {
    rp[lo + t] = bb + sc[t];            // inclusive end
    cur[t] = bb + sc[t] - hist[t];      // exclusive start cursor
  }
  __syncthreads();
  unsigned* col = dir ? col_src : col_dst;
  for (int i = t * 4; i < cnt4; i += 1024) {
    const uint4 v = *(const uint4*)(p + i);
    const unsigned vs[4] = {v.x, v.y, v.z, v.w};
#pragma unroll
    for (int k = 0; k < 4; ++k) {
      const unsigned n = dir ? (vs[k] & 0xFFFFu) : (vs[k] >> 16);
      const unsigned q = dir ? (vs[k] >> 16) : (vs[k] & 0xFFFFu);
      col[atomicAdd(&cur[n - lo], 1)] = q << 7;   // byte offset into Y plane
    }
  }
  for (int i = cnt4 + t; i < cnt; i += 256) {
    const unsigned v = p[i];
    const unsigned n = dir ? (v & 0xFFFFu) : (v >> 16);
    const unsigned q = dir ? (v >> 16) : (v & 0xFFFFu);
    col[atomicAdd(&cur[n - lo], 1)] = q << 7;
  }
}

// ---------------------------------------------------------------------------
// pull-gather mean from fp16 Y rows (128B) with packed fp16 accumulation.
// col holds pre-shifted u32 byte offsets. Epilogue is wave-parallel: the
// xor-reduce leaves full sums in all lanes; lane j takes column j via 4
// bpermutes + select, then one split1 and two coalesced 2B stores.
// ---------------------------------------------------------------------------
__device__ __forceinline__ void gatherh_dev(
    const unsigned short* __restrict__ Yh, const int* __restrict__ rowptr,
    const unsigned* __restrict__ col,
    unsigned short* __restrict__ aggh, unsigned short* __restrict__ aggl,
    int seg, int tid) {
  const int w = tid >> 6;
  const int lane = tid & 63;
  const int off = (seg >> 3) * 4 + w;
  if (off >= 6250) return;
  const int node = (seg & 7) * 6250 + off;
  const int eg = lane >> 3;          // 0..7
  const unsigned lb = (unsigned)((lane & 7) << 4);  // lane byte offset
  const char* Yb = (const char*)Yh;
  const int start = (node == 0) ? 0 : rowptr[node - 1];
  const int end = rowptr[node];
  half2v a0 = h2_of(0u), a1 = h2_of(0u), a2 = h2_of(0u), a3 = h2_of(0u);
  int e = start + eg;
  for (; e + 8 < end; e += 16) {
    const unsigned o0 = col[e] + lb;
    const unsigned o1 = col[e + 8] + lb;
    const uint4 v0 = *(const uint4*)(Yb + o0);
    const uint4 v1 = *(const uint4*)(Yb + o1);
    a0 += h2_of(v0.x) + h2_of(v1.x);
    a1 += h2_of(v0.y) + h2_of(v1.y);
    a2 += h2_of(v0.z) + h2_of(v1.z);
    a3 += h2_of(v0.w) + h2_of(v1.w);
  }
  for (; e < end; e += 8) {
    const unsigned o = col[e] + lb;
    const uint4 v = *(const uint4*)(Yb + o);
    a0 += h2_of(v.x);
    a1 += h2_of(v.y);
    a2 += h2_of(v.z);
    a3 += h2_of(v.w);
  }
  // packed shuffle-reduce across the 8 edge groups (sums land in ALL lanes)
#pragma unroll
  for (int d = 8; d <= 32; d <<= 1) {
    a0 += h2_of((unsigned)__shfl_xor((int)u_of(a0), d));
    a1 += h2_of((unsigned)__shfl_xor((int)u_of(a1), d));
    a2 += h2_of((unsigned)__shfl_xor((int)u_of(a2), d));
    a3 += h2_of((unsigned)__shfl_xor((int)u_of(a3), d));
  }
  // wave-parallel epilogue: lane j owns output column j.
  // lane k (k<8) holds cols 8k..8k+7; source lane = j>>3, element m = j&7.
  const int srcl = lane >> 3;
  const unsigned u0 = (unsigned)__shfl((int)u_of(a0), srcl);
  const unsigned u1 = (unsigned)__shfl((int)u_of(a1), srcl);
  const unsigned u2 = (unsigned)__shfl((int)u_of(a2), srcl);
  const unsigned u3 = (unsigned)__shfl((int)u_of(a3), srcl);
  const int m = lane & 7;
  const unsigned pick = (m & 4) ? ((m & 2) ? u3 : u2)
                                : ((m & 2) ? u1 : u0);
  union { unsigned short us; _Float16 hf; } cc;
  cc.us = (m & 1) ? (unsigned short)(pick >> 16)
                  : (unsigned short)(pick & 0xFFFFu);
  const float inv = 1.f / (float)max(end - start, 1);
  const float val = (float)cc.hf * inv;
  unsigned short h, l;
  split1(val, h, l);
  aggh[(size_t)node * 64 + lane] = h;
  aggl[(size_t)node * 64 + lane] = l;
}

__global__ __launch_bounds__(256) void gatherh_kernel(
    const unsigned short* __restrict__ Yh, const int* __restrict__ rowptr,
    const unsigned* __restrict__ col,
    unsigned short* __restrict__ aggh, unsigned short* __restrict__ aggl) {
  gatherh_dev(Yh, rowptr, col, aggh, aggl, blockIdx.x, threadIdx.x);
}

__global__ __launch_bounds__(256) void gatherh2_kernel(
    const unsigned short* __restrict__ Yhu, const int* __restrict__ rp_dst,
    const unsigned* __restrict__ col_dst,
    unsigned short* auh, unsigned short* aul,
    const unsigned short* __restrict__ Yhd, const int* __restrict__ rp_src,
    const unsigned* __restrict__ col_src,
    unsigned short* adh, unsigned short* adl) {
  if (blockIdx.x < GBS)
    gatherh_dev(Yhu, rp_dst, col_dst, auh, aul, blockIdx.x, threadIdx.x);
  else
    gatherh_dev(Yhd, rp_src, col_src, adh, adl, blockIdx.x - GBS, threadIdx.x);
}

// ===========================================================================
// Fallback path (vector-f32 GEMM + replicated edge pass) for small workspaces
// ===========================================================================
__global__ __launch_bounds__(256) void pack_kernel(
    const int* __restrict__ src, const int* __restrict__ dst,
    unsigned* __restrict__ epack) {
  for (int e = blockIdx.x * 256 + threadIdx.x; e < NE; e += 1024 * 256)
    epack[e] = (unsigned)src[e] | ((unsigned)dst[e] << 16);
}

__device__ __forceinline__ void place_dev4(
    const unsigned* __restrict__ epack,
    int* __restrict__ rp_dst, int* __restrict__ rp_src,
    unsigned short* __restrict__ col_dst, unsigned short* __restrict__ col_src,
    int bi, int tid) {
  const unsigned lo = (unsigned)(bi & 7) * 6250u;
  const int g = (bi >> 3) * 256 + tid;
  for (int e = g * 4; e < NE; e += 262144) {
    const uint4 v4 = *(const uint4*)(epack + e);
    const unsigned vs[4] = {v4.x, v4.y, v4.z, v4.w};
#pragma unroll
    for (int i = 0; i < 4; ++i) {
      const unsigned s = vs[i] & 0xFFFFu, d = vs[i] >> 16;
      if (d - lo < 6250u)
        col_dst[atomicAdd(&rp_dst[d], 1)] = (unsigned short)s;
      if (s - lo < 6250u)
        col_src[atomicAdd(&rp_src[s], 1)] = (unsigned short)d;
    }
  }
}

__global__ __launch_bounds__(256) void count_old_kernel(
    const unsigned* __restrict__ epack,
    int* __restrict__ rp_dst, int* __restrict__ rp_src) {
  const int bi = blockIdx.x;
  const unsigned lo = (unsigned)(bi & 7) * 6250u;
  const int g = (bi >> 3) * 256 + threadIdx.x;
  for (int e = g * 4; e < NE; e += 262144) {
    const uint4 v4 = *(const uint4*)(epack + e);
    const unsigned vs[4] = {v4.x, v4.y, v4.z, v4.w};
#pragma unroll
    for (int i = 0; i < 4; ++i) {
      const unsigned s = vs[i] & 0xFFFFu, d = vs[i] >> 16;
      if (d - lo < 6250u) atomicAdd(&rp_dst[d], 1);
      if (s - lo < 6250u) atomicAdd(&rp_src[s], 1);
    }
  }
}

#define CHUNK 49
__global__ __launch_bounds__(1024) void scan_kernel(
    int* __restrict__ a0, int* __restrict__ a1) {
  int* a = (blockIdx.x == 0) ? a0 : a1;
  __shared__ int part[1024];
  const int t = threadIdx.x;
  const int beg = t * CHUNK;
  const int end = min(beg + CHUNK, NN);
  int s = 0;
  for (int i = beg; i < end; ++i) s += a[i];
  part[t] = s;
  __syncthreads();
  for (int off = 1; off < 1024; off <<= 1) {
    int add = (t >= off) ? part[t - off] : 0;
    __syncthreads();
    part[t] += add;
    __syncthreads();
  }
  int run = (t == 0) ? 0 : part[t - 1];
  for (int i = beg; i < end; ++i) {
    const int c = a[i];
    a[i] = run;
    run += c;
  }
}

__device__ __forceinline__ void gatherF_dev(
    const float* __restrict__ Y, const int* __restrict__ rowptr,
    const unsigned short* __restrict__ col, float* __restrict__ AGGf,
    int seg, int tid) {
  const int w = tid >> 6;
  const int lane = tid & 63;
  const int off = (seg >> 3) * 4 + w;
  if (off >= 6250) return;
  const int node = (seg & 7) * 6250 + off;
  const int eg = lane >> 4;
  const int cq = (lane & 15) << 2;
  const int start = (node == 0) ? 0 : rowptr[node - 1];
  const int end = rowptr[node];
  float4 acc = make_float4(0.f, 0.f, 0.f, 0.f);
  for (int e = start + eg; e < end; e += 4) {
    const float4 y = *(const float4*)(Y + (size_t)col[e] * 64 + cq);
    acc.x += y.x; acc.y += y.y; acc.z += y.z; acc.w += y.w;
  }
  acc.x += __shfl_xor(acc.x, 16);
  acc.y += __shfl_xor(acc.y, 16);
  acc.z += __shfl_xor(acc.z, 16);
  acc.w += __shfl_xor(acc.w, 16);
  acc.x += __shfl_xor(acc.x, 32);
  acc.y += __shfl_xor(acc.y, 32);
  acc.z += __shfl_xor(acc.z, 32);
  acc.w += __shfl_xor(acc.w, 32);
  if (eg == 0) {
    const float inv = 1.f / (float)max(end - start, 1);
    float4 o;
    o.x = acc.x * inv; o.y = acc.y * inv;
    o.z = acc.z * inv; o.w = acc.w * inv;
    *(float4*)(AGGf + (size_t)node * 64 + cq) = o;
  }
}

__global__ __launch_bounds__(256) void gatherF_kernel(
    const float* __restrict__ Y, const int* __restrict__ rowptr,
    const unsigned short* __restrict__ col, float* __restrict__ AGGf) {
  gatherF_dev(Y, rowptr, col, AGGf, blockIdx.x, threadIdx.x);
}

__device__ __forceinline__ void gemm64_dev(
    float (*Xt)[68], float* Ws, const float* __restrict__ X, int ldx,
    const float* __restrict__ AGG, const float* __restrict__ W,
    const float* __restrict__ b, float* __restrict__ out, int ldo,
    int colbase, int dup, int kchunks, int xchunks, int row0, int tid) {
  const int tx = tid & 15, ty = tid >> 4;
  float acc[4][4] = {{0.f}};
  for (int c = 0; c < kchunks; ++c) {
    {
      const int rr = tid >> 2;
      const int cg = (tid & 3) << 4;
      const float* srcp;
      int ld, co;
      if (c < xchunks) { srcp = X; ld = ldx; co = c * 64; }
      else             { srcp = AGG; ld = 64; co = 0; }
      int row = row0 + rr;
      if (row > NN - 1) row = NN - 1;
      const float* g = srcp + row * ld + co + cg;
      const float4 v0 = *(const float4*)(g + 0);
      const float4 v1 = *(const float4*)(g + 4);
      const float4 v2 = *(const float4*)(g + 8);
      const float4 v3 = *(const float4*)(g + 12);
      Xt[cg + 0][rr] = v0.x;  Xt[cg + 1][rr] = v0.y;
      Xt[cg + 2][rr] = v0.z;  Xt[cg + 3][rr] = v0.w;
      Xt[cg + 4][rr] = v1.x;  Xt[cg + 5][rr] = v1.y;
      Xt[cg + 6][rr] = v1.z;  Xt[cg + 7][rr] = v1.w;
      Xt[cg + 8][rr] = v2.x;  Xt[cg + 9][rr] = v2.y;
      Xt[cg + 10][rr] = v2.z; Xt[cg + 11][rr] = v2.w;
      Xt[cg + 12][rr] = v3.x; Xt[cg + 13][rr] = v3.y;
      Xt[cg + 14][rr] = v3.z; Xt[cg + 15][rr] = v3.w;
      const float4* wg = (const float4*)(W + c * 64 * 64);
      float4* wl = (float4*)Ws;
      wl[tid] = wg[tid];
      wl[tid + 256] = wg[tid + 256];
      wl[tid + 512] = wg[tid + 512];
      wl[tid + 768] = wg[tid + 768];
    }
    __syncthreads();
#pragma unroll 8
    for (int kk = 0; kk < 64; ++kk) {
      const float4 a = *(const float4*)&Xt[kk][tx << 2];
      const float4 w = *(const float4*)&Ws[kk * 64 + (ty << 2)];
      acc[0][0] += a.x * w.x; acc[0][1] += a.x * w.y;
      acc[0][2] += a.x * w.z; acc[0][3] += a.x * w.w;
      acc[1][0] += a.y * w.x; acc[1][1] += a.y * w.y;
      acc[1][2] += a.y * w.z; acc[1][3] += a.y * w.w;
      acc[2][0] += a.z * w.x; acc[2][1] += a.z * w.y;
      acc[2][2] += a.z * w.z; acc[2][3] += a.z * w.w;
      acc[3][0] += a.w * w.x; acc[3][1] += a.w * w.y;
      acc[3][2] += a.w * w.z; acc[3][3] += a.w * w.w;
    }
    __syncthreads();
  }
  float4 bv = make_float4(0.f, 0.f, 0.f, 0.f);
  if (b) bv = *(const float4*)(b + (ty << 2));
#pragma unroll
  for (int i = 0; i < 4; ++i) {
    const int row = row0 + (tx << 2) + i;
    if (row < NN) {
      float4 o;
      o.x = fmaxf(acc[i][0] + bv.x, 0.f);
      o.y = fmaxf(acc[i][1] + bv.y, 0.f);
      o.z = fmaxf(acc[i][2] + bv.z, 0.f);
      o.w = fmaxf(acc[i][3] + bv.w, 0.f);
      *(float4*)(out + row * ldo + colbase + (ty << 2)) = o;
      if (dup) *(float4*)(out + row * ldo + 64 + (ty << 2)) = o;
    }
  }
}

__global__ __launch_bounds__(256) void gemm_kernel(
    const float* __restrict__ X, int ldx, const float* __restrict__ AGG,
    const float* __restrict__ W, const float* __restrict__ b,
    float* __restrict__ out, int ldo, int colbase, int dup,
    int kchunks, int xchunks) {
  __shared__ __align__(16) float Xt[64][68];
  __shared__ __align__(16) float Ws[4096];
  gemm64_dev(Xt, Ws, X, ldx, AGG, W, b, out, ldo, colbase, dup, kchunks,
             xchunks, blockIdx.x * 64, threadIdx.x);
}

__global__ __launch_bounds__(256) void fused0_kernel(
    const unsigned* __restrict__ epack,
    int* __restrict__ rp_dst, int* __restrict__ rp_src,
    unsigned short* __restrict__ col_dst, unsigned short* __restrict__ col_src,
    const float* __restrict__ x,
    const float* __restrict__ W_u1, const float* __restrict__ b_u1,
    float* __restrict__ Y_u,
    const float* __restrict__ W_d1, const float* __restrict__ b_d1,
    float* __restrict__ Y_d) {
  __shared__ __align__(16) float Xt[64][68];
  __shared__ __align__(16) float Ws[4096];
  int bi = blockIdx.x;
  if (bi < 2048) {
    place_dev4(epack, rp_dst, rp_src, col_dst, col_src, bi, threadIdx.x);
    return;
  }
  bi -= 2048;
  if (bi < TB)
    gemm64_dev(Xt, Ws, x, 128, nullptr, W_u1, b_u1, Y_u, 64, 0, 0, 2, 2,
               bi * 64, threadIdx.x);
  else
    gemm64_dev(Xt, Ws, x, 128, nullptr, W_d1, b_d1, Y_d, 64, 0, 0, 2, 2,
               (bi - TB) * 64, threadIdx.x);
}

// ===========================================================================
extern "C" void kernel_launch(void* const* d_in, const int* in_sizes, int n_in,
                              void* d_out, int out_size, void* d_ws, size_t ws_size,
                              hipStream_t stream) {
  const float* x    = (const float*)d_in[0];
  const int*   ei   = (const int*)d_in[1];
  const float* W_u1 = (const float*)d_in[2];
  const float* b_u1 = (const float*)d_in[3];
  const float* U_u1 = (const float*)d_in[4];
  const float* W_d1 = (const float*)d_in[5];
  const float* b_d1 = (const float*)d_in[6];
  const float* U_d1 = (const float*)d_in[7];
  const float* W_u2 = (const float*)d_in[8];
  const float* b_u2 = (const float*)d_in[9];
  const float* U_u2 = (const float*)d_in[10];
  const int* src = ei;
  const int* dst = ei + NE;
  float* out = (float*)d_out;

  char* wsb = (char*)d_ws;
  int* rp_dst  = (int*)wsb;              wsb += NN * sizeof(int);
  int* rp_src  = (int*)wsb;              wsb += NN * sizeof(int);
  int* gcur    = (int*)wsb;              wsb += 512 * sizeof(int);
  int* binbase = (int*)wsb;              wsb += 512 * sizeof(int);
  unsigned* col_dst = (unsigned*)wsb;    wsb += (size_t)NE * 4;
  unsigned* col_src = (unsigned*)wsb;    wsb += (size_t)NE * 4;

  const size_t plane = (size_t)NN * 64 * 2;   // 6.4 MB u16 plane
  const size_t needM = (size_t)2 * NN * 4 + 4096 + (size_t)NE * 8 +
                       (size_t)WBUF_USHORTS * 2 +
                       6 * plane +               // A..F
                       2 * (size_t)NN * 128 * 2; // outh, outl

  hipMemsetAsync(gcur, 0, 512 * sizeof(int), stream);

  if (ws_size >= needM) {
    unsigned short* wbuf = (unsigned short*)wsb; wsb += (size_t)WBUF_USHORTS * 2;
    unsigned short* A = (unsigned short*)wsb; wsb += plane;  // Yh_u
    unsigned short* B = (unsigned short*)wsb; wsb += plane;  // Yh_d
    unsigned short* C = (unsigned short*)wsb; wsb += plane;  // agg_uh
    unsigned short* D = (unsigned short*)wsb; wsb += plane;  // agg_ul
    unsigned short* E = (unsigned short*)wsb; wsb += plane;  // agg_dh
    unsigned short* F = (unsigned short*)wsb; wsb += plane;  // agg_dl
    unsigned short* outh = (unsigned short*)wsb; wsb += (size_t)NN * 128 * 2;
    unsigned short* outl = (unsigned short*)wsb;

    // aliases (strict sequential lifetimes):
    unsigned* bdst = (unsigned*)C;   // bins (4MB) live until placeC
    unsigned* bsrc = (unsigned*)D;
    unsigned short* Yh2  = C;        // r2 trans output (bins dead)
    unsigned short* agg2h = E;       // r2 gather out (agg_dh/dl dead)
    unsigned short* agg2l = F;
    unsigned short* O2h = C;         // r2 update out (Yh2 dead)
    unsigned short* O2l = D;
    unsigned short* Yh3 = E;         // r3 trans out (agg2 dead)
    unsigned short* agg3h = A;       // r3 gather out (Yh_u/d dead)
    unsigned short* agg3l = B;

    const unsigned short* U1uh = wbuf + WOFF_U1U;
    const unsigned short* U1ul = wbuf + WOFF_U1U + 64 * 192;
    const unsigned short* U1dh = wbuf + WOFF_U1D;
    const unsigned short* U1dl = wbuf + WOFF_U1D + 64 * 192;
    const unsigned short* W1uh = wbuf + WOFF_W1U;
    const unsigned short* W1ul = wbuf + WOFF_W1U + 64 * 128;
    const unsigned short* W1dh = wbuf + WOFF_W1D;
    const unsigned short* W1dl = wbuf + WOFF_W1D + 64 * 128;
    const unsigned short* W2uh = wbuf + WOFF_W2U;
    const unsigned short* W2ul = wbuf + WOFF_W2U + 64 * 128;
    const unsigned short* U2uh = wbuf + WOFF_U2U;
    const unsigned short* U2ul = wbuf + WOFF_U2U + 64 * 192;
    const unsigned short* Wsh  = wbuf + WOFF_WSUM;
    const unsigned short* Wsl  = wbuf + WOFF_WSUM + 64 * 64;
    const unsigned short* Ush  = wbuf + WOFF_USUM;
    const unsigned short* Usl  = wbuf + WOFF_USUM + 64 * 128;

    // fine counting-sort || weight conversion
    prep_kernel<<<BBK + 32, 256, 0, stream>>>(
        src, dst, gcur, bdst, bsrc, U_u1, U_d1, W_u1, W_d1, W_u2, U_u2, wbuf);
    binscan_kernel<<<2, 256, 0, stream>>>(gcur, binbase);
    // per-bin CSR finalize (reads bins in C,D; cols = byte offsets)
    placeC_kernel<<<512, 256, 0, stream>>>(gcur, binbase, bdst, bsrc,
                                           rp_dst, rp_src, col_dst, col_src);
    // layer-1 transforms -> fp16 Y planes
    trans2_kernel<<<TB, 256, 0, stream>>>(x, W1uh, W1ul, W1dh, W1dl,
                                          b_u1, b_d1, A, B);
    // layer-1 gathers (both dirs), packed fp16 accumulate
    gatherh2_kernel<<<2 * GBS, 256, 0, stream>>>(A, rp_dst, col_dst, C, D,
                                                 B, rp_src, col_src, E, F);
    update2m_kernel<<<2 * TB, 256, 0, stream>>>(x, C, D, E, F, U1uh, U1ul,
                                                U1dh, U1dl, outh, outl);
    // round 2
    mgemm_kernel<<<TB, 256, 0, stream>>>(outh, outl, 128, nullptr, nullptr,
                                         W2uh, W2ul, 128, b_u2, nullptr,
                                         Yh2, nullptr, 64, 0, 0, 2, 2);
    gatherh_kernel<<<GBS, 256, 0, stream>>>(Yh2, rp_dst, col_dst, agg2h,
                                            agg2l);
    mgemm_kernel<<<TB, 256, 0, stream>>>(outh, outl, 128, agg2h, agg2l,
                                         U2uh, U2ul, 192, nullptr, nullptr,
                                         O2h, O2l, 64, 0, 0, 3, 2);
    // round 3 (h = [O2,O2] folded into presummed weights)
    mgemm_kernel<<<TB, 256, 0, stream>>>(O2h, O2l, 64, nullptr, nullptr,
                                         Wsh, Wsl, 64, b_u2, nullptr,
                                         Yh3, nullptr, 64, 0, 0, 1, 1);
    gatherh_kernel<<<GBS, 256, 0, stream>>>(Yh3, rp_dst, col_dst, agg3h,
                                            agg3l);
    mgemm_kernel<<<TB, 256, 0, stream>>>(O2h, O2l, 64, agg3h, agg3l,
                                         Ush, Usl, 128, nullptr, out,
                                         nullptr, nullptr, 128, 0, 1, 2, 1);
  } else {
    // fallback: vector-f32 path with replicated edge passes (u16 cols)
    unsigned* epack = (unsigned*)wsb; wsb += (size_t)NE * 4;
    float* Y_u = (float*)wsb; wsb += (size_t)NN * 64 * sizeof(float);
    float* Y_d = (float*)wsb; wsb += (size_t)NN * 64 * sizeof(float);
    float* AGG = (float*)wsb;
    unsigned short* cds = (unsigned short*)col_dst;
    unsigned short* css = (unsigned short*)col_src;
    hipMemsetAsync(rp_dst, 0, 2 * NN * sizeof(int), stream);
    pack_kernel<<<1024, 256, 0, stream>>>(src, dst, epack);
    count_old_kernel<<<2048, 256, 0, stream>>>(epack, rp_dst, rp_src);
    scan_kernel<<<2, 1024, 0, stream>>>(rp_dst, rp_src);
    fused0_kernel<<<2048 + 2 * TB, 256, 0, stream>>>(
        epack, rp_dst, rp_src, cds, css, x, W_u1, b_u1, Y_u, W_d1,
        b_d1, Y_d);
    gatherF_kernel<<<GBS, 256, 0, stream>>>(Y_u, rp_dst, cds, AGG);
    gemm_kernel<<<TB, 256, 0, stream>>>(x, 128, AGG, U_u1, nullptr, out,
                                        128, 0, 0, 3, 2);
    gatherF_kernel<<<GBS, 256, 0, stream>>>(Y_d, rp_src, css, AGG);
    gemm_kernel<<<TB, 256, 0, stream>>>(x, 128, AGG, U_d1, nullptr, out,
                                        128, 64, 0, 3, 2);
    for (int r = 0; r < 2; ++r) {
      gemm_kernel<<<TB, 256, 0, stream>>>(out, 128, nullptr, W_u2, b_u2,
                                          Y_u, 64, 0, 0, 2, 2);
      gatherF_kernel<<<GBS, 256, 0, stream>>>(Y_u, rp_dst, cds, AGG);
      gemm_kernel<<<TB, 256, 0, stream>>>(out, 128, AGG, U_u2, nullptr,
                                          out, 128, 0, 1, 3, 2);
    }
  }
}

// Round 17
// 190.219 us; speedup vs baseline: 2.1147x; 1.0206x over previous
//
#include <hip/hip_runtime.h>

#define NN 50000
#define NE 800000
#define TB 782             // ceil(NN/64) gemm row-tile blocks
#define GBS 12504          // 8 * 1563 swizzled gather blocks (4 nodes each)
#define BBK 391            // bucket blocks = ceil(NE/2048)
#define CHKE 2048          // edges per bucket block
#define BINS 256           // bins per direction
#define BINCAP 4096        // per-bin capacity (mean 3125, >17 sigma slack)
#define SUBW 196           // nodes per bin

typedef __attribute__((ext_vector_type(8))) short bhalf8;
typedef __attribute__((ext_vector_type(4))) float floatx4;
typedef __attribute__((ext_vector_type(2))) _Float16 half2v;

// weight buffer offsets (ushort units); l plane = h + 64*K
#define WOFF_U1U 0
#define WOFF_U1D 24576
#define WOFF_W1U 49152
#define WOFF_W1D 65536
#define WOFF_W2U 81920
#define WOFF_U2U 98304
#define WOFF_WSUM 122880
#define WOFF_USUM 131072
#define WBUF_USHORTS 147456

// ---------------------------------------------------------------------------
// bf16 / fp16 helpers
// ---------------------------------------------------------------------------
__device__ __forceinline__ unsigned short bf16hi(float v) {
  union { float f; unsigned u; } c; c.f = v;
  return (unsigned short)((c.u + 0x7FFFu + ((c.u >> 16) & 1u)) >> 16);
}
__device__ __forceinline__ float bf16tof(unsigned short h) {
  union { unsigned u; float f; } c; c.u = ((unsigned)h) << 16;
  return c.f;
}
__device__ __forceinline__ void split1(float v, unsigned short& h,
                                       unsigned short& l) {
  h = bf16hi(v);
  l = bf16hi(v - bf16tof(h));
}
__device__ __forceinline__ void split8(const float4 v0, const float4 v1,
                                       uint4& H, uint4& L) {
  unsigned short h0, l0, h1, l1;
  split1(v0.x, h0, l0); split1(v0.y, h1, l1);
  H.x = (unsigned)h0 | ((unsigned)h1 << 16);
  L.x = (unsigned)l0 | ((unsigned)l1 << 16);
  split1(v0.z, h0, l0); split1(v0.w, h1, l1);
  H.y = (unsigned)h0 | ((unsigned)h1 << 16);
  L.y = (unsigned)l0 | ((unsigned)l1 << 16);
  split1(v1.x, h0, l0); split1(v1.y, h1, l1);
  H.z = (unsigned)h0 | ((unsigned)h1 << 16);
  L.z = (unsigned)l0 | ((unsigned)l1 << 16);
  split1(v1.z, h0, l0); split1(v1.w, h1, l1);
  H.w = (unsigned)h0 | ((unsigned)h1 << 16);
  L.w = (unsigned)l0 | ((unsigned)l1 << 16);
}
__device__ __forceinline__ unsigned short f16b(float v) {
  union { _Float16 h; unsigned short u; } c;
  c.h = (_Float16)v;
  return c.u;
}
__device__ __forceinline__ half2v h2_of(unsigned u) {
  union { unsigned v; half2v h; } c; c.v = u; return c.h;
}
__device__ __forceinline__ unsigned u_of(half2v h) {
  union { half2v h; unsigned v; } c; c.h = h; return c.v;
}

// swizzled LDS byte address for bf16 tile [64 rows][64 k] (128B rows)
#define SWZ(row, inrow) (((row) << 7) + ((inrow) ^ (((row)&7) << 4)))

// ---------------------------------------------------------------------------
// MFMA split-bf16 GEMM (single B): out = relu([A|G] @ B^T (+bias))
// outF: f32 (optional dup). outH+outL: bf16 hi/lo. outH only: fp16 plane.
// ---------------------------------------------------------------------------
template <bool AF32>
__device__ __forceinline__ void mfma_gemm_dev(
    unsigned short* tAh, unsigned short* tAl,
    unsigned short* tBh, unsigned short* tBl,
    const unsigned short* __restrict__ Ah, const unsigned short* __restrict__ Al,
    int lda,
    const unsigned short* __restrict__ Gh, const unsigned short* __restrict__ Gl,
    const unsigned short* __restrict__ Bh, const unsigned short* __restrict__ Bl,
    int ldb, const float* __restrict__ bias,
    float* __restrict__ outF, unsigned short* __restrict__ outH,
    unsigned short* __restrict__ outL,
    int ldo, int colbase, int dup, int kchunks, int xchunks,
    int row0, int tid) {
  const int lane = tid & 63;
  const int wm = tid >> 6;
  const int m = lane & 15;
  const int kg = lane >> 4;
  floatx4 acc[4];
#pragma unroll
  for (int i = 0; i < 4; ++i) acc[i] = (floatx4){0.f, 0.f, 0.f, 0.f};

  for (int c = 0; c < kchunks; ++c) {
#pragma unroll
    for (int q = tid; q < 512; q += 256) {
      const int row = q >> 3, slot = q & 7;
      int gr = row0 + row;
      gr = (gr > NN - 1) ? NN - 1 : gr;
      const int ad = SWZ(row, slot << 4);
      if (AF32 && c < xchunks) {
        const float* f = (const float*)Ah;
        const size_t go = (size_t)gr * lda + (c << 6) + slot * 8;
        const float4 v0 = *(const float4*)(f + go);
        const float4 v1 = *(const float4*)(f + go + 4);
        uint4 H, L;
        split8(v0, v1, H, L);
        *(uint4*)((char*)tAh + ad) = H;
        *(uint4*)((char*)tAl + ad) = L;
      } else {
        const unsigned short* sh;
        const unsigned short* sl;
        int ld, kc;
        if (c < xchunks) { sh = Ah; sl = Al; ld = lda; kc = c << 6; }
        else             { sh = Gh; sl = Gl; ld = 64;  kc = 0; }
        const size_t go = (size_t)gr * ld + kc + slot * 8;
        *(uint4*)((char*)tAh + ad) = *(const uint4*)(sh + go);
        *(uint4*)((char*)tAl + ad) = *(const uint4*)(sl + go);
      }
      const size_t gob = (size_t)row * ldb + (c << 6) + slot * 8;
      *(uint4*)((char*)tBh + ad) = *(const uint4*)(Bh + gob);
      *(uint4*)((char*)tBl + ad) = *(const uint4*)(Bl + gob);
    }
    __syncthreads();
#pragma unroll
    for (int ks = 0; ks < 2; ++ks) {
      const int inrow = (ks << 6) + (kg << 4);
      const int rA = (wm << 4) + m;
      const bhalf8 ah = *(const bhalf8*)((const char*)tAh + SWZ(rA, inrow));
      const bhalf8 al = *(const bhalf8*)((const char*)tAl + SWZ(rA, inrow));
#pragma unroll
      for (int nt = 0; nt < 4; ++nt) {
        const int rB = (nt << 4) + m;
        const bhalf8 bh = *(const bhalf8*)((const char*)tBh + SWZ(rB, inrow));
        const bhalf8 bl = *(const bhalf8*)((const char*)tBl + SWZ(rB, inrow));
        acc[nt] = __builtin_amdgcn_mfma_f32_16x16x32_bf16(ah, bh, acc[nt], 0, 0, 0);
        acc[nt] = __builtin_amdgcn_mfma_f32_16x16x32_bf16(ah, bl, acc[nt], 0, 0, 0);
        acc[nt] = __builtin_amdgcn_mfma_f32_16x16x32_bf16(al, bh, acc[nt], 0, 0, 0);
      }
    }
    __syncthreads();
  }
#pragma unroll
  for (int nt = 0; nt < 4; ++nt) {
    const int col = colbase + (nt << 4) + m;
    const float bv = bias ? bias[(nt << 4) + m] : 0.f;
#pragma unroll
    for (int r = 0; r < 4; ++r) {
      const int row = row0 + (wm << 4) + (kg << 2) + r;
      if (row < NN) {
        const float v = fmaxf(acc[nt][r] + bv, 0.f);
        if (outF) {
          outF[(size_t)row * ldo + col] = v;
          if (dup) outF[(size_t)row * ldo + col + 64] = v;
        }
        if (outH) {
          if (outL) {
            unsigned short h, l;
            split1(v, h, l);
            outH[(size_t)row * ldo + col] = h;
            outL[(size_t)row * ldo + col] = l;
          } else {
            outH[(size_t)row * ldo + col] = f16b(v);
          }
        }
      }
    }
  }
}

// ---------------------------------------------------------------------------
// Dual-output transform, 4-tile (32KB); Y outputs are fp16 planes
// ---------------------------------------------------------------------------
__device__ __forceinline__ void trans2_dev(
    unsigned short* tAh, unsigned short* tAl,
    unsigned short* tBh, unsigned short* tBl,
    const float* __restrict__ x,
    const unsigned short* __restrict__ Wuh, const unsigned short* __restrict__ Wul,
    const unsigned short* __restrict__ Wdh, const unsigned short* __restrict__ Wdl,
    const float* __restrict__ bu, const float* __restrict__ bd,
    unsigned short* __restrict__ Yu, unsigned short* __restrict__ Yd,
    int row0, int tid) {
  const int lane = tid & 63;
  const int wm = tid >> 6;
  const int m = lane & 15;
  const int kg = lane >> 4;
  floatx4 accU[4], accD[4];
#pragma unroll
  for (int i = 0; i < 4; ++i) {
    accU[i] = (floatx4){0.f, 0.f, 0.f, 0.f};
    accD[i] = (floatx4){0.f, 0.f, 0.f, 0.f};
  }
  for (int c = 0; c < 2; ++c) {
#pragma unroll
    for (int q = tid; q < 512; q += 256) {
      const int row = q >> 3, slot = q & 7;
      int gr = row0 + row;
      gr = (gr > NN - 1) ? NN - 1 : gr;
      const int ad = SWZ(row, slot << 4);
      const size_t go = (size_t)gr * 128 + (c << 6) + slot * 8;
      const float4 v0 = *(const float4*)(x + go);
      const float4 v1 = *(const float4*)(x + go + 4);
      uint4 H, L;
      split8(v0, v1, H, L);
      *(uint4*)((char*)tAh + ad) = H;
      *(uint4*)((char*)tAl + ad) = L;
      const size_t gob = (size_t)row * 128 + (c << 6) + slot * 8;
      *(uint4*)((char*)tBh + ad) = *(const uint4*)(Wuh + gob);
      *(uint4*)((char*)tBl + ad) = *(const uint4*)(Wul + gob);
    }
    __syncthreads();
#pragma unroll
    for (int ks = 0; ks < 2; ++ks) {
      const int inrow = (ks << 6) + (kg << 4);
      const int rA = (wm << 4) + m;
      const bhalf8 ah = *(const bhalf8*)((const char*)tAh + SWZ(rA, inrow));
      const bhalf8 al = *(const bhalf8*)((const char*)tAl + SWZ(rA, inrow));
#pragma unroll
      for (int nt = 0; nt < 4; ++nt) {
        const int rB = (nt << 4) + m;
        const int adB = SWZ(rB, inrow);
        const bhalf8 bh = *(const bhalf8*)((const char*)tBh + adB);
        const bhalf8 bl = *(const bhalf8*)((const char*)tBl + adB);
        accU[nt] = __builtin_amdgcn_mfma_f32_16x16x32_bf16(ah, bh, accU[nt], 0, 0, 0);
        accU[nt] = __builtin_amdgcn_mfma_f32_16x16x32_bf16(ah, bl, accU[nt], 0, 0, 0);
        accU[nt] = __builtin_amdgcn_mfma_f32_16x16x32_bf16(al, bh, accU[nt], 0, 0, 0);
      }
    }
    __syncthreads();
#pragma unroll
    for (int q = tid; q < 512; q += 256) {
      const int row = q >> 3, slot = q & 7;
      const int ad = SWZ(row, slot << 4);
      const size_t gob = (size_t)row * 128 + (c << 6) + slot * 8;
      *(uint4*)((char*)tBh + ad) = *(const uint4*)(Wdh + gob);
      *(uint4*)((char*)tBl + ad) = *(const uint4*)(Wdl + gob);
    }
    __syncthreads();
#pragma unroll
    for (int ks = 0; ks < 2; ++ks) {
      const int inrow = (ks << 6) + (kg << 4);
      const int rA = (wm << 4) + m;
      const bhalf8 ah = *(const bhalf8*)((const char*)tAh + SWZ(rA, inrow));
      const bhalf8 al = *(const bhalf8*)((const char*)tAl + SWZ(rA, inrow));
#pragma unroll
      for (int nt = 0; nt < 4; ++nt) {
        const int rB = (nt << 4) + m;
        const int adB = SWZ(rB, inrow);
        const bhalf8 bh = *(const bhalf8*)((const char*)tBh + adB);
        const bhalf8 bl = *(const bhalf8*)((const char*)tBl + adB);
        accD[nt] = __builtin_amdgcn_mfma_f32_16x16x32_bf16(ah, bh, accD[nt], 0, 0, 0);
        accD[nt] = __builtin_amdgcn_mfma_f32_16x16x32_bf16(ah, bl, accD[nt], 0, 0, 0);
        accD[nt] = __builtin_amdgcn_mfma_f32_16x16x32_bf16(al, bh, accD[nt], 0, 0, 0);
      }
    }
    __syncthreads();
  }
#pragma unroll
  for (int nt = 0; nt < 4; ++nt) {
    const int col = (nt << 4) + m;
    const float bvu = bu[col];
    const float bvd = bd[col];
#pragma unroll
    for (int r = 0; r < 4; ++r) {
      const int row = row0 + (wm << 4) + (kg << 2) + r;
      if (row < NN) {
        Yu[(size_t)row * 64 + col] = f16b(fmaxf(accU[nt][r] + bvu, 0.f));
        Yd[(size_t)row * 64 + col] = f16b(fmaxf(accD[nt][r] + bvd, 0.f));
      }
    }
  }
}

__global__ __launch_bounds__(256) void mgemm_kernel(
    const unsigned short* Ah, const unsigned short* Al, int lda,
    const unsigned short* Gh, const unsigned short* Gl,
    const unsigned short* Bh, const unsigned short* Bl, int ldb,
    const float* bias, float* outF, unsigned short* outH, unsigned short* outL,
    int ldo, int colbase, int dup, int kchunks, int xchunks) {
  __shared__ unsigned short tiles[4][4096];
  mfma_gemm_dev<false>(tiles[0], tiles[1], tiles[2], tiles[3], Ah, Al, lda,
                       Gh, Gl, Bh, Bl, ldb, bias, outF, outH, outL, ldo,
                       colbase, dup, kchunks, xchunks, blockIdx.x * 64,
                       threadIdx.x);
}

// both layer-1 updates in one launch; A = f32 x (inline split)
__global__ __launch_bounds__(256) void update2m_kernel(
    const float* __restrict__ x,
    const unsigned short* auh, const unsigned short* aul,
    const unsigned short* adh, const unsigned short* adl,
    const unsigned short* U1uh, const unsigned short* U1ul,
    const unsigned short* U1dh, const unsigned short* U1dl,
    unsigned short* outH, unsigned short* outL) {
  __shared__ unsigned short tiles[4][4096];
  if (blockIdx.x < TB)
    mfma_gemm_dev<true>(tiles[0], tiles[1], tiles[2], tiles[3],
                        (const unsigned short*)x, nullptr, 128, auh, aul,
                        U1uh, U1ul, 192, nullptr, nullptr, outH, outL, 128,
                        0, 0, 3, 2, blockIdx.x * 64, threadIdx.x);
  else
    mfma_gemm_dev<true>(tiles[0], tiles[1], tiles[2], tiles[3],
                        (const unsigned short*)x, nullptr, 128, adh, adl,
                        U1dh, U1dl, 192, nullptr, nullptr, outH, outL, 128,
                        64, 0, 3, 2, (blockIdx.x - TB) * 64, threadIdx.x);
}

// ---------------------------------------------------------------------------
// bin index: node -> (node/6250)*32 + (node%6250)/196, in [0,256)
// ---------------------------------------------------------------------------
__device__ __forceinline__ int bin_of(unsigned n) {
  const unsigned bucket = n / 6250u;
  const unsigned rem = n - bucket * 6250u;
  return (int)(bucket * 32u + rem / 196u);
}

// ---------------------------------------------------------------------------
// prep: fine counting-sort into 256 bins/dir (blocks [0,BBK)) || weights (32)
// ---------------------------------------------------------------------------
__global__ __launch_bounds__(256) void prep_kernel(
    const int* __restrict__ src, const int* __restrict__ dst,
    int* __restrict__ gcur,
    unsigned* __restrict__ bdst, unsigned* __restrict__ bsrc,
    const float* __restrict__ U_u1, const float* __restrict__ U_d1,
    const float* __restrict__ W_u1, const float* __restrict__ W_d1,
    const float* __restrict__ W_u2, const float* __restrict__ U_u2,
    unsigned short* __restrict__ wbuf) {
  int bi = blockIdx.x;
  const int t = threadIdx.x;
  if (bi < BBK) {
    __shared__ int hist[512];
    __shared__ int base[512];
    __shared__ int cur[512];
    const int chunk = bi * CHKE;
    for (int j = t; j < 512; j += 256) { hist[j] = 0; cur[j] = 0; }
    __syncthreads();
    unsigned ev[8];
    int bd[8], bs[8];
    bool ok[8];
#pragma unroll
    for (int i = 0; i < 8; ++i) {
      const int e = chunk + i * 256 + t;
      ok[i] = e < NE;
      bd[i] = 0; bs[i] = 0; ev[i] = 0;
      if (ok[i]) {
        const unsigned s = (unsigned)src[e], d = (unsigned)dst[e];
        ev[i] = s | (d << 16);
        bd[i] = bin_of(d);
        bs[i] = bin_of(s);
        atomicAdd(&hist[bd[i]], 1);
        atomicAdd(&hist[256 + bs[i]], 1);
      }
    }
    __syncthreads();
    for (int j = t; j < 512; j += 256)
      base[j] = atomicAdd(&gcur[j], hist[j]);
    __syncthreads();
#pragma unroll
    for (int i = 0; i < 8; ++i) {
      if (ok[i]) {
        const int r1 = base[bd[i]] + atomicAdd(&cur[bd[i]], 1);
        if (r1 < BINCAP) bdst[bd[i] * BINCAP + r1] = ev[i];
        const int r2 = base[256 + bs[i]] + atomicAdd(&cur[256 + bs[i]], 1);
        if (r2 < BINCAP) bsrc[bs[i] * BINCAP + r2] = ev[i];
      }
    }
    return;
  }
  bi -= BBK;
  const int widx = bi >> 2;
  const int quad = bi & 3;
  const int Ks[8] = {192, 192, 128, 128, 128, 192, 64, 128};
  const int offs[8] = {WOFF_U1U, WOFF_U1D, WOFF_W1U, WOFF_W1D,
                       WOFF_W2U, WOFF_U2U, WOFF_WSUM, WOFF_USUM};
  const float* srcs[6] = {U_u1, U_d1, W_u1, W_d1, W_u2, U_u2};
  const int K = Ks[widx];
  const int off = offs[widx];
  const int qsz = K << 4;
  const int beg = quad * qsz;
  for (int e = beg + t; e < beg + qsz; e += 256) {
    const int cc = e / K;
    const int kk = e - cc * K;
    float v;
    if (widx < 6) v = srcs[widx][kk * 64 + cc];
    else if (widx == 6) v = W_u2[kk * 64 + cc] + W_u2[(kk + 64) * 64 + cc];
    else v = (kk < 64) ? (U_u2[kk * 64 + cc] + U_u2[(kk + 64) * 64 + cc])
                       : U_u2[(kk + 64) * 64 + cc];
    unsigned short h, l;
    split1(v, h, l);
    wbuf[off + cc * K + kk] = h;
    wbuf[off + (K << 6) + cc * K + kk] = l;
  }
}

// ---------------------------------------------------------------------------
// binscan: per-direction exclusive scan of 256 bin counts -> binbase
// ---------------------------------------------------------------------------
__global__ __launch_bounds__(256) void binscan_kernel(
    const int* __restrict__ gcur, int* __restrict__ binbase) {
  const int dir = blockIdx.x;
  const int t = threadIdx.x;
  __shared__ int sc[256];
  const int v = gcur[dir * 256 + t];
  sc[t] = v;
  __syncthreads();
  for (int off = 1; off < 256; off <<= 1) {
    int add = (t >= off) ? sc[t - off] : 0;
    __syncthreads();
    sc[t] += add;
    __syncthreads();
  }
  binbase[dir * 256 + t] = sc[t] - v;  // exclusive
}

// ---------------------------------------------------------------------------
// placeC body (device): LDS hist -> scan -> rowptr + cols (u32 byte offsets)
// ---------------------------------------------------------------------------
__device__ __forceinline__ void placeC_dev(
    int* hist, int* sc, int* cur,
    const int* __restrict__ gcur, const int* __restrict__ binbase,
    const unsigned* __restrict__ bdst, const unsigned* __restrict__ bsrc,
    int* __restrict__ rp_dst, int* __restrict__ rp_src,
    unsigned* __restrict__ col_dst, unsigned* __restrict__ col_src,
    int gbin, int t) {
  const int dir = gbin >> 8;
  const int bin = gbin & 255;
  const int bucket = bin >> 5;
  const int sub = bin & 31;
  const unsigned lo = (unsigned)(bucket * 6250 + sub * SUBW);
  const int subn = min(SUBW, 6250 - sub * SUBW);
  if (t < subn) hist[t] = 0;
  __syncthreads();
  const int cnt = min(gcur[gbin], BINCAP);
  const unsigned* p = (dir ? bsrc : bdst) + (size_t)bin * BINCAP;
  const int cnt4 = cnt & ~3;
  for (int i = t * 4; i < cnt4; i += 1024) {
    const uint4 v = *(const uint4*)(p + i);
    const unsigned n0 = dir ? (v.x & 0xFFFFu) : (v.x >> 16);
    const unsigned n1 = dir ? (v.y & 0xFFFFu) : (v.y >> 16);
    const unsigned n2 = dir ? (v.z & 0xFFFFu) : (v.z >> 16);
    const unsigned n3 = dir ? (v.w & 0xFFFFu) : (v.w >> 16);
    atomicAdd(&hist[n0 - lo], 1);
    atomicAdd(&hist[n1 - lo], 1);
    atomicAdd(&hist[n2 - lo], 1);
    atomicAdd(&hist[n3 - lo], 1);
  }
  for (int i = cnt4 + t; i < cnt; i += 256) {
    const unsigned n = dir ? (p[i] & 0xFFFFu) : (p[i] >> 16);
    atomicAdd(&hist[n - lo], 1);
  }
  __syncthreads();
  if (t < subn) sc[t] = hist[t];
  __syncthreads();
  for (int off = 1; off < SUBW; off <<= 1) {
    int add = (t < subn && t >= off) ? sc[t - off] : 0;
    __syncthreads();
    if (t < subn) sc[t] += add;
    __syncthreads();
  }
  const int bb = binbase[gbin];
  int* rp = dir ? rp_src : rp_dst;
  if (t < subn) {
    rp[lo + t] = bb + sc[t];            // inclusive end
    cur[t] = bb + sc[t] - hist[t];      // exclusive start cursor
  }
  __syncthreads();
  unsigned* col = dir ? col_src : col_dst;
  for (int i = t * 4; i < cnt4; i += 1024) {
    const uint4 v = *(const uint4*)(p + i);
    const unsigned vs[4] = {v.x, v.y, v.z, v.w};
#pragma unroll
    for (int k = 0; k < 4; ++k) {
      const unsigned n = dir ? (vs[k] & 0xFFFFu) : (vs[k] >> 16);
      const unsigned q = dir ? (vs[k] >> 16) : (vs[k] & 0xFFFFu);
      col[atomicAdd(&cur[n - lo], 1)] = q << 7;   // byte offset into Y plane
    }
  }
  for (int i = cnt4 + t; i < cnt; i += 256) {
    const unsigned v = p[i];
    const unsigned n = dir ? (v & 0xFFFFu) : (v >> 16);
    const unsigned q = dir ? (v >> 16) : (v & 0xFFFFu);
    col[atomicAdd(&cur[n - lo], 1)] = q << 7;
  }
}

// ---------------------------------------------------------------------------
// fusedPT: placeC (blocks [0,512)) || trans2 (TB blocks) -- independent work
// ---------------------------------------------------------------------------
__global__ __launch_bounds__(256) void fusedPT_kernel(
    const int* __restrict__ gcur, const int* __restrict__ binbase,
    const unsigned* __restrict__ bdst, const unsigned* __restrict__ bsrc,
    int* __restrict__ rp_dst, int* __restrict__ rp_src,
    unsigned* __restrict__ col_dst, unsigned* __restrict__ col_src,
    const float* __restrict__ x,
    const unsigned short* W1uh, const unsigned short* W1ul,
    const unsigned short* W1dh, const unsigned short* W1dl,
    const float* __restrict__ b_u1, const float* __restrict__ b_d1,
    unsigned short* __restrict__ Yu, unsigned short* __restrict__ Yd) {
  __shared__ unsigned short tiles[4][4096];
  int bi = blockIdx.x;
  if (bi < 512) {
    int* hist = (int*)&tiles[0][0];
    int* sc = hist + SUBW;
    int* cur = sc + SUBW;
    placeC_dev(hist, sc, cur, gcur, binbase, bdst, bsrc, rp_dst, rp_src,
               col_dst, col_src, bi, threadIdx.x);
    return;
  }
  bi -= 512;
  trans2_dev(tiles[0], tiles[1], tiles[2], tiles[3], x, W1uh, W1ul, W1dh,
             W1dl, b_u1, b_d1, Yu, Yd, bi * 64, threadIdx.x);
}

// ---------------------------------------------------------------------------
// pull-gather mean from fp16 Y rows (128B) with packed fp16 accumulation.
// col holds pre-shifted u32 byte offsets; wave-parallel epilogue.
// ---------------------------------------------------------------------------
__device__ __forceinline__ void gatherh_dev(
    const unsigned short* __restrict__ Yh, const int* __restrict__ rowptr,
    const unsigned* __restrict__ col,
    unsigned short* __restrict__ aggh, unsigned short* __restrict__ aggl,
    int seg, int tid) {
  const int w = tid >> 6;
  const int lane = tid & 63;
  const int off = (seg >> 3) * 4 + w;
  if (off >= 6250) return;
  const int node = (seg & 7) * 6250 + off;
  const int eg = lane >> 3;          // 0..7
  const unsigned lb = (unsigned)((lane & 7) << 4);  // lane byte offset
  const char* Yb = (const char*)Yh;
  const int start = (node == 0) ? 0 : rowptr[node - 1];
  const int end = rowptr[node];
  half2v a0 = h2_of(0u), a1 = h2_of(0u), a2 = h2_of(0u), a3 = h2_of(0u);
  int e = start + eg;
  for (; e + 8 < end; e += 16) {
    const unsigned o0 = col[e] + lb;
    const unsigned o1 = col[e + 8] + lb;
    const uint4 v0 = *(const uint4*)(Yb + o0);
    const uint4 v1 = *(const uint4*)(Yb + o1);
    a0 += h2_of(v0.x) + h2_of(v1.x);
    a1 += h2_of(v0.y) + h2_of(v1.y);
    a2 += h2_of(v0.z) + h2_of(v1.z);
    a3 += h2_of(v0.w) + h2_of(v1.w);
  }
  for (; e < end; e += 8) {
    const unsigned o = col[e] + lb;
    const uint4 v = *(const uint4*)(Yb + o);
    a0 += h2_of(v.x);
    a1 += h2_of(v.y);
    a2 += h2_of(v.z);
    a3 += h2_of(v.w);
  }
#pragma unroll
  for (int d = 8; d <= 32; d <<= 1) {
    a0 += h2_of((unsigned)__shfl_xor((int)u_of(a0), d));
    a1 += h2_of((unsigned)__shfl_xor((int)u_of(a1), d));
    a2 += h2_of((unsigned)__shfl_xor((int)u_of(a2), d));
    a3 += h2_of((unsigned)__shfl_xor((int)u_of(a3), d));
  }
  // wave-parallel epilogue: lane j owns output column j
  const int srcl = lane >> 3;
  const unsigned u0 = (unsigned)__shfl((int)u_of(a0), srcl);
  const unsigned u1 = (unsigned)__shfl((int)u_of(a1), srcl);
  const unsigned u2 = (unsigned)__shfl((int)u_of(a2), srcl);
  const unsigned u3 = (unsigned)__shfl((int)u_of(a3), srcl);
  const int m = lane & 7;
  const unsigned pick = (m & 4) ? ((m & 2) ? u3 : u2)
                                : ((m & 2) ? u1 : u0);
  union { unsigned short us; _Float16 hf; } cc;
  cc.us = (m & 1) ? (unsigned short)(pick >> 16)
                  : (unsigned short)(pick & 0xFFFFu);
  const float inv = 1.f / (float)max(end - start, 1);
  const float val = (float)cc.hf * inv;
  unsigned short h, l;
  split1(val, h, l);
  aggh[(size_t)node * 64 + lane] = h;
  aggl[(size_t)node * 64 + lane] = l;
}

__global__ __launch_bounds__(256) void gatherh_kernel(
    const unsigned short* __restrict__ Yh, const int* __restrict__ rowptr,
    const unsigned* __restrict__ col,
    unsigned short* __restrict__ aggh, unsigned short* __restrict__ aggl) {
  gatherh_dev(Yh, rowptr, col, aggh, aggl, blockIdx.x, threadIdx.x);
}

__global__ __launch_bounds__(256) void gatherh2_kernel(
    const unsigned short* __restrict__ Yhu, const int* __restrict__ rp_dst,
    const unsigned* __restrict__ col_dst,
    unsigned short* auh, unsigned short* aul,
    const unsigned short* __restrict__ Yhd, const int* __restrict__ rp_src,
    const unsigned* __restrict__ col_src,
    unsigned short* adh, unsigned short* adl) {
  if (blockIdx.x < GBS)
    gatherh_dev(Yhu, rp_dst, col_dst, auh, aul, blockIdx.x, threadIdx.x);
  else
    gatherh_dev(Yhd, rp_src, col_src, adh, adl, blockIdx.x - GBS, threadIdx.x);
}

// ===========================================================================
// Fallback path (vector-f32 GEMM + replicated edge pass) for small workspaces
// ===========================================================================
__global__ __launch_bounds__(256) void pack_kernel(
    const int* __restrict__ src, const int* __restrict__ dst,
    unsigned* __restrict__ epack) {
  for (int e = blockIdx.x * 256 + threadIdx.x; e < NE; e += 1024 * 256)
    epack[e] = (unsigned)src[e] | ((unsigned)dst[e] << 16);
}

__device__ __forceinline__ void place_dev4(
    const unsigned* __restrict__ epack,
    int* __restrict__ rp_dst, int* __restrict__ rp_src,
    unsigned short* __restrict__ col_dst, unsigned short* __restrict__ col_src,
    int bi, int tid) {
  const unsigned lo = (unsigned)(bi & 7) * 6250u;
  const int g = (bi >> 3) * 256 + tid;
  for (int e = g * 4; e < NE; e += 262144) {
    const uint4 v4 = *(const uint4*)(epack + e);
    const unsigned vs[4] = {v4.x, v4.y, v4.z, v4.w};
#pragma unroll
    for (int i = 0; i < 4; ++i) {
      const unsigned s = vs[i] & 0xFFFFu, d = vs[i] >> 16;
      if (d - lo < 6250u)
        col_dst[atomicAdd(&rp_dst[d], 1)] = (unsigned short)s;
      if (s - lo < 6250u)
        col_src[atomicAdd(&rp_src[s], 1)] = (unsigned short)d;
    }
  }
}

__global__ __launch_bounds__(256) void count_old_kernel(
    const unsigned* __restrict__ epack,
    int* __restrict__ rp_dst, int* __restrict__ rp_src) {
  const int bi = blockIdx.x;
  const unsigned lo = (unsigned)(bi & 7) * 6250u;
  const int g = (bi >> 3) * 256 + threadIdx.x;
  for (int e = g * 4; e < NE; e += 262144) {
    const uint4 v4 = *(const uint4*)(epack + e);
    const unsigned vs[4] = {v4.x, v4.y, v4.z, v4.w};
#pragma unroll
    for (int i = 0; i < 4; ++i) {
      const unsigned s = vs[i] & 0xFFFFu, d = vs[i] >> 16;
      if (d - lo < 6250u) atomicAdd(&rp_dst[d], 1);
      if (s - lo < 6250u) atomicAdd(&rp_src[s], 1);
    }
  }
}

#define CHUNK 49
__global__ __launch_bounds__(1024) void scan_kernel(
    int* __restrict__ a0, int* __restrict__ a1) {
  int* a = (blockIdx.x == 0) ? a0 : a1;
  __shared__ int part[1024];
  const int t = threadIdx.x;
  const int beg = t * CHUNK;
  const int end = min(beg + CHUNK, NN);
  int s = 0;
  for (int i = beg; i < end; ++i) s += a[i];
  part[t] = s;
  __syncthreads();
  for (int off = 1; off < 1024; off <<= 1) {
    int add = (t >= off) ? part[t - off] : 0;
    __syncthreads();
    part[t] += add;
    __syncthreads();
  }
  int run = (t == 0) ? 0 : part[t - 1];
  for (int i = beg; i < end; ++i) {
    const int c = a[i];
    a[i] = run;
    run += c;
  }
}

__device__ __forceinline__ void gatherF_dev(
    const float* __restrict__ Y, const int* __restrict__ rowptr,
    const unsigned short* __restrict__ col, float* __restrict__ AGGf,
    int seg, int tid) {
  const int w = tid >> 6;
  const int lane = tid & 63;
  const int off = (seg >> 3) * 4 + w;
  if (off >= 6250) return;
  const int node = (seg & 7) * 6250 + off;
  const int eg = lane >> 4;
  const int cq = (lane & 15) << 2;
  const int start = (node == 0) ? 0 : rowptr[node - 1];
  const int end = rowptr[node];
  float4 acc = make_float4(0.f, 0.f, 0.f, 0.f);
  for (int e = start + eg; e < end; e += 4) {
    const float4 y = *(const float4*)(Y + (size_t)col[e] * 64 + cq);
    acc.x += y.x; acc.y += y.y; acc.z += y.z; acc.w += y.w;
  }
  acc.x += __shfl_xor(acc.x, 16);
  acc.y += __shfl_xor(acc.y, 16);
  acc.z += __shfl_xor(acc.z, 16);
  acc.w += __shfl_xor(acc.w, 16);
  acc.x += __shfl_xor(acc.x, 32);
  acc.y += __shfl_xor(acc.y, 32);
  acc.z += __shfl_xor(acc.z, 32);
  acc.w += __shfl_xor(acc.w, 32);
  if (eg == 0) {
    const float inv = 1.f / (float)max(end - start, 1);
    float4 o;
    o.x = acc.x * inv; o.y = acc.y * inv;
    o.z = acc.z * inv; o.w = acc.w * inv;
    *(float4*)(AGGf + (size_t)node * 64 + cq) = o;
  }
}

__global__ __launch_bounds__(256) void gatherF_kernel(
    const float* __restrict__ Y, const int* __restrict__ rowptr,
    const unsigned short* __restrict__ col, float* __restrict__ AGGf) {
  gatherF_dev(Y, rowptr, col, AGGf, blockIdx.x, threadIdx.x);
}

__device__ __forceinline__ void gemm64_dev(
    float (*Xt)[68], float* Ws, const float* __restrict__ X, int ldx,
    const float* __restrict__ AGG, const float* __restrict__ W,
    const float* __restrict__ b, float* __restrict__ out, int ldo,
    int colbase, int dup, int kchunks, int xchunks, int row0, int tid) {
  const int tx = tid & 15, ty = tid >> 4;
  float acc[4][4] = {{0.f}};
  for (int c = 0; c < kchunks; ++c) {
    {
      const int rr = tid >> 2;
      const int cg = (tid & 3) << 4;
      const float* srcp;
      int ld, co;
      if (c < xchunks) { srcp = X; ld = ldx; co = c * 64; }
      else             { srcp = AGG; ld = 64; co = 0; }
      int row = row0 + rr;
      if (row > NN - 1) row = NN - 1;
      const float* g = srcp + row * ld + co + cg;
      const float4 v0 = *(const float4*)(g + 0);
      const float4 v1 = *(const float4*)(g + 4);
      const float4 v2 = *(const float4*)(g + 8);
      const float4 v3 = *(const float4*)(g + 12);
      Xt[cg + 0][rr] = v0.x;  Xt[cg + 1][rr] = v0.y;
      Xt[cg + 2][rr] = v0.z;  Xt[cg + 3][rr] = v0.w;
      Xt[cg + 4][rr] = v1.x;  Xt[cg + 5][rr] = v1.y;
      Xt[cg + 6][rr] = v1.z;  Xt[cg + 7][rr] = v1.w;
      Xt[cg + 8][rr] = v2.x;  Xt[cg + 9][rr] = v2.y;
      Xt[cg + 10][rr] = v2.z; Xt[cg + 11][rr] = v2.w;
      Xt[cg + 12][rr] = v3.x; Xt[cg + 13][rr] = v3.y;
      Xt[cg + 14][rr] = v3.z; Xt[cg + 15][rr] = v3.w;
      const float4* wg = (const float4*)(W + c * 64 * 64);
      float4* wl = (float4*)Ws;
      wl[tid] = wg[tid];
      wl[tid + 256] = wg[tid + 256];
      wl[tid + 512] = wg[tid + 512];
      wl[tid + 768] = wg[tid + 768];
    }
    __syncthreads();
#pragma unroll 8
    for (int kk = 0; kk < 64; ++kk) {
      const float4 a = *(const float4*)&Xt[kk][tx << 2];
      const float4 w = *(const float4*)&Ws[kk * 64 + (ty << 2)];
      acc[0][0] += a.x * w.x; acc[0][1] += a.x * w.y;
      acc[0][2] += a.x * w.z; acc[0][3] += a.x * w.w;
      acc[1][0] += a.y * w.x; acc[1][1] += a.y * w.y;
      acc[1][2] += a.y * w.z; acc[1][3] += a.y * w.w;
      acc[2][0] += a.z * w.x; acc[2][1] += a.z * w.y;
      acc[2][2] += a.z * w.z; acc[2][3] += a.z * w.w;
      acc[3][0] += a.w * w.x; acc[3][1] += a.w * w.y;
      acc[3][2] += a.w * w.z; acc[3][3] += a.w * w.w;
    }
    __syncthreads();
  }
  float4 bv = make_float4(0.f, 0.f, 0.f, 0.f);
  if (b) bv = *(const float4*)(b + (ty << 2));
#pragma unroll
  for (int i = 0; i < 4; ++i) {
    const int row = row0 + (tx << 2) + i;
    if (row < NN) {
      float4 o;
      o.x = fmaxf(acc[i][0] + bv.x, 0.f);
      o.y = fmaxf(acc[i][1] + bv.y, 0.f);
      o.z = fmaxf(acc[i][2] + bv.z, 0.f);
      o.w = fmaxf(acc[i][3] + bv.w, 0.f);
      *(float4*)(out + row * ldo + colbase + (ty << 2)) = o;
      if (dup) *(float4*)(out + row * ldo + 64 + (ty << 2)) = o;
    }
  }
}

__global__ __launch_bounds__(256) void gemm_kernel(
    const float* __restrict__ X, int ldx, const float* __restrict__ AGG,
    const float* __restrict__ W, const float* __restrict__ b,
    float* __restrict__ out, int ldo, int colbase, int dup,
    int kchunks, int xchunks) {
  __shared__ __align__(16) float Xt[64][68];
  __shared__ __align__(16) float Ws[4096];
  gemm64_dev(Xt, Ws, X, ldx, AGG, W, b, out, ldo, colbase, dup, kchunks,
             xchunks, blockIdx.x * 64, threadIdx.x);
}

__global__ __launch_bounds__(256) void fused0_kernel(
    const unsigned* __restrict__ epack,
    int* __restrict__ rp_dst, int* __restrict__ rp_src,
    unsigned short* __restrict__ col_dst, unsigned short* __restrict__ col_src,
    const float* __restrict__ x,
    const float* __restrict__ W_u1, const float* __restrict__ b_u1,
    float* __restrict__ Y_u,
    const float* __restrict__ W_d1, const float* __restrict__ b_d1,
    float* __restrict__ Y_d) {
  __shared__ __align__(16) float Xt[64][68];
  __shared__ __align__(16) float Ws[4096];
  int bi = blockIdx.x;
  if (bi < 2048) {
    place_dev4(epack, rp_dst, rp_src, col_dst, col_src, bi, threadIdx.x);
    return;
  }
  bi -= 2048;
  if (bi < TB)
    gemm64_dev(Xt, Ws, x, 128, nullptr, W_u1, b_u1, Y_u, 64, 0, 0, 2, 2,
               bi * 64, threadIdx.x);
  else
    gemm64_dev(Xt, Ws, x, 128, nullptr, W_d1, b_d1, Y_d, 64, 0, 0, 2, 2,
               (bi - TB) * 64, threadIdx.x);
}

// ===========================================================================
extern "C" void kernel_launch(void* const* d_in, const int* in_sizes, int n_in,
                              void* d_out, int out_size, void* d_ws, size_t ws_size,
                              hipStream_t stream) {
  const float* x    = (const float*)d_in[0];
  const int*   ei   = (const int*)d_in[1];
  const float* W_u1 = (const float*)d_in[2];
  const float* b_u1 = (const float*)d_in[3];
  const float* U_u1 = (const float*)d_in[4];
  const float* W_d1 = (const float*)d_in[5];
  const float* b_d1 = (const float*)d_in[6];
  const float* U_d1 = (const float*)d_in[7];
  const float* W_u2 = (const float*)d_in[8];
  const float* b_u2 = (const float*)d_in[9];
  const float* U_u2 = (const float*)d_in[10];
  const int* src = ei;
  const int* dst = ei + NE;
  float* out = (float*)d_out;

  char* wsb = (char*)d_ws;
  int* rp_dst  = (int*)wsb;              wsb += NN * sizeof(int);
  int* rp_src  = (int*)wsb;              wsb += NN * sizeof(int);
  int* gcur    = (int*)wsb;              wsb += 512 * sizeof(int);
  int* binbase = (int*)wsb;              wsb += 512 * sizeof(int);
  unsigned* col_dst = (unsigned*)wsb;    wsb += (size_t)NE * 4;
  unsigned* col_src = (unsigned*)wsb;    wsb += (size_t)NE * 4;

  const size_t plane = (size_t)NN * 64 * 2;   // 6.4 MB u16 plane
  const size_t needM = (size_t)2 * NN * 4 + 4096 + (size_t)NE * 8 +
                       (size_t)WBUF_USHORTS * 2 +
                       6 * plane +               // A..F
                       2 * (size_t)NN * 128 * 2; // outh, outl

  hipMemsetAsync(gcur, 0, 512 * sizeof(int), stream);

  if (ws_size >= needM) {
    unsigned short* wbuf = (unsigned short*)wsb; wsb += (size_t)WBUF_USHORTS * 2;
    unsigned short* A = (unsigned short*)wsb; wsb += plane;  // Yh_u
    unsigned short* B = (unsigned short*)wsb; wsb += plane;  // Yh_d
    unsigned short* C = (unsigned short*)wsb; wsb += plane;  // agg_uh
    unsigned short* D = (unsigned short*)wsb; wsb += plane;  // agg_ul
    unsigned short* E = (unsigned short*)wsb; wsb += plane;  // agg_dh
    unsigned short* F = (unsigned short*)wsb; wsb += plane;  // agg_dl
    unsigned short* outh = (unsigned short*)wsb; wsb += (size_t)NN * 128 * 2;
    unsigned short* outl = (unsigned short*)wsb;

    // aliases (strict sequential lifetimes):
    unsigned* bdst = (unsigned*)C;   // bins (4MB) live until placeC
    unsigned* bsrc = (unsigned*)D;
    unsigned short* Yh2  = C;        // r2 trans output (bins dead)
    unsigned short* agg2h = E;       // r2 gather out (agg_dh/dl dead)
    unsigned short* agg2l = F;
    unsigned short* O2h = C;         // r2 update out (Yh2 dead)
    unsigned short* O2l = D;
    unsigned short* Yh3 = E;         // r3 trans out (agg2 dead)
    unsigned short* agg3h = A;       // r3 gather out (Yh_u/d dead)
    unsigned short* agg3l = B;

    const unsigned short* U1uh = wbuf + WOFF_U1U;
    const unsigned short* U1ul = wbuf + WOFF_U1U + 64 * 192;
    const unsigned short* U1dh = wbuf + WOFF_U1D;
    const unsigned short* U1dl = wbuf + WOFF_U1D + 64 * 192;
    const unsigned short* W1uh = wbuf + WOFF_W1U;
    const unsigned short* W1ul = wbuf + WOFF_W1U + 64 * 128;
    const unsigned short* W1dh = wbuf + WOFF_W1D;
    const unsigned short* W1dl = wbuf + WOFF_W1D + 64 * 128;
    const unsigned short* W2uh = wbuf + WOFF_W2U;
    const unsigned short* W2ul = wbuf + WOFF_W2U + 64 * 128;
    const unsigned short* U2uh = wbuf + WOFF_U2U;
    const unsigned short* U2ul = wbuf + WOFF_U2U + 64 * 192;
    const unsigned short* Wsh  = wbuf + WOFF_WSUM;
    const unsigned short* Wsl  = wbuf + WOFF_WSUM + 64 * 64;
    const unsigned short* Ush  = wbuf + WOFF_USUM;
    const unsigned short* Usl  = wbuf + WOFF_USUM + 64 * 128;

    // fine counting-sort || weight conversion
    prep_kernel<<<BBK + 32, 256, 0, stream>>>(
        src, dst, gcur, bdst, bsrc, U_u1, U_d1, W_u1, W_d1, W_u2, U_u2, wbuf);
    binscan_kernel<<<2, 256, 0, stream>>>(gcur, binbase);
    // placeC || layer-1 transforms (independent) in one launch
    fusedPT_kernel<<<512 + TB, 256, 0, stream>>>(
        gcur, binbase, bdst, bsrc, rp_dst, rp_src, col_dst, col_src,
        x, W1uh, W1ul, W1dh, W1dl, b_u1, b_d1, A, B);
    // layer-1 gathers (both dirs), packed fp16 accumulate
    gatherh2_kernel<<<2 * GBS, 256, 0, stream>>>(A, rp_dst, col_dst, C, D,
                                                 B, rp_src, col_src, E, F);
    update2m_kernel<<<2 * TB, 256, 0, stream>>>(x, C, D, E, F, U1uh, U1ul,
                                                U1dh, U1dl, outh, outl);
    // round 2
    mgemm_kernel<<<TB, 256, 0, stream>>>(outh, outl, 128, nullptr, nullptr,
                                         W2uh, W2ul, 128, b_u2, nullptr,
                                         Yh2, nullptr, 64, 0, 0, 2, 2);
    gatherh_kernel<<<GBS, 256, 0, stream>>>(Yh2, rp_dst, col_dst, agg2h,
                                            agg2l);
    mgemm_kernel<<<TB, 256, 0, stream>>>(outh, outl, 128, agg2h, agg2l,
                                         U2uh, U2ul, 192, nullptr, nullptr,
                                         O2h, O2l, 64, 0, 0, 3, 2);
    // round 3 (h = [O2,O2] folded into presummed weights)
    mgemm_kernel<<<TB, 256, 0, stream>>>(O2h, O2l, 64, nullptr, nullptr,
                                         Wsh, Wsl, 64, b_u2, nullptr,
                                         Yh3, nullptr, 64, 0, 0, 1, 1);
    gatherh_kernel<<<GBS, 256, 0, stream>>>(Yh3, rp_dst, col_dst, agg3h,
                                            agg3l);
    mgemm_kernel<<<TB, 256, 0, stream>>>(O2h, O2l, 64, agg3h, agg3l,
                                         Ush, Usl, 128, nullptr, out,
                                         nullptr, nullptr, 128, 0, 1, 2, 1);
  } else {
    // fallback: vector-f32 path with replicated edge passes (u16 cols)
    unsigned* epack = (unsigned*)wsb; wsb += (size_t)NE * 4;
    float* Y_u = (float*)wsb; wsb += (size_t)NN * 64 * sizeof(float);
    float* Y_d = (float*)wsb; wsb += (size_t)NN * 64 * sizeof(float);
    float* AGG = (float*)wsb;
    unsigned short* cds = (unsigned short*)col_dst;
    unsigned short* css = (unsigned short*)col_src;
    hipMemsetAsync(rp_dst, 0, 2 * NN * sizeof(int), stream);
    pack_kernel<<<1024, 256, 0, stream>>>(src, dst, epack);
    count_old_kernel<<<2048, 256, 0, stream>>>(epack, rp_dst, rp_src);
    scan_kernel<<<2, 1024, 0, stream>>>(rp_dst, rp_src);
    fused0_kernel<<<2048 + 2 * TB, 256, 0, stream>>>(
        epack, rp_dst, rp_src, cds, css, x, W_u1, b_u1, Y_u, W_d1,
        b_d1, Y_d);
    gatherF_kernel<<<GBS, 256, 0, stream>>>(Y_u, rp_dst, cds, AGG);
    gemm_kernel<<<TB, 256, 0, stream>>>(x, 128, AGG, U_u1, nullptr, out,
                                        128, 0, 0, 3, 2);
    gatherF_kernel<<<GBS, 256, 0, stream>>>(Y_d, rp_src, css, AGG);
    gemm_kernel<<<TB, 256, 0, stream>>>(x, 128, AGG, U_d1, nullptr, out,
                                        128, 64, 0, 3, 2);
    for (int r = 0; r < 2; ++r) {
      gemm_kernel<<<TB, 256, 0, stream>>>(out, 128, nullptr, W_u2, b_u2,
                                          Y_u, 64, 0, 0, 2, 2);
      gatherF_kernel<<<GBS, 256, 0, stream>>>(Y_u, rp_dst, cds, AGG);
      gemm_kernel<<<TB, 256, 0, stream>>>(out, 128, AGG, U_u2, nullptr,
                                          out, 128, 0, 1, 3, 2);
    }
  }
}